// Round 1
// baseline (4959.047 us; speedup 1.0000x reference)
//
#include <hip/hip_runtime.h>
#include <math.h>

#define NN 30000
#define EE 480000
#define FD 256
#define CH 128
#define NCLS 16
#define GH 64
#define MH 128
#define BT 4096
#define CL1c 0.5f
#define CL2c 0.5f
#define LAMc 0.5f
#define ALPHAc 1.0f
#define TAUc 0.5f
#define EPSc 1e-8f

// ---------- helpers ----------
__device__ __forceinline__ unsigned enc_f32(float f) {
    unsigned b = __float_as_uint(f);
    return (b & 0x80000000u) ? ~b : (b | 0x80000000u);
}
__device__ __forceinline__ float dec_f32(unsigned u) {
    return (u & 0x80000000u) ? __uint_as_float(u ^ 0x80000000u) : __uint_as_float(~u);
}

// ---------- generic fp32 GEMM: C[MxN] = A[MxK] @ B[KxN], row-major ----------
// 64x64 tile, 256 threads, 4x4 per thread, K-chunk 16. K must be multiple of 16.
__global__ __launch_bounds__(256) void gemm_f32(
    const float* __restrict__ A, const float* __restrict__ B, float* __restrict__ C,
    int M, int K, int Ncol)
{
    __shared__ float As[16][65];
    __shared__ float Bs[16][64];
    int t = threadIdx.x;
    int tx = t & 15, ty = t >> 4;
    int row0 = blockIdx.y * 64, col0 = blockIdx.x * 64;
    float acc[4][4] = {};
    for (int k0 = 0; k0 < K; k0 += 16) {
#pragma unroll
        for (int i = 0; i < 4; i++) {
            int id = t + i * 256;
            int ar = id >> 4, ak = id & 15;
            int gr = row0 + ar;
            As[ak][ar] = (gr < M) ? A[(size_t)gr * K + k0 + ak] : 0.f;
            int br = id >> 6, bc = id & 63;
            int gc = col0 + bc;
            Bs[br][bc] = (gc < Ncol) ? B[(size_t)(k0 + br) * Ncol + gc] : 0.f;
        }
        __syncthreads();
#pragma unroll
        for (int kk = 0; kk < 16; kk++) {
            float a[4], b[4];
#pragma unroll
            for (int i = 0; i < 4; i++) a[i] = As[kk][ty * 4 + i];
#pragma unroll
            for (int j = 0; j < 4; j++) b[j] = Bs[kk][tx * 4 + j];
#pragma unroll
            for (int i = 0; i < 4; i++)
#pragma unroll
                for (int j = 0; j < 4; j++)
                    acc[i][j] = fmaf(a[i], b[j], acc[i][j]);
        }
        __syncthreads();
    }
#pragma unroll
    for (int i = 0; i < 4; i++) {
        int r = row0 + ty * 4 + i;
        if (r >= M) continue;
#pragma unroll
        for (int j = 0; j < 4; j++) {
            int c = col0 + tx * 4 + j;
            if (c < Ncol) C[(size_t)r * Ncol + c] = acc[i][j];
        }
    }
}

__global__ void relu_k(float* __restrict__ x, long n) {
    long i = (long)blockIdx.x * blockDim.x + threadIdx.x;
    if (i < n) x[i] = fmaxf(x[i], 0.f);
}

// ---------- SpMM (atomic scatter): out[r,:] += v * x[c,:] ----------
template <int F>
__global__ __launch_bounds__(256) void spmm_dir(
    const int* __restrict__ ridx, const int* __restrict__ cidx,
    const float* __restrict__ vals,
    const float* __restrict__ x, float* __restrict__ out, int nE)
{
    const int EPB = 256 / F;
    int e = blockIdx.x * EPB + threadIdx.x / F;
    int lane = threadIdx.x % F;
    if (e >= nE) return;
    int r = ridx[e], c = cidx[e];
    float v = vals[e];
    atomicAdd(&out[(size_t)r * F + lane], v * x[(size_t)c * F + lane]);
}

// symmetric graph: 2E directed edges from E undirected entries
template <int F>
__global__ __launch_bounds__(256) void spmm_sym(
    const int* __restrict__ ind,   // [2*E]: rows then cols
    const float* __restrict__ nv,
    const float* __restrict__ x, float* __restrict__ out)
{
    const int EPB = 256 / F;
    long de = (long)blockIdx.x * EPB + threadIdx.x / F;
    int lane = threadIdx.x % F;
    if (de >= 2L * EE) return;
    int e = (int)(de % EE);
    int swap = (int)(de / EE);
    int r = ind[e], c = ind[EE + e];
    if (swap) { int tmp = r; r = c; c = tmp; }
    float v = nv[e];
    atomicAdd(&out[(size_t)r * F + lane], v * x[(size_t)c * F + lane]);
}

// fused graph: sym(view1) scaled by b1[row] plus sym(view2) scaled by b2[row]
template <int F>
__global__ __launch_bounds__(256) void spmm_fused(
    const int* __restrict__ i1, const float* __restrict__ nv1, const float* __restrict__ b1,
    const int* __restrict__ i2, const float* __restrict__ nv2, const float* __restrict__ b2,
    const float* __restrict__ x, float* __restrict__ out)
{
    const int EPB = 256 / F;
    long de = (long)blockIdx.x * EPB + threadIdx.x / F;
    int lane = threadIdx.x % F;
    if (de >= 4L * EE) return;
    int g = (int)(de / (2L * EE));
    long rem = de % (2L * EE);
    int swap = (int)(rem / EE);
    int e = (int)(rem % EE);
    const int* ind = g ? i2 : i1;
    const float* nv = g ? nv2 : nv1;
    const float* bb = g ? b2 : b1;
    int r = ind[e], c = ind[EE + e];
    if (swap) { int tmp = r; r = c; c = tmp; }
    float v = bb[r] * nv[e];
    atomicAdd(&out[(size_t)r * F + lane], v * x[(size_t)c * F + lane]);
}

// ---------- gen_view: per-node edge-score halves a[i]=emb[i].Wm[:64], b[i]=emb[i].Wm[64:] ----------
__global__ __launch_bounds__(256) void node_scores(
    const float* __restrict__ emb, const float* __restrict__ Wm,
    float* __restrict__ sa, float* __restrict__ sb)
{
    int node = blockIdx.x * 4 + threadIdx.x / 64;
    int lane = threadIdx.x % 64;
    if (node >= NN) return;
    float e = emb[(size_t)node * GH + lane];
    float va = e * Wm[lane];
    float vb = e * Wm[GH + lane];
#pragma unroll
    for (int off = 32; off; off >>= 1) {
        va += __shfl_down(va, off);
        vb += __shfl_down(vb, off);
    }
    if (lane == 0) { sa[node] = va; sb[node] = vb; }
}

__global__ void edge_score(const float* __restrict__ sa, const float* __restrict__ sb,
                           const float* __restrict__ bm, const int* __restrict__ ind,
                           float* __restrict__ ebuf, unsigned* __restrict__ rowmax)
{
    int e = blockIdx.x * 256 + threadIdx.x;
    if (e >= EE) return;
    int r = ind[e], c = ind[EE + e];
    float s = sa[r] + sb[c] + bm[0];
    ebuf[e] = s;
    atomicMax(&rowmax[r], enc_f32(s));
}

__global__ void edge_exp(const int* __restrict__ ind, float* __restrict__ ebuf,
                         const unsigned* __restrict__ rowmax, float* __restrict__ rowsum)
{
    int e = blockIdx.x * 256 + threadIdx.x;
    if (e >= EE) return;
    int r = ind[e];
    float ex = expf(ebuf[e] - dec_f32(rowmax[r]));
    ebuf[e] = ex;
    atomicAdd(&rowsum[r], ex);
}

__global__ void edge_nv(const int* __restrict__ ind, const float* __restrict__ ebuf,
                        const float* __restrict__ rowsum, const float* __restrict__ vals,
                        float coml, float* __restrict__ nv)
{
    int e = blockIdx.x * 256 + threadIdx.x;
    if (e >= EE) return;
    int r = ind[e];
    nv[e] = vals[e] + coml * ebuf[e] / rowsum[r];
}

// ---------- per-node softmax over 16 classes + log-prob + top2 weight ----------
__global__ void softmax16(const float* __restrict__ S, float* __restrict__ logits,
                          float* __restrict__ w)
{
    int node = blockIdx.x * 256 + threadIdx.x;
    if (node >= NN) return;
    float v[NCLS];
    float mx = -3.4e38f;
#pragma unroll
    for (int j = 0; j < NCLS; j++) { v[j] = S[(size_t)node * NCLS + j]; mx = fmaxf(mx, v[j]); }
    float s = 0.f;
#pragma unroll
    for (int j = 0; j < NCLS; j++) { v[j] = expf(v[j] - mx); s += v[j]; }
    float inv = 1.f / s;
    float fir = -1.f, sec = -1.f;
#pragma unroll
    for (int j = 0; j < NCLS; j++) {
        float p = v[j] * inv;
        logits[(size_t)node * NCLS + j] = logf(p + EPSc);
        if (p > fir) { sec = fir; fir = p; }
        else if (p > sec) { sec = p; }
    }
    if (w) w[node] = expf(ALPHAc * (LAMc * logf(fir + EPSc) + (1.f - LAMc) * logf(fir - sec + EPSc)));
}

__global__ void bweights(const float* __restrict__ w1, const float* __restrict__ w2,
                         float* __restrict__ b1, float* __restrict__ b2)
{
    int i = blockIdx.x * 256 + threadIdx.x;
    if (i >= NN) return;
    float a = w1[i], b = w2[i];
    float inv = 1.f / (a + b);
    b1[i] = a * inv;
    b2[i] = b * inv;
}

// ---------- projection head on batch rows + L2-normalize ----------
__global__ __launch_bounds__(128) void proj_norm(
    const float* __restrict__ G, const int* __restrict__ idx,
    const float* __restrict__ Wp1, const float* __restrict__ bp1,
    const float* __restrict__ Wp2, const float* __restrict__ bp2,
    float* __restrict__ z)
{
    __shared__ float g[MH], u[MH];
    __shared__ float red[2];
    int i = blockIdx.x, t = threadIdx.x;
    int node = idx[i];
    g[t] = G[(size_t)node * MH + t];
    __syncthreads();
    float acc = bp1[t];
    for (int k = 0; k < MH; k++) acc = fmaf(g[k], Wp1[k * MH + t], acc);
    u[t] = acc > 0.f ? acc : (expf(acc) - 1.f);   // elu
    __syncthreads();
    float acc2 = bp2[t];
    for (int k = 0; k < MH; k++) acc2 = fmaf(u[k], Wp2[k * MH + t], acc2);
    float sq = acc2 * acc2;
#pragma unroll
    for (int off = 32; off; off >>= 1) sq += __shfl_down(sq, off);
    if ((t & 63) == 0) red[t >> 6] = sq;
    __syncthreads();
    float nrm = sqrtf(red[0] + red[1]);
    z[(size_t)i * MH + t] = acc2 / nrm;
}

// ---------- contrast: diag/rowsum/colsum of exp(cos/tau), tile-wise ----------
__global__ __launch_bounds__(256) void contrast_tiles(
    const float* __restrict__ z, float* __restrict__ stats)
{
    int p = blockIdx.z;
    int pa = (p == 2) ? 1 : 0;
    int pb = (p == 0) ? 1 : 2;
    const float* za = z + (size_t)pa * BT * MH;
    const float* zb = z + (size_t)pb * BT * MH;
    float* diag = stats + (size_t)p * 3 * BT;
    float* rs = diag + BT;
    float* cs = rs + BT;
    __shared__ float As[32][65], Bs[32][65];
    __shared__ float srow[64], scol[64];
    int t = threadIdx.x;
    int tx = t & 15, ty = t >> 4;
    int i0 = blockIdx.y * 64, j0 = blockIdx.x * 64;
    float acc[4][4] = {};
    for (int k0 = 0; k0 < MH; k0 += 32) {
#pragma unroll
        for (int i = 0; i < 8; i++) {
            int id = t + i * 256;
            int ar = id >> 5, ak = id & 31;
            As[ak][ar] = za[(size_t)(i0 + ar) * MH + k0 + ak];
            Bs[ak][ar] = zb[(size_t)(j0 + ar) * MH + k0 + ak];
        }
        __syncthreads();
#pragma unroll
        for (int kk = 0; kk < 32; kk++) {
            float a[4], b[4];
#pragma unroll
            for (int i = 0; i < 4; i++) a[i] = As[kk][ty * 4 + i];
#pragma unroll
            for (int j = 0; j < 4; j++) b[j] = Bs[kk][tx * 4 + j];
#pragma unroll
            for (int i = 0; i < 4; i++)
#pragma unroll
                for (int j = 0; j < 4; j++)
                    acc[i][j] = fmaf(a[i], b[j], acc[i][j]);
        }
        __syncthreads();
    }
    if (t < 64) { srow[t] = 0.f; scol[t] = 0.f; }
    __syncthreads();
    float rpart[4] = {}, cpart[4] = {};
#pragma unroll
    for (int i = 0; i < 4; i++)
#pragma unroll
        for (int j = 0; j < 4; j++) {
            float m = expf(acc[i][j] * (1.0f / TAUc));
            rpart[i] += m;
            cpart[j] += m;
            int gi = i0 + ty * 4 + i, gj = j0 + tx * 4 + j;
            if (gi == gj) diag[gi] = m;
        }
#pragma unroll
    for (int i = 0; i < 4; i++) atomicAdd(&srow[ty * 4 + i], rpart[i]);
#pragma unroll
    for (int j = 0; j < 4; j++) atomicAdd(&scol[tx * 4 + j], cpart[j]);
    __syncthreads();
    if (t < 64) {
        atomicAdd(&rs[i0 + t], srow[t]);
        atomicAdd(&cs[j0 + t], scol[t]);
    }
}

__global__ void contrast_reduce(const float* __restrict__ stats, float* __restrict__ out3)
{
    int p = blockIdx.x, t = threadIdx.x;
    const float* diag = stats + (size_t)p * 3 * BT;
    const float* rs = diag + BT;
    const float* cs = rs + BT;
    float s1 = 0.f, s2 = 0.f;
    for (int i = t; i < BT; i += 256) {
        float d = diag[i];
        s1 += logf(d / (rs[i] + EPSc) + EPSc);
        s2 += logf(d / (cs[i] + EPSc) + EPSc);
    }
#pragma unroll
    for (int off = 32; off; off >>= 1) { s1 += __shfl_down(s1, off); s2 += __shfl_down(s2, off); }
    __shared__ float sh[8];
    if ((t & 63) == 0) { sh[(t >> 6) * 2] = s1; sh[(t >> 6) * 2 + 1] = s2; }
    __syncthreads();
    if (t == 0) {
        float a = sh[0] + sh[2] + sh[4] + sh[6];
        float b = sh[1] + sh[3] + sh[5] + sh[7];
        float l12 = -a / BT, l21 = -b / BT;
        out3[p] = 0.5f * (l12 + l21);
    }
}

// ---------- host ----------
extern "C" void kernel_launch(void* const* d_in, const int* in_sizes, int n_in,
                              void* d_out, int out_size, void* d_ws, size_t ws_size,
                              hipStream_t stream)
{
    const float* feat   = (const float*)d_in[0];
    const int*   ind1   = (const int*)d_in[1];
    const float* vals1  = (const float*)d_in[2];
    const int*   ind2   = (const int*)d_in[3];
    const float* vals2  = (const float*)d_in[4];
    const int*   idxb   = (const int*)d_in[5];
    const float* W_gen1 = (const float*)d_in[6];
    const float* Wm1    = (const float*)d_in[7];
    const float* bm1    = (const float*)d_in[8];
    const float* W_gen2 = (const float*)d_in[9];
    const float* Wm2    = (const float*)d_in[10];
    const float* bm2    = (const float*)d_in[11];
    const float* W1_v1  = (const float*)d_in[12];
    const float* W2_v1  = (const float*)d_in[13];
    const float* W1_v2  = (const float*)d_in[14];
    const float* W2_v2  = (const float*)d_in[15];
    const float* W1_v   = (const float*)d_in[16];
    const float* W2_v   = (const float*)d_in[17];
    const float* Wg     = (const float*)d_in[18];
    const float* Wg1    = (const float*)d_in[19];
    const float* Wg2    = (const float*)d_in[20];
    const float* Wp1    = (const float*)d_in[21];
    const float* bp1    = (const float*)d_in[22];
    const float* Wp2    = (const float*)d_in[23];
    const float* bp2    = (const float*)d_in[24];
    float* dout = (float*)d_out;

    // workspace carve-up (floats)
    float* ws = (float*)d_ws;
    size_t off = 0;
    auto alloc = [&](size_t n) { float* p = ws + off; off += n; return p; };
    float* bufP = alloc((size_t)NN * CH);
    float* bufQ = alloc((size_t)NN * CH);
    float* bufR = alloc((size_t)NN * NCLS);
    float* bufT = alloc((size_t)NN * NCLS);
    float* nv1  = alloc(EE);
    float* nv2  = alloc(EE);
    float* ebuf = alloc(EE);
    float* sa   = alloc(NN);
    float* sb   = alloc(NN);
    unsigned* rowmax = (unsigned*)alloc(NN);
    float* rowsum = alloc(NN);
    float* w1 = alloc(NN);
    float* w2 = alloc(NN);
    float* bb1 = alloc(NN);
    float* bb2 = alloc(NN);
    float* zbuf = alloc((size_t)3 * BT * MH);
    float* stats = alloc((size_t)3 * 3 * BT);

    auto gemm = [&](const float* A, const float* B, float* C, int M, int K, int Ncol) {
        dim3 g((Ncol + 63) / 64, (M + 63) / 64);
        gemm_f32<<<g, 256, 0, stream>>>(A, B, C, M, K, Ncol);
    };

    // ---- gen_view (per view) ----
    auto gen_view = [&](const int* ind, const float* vals, const float* Wgen,
                        const float* Wm, const float* bm, float coml, float* nv) {
        gemm(feat, Wgen, bufP, NN, FD, GH);
        hipMemsetAsync(bufQ, 0, (size_t)NN * GH * 4, stream);
        spmm_dir<64><<<(EE + 3) / 4, 256, 0, stream>>>(ind, ind + EE, vals, bufP, bufQ, EE);
        relu_k<<<((long)NN * GH + 255) / 256, 256, 0, stream>>>(bufQ, (long)NN * GH);
        node_scores<<<(NN + 3) / 4, 256, 0, stream>>>(bufQ, Wm, sa, sb);
        hipMemsetAsync(rowmax, 0, NN * 4, stream);
        hipMemsetAsync(rowsum, 0, NN * 4, stream);
        edge_score<<<(EE + 255) / 256, 256, 0, stream>>>(sa, sb, bm, ind, ebuf, rowmax);
        edge_exp<<<(EE + 255) / 256, 256, 0, stream>>>(ind, ebuf, rowmax, rowsum);
        edge_nv<<<(EE + 255) / 256, 256, 0, stream>>>(ind, ebuf, rowsum, vals, coml, nv);
    };

    auto run_spmm128 = [&](int mode, const float* x, float* out) {
        hipMemsetAsync(out, 0, (size_t)NN * CH * 4, stream);
        if (mode == 0)
            spmm_sym<128><<<EE, 256, 0, stream>>>(ind1, nv1, x, out);
        else if (mode == 1)
            spmm_sym<128><<<EE, 256, 0, stream>>>(ind2, nv2, x, out);
        else
            spmm_fused<128><<<2 * EE, 256, 0, stream>>>(ind1, nv1, bb1, ind2, nv2, bb2, x, out);
    };

    // ---- classifier branch ----
    auto branch = [&](int mode, const float* W1, const float* W2, float* logits, float* w) {
        gemm(feat, W1, bufP, NN, FD, CH);
        run_spmm128(mode, bufP, bufQ);
        relu_k<<<((long)NN * CH + 255) / 256, 256, 0, stream>>>(bufQ, (long)NN * CH);
        gemm(bufQ, W2, bufR, NN, CH, NCLS);
        hipMemsetAsync(bufT, 0, (size_t)NN * NCLS * 4, stream);
        if (mode == 0)
            spmm_sym<16><<<2 * EE / 16, 256, 0, stream>>>(ind1, nv1, bufR, bufT);
        else if (mode == 1)
            spmm_sym<16><<<2 * EE / 16, 256, 0, stream>>>(ind2, nv2, bufR, bufT);
        else
            spmm_fused<16><<<4 * EE / 16, 256, 0, stream>>>(ind1, nv1, bb1, ind2, nv2, bb2, bufR, bufT);
        softmax16<<<(NN + 255) / 256, 256, 0, stream>>>(bufT, logits, w);
    };

    // ---- MI branch: GCN + projection + normalize ----
    auto mi = [&](int mode, const float* Wgx, float* zout) {
        gemm(feat, Wgx, bufP, NN, FD, MH);
        run_spmm128(mode, bufP, bufQ);
        relu_k<<<((long)NN * MH + 255) / 256, 256, 0, stream>>>(bufQ, (long)NN * MH);
        proj_norm<<<BT, 128, 0, stream>>>(bufQ, idxb, Wp1, bp1, Wp2, bp2, zout);
    };

    // ================= sequence =================
    gen_view(ind1, vals1, W_gen1, Wm1, bm1, CL1c, nv1);
    gen_view(ind2, vals2, W_gen2, Wm2, bm2, CL2c, nv2);

    branch(0, W1_v1, W2_v1, dout + (size_t)NN * NCLS, w1);
    branch(1, W1_v2, W2_v2, dout + 2 * (size_t)NN * NCLS, w2);
    bweights<<<(NN + 255) / 256, 256, 0, stream>>>(w1, w2, bb1, bb2);
    branch(2, W1_v, W2_v, dout, nullptr);

    mi(2, Wg, zbuf);
    mi(0, Wg1, zbuf + (size_t)BT * MH);
    mi(1, Wg2, zbuf + 2 * (size_t)BT * MH);

    hipMemsetAsync(stats, 0, (size_t)3 * 3 * BT * 4, stream);
    contrast_tiles<<<dim3(64, 64, 3), 256, 0, stream>>>(zbuf, stats);
    contrast_reduce<<<3, 256, 0, stream>>>(stats, dout + (size_t)3 * NN * NCLS);
}

// Round 2
// 2919.896 us; speedup vs baseline: 1.6984x; 1.6984x over previous
//
#include <hip/hip_runtime.h>
#include <math.h>

#define NN 30000
#define EE 480000
#define FD 256
#define CH 128
#define NCLS 16
#define GH 64
#define MH 128
#define BT 4096
#define CL1c 0.5f
#define CL2c 0.5f
#define LAMc 0.5f
#define ALPHAc 1.0f
#define TAUc 0.5f
#define EPSc 1e-8f

// ---------- helpers ----------
__device__ __forceinline__ unsigned enc_f32(float f) {
    unsigned b = __float_as_uint(f);
    return (b & 0x80000000u) ? ~b : (b | 0x80000000u);
}
__device__ __forceinline__ float dec_f32(unsigned u) {
    return (u & 0x80000000u) ? __uint_as_float(u ^ 0x80000000u) : __uint_as_float(~u);
}

// ---------- generic fp32 GEMM: C[MxN] = A[MxK] @ B[KxN], row-major ----------
__global__ __launch_bounds__(256) void gemm_f32(
    const float* __restrict__ A, const float* __restrict__ B, float* __restrict__ C,
    int M, int K, int Ncol)
{
    __shared__ float As[16][65];
    __shared__ float Bs[16][64];
    int t = threadIdx.x;
    int tx = t & 15, ty = t >> 4;
    int row0 = blockIdx.y * 64, col0 = blockIdx.x * 64;
    float acc[4][4] = {};
    for (int k0 = 0; k0 < K; k0 += 16) {
#pragma unroll
        for (int i = 0; i < 4; i++) {
            int id = t + i * 256;
            int ar = id >> 4, ak = id & 15;
            int gr = row0 + ar;
            As[ak][ar] = (gr < M) ? A[(size_t)gr * K + k0 + ak] : 0.f;
            int br = id >> 6, bc = id & 63;
            int gc = col0 + bc;
            Bs[br][bc] = (gc < Ncol) ? B[(size_t)(k0 + br) * Ncol + gc] : 0.f;
        }
        __syncthreads();
#pragma unroll
        for (int kk = 0; kk < 16; kk++) {
            float a[4], b[4];
#pragma unroll
            for (int i = 0; i < 4; i++) a[i] = As[kk][ty * 4 + i];
#pragma unroll
            for (int j = 0; j < 4; j++) b[j] = Bs[kk][tx * 4 + j];
#pragma unroll
            for (int i = 0; i < 4; i++)
#pragma unroll
                for (int j = 0; j < 4; j++)
                    acc[i][j] = fmaf(a[i], b[j], acc[i][j]);
        }
        __syncthreads();
    }
#pragma unroll
    for (int i = 0; i < 4; i++) {
        int r = row0 + ty * 4 + i;
        if (r >= M) continue;
#pragma unroll
        for (int j = 0; j < 4; j++) {
            int c = col0 + tx * 4 + j;
            if (c < Ncol) C[(size_t)r * Ncol + c] = acc[i][j];
        }
    }
}

// ---------- CSR build ----------
__global__ void count_dir(const int* __restrict__ ind, int* __restrict__ cnt) {
    int e = blockIdx.x * 256 + threadIdx.x;
    if (e >= EE) return;
    atomicAdd(&cnt[ind[e]], 1);
}
__global__ void count_sym(const int* __restrict__ ind, int* __restrict__ cnt) {
    int e = blockIdx.x * 256 + threadIdx.x;
    if (e >= EE) return;
    atomicAdd(&cnt[ind[e]], 1);
    atomicAdd(&cnt[ind[EE + e]], 1);
}
__global__ __launch_bounds__(1024) void scan_block(const int* __restrict__ cnt,
                                                   int* __restrict__ rowptr,
                                                   int* __restrict__ bsum) {
    __shared__ int tmp[1024];
    int t = threadIdx.x;
    int i = blockIdx.x * 1024 + t;
    int v = (i < NN) ? cnt[i] : 0;
    tmp[t] = v;
    __syncthreads();
    for (int off = 1; off < 1024; off <<= 1) {
        int add = (t >= off) ? tmp[t - off] : 0;
        __syncthreads();
        tmp[t] += add;
        __syncthreads();
    }
    if (i <= NN) rowptr[i] = tmp[t] - v;  // local exclusive
    if (t == 1023) bsum[blockIdx.x] = tmp[1023];
}
__global__ void scan_bsum(int* __restrict__ bsum, int nb) {
    int t = threadIdx.x;  // 64 threads, one wave
    int orig = (t < nb) ? bsum[t] : 0;
    int v = orig;
    for (int off = 1; off < 64; off <<= 1) {
        int u = __shfl_up(v, off);
        if (t >= off) v += u;
    }
    if (t < nb) bsum[t] = v - orig;  // exclusive
}
__global__ void scan_add(const int* __restrict__ bsum, int* __restrict__ rowptr,
                         int* __restrict__ cursor) {
    int i = blockIdx.x * 1024 + threadIdx.x;
    if (i <= NN) {
        int r = rowptr[i] + bsum[blockIdx.x];
        rowptr[i] = r;
        if (i < NN) cursor[i] = r;
    }
}
__global__ void scatter_dir(const int* __restrict__ ind, const float* __restrict__ vals,
                            int* __restrict__ cur, int* __restrict__ col,
                            float* __restrict__ val) {
    int e = blockIdx.x * 256 + threadIdx.x;
    if (e >= EE) return;
    int r = ind[e];
    int p = atomicAdd(&cur[r], 1);
    col[p] = ind[EE + e];
    val[p] = vals[e];
}
__global__ void scatter_sym(const int* __restrict__ ind, const float* __restrict__ nv,
                            int* __restrict__ cur, int* __restrict__ col,
                            float* __restrict__ val) {
    int e = blockIdx.x * 256 + threadIdx.x;
    if (e >= EE) return;
    int r = ind[e], c = ind[EE + e];
    float v = nv[e];
    int p = atomicAdd(&cur[r], 1);
    col[p] = c; val[p] = v;
    int q = atomicAdd(&cur[c], 1);
    col[q] = r; val[q] = v;
}

// ---------- CSR SpMM: out[r,:] = (relu?) sum_j val[j] * x[col[j],:] ----------
template <int F, bool RELU>
__global__ __launch_bounds__(128) void spmm_csr(
    const int* __restrict__ rowptr, const int* __restrict__ col,
    const float* __restrict__ val,
    const float* __restrict__ x, float* __restrict__ out)
{
    const int RPB = 128 / F;
    int row = blockIdx.x * RPB + threadIdx.x / F;
    int lane = threadIdx.x % F;
    if (row >= NN) return;
    int p0 = rowptr[row], p1 = rowptr[row + 1];
    float acc = 0.f;
    for (int j = p0; j < p1; j++)
        acc = fmaf(val[j], x[(size_t)col[j] * F + lane], acc);
    out[(size_t)row * F + lane] = RELU ? fmaxf(acc, 0.f) : acc;
}

template <int F, bool RELU>
__global__ __launch_bounds__(128) void spmm_csr_fused(
    const int* __restrict__ rp1, const int* __restrict__ col1, const float* __restrict__ val1,
    const float* __restrict__ b1,
    const int* __restrict__ rp2, const int* __restrict__ col2, const float* __restrict__ val2,
    const float* __restrict__ b2,
    const float* __restrict__ x, float* __restrict__ out)
{
    const int RPB = 128 / F;
    int row = blockIdx.x * RPB + threadIdx.x / F;
    int lane = threadIdx.x % F;
    if (row >= NN) return;
    float a1 = 0.f, a2 = 0.f;
    int p0 = rp1[row], p1 = rp1[row + 1];
    for (int j = p0; j < p1; j++)
        a1 = fmaf(val1[j], x[(size_t)col1[j] * F + lane], a1);
    p0 = rp2[row]; p1 = rp2[row + 1];
    for (int j = p0; j < p1; j++)
        a2 = fmaf(val2[j], x[(size_t)col2[j] * F + lane], a2);
    float acc = b1[row] * a1 + b2[row] * a2;
    out[(size_t)row * F + lane] = RELU ? fmaxf(acc, 0.f) : acc;
}

// ---------- gen_view edge-score pipeline ----------
__global__ __launch_bounds__(256) void node_scores(
    const float* __restrict__ emb, const float* __restrict__ Wm,
    float* __restrict__ sa, float* __restrict__ sb)
{
    int node = blockIdx.x * 4 + threadIdx.x / 64;
    int lane = threadIdx.x % 64;
    if (node >= NN) return;
    float e = emb[(size_t)node * GH + lane];
    float va = e * Wm[lane];
    float vb = e * Wm[GH + lane];
#pragma unroll
    for (int off = 32; off; off >>= 1) {
        va += __shfl_down(va, off);
        vb += __shfl_down(vb, off);
    }
    if (lane == 0) { sa[node] = va; sb[node] = vb; }
}

__global__ void edge_score(const float* __restrict__ sa, const float* __restrict__ sb,
                           const float* __restrict__ bm, const int* __restrict__ ind,
                           float* __restrict__ ebuf, unsigned* __restrict__ rowmax)
{
    int e = blockIdx.x * 256 + threadIdx.x;
    if (e >= EE) return;
    int r = ind[e], c = ind[EE + e];
    float s = sa[r] + sb[c] + bm[0];
    ebuf[e] = s;
    atomicMax(&rowmax[r], enc_f32(s));
}

__global__ void edge_exp(const int* __restrict__ ind, float* __restrict__ ebuf,
                         const unsigned* __restrict__ rowmax, float* __restrict__ rowsum)
{
    int e = blockIdx.x * 256 + threadIdx.x;
    if (e >= EE) return;
    int r = ind[e];
    float ex = expf(ebuf[e] - dec_f32(rowmax[r]));
    ebuf[e] = ex;
    atomicAdd(&rowsum[r], ex);
}

__global__ void edge_nv(const int* __restrict__ ind, const float* __restrict__ ebuf,
                        const float* __restrict__ rowsum, const float* __restrict__ vals,
                        float coml, float* __restrict__ nv)
{
    int e = blockIdx.x * 256 + threadIdx.x;
    if (e >= EE) return;
    int r = ind[e];
    nv[e] = vals[e] + coml * ebuf[e] / rowsum[r];
}

// ---------- per-node softmax over 16 classes + log-prob + top2 weight ----------
__global__ void softmax16(const float* __restrict__ S, float* __restrict__ logits,
                          float* __restrict__ w)
{
    int node = blockIdx.x * 256 + threadIdx.x;
    if (node >= NN) return;
    float v[NCLS];
    float mx = -3.4e38f;
#pragma unroll
    for (int j = 0; j < NCLS; j++) { v[j] = S[(size_t)node * NCLS + j]; mx = fmaxf(mx, v[j]); }
    float s = 0.f;
#pragma unroll
    for (int j = 0; j < NCLS; j++) { v[j] = expf(v[j] - mx); s += v[j]; }
    float inv = 1.f / s;
    float fir = -1.f, sec = -1.f;
#pragma unroll
    for (int j = 0; j < NCLS; j++) {
        float p = v[j] * inv;
        logits[(size_t)node * NCLS + j] = logf(p + EPSc);
        if (p > fir) { sec = fir; fir = p; }
        else if (p > sec) { sec = p; }
    }
    if (w) w[node] = expf(ALPHAc * (LAMc * logf(fir + EPSc) + (1.f - LAMc) * logf(fir - sec + EPSc)));
}

__global__ void bweights(const float* __restrict__ w1, const float* __restrict__ w2,
                         float* __restrict__ b1, float* __restrict__ b2)
{
    int i = blockIdx.x * 256 + threadIdx.x;
    if (i >= NN) return;
    float a = w1[i], b = w2[i];
    float inv = 1.f / (a + b);
    b1[i] = a * inv;
    b2[i] = b * inv;
}

// ---------- projection head on batch rows + L2-normalize ----------
__global__ __launch_bounds__(128) void proj_norm(
    const float* __restrict__ G, const int* __restrict__ idx,
    const float* __restrict__ Wp1, const float* __restrict__ bp1,
    const float* __restrict__ Wp2, const float* __restrict__ bp2,
    float* __restrict__ z)
{
    __shared__ float g[MH], u[MH];
    __shared__ float red[2];
    int i = blockIdx.x, t = threadIdx.x;
    int node = idx[i];
    g[t] = G[(size_t)node * MH + t];
    __syncthreads();
    float acc = bp1[t];
    for (int k = 0; k < MH; k++) acc = fmaf(g[k], Wp1[k * MH + t], acc);
    u[t] = acc > 0.f ? acc : (expf(acc) - 1.f);   // elu
    __syncthreads();
    float acc2 = bp2[t];
    for (int k = 0; k < MH; k++) acc2 = fmaf(u[k], Wp2[k * MH + t], acc2);
    float sq = acc2 * acc2;
#pragma unroll
    for (int off = 32; off; off >>= 1) sq += __shfl_down(sq, off);
    if ((t & 63) == 0) red[t >> 6] = sq;
    __syncthreads();
    float nrm = sqrtf(red[0] + red[1]);
    z[(size_t)i * MH + t] = acc2 / nrm;
}

// ---------- contrast: diag/rowsum/colsum of exp(cos/tau), tile-wise ----------
__global__ __launch_bounds__(256) void contrast_tiles(
    const float* __restrict__ z, float* __restrict__ stats)
{
    int p = blockIdx.z;
    int pa = (p == 2) ? 1 : 0;
    int pb = (p == 0) ? 1 : 2;
    const float* za = z + (size_t)pa * BT * MH;
    const float* zb = z + (size_t)pb * BT * MH;
    float* diag = stats + (size_t)p * 3 * BT;
    float* rs = diag + BT;
    float* cs = rs + BT;
    __shared__ float As[32][65], Bs[32][65];
    __shared__ float srow[64], scol[64];
    int t = threadIdx.x;
    int tx = t & 15, ty = t >> 4;
    int i0 = blockIdx.y * 64, j0 = blockIdx.x * 64;
    float acc[4][4] = {};
    for (int k0 = 0; k0 < MH; k0 += 32) {
#pragma unroll
        for (int i = 0; i < 8; i++) {
            int id = t + i * 256;
            int ar = id >> 5, ak = id & 31;
            As[ak][ar] = za[(size_t)(i0 + ar) * MH + k0 + ak];
            Bs[ak][ar] = zb[(size_t)(j0 + ar) * MH + k0 + ak];
        }
        __syncthreads();
#pragma unroll
        for (int kk = 0; kk < 32; kk++) {
            float a[4], b[4];
#pragma unroll
            for (int i = 0; i < 4; i++) a[i] = As[kk][ty * 4 + i];
#pragma unroll
            for (int j = 0; j < 4; j++) b[j] = Bs[kk][tx * 4 + j];
#pragma unroll
            for (int i = 0; i < 4; i++)
#pragma unroll
                for (int j = 0; j < 4; j++)
                    acc[i][j] = fmaf(a[i], b[j], acc[i][j]);
        }
        __syncthreads();
    }
    if (t < 64) { srow[t] = 0.f; scol[t] = 0.f; }
    __syncthreads();
    float rpart[4] = {}, cpart[4] = {};
#pragma unroll
    for (int i = 0; i < 4; i++)
#pragma unroll
        for (int j = 0; j < 4; j++) {
            float m = expf(acc[i][j] * (1.0f / TAUc));
            rpart[i] += m;
            cpart[j] += m;
            int gi = i0 + ty * 4 + i, gj = j0 + tx * 4 + j;
            if (gi == gj) diag[gi] = m;
        }
#pragma unroll
    for (int i = 0; i < 4; i++) atomicAdd(&srow[ty * 4 + i], rpart[i]);
#pragma unroll
    for (int j = 0; j < 4; j++) atomicAdd(&scol[tx * 4 + j], cpart[j]);
    __syncthreads();
    if (t < 64) {
        atomicAdd(&rs[i0 + t], srow[t]);
        atomicAdd(&cs[j0 + t], scol[t]);
    }
}

__global__ void contrast_reduce(const float* __restrict__ stats, float* __restrict__ out3)
{
    int p = blockIdx.x, t = threadIdx.x;
    const float* diag = stats + (size_t)p * 3 * BT;
    const float* rs = diag + BT;
    const float* cs = rs + BT;
    float s1 = 0.f, s2 = 0.f;
    for (int i = t; i < BT; i += 256) {
        float d = diag[i];
        s1 += logf(d / (rs[i] + EPSc) + EPSc);
        s2 += logf(d / (cs[i] + EPSc) + EPSc);
    }
#pragma unroll
    for (int off = 32; off; off >>= 1) { s1 += __shfl_down(s1, off); s2 += __shfl_down(s2, off); }
    __shared__ float sh[8];
    if ((t & 63) == 0) { sh[(t >> 6) * 2] = s1; sh[(t >> 6) * 2 + 1] = s2; }
    __syncthreads();
    if (t == 0) {
        float a = sh[0] + sh[2] + sh[4] + sh[6];
        float b = sh[1] + sh[3] + sh[5] + sh[7];
        float l12 = -a / BT, l21 = -b / BT;
        out3[p] = 0.5f * (l12 + l21);
    }
}

// ---------- host ----------
extern "C" void kernel_launch(void* const* d_in, const int* in_sizes, int n_in,
                              void* d_out, int out_size, void* d_ws, size_t ws_size,
                              hipStream_t stream)
{
    const float* feat   = (const float*)d_in[0];
    const int*   ind1   = (const int*)d_in[1];
    const float* vals1  = (const float*)d_in[2];
    const int*   ind2   = (const int*)d_in[3];
    const float* vals2  = (const float*)d_in[4];
    const int*   idxb   = (const int*)d_in[5];
    const float* W_gen1 = (const float*)d_in[6];
    const float* Wm1    = (const float*)d_in[7];
    const float* bm1    = (const float*)d_in[8];
    const float* W_gen2 = (const float*)d_in[9];
    const float* Wm2    = (const float*)d_in[10];
    const float* bm2    = (const float*)d_in[11];
    const float* W1_v1  = (const float*)d_in[12];
    const float* W2_v1  = (const float*)d_in[13];
    const float* W1_v2  = (const float*)d_in[14];
    const float* W2_v2  = (const float*)d_in[15];
    const float* W1_v   = (const float*)d_in[16];
    const float* W2_v   = (const float*)d_in[17];
    const float* Wg     = (const float*)d_in[18];
    const float* Wg1    = (const float*)d_in[19];
    const float* Wg2    = (const float*)d_in[20];
    const float* Wp1    = (const float*)d_in[21];
    const float* bp1    = (const float*)d_in[22];
    const float* Wp2    = (const float*)d_in[23];
    const float* bp2    = (const float*)d_in[24];
    float* dout = (float*)d_out;

    // workspace carve-up (floats)
    float* ws = (float*)d_ws;
    size_t off = 0;
    auto alloc = [&](size_t n) { float* p = ws + off; off += n; return p; };
    float* bufP = alloc((size_t)NN * CH);
    float* bufQ = alloc((size_t)NN * CH);
    float* bufR = alloc((size_t)NN * NCLS);
    float* nv1  = alloc(EE);
    float* nv2  = alloc(EE);
    float* ebuf = alloc(EE);
    float* sa   = alloc(NN);
    float* sb   = alloc(NN);
    unsigned* rowmax = (unsigned*)alloc(NN);
    float* rowsum = alloc(NN);
    float* w1 = alloc(NN);
    float* w2 = alloc(NN);
    float* bb1 = alloc(NN);
    float* bb2 = alloc(NN);
    float* zbuf = alloc((size_t)3 * BT * MH);
    float* stats = alloc((size_t)3 * 3 * BT);
    // CSR storage
    int*   col_s1 = (int*)alloc(2 * (size_t)EE);
    float* val_s1 = alloc(2 * (size_t)EE);
    int*   col_s2 = (int*)alloc(2 * (size_t)EE);
    float* val_s2 = alloc(2 * (size_t)EE);
    int*   col_d1 = (int*)alloc(EE);
    float* val_d1 = alloc(EE);
    int*   col_d2 = (int*)alloc(EE);
    float* val_d2 = alloc(EE);
    int* rp_s1 = (int*)alloc(NN + 1);
    int* rp_s2 = (int*)alloc(NN + 1);
    int* rp_d1 = (int*)alloc(NN + 1);
    int* rp_d2 = (int*)alloc(NN + 1);
    int* cnt    = (int*)alloc(NN);
    int* cursor = (int*)alloc(NN);
    int* bsum   = (int*)alloc(64);
    float* bufT = bufP;  // alias: free when spmm16 runs

    const int NB = (NN + 1 + 1023) / 1024;  // scan blocks over NN+1 entries

    auto scan = [&](int* rowptr) {
        scan_block<<<NB, 1024, 0, stream>>>(cnt, rowptr, bsum);
        scan_bsum<<<1, 64, 0, stream>>>(bsum, NB);
        scan_add<<<NB, 1024, 0, stream>>>(bsum, rowptr, cursor);
    };
    auto build_dir = [&](const int* ind, const float* vals, int* rowptr, int* col, float* val) {
        hipMemsetAsync(cnt, 0, NN * 4, stream);
        count_dir<<<(EE + 255) / 256, 256, 0, stream>>>(ind, cnt);
        scan(rowptr);
        scatter_dir<<<(EE + 255) / 256, 256, 0, stream>>>(ind, vals, cursor, col, val);
    };
    auto build_sym = [&](const int* ind, const float* nv, int* rowptr, int* col, float* val) {
        hipMemsetAsync(cnt, 0, NN * 4, stream);
        count_sym<<<(EE + 255) / 256, 256, 0, stream>>>(ind, cnt);
        scan(rowptr);
        scatter_sym<<<(EE + 255) / 256, 256, 0, stream>>>(ind, nv, cursor, col, val);
    };

    auto gemm = [&](const float* A, const float* B, float* C, int M, int K, int Ncol) {
        dim3 g((Ncol + 63) / 64, (M + 63) / 64);
        gemm_f32<<<g, 256, 0, stream>>>(A, B, C, M, K, Ncol);
    };

    // ---- gen_view (per view) ----
    auto gen_view = [&](const int* ind, const float* vals, const float* Wgen,
                        const float* Wm, const float* bm, float coml,
                        const int* rp_d, const int* col_d, const float* val_d, float* nv) {
        gemm(feat, Wgen, bufP, NN, FD, GH);
        spmm_csr<64, true><<<NN / 2, 128, 0, stream>>>(rp_d, col_d, val_d, bufP, bufQ);
        node_scores<<<(NN + 3) / 4, 256, 0, stream>>>(bufQ, Wm, sa, sb);
        hipMemsetAsync(rowmax, 0, NN * 4, stream);
        hipMemsetAsync(rowsum, 0, NN * 4, stream);
        edge_score<<<(EE + 255) / 256, 256, 0, stream>>>(sa, sb, bm, ind, ebuf, rowmax);
        edge_exp<<<(EE + 255) / 256, 256, 0, stream>>>(ind, ebuf, rowmax, rowsum);
        edge_nv<<<(EE + 255) / 256, 256, 0, stream>>>(ind, ebuf, rowsum, vals, coml, nv);
    };

    auto run_spmm128 = [&](int mode, const float* x, float* out) {
        if (mode == 0)
            spmm_csr<128, true><<<NN, 128, 0, stream>>>(rp_s1, col_s1, val_s1, x, out);
        else if (mode == 1)
            spmm_csr<128, true><<<NN, 128, 0, stream>>>(rp_s2, col_s2, val_s2, x, out);
        else
            spmm_csr_fused<128, true><<<NN, 128, 0, stream>>>(
                rp_s1, col_s1, val_s1, bb1, rp_s2, col_s2, val_s2, bb2, x, out);
    };
    auto run_spmm16 = [&](int mode, const float* x, float* out) {
        if (mode == 0)
            spmm_csr<16, false><<<NN / 8, 128, 0, stream>>>(rp_s1, col_s1, val_s1, x, out);
        else if (mode == 1)
            spmm_csr<16, false><<<NN / 8, 128, 0, stream>>>(rp_s2, col_s2, val_s2, x, out);
        else
            spmm_csr_fused<16, false><<<NN / 8, 128, 0, stream>>>(
                rp_s1, col_s1, val_s1, bb1, rp_s2, col_s2, val_s2, bb2, x, out);
    };

    // ---- classifier branch ----
    auto branch = [&](int mode, const float* W1, const float* W2, float* logits, float* w) {
        gemm(feat, W1, bufP, NN, FD, CH);
        run_spmm128(mode, bufP, bufQ);
        gemm(bufQ, W2, bufR, NN, CH, NCLS);
        run_spmm16(mode, bufR, bufT);
        softmax16<<<(NN + 255) / 256, 256, 0, stream>>>(bufT, logits, w);
    };

    // ---- MI branch: GCN + projection + normalize ----
    auto mi = [&](int mode, const float* Wgx, float* zout) {
        gemm(feat, Wgx, bufP, NN, FD, MH);
        run_spmm128(mode, bufP, bufQ);
        proj_norm<<<BT, 128, 0, stream>>>(bufQ, idxb, Wp1, bp1, Wp2, bp2, zout);
    };

    // ================= sequence =================
    build_dir(ind1, vals1, rp_d1, col_d1, val_d1);
    build_dir(ind2, vals2, rp_d2, col_d2, val_d2);

    gen_view(ind1, vals1, W_gen1, Wm1, bm1, CL1c, rp_d1, col_d1, val_d1, nv1);
    gen_view(ind2, vals2, W_gen2, Wm2, bm2, CL2c, rp_d2, col_d2, val_d2, nv2);

    build_sym(ind1, nv1, rp_s1, col_s1, val_s1);
    build_sym(ind2, nv2, rp_s2, col_s2, val_s2);

    branch(0, W1_v1, W2_v1, dout + (size_t)NN * NCLS, w1);
    branch(1, W1_v2, W2_v2, dout + 2 * (size_t)NN * NCLS, w2);
    bweights<<<(NN + 255) / 256, 256, 0, stream>>>(w1, w2, bb1, bb2);
    branch(2, W1_v, W2_v, dout, nullptr);

    mi(2, Wg, zbuf);
    mi(0, Wg1, zbuf + (size_t)BT * MH);
    mi(1, Wg2, zbuf + 2 * (size_t)BT * MH);

    hipMemsetAsync(stats, 0, (size_t)3 * 3 * BT * 4, stream);
    contrast_tiles<<<dim3(64, 64, 3), 256, 0, stream>>>(zbuf, stats);
    contrast_reduce<<<3, 256, 0, stream>>>(stats, dout + (size_t)3 * NN * NCLS);
}

// Round 3
// 2424.512 us; speedup vs baseline: 2.0454x; 1.2043x over previous
//
#include <hip/hip_runtime.h>
#include <math.h>

#define NN 30000
#define EE 480000
#define FD 256
#define CH 128
#define NCLS 16
#define GH 64
#define MH 128
#define BT 4096
#define CL1c 0.5f
#define CL2c 0.5f
#define LAMc 0.5f
#define ALPHAc 1.0f
#define TAUc 0.5f
#define EPSc 1e-8f

typedef __attribute__((ext_vector_type(8))) short short8;
typedef __attribute__((ext_vector_type(4))) float f32x4;

// ---------- helpers ----------
__device__ __forceinline__ unsigned enc_f32(float f) {
    unsigned b = __float_as_uint(f);
    return (b & 0x80000000u) ? ~b : (b | 0x80000000u);
}
__device__ __forceinline__ float dec_f32(unsigned u) {
    return (u & 0x80000000u) ? __uint_as_float(u ^ 0x80000000u) : __uint_as_float(~u);
}
__device__ __forceinline__ unsigned short f2bf(float x) {
    unsigned b = __float_as_uint(x);
    unsigned r = b + 0x7FFFu + ((b >> 16) & 1u);
    return (unsigned short)(r >> 16);
}
__device__ __forceinline__ float bf2f(unsigned short h) {
    return __uint_as_float(((unsigned)h) << 16);
}

// ---------- bf16 hi/lo split ----------
__global__ void split_bf16(const float* __restrict__ x, unsigned short* __restrict__ hi,
                           unsigned short* __restrict__ lo, long n) {
    long i = (long)blockIdx.x * 256 + threadIdx.x;
    if (i >= n) return;
    float v = x[i];
    unsigned short h = f2bf(v);
    hi[i] = h;
    lo[i] = f2bf(v - bf2f(h));
}

// split + transpose: B[K][N] -> BT hi/lo [N][K]
__global__ void splitT_bf16(const float* __restrict__ B, unsigned short* __restrict__ hi,
                            unsigned short* __restrict__ lo, int K, int N) {
    int i = blockIdx.x * 256 + threadIdx.x;
    if (i >= K * N) return;
    int k = i / N, n = i % N;
    float v = B[i];
    unsigned short h = f2bf(v);
    hi[(size_t)n * K + k] = h;
    lo[(size_t)n * K + k] = f2bf(v - bf2f(h));
}

// ---------- MFMA GEMM: C[M x NT*16] = A[M x K] @ B (BT given as [N][K]) ----------
// 3-pass bf16 hi/lo for ~fp32 accuracy. K multiple of 32.
template <int NT>
__global__ __launch_bounds__(256) void gemm_mfma(
    const unsigned short* __restrict__ Ahi, const unsigned short* __restrict__ Alo,
    const unsigned short* __restrict__ BThi, const unsigned short* __restrict__ BTlo,
    float* __restrict__ C, int M, int K)
{
    __shared__ unsigned short Ah[128 * 40], Al[128 * 40];
    __shared__ unsigned short Bh[NT * 16 * 40], Bl[NT * 16 * 40];
    int t = threadIdx.x;
    int w = t >> 6, l = t & 63;
    int lane = l & 15, quad = l >> 4;
    int row0 = blockIdx.x * 128;
    f32x4 acc[2][NT];
#pragma unroll
    for (int s = 0; s < 2; s++)
#pragma unroll
        for (int n = 0; n < NT; n++) acc[s][n] = (f32x4)(0.f);

    int ar = t >> 1, ako = (t & 1) << 4;  // 2 threads/row, 16 shorts each
    int nkc = K >> 5;
    for (int kc = 0; kc < nkc; kc++) {
        int kb = kc << 5;
        {   // stage A (128 x 32, hi+lo)
            int gr = row0 + ar;
            float4 h0, h1, l0, l1;
            if (gr < M) {
                const float4* pH = (const float4*)&Ahi[(size_t)gr * K + kb + ako];
                const float4* pL = (const float4*)&Alo[(size_t)gr * K + kb + ako];
                h0 = pH[0]; h1 = pH[1]; l0 = pL[0]; l1 = pL[1];
            } else {
                h0 = h1 = l0 = l1 = make_float4(0.f, 0.f, 0.f, 0.f);
            }
            float4* dH = (float4*)&Ah[ar * 40 + ako];
            dH[0] = h0; dH[1] = h1;
            float4* dL = (float4*)&Al[ar * 40 + ako];
            dL[0] = l0; dL[1] = l1;
        }
        if (ar < NT * 16) {  // stage B^T rows (N x 32, hi+lo)
            const float4* pH = (const float4*)&BThi[(size_t)ar * K + kb + ako];
            const float4* pL = (const float4*)&BTlo[(size_t)ar * K + kb + ako];
            float4 h0 = pH[0], h1 = pH[1], l0 = pL[0], l1 = pL[1];
            float4* dH = (float4*)&Bh[ar * 40 + ako];
            dH[0] = h0; dH[1] = h1;
            float4* dL = (float4*)&Bl[ar * 40 + ako];
            dL[0] = l0; dL[1] = l1;
        }
        __syncthreads();
        short8 aH[2], aL[2];
#pragma unroll
        for (int s = 0; s < 2; s++) {
            int r = w * 32 + s * 16 + lane;
            aH[s] = *(const short8*)&Ah[r * 40 + quad * 8];
            aL[s] = *(const short8*)&Al[r * 40 + quad * 8];
        }
#pragma unroll
        for (int n = 0; n < NT; n++) {
            int r = n * 16 + lane;
            short8 bH = *(const short8*)&Bh[r * 40 + quad * 8];
            short8 bL = *(const short8*)&Bl[r * 40 + quad * 8];
#pragma unroll
            for (int s = 0; s < 2; s++) {
                acc[s][n] = __builtin_amdgcn_mfma_f32_16x16x32_bf16(aH[s], bH, acc[s][n], 0, 0, 0);
                acc[s][n] = __builtin_amdgcn_mfma_f32_16x16x32_bf16(aH[s], bL, acc[s][n], 0, 0, 0);
                acc[s][n] = __builtin_amdgcn_mfma_f32_16x16x32_bf16(aL[s], bH, acc[s][n], 0, 0, 0);
            }
        }
        __syncthreads();
    }
    const int N = NT * 16;
#pragma unroll
    for (int s = 0; s < 2; s++) {
        int rb = row0 + w * 32 + s * 16 + quad * 4;
#pragma unroll
        for (int reg = 0; reg < 4; reg++) {
            int gr = rb + reg;
            if (gr >= M) continue;
#pragma unroll
            for (int n = 0; n < NT; n++)
                C[(size_t)gr * N + n * 16 + lane] = acc[s][n][reg];
        }
    }
}

// ---------- MFMA contrast: diag/rowsum/colsum of exp(2 * za.zb^T) ----------
__global__ __launch_bounds__(256) void contrast_mfma(
    const unsigned short* __restrict__ zhi, const unsigned short* __restrict__ zlo,
    float* __restrict__ stats)
{
    int p = blockIdx.z;
    int pa = (p == 2) ? 1 : 0;
    int pb = (p == 0) ? 1 : 2;
    const unsigned short* Ag = zhi + (size_t)pa * BT * MH;
    const unsigned short* Agl = zlo + (size_t)pa * BT * MH;
    const unsigned short* Bg = zhi + (size_t)pb * BT * MH;
    const unsigned short* Bgl = zlo + (size_t)pb * BT * MH;
    float* diag = stats + (size_t)p * 3 * BT;
    float* rs = diag + BT;
    float* cs = rs + BT;
    __shared__ unsigned short Ah[64 * 136], Al[64 * 136], Bh[64 * 136], Bl[64 * 136];
    int t = threadIdx.x;
    int w = t >> 6, l = t & 63, lane = l & 15, quad = l >> 4;
    int i0 = blockIdx.y * 64, j0 = blockIdx.x * 64;
    {   // stage all four buffers: r = t>>2, 32 shorts each
        int r = t >> 2, ko = (t & 3) << 5;
        const float4* s; float4* d;
        s = (const float4*)&Ag[(size_t)(i0 + r) * MH + ko];  d = (float4*)&Ah[r * 136 + ko];
        d[0] = s[0]; d[1] = s[1]; d[2] = s[2]; d[3] = s[3];
        s = (const float4*)&Agl[(size_t)(i0 + r) * MH + ko]; d = (float4*)&Al[r * 136 + ko];
        d[0] = s[0]; d[1] = s[1]; d[2] = s[2]; d[3] = s[3];
        s = (const float4*)&Bg[(size_t)(j0 + r) * MH + ko];  d = (float4*)&Bh[r * 136 + ko];
        d[0] = s[0]; d[1] = s[1]; d[2] = s[2]; d[3] = s[3];
        s = (const float4*)&Bgl[(size_t)(j0 + r) * MH + ko]; d = (float4*)&Bl[r * 136 + ko];
        d[0] = s[0]; d[1] = s[1]; d[2] = s[2]; d[3] = s[3];
    }
    __syncthreads();
    f32x4 acc[4];
#pragma unroll
    for (int n = 0; n < 4; n++) acc[n] = (f32x4)(0.f);
#pragma unroll
    for (int kc = 0; kc < 4; kc++) {
        int kb = kc * 32 + quad * 8;
        int rA = (w * 16 + lane) * 136 + kb;
        short8 aH = *(const short8*)&Ah[rA];
        short8 aL = *(const short8*)&Al[rA];
#pragma unroll
        for (int n = 0; n < 4; n++) {
            int rB = (n * 16 + lane) * 136 + kb;
            short8 bH = *(const short8*)&Bh[rB];
            short8 bL = *(const short8*)&Bl[rB];
            acc[n] = __builtin_amdgcn_mfma_f32_16x16x32_bf16(aH, bH, acc[n], 0, 0, 0);
            acc[n] = __builtin_amdgcn_mfma_f32_16x16x32_bf16(aH, bL, acc[n], 0, 0, 0);
            acc[n] = __builtin_amdgcn_mfma_f32_16x16x32_bf16(aL, bH, acc[n], 0, 0, 0);
        }
    }
    // epilogue: m = exp(2*dot); diag + row/col sums
    float rowp[4] = {0.f, 0.f, 0.f, 0.f};
    float colp[4] = {0.f, 0.f, 0.f, 0.f};
#pragma unroll
    for (int n = 0; n < 4; n++)
#pragma unroll
        for (int reg = 0; reg < 4; reg++) {
            float m = expf(acc[n][reg] * (1.0f / TAUc));
            rowp[reg] += m;
            colp[n] += m;
            int gi = i0 + w * 16 + quad * 4 + reg;
            int gj = j0 + n * 16 + lane;
            if (gi == gj) diag[gi] = m;
        }
#pragma unroll
    for (int reg = 0; reg < 4; reg++) {
        float v = rowp[reg];
        v += __shfl_xor(v, 1); v += __shfl_xor(v, 2);
        v += __shfl_xor(v, 4); v += __shfl_xor(v, 8);
        if (lane == 0) atomicAdd(&rs[i0 + w * 16 + quad * 4 + reg], v);
    }
    float cval = 0.f;
#pragma unroll
    for (int n = 0; n < 4; n++) {
        float v = colp[n];
        v += __shfl_xor(v, 16); v += __shfl_xor(v, 32);
        if (quad == n) cval = v;
    }
    __syncthreads();
    float* scol = (float*)Ah;
    if (t < 64) scol[t] = 0.f;
    __syncthreads();
    atomicAdd(&scol[quad * 16 + lane], cval);
    __syncthreads();
    if (t < 64) atomicAdd(&cs[j0 + t], scol[t]);
}

// ---------- CSR build ----------
__global__ void count_dir(const int* __restrict__ ind, int* __restrict__ cnt) {
    int e = blockIdx.x * 256 + threadIdx.x;
    if (e >= EE) return;
    atomicAdd(&cnt[ind[e]], 1);
}
__global__ void count_sym(const int* __restrict__ ind, int* __restrict__ cnt) {
    int e = blockIdx.x * 256 + threadIdx.x;
    if (e >= EE) return;
    atomicAdd(&cnt[ind[e]], 1);
    atomicAdd(&cnt[ind[EE + e]], 1);
}
__global__ __launch_bounds__(1024) void scan_block(const int* __restrict__ cnt,
                                                   int* __restrict__ rowptr,
                                                   int* __restrict__ bsum) {
    __shared__ int tmp[1024];
    int t = threadIdx.x;
    int i = blockIdx.x * 1024 + t;
    int v = (i < NN) ? cnt[i] : 0;
    tmp[t] = v;
    __syncthreads();
    for (int off = 1; off < 1024; off <<= 1) {
        int add = (t >= off) ? tmp[t - off] : 0;
        __syncthreads();
        tmp[t] += add;
        __syncthreads();
    }
    if (i <= NN) rowptr[i] = tmp[t] - v;
    if (t == 1023) bsum[blockIdx.x] = tmp[1023];
}
__global__ void scan_bsum(int* __restrict__ bsum, int nb) {
    int t = threadIdx.x;
    int orig = (t < nb) ? bsum[t] : 0;
    int v = orig;
    for (int off = 1; off < 64; off <<= 1) {
        int u = __shfl_up(v, off);
        if (t >= off) v += u;
    }
    if (t < nb) bsum[t] = v - orig;
}
__global__ void scan_add(const int* __restrict__ bsum, int* __restrict__ rowptr,
                         int* __restrict__ cursor) {
    int i = blockIdx.x * 1024 + threadIdx.x;
    if (i <= NN) {
        int r = rowptr[i] + bsum[blockIdx.x];
        rowptr[i] = r;
        if (i < NN) cursor[i] = r;
    }
}
__global__ void scatter_dir(const int* __restrict__ ind, const float* __restrict__ vals,
                            int* __restrict__ cur, int* __restrict__ col,
                            float* __restrict__ val) {
    int e = blockIdx.x * 256 + threadIdx.x;
    if (e >= EE) return;
    int r = ind[e];
    int p = atomicAdd(&cur[r], 1);
    col[p] = ind[EE + e];
    val[p] = vals[e];
}
__global__ void scatter_sym(const int* __restrict__ ind, const float* __restrict__ nv,
                            int* __restrict__ cur, int* __restrict__ col,
                            float* __restrict__ val) {
    int e = blockIdx.x * 256 + threadIdx.x;
    if (e >= EE) return;
    int r = ind[e], c = ind[EE + e];
    float v = nv[e];
    int p = atomicAdd(&cur[r], 1);
    col[p] = c; val[p] = v;
    int q = atomicAdd(&cur[c], 1);
    col[q] = r; val[q] = v;
}

// ---------- CSR SpMM ----------
template <int F, bool RELU>
__global__ __launch_bounds__(128) void spmm_csr(
    const int* __restrict__ rowptr, const int* __restrict__ col,
    const float* __restrict__ val,
    const float* __restrict__ x, float* __restrict__ out)
{
    const int RPB = 128 / F;
    int row = blockIdx.x * RPB + threadIdx.x / F;
    int lane = threadIdx.x % F;
    if (row >= NN) return;
    int p0 = rowptr[row], p1 = rowptr[row + 1];
    float acc = 0.f;
    for (int j = p0; j < p1; j++)
        acc = fmaf(val[j], x[(size_t)col[j] * F + lane], acc);
    out[(size_t)row * F + lane] = RELU ? fmaxf(acc, 0.f) : acc;
}

template <int F, bool RELU>
__global__ __launch_bounds__(128) void spmm_csr_fused(
    const int* __restrict__ rp1, const int* __restrict__ col1, const float* __restrict__ val1,
    const float* __restrict__ b1,
    const int* __restrict__ rp2, const int* __restrict__ col2, const float* __restrict__ val2,
    const float* __restrict__ b2,
    const float* __restrict__ x, float* __restrict__ out)
{
    const int RPB = 128 / F;
    int row = blockIdx.x * RPB + threadIdx.x / F;
    int lane = threadIdx.x % F;
    if (row >= NN) return;
    float a1 = 0.f, a2 = 0.f;
    int p0 = rp1[row], p1 = rp1[row + 1];
    for (int j = p0; j < p1; j++)
        a1 = fmaf(val1[j], x[(size_t)col1[j] * F + lane], a1);
    p0 = rp2[row]; p1 = rp2[row + 1];
    for (int j = p0; j < p1; j++)
        a2 = fmaf(val2[j], x[(size_t)col2[j] * F + lane], a2);
    float acc = b1[row] * a1 + b2[row] * a2;
    out[(size_t)row * F + lane] = RELU ? fmaxf(acc, 0.f) : acc;
}

// ---------- gen_view edge-score pipeline ----------
__global__ __launch_bounds__(256) void node_scores(
    const float* __restrict__ emb, const float* __restrict__ Wm,
    float* __restrict__ sa, float* __restrict__ sb)
{
    int node = blockIdx.x * 4 + threadIdx.x / 64;
    int lane = threadIdx.x % 64;
    if (node >= NN) return;
    float e = emb[(size_t)node * GH + lane];
    float va = e * Wm[lane];
    float vb = e * Wm[GH + lane];
#pragma unroll
    for (int off = 32; off; off >>= 1) {
        va += __shfl_down(va, off);
        vb += __shfl_down(vb, off);
    }
    if (lane == 0) { sa[node] = va; sb[node] = vb; }
}

__global__ void edge_score(const float* __restrict__ sa, const float* __restrict__ sb,
                           const float* __restrict__ bm, const int* __restrict__ ind,
                           float* __restrict__ ebuf, unsigned* __restrict__ rowmax)
{
    int e = blockIdx.x * 256 + threadIdx.x;
    if (e >= EE) return;
    int r = ind[e], c = ind[EE + e];
    float s = sa[r] + sb[c] + bm[0];
    ebuf[e] = s;
    atomicMax(&rowmax[r], enc_f32(s));
}

__global__ void edge_exp(const int* __restrict__ ind, float* __restrict__ ebuf,
                         const unsigned* __restrict__ rowmax, float* __restrict__ rowsum)
{
    int e = blockIdx.x * 256 + threadIdx.x;
    if (e >= EE) return;
    int r = ind[e];
    float ex = expf(ebuf[e] - dec_f32(rowmax[r]));
    ebuf[e] = ex;
    atomicAdd(&rowsum[r], ex);
}

__global__ void edge_nv(const int* __restrict__ ind, const float* __restrict__ ebuf,
                        const float* __restrict__ rowsum, const float* __restrict__ vals,
                        float coml, float* __restrict__ nv)
{
    int e = blockIdx.x * 256 + threadIdx.x;
    if (e >= EE) return;
    int r = ind[e];
    nv[e] = vals[e] + coml * ebuf[e] / rowsum[r];
}

// ---------- per-node softmax / logits / top2 weight ----------
__global__ void softmax16(const float* __restrict__ S, float* __restrict__ logits,
                          float* __restrict__ w)
{
    int node = blockIdx.x * 256 + threadIdx.x;
    if (node >= NN) return;
    float v[NCLS];
    float mx = -3.4e38f;
#pragma unroll
    for (int j = 0; j < NCLS; j++) { v[j] = S[(size_t)node * NCLS + j]; mx = fmaxf(mx, v[j]); }
    float s = 0.f;
#pragma unroll
    for (int j = 0; j < NCLS; j++) { v[j] = expf(v[j] - mx); s += v[j]; }
    float inv = 1.f / s;
    float fir = -1.f, sec = -1.f;
#pragma unroll
    for (int j = 0; j < NCLS; j++) {
        float p = v[j] * inv;
        logits[(size_t)node * NCLS + j] = logf(p + EPSc);
        if (p > fir) { sec = fir; fir = p; }
        else if (p > sec) { sec = p; }
    }
    if (w) w[node] = expf(ALPHAc * (LAMc * logf(fir + EPSc) + (1.f - LAMc) * logf(fir - sec + EPSc)));
}

__global__ void bweights(const float* __restrict__ w1, const float* __restrict__ w2,
                         float* __restrict__ b1, float* __restrict__ b2)
{
    int i = blockIdx.x * 256 + threadIdx.x;
    if (i >= NN) return;
    float a = w1[i], b = w2[i];
    float inv = 1.f / (a + b);
    b1[i] = a * inv;
    b2[i] = b * inv;
}

// ---------- projection head on batch rows + L2-normalize ----------
__global__ __launch_bounds__(128) void proj_norm(
    const float* __restrict__ G, const int* __restrict__ idx,
    const float* __restrict__ Wp1, const float* __restrict__ bp1,
    const float* __restrict__ Wp2, const float* __restrict__ bp2,
    float* __restrict__ z)
{
    __shared__ float g[MH], u[MH];
    __shared__ float red[2];
    int i = blockIdx.x, t = threadIdx.x;
    int node = idx[i];
    g[t] = G[(size_t)node * MH + t];
    __syncthreads();
    float acc = bp1[t];
    for (int k = 0; k < MH; k++) acc = fmaf(g[k], Wp1[k * MH + t], acc);
    u[t] = acc > 0.f ? acc : (expf(acc) - 1.f);
    __syncthreads();
    float acc2 = bp2[t];
    for (int k = 0; k < MH; k++) acc2 = fmaf(u[k], Wp2[k * MH + t], acc2);
    float sq = acc2 * acc2;
#pragma unroll
    for (int off = 32; off; off >>= 1) sq += __shfl_down(sq, off);
    if ((t & 63) == 0) red[t >> 6] = sq;
    __syncthreads();
    float nrm = sqrtf(red[0] + red[1]);
    z[(size_t)i * MH + t] = acc2 / nrm;
}

__global__ void contrast_reduce(const float* __restrict__ stats, float* __restrict__ out3)
{
    int p = blockIdx.x, t = threadIdx.x;
    const float* diag = stats + (size_t)p * 3 * BT;
    const float* rs = diag + BT;
    const float* cs = rs + BT;
    float s1 = 0.f, s2 = 0.f;
    for (int i = t; i < BT; i += 256) {
        float d = diag[i];
        s1 += logf(d / (rs[i] + EPSc) + EPSc);
        s2 += logf(d / (cs[i] + EPSc) + EPSc);
    }
#pragma unroll
    for (int off = 32; off; off >>= 1) { s1 += __shfl_down(s1, off); s2 += __shfl_down(s2, off); }
    __shared__ float sh[8];
    if ((t & 63) == 0) { sh[(t >> 6) * 2] = s1; sh[(t >> 6) * 2 + 1] = s2; }
    __syncthreads();
    if (t == 0) {
        float a = sh[0] + sh[2] + sh[4] + sh[6];
        float b = sh[1] + sh[3] + sh[5] + sh[7];
        out3[p] = 0.5f * (-a / BT - b / BT);
    }
}

// ---------- host ----------
extern "C" void kernel_launch(void* const* d_in, const int* in_sizes, int n_in,
                              void* d_out, int out_size, void* d_ws, size_t ws_size,
                              hipStream_t stream)
{
    const float* feat   = (const float*)d_in[0];
    const int*   ind1   = (const int*)d_in[1];
    const float* vals1  = (const float*)d_in[2];
    const int*   ind2   = (const int*)d_in[3];
    const float* vals2  = (const float*)d_in[4];
    const int*   idxb   = (const int*)d_in[5];
    const float* W_gen1 = (const float*)d_in[6];
    const float* Wm1    = (const float*)d_in[7];
    const float* bm1    = (const float*)d_in[8];
    const float* W_gen2 = (const float*)d_in[9];
    const float* Wm2    = (const float*)d_in[10];
    const float* bm2    = (const float*)d_in[11];
    const float* W1_v1  = (const float*)d_in[12];
    const float* W2_v1  = (const float*)d_in[13];
    const float* W1_v2  = (const float*)d_in[14];
    const float* W2_v2  = (const float*)d_in[15];
    const float* W1_v   = (const float*)d_in[16];
    const float* W2_v   = (const float*)d_in[17];
    const float* Wg     = (const float*)d_in[18];
    const float* Wg1    = (const float*)d_in[19];
    const float* Wg2    = (const float*)d_in[20];
    const float* Wp1    = (const float*)d_in[21];
    const float* bp1    = (const float*)d_in[22];
    const float* Wp2    = (const float*)d_in[23];
    const float* bp2    = (const float*)d_in[24];
    float* dout = (float*)d_out;

    float* ws = (float*)d_ws;
    size_t off = 0;
    auto alloc = [&](size_t n) { n = (n + 3) & ~(size_t)3; float* p = ws + off; off += n; return p; };
    auto alloc_s = [&](size_t n) { return (unsigned short*)alloc((n + 1) / 2); };

    float* bufP = alloc((size_t)NN * CH);
    float* bufQ = alloc((size_t)NN * CH);
    float* bufR = alloc((size_t)NN * NCLS);
    float* nv1  = alloc(EE);
    float* nv2  = alloc(EE);
    float* ebuf = alloc(EE);
    float* sa   = alloc(NN);
    float* sb   = alloc(NN);
    unsigned* rowmax = (unsigned*)alloc(NN);
    float* rowsum = alloc(NN);
    float* w1 = alloc(NN);
    float* w2 = alloc(NN);
    float* bb1 = alloc(NN);
    float* bb2 = alloc(NN);
    float* zbuf = alloc((size_t)3 * BT * MH);
    float* stats = alloc((size_t)3 * 3 * BT);
    int*   col_s1 = (int*)alloc(2 * (size_t)EE);
    float* val_s1 = alloc(2 * (size_t)EE);
    int*   col_s2 = (int*)alloc(2 * (size_t)EE);
    float* val_s2 = alloc(2 * (size_t)EE);
    int*   col_d1 = (int*)alloc(EE);
    float* val_d1 = alloc(EE);
    int*   col_d2 = (int*)alloc(EE);
    float* val_d2 = alloc(EE);
    int* rp_s1 = (int*)alloc(NN + 1);
    int* rp_s2 = (int*)alloc(NN + 1);
    int* rp_d1 = (int*)alloc(NN + 1);
    int* rp_d2 = (int*)alloc(NN + 1);
    int* cnt    = (int*)alloc(NN);
    int* cursor = (int*)alloc(NN);
    int* bsum   = (int*)alloc(64);
    // bf16 hi/lo buffers
    unsigned short* feat_hi = alloc_s((size_t)NN * FD);
    unsigned short* feat_lo = alloc_s((size_t)NN * FD);
    unsigned short* q_hi = alloc_s((size_t)NN * CH);
    unsigned short* q_lo = alloc_s((size_t)NN * CH);
    unsigned short* z_hi = alloc_s((size_t)3 * BT * MH);
    unsigned short* z_lo = alloc_s((size_t)3 * BT * MH);
    // transposed split weights
    auto wsplit = [&](const float* W, int K, int N, unsigned short*& hi, unsigned short*& lo) {
        hi = alloc_s((size_t)N * K);
        lo = alloc_s((size_t)N * K);
        splitT_bf16<<<(K * N + 255) / 256, 256, 0, stream>>>(W, hi, lo, K, N);
    };
    float* bufT = bufP;  // alias

    // split feat once
    split_bf16<<<((long)NN * FD + 255) / 256, 256, 0, stream>>>(feat, feat_hi, feat_lo, (long)NN * FD);
    unsigned short *wg1h, *wg1l, *wg2h, *wg2l;
    unsigned short *w1v1h, *w1v1l, *w1v2h, *w1v2l, *w1vh, *w1vl;
    unsigned short *w2v1h, *w2v1l, *w2v2h, *w2v2l, *w2vh, *w2vl;
    unsigned short *wgh, *wgl, *wgg1h, *wgg1l, *wgg2h, *wgg2l;
    wsplit(W_gen1, FD, GH, wg1h, wg1l);
    wsplit(W_gen2, FD, GH, wg2h, wg2l);
    wsplit(W1_v1, FD, CH, w1v1h, w1v1l);
    wsplit(W1_v2, FD, CH, w1v2h, w1v2l);
    wsplit(W1_v, FD, CH, w1vh, w1vl);
    wsplit(W2_v1, CH, NCLS, w2v1h, w2v1l);
    wsplit(W2_v2, CH, NCLS, w2v2h, w2v2l);
    wsplit(W2_v, CH, NCLS, w2vh, w2vl);
    wsplit(Wg, FD, MH, wgh, wgl);
    wsplit(Wg1, FD, MH, wgg1h, wgg1l);
    wsplit(Wg2, FD, MH, wgg2h, wgg2l);

    const int NB = (NN + 1 + 1023) / 1024;
    auto scan = [&](int* rowptr) {
        scan_block<<<NB, 1024, 0, stream>>>(cnt, rowptr, bsum);
        scan_bsum<<<1, 64, 0, stream>>>(bsum, NB);
        scan_add<<<NB, 1024, 0, stream>>>(bsum, rowptr, cursor);
    };
    auto build_dir = [&](const int* ind, const float* vals, int* rowptr, int* col, float* val) {
        hipMemsetAsync(cnt, 0, NN * 4, stream);
        count_dir<<<(EE + 255) / 256, 256, 0, stream>>>(ind, cnt);
        scan(rowptr);
        scatter_dir<<<(EE + 255) / 256, 256, 0, stream>>>(ind, vals, cursor, col, val);
    };
    auto build_sym = [&](const int* ind, const float* nv, int* rowptr, int* col, float* val) {
        hipMemsetAsync(cnt, 0, NN * 4, stream);
        count_sym<<<(EE + 255) / 256, 256, 0, stream>>>(ind, cnt);
        scan(rowptr);
        scatter_sym<<<(EE + 255) / 256, 256, 0, stream>>>(ind, nv, cursor, col, val);
    };

    const int GB = (NN + 127) / 128;  // gemm blocks

    auto gen_view = [&](const int* ind, const float* vals,
                        const unsigned short* wh, const unsigned short* wl,
                        const float* Wm, const float* bm, float coml,
                        const int* rp_d, const int* col_d, const float* val_d, float* nv) {
        gemm_mfma<4><<<GB, 256, 0, stream>>>(feat_hi, feat_lo, wh, wl, bufP, NN, FD);
        spmm_csr<64, true><<<NN / 2, 128, 0, stream>>>(rp_d, col_d, val_d, bufP, bufQ);
        node_scores<<<(NN + 3) / 4, 256, 0, stream>>>(bufQ, Wm, sa, sb);
        hipMemsetAsync(rowmax, 0, NN * 4, stream);
        hipMemsetAsync(rowsum, 0, NN * 4, stream);
        edge_score<<<(EE + 255) / 256, 256, 0, stream>>>(sa, sb, bm, ind, ebuf, rowmax);
        edge_exp<<<(EE + 255) / 256, 256, 0, stream>>>(ind, ebuf, rowmax, rowsum);
        edge_nv<<<(EE + 255) / 256, 256, 0, stream>>>(ind, ebuf, rowsum, vals, coml, nv);
    };

    auto run_spmm128 = [&](int mode, const float* x, float* out) {
        if (mode == 0)
            spmm_csr<128, true><<<NN, 128, 0, stream>>>(rp_s1, col_s1, val_s1, x, out);
        else if (mode == 1)
            spmm_csr<128, true><<<NN, 128, 0, stream>>>(rp_s2, col_s2, val_s2, x, out);
        else
            spmm_csr_fused<128, true><<<NN, 128, 0, stream>>>(
                rp_s1, col_s1, val_s1, bb1, rp_s2, col_s2, val_s2, bb2, x, out);
    };
    auto run_spmm16 = [&](int mode, const float* x, float* out) {
        if (mode == 0)
            spmm_csr<16, false><<<NN / 8, 128, 0, stream>>>(rp_s1, col_s1, val_s1, x, out);
        else if (mode == 1)
            spmm_csr<16, false><<<NN / 8, 128, 0, stream>>>(rp_s2, col_s2, val_s2, x, out);
        else
            spmm_csr_fused<16, false><<<NN / 8, 128, 0, stream>>>(
                rp_s1, col_s1, val_s1, bb1, rp_s2, col_s2, val_s2, bb2, x, out);
    };

    auto branch = [&](int mode, const unsigned short* w1h, const unsigned short* w1l,
                      const unsigned short* w2h, const unsigned short* w2l,
                      float* logits, float* w) {
        gemm_mfma<8><<<GB, 256, 0, stream>>>(feat_hi, feat_lo, w1h, w1l, bufP, NN, FD);
        run_spmm128(mode, bufP, bufQ);
        split_bf16<<<((long)NN * CH + 255) / 256, 256, 0, stream>>>(bufQ, q_hi, q_lo, (long)NN * CH);
        gemm_mfma<1><<<GB, 256, 0, stream>>>(q_hi, q_lo, w2h, w2l, bufR, NN, CH);
        run_spmm16(mode, bufR, bufT);
        softmax16<<<(NN + 255) / 256, 256, 0, stream>>>(bufT, logits, w);
    };

    auto mi = [&](int mode, const unsigned short* wh, const unsigned short* wl, float* zout) {
        gemm_mfma<8><<<GB, 256, 0, stream>>>(feat_hi, feat_lo, wh, wl, bufP, NN, FD);
        run_spmm128(mode, bufP, bufQ);
        proj_norm<<<BT, 128, 0, stream>>>(bufQ, idxb, Wp1, bp1, Wp2, bp2, zout);
    };

    // ================= sequence =================
    build_dir(ind1, vals1, rp_d1, col_d1, val_d1);
    build_dir(ind2, vals2, rp_d2, col_d2, val_d2);

    gen_view(ind1, vals1, wg1h, wg1l, Wm1, bm1, CL1c, rp_d1, col_d1, val_d1, nv1);
    gen_view(ind2, vals2, wg2h, wg2l, Wm2, bm2, CL2c, rp_d2, col_d2, val_d2, nv2);

    build_sym(ind1, nv1, rp_s1, col_s1, val_s1);
    build_sym(ind2, nv2, rp_s2, col_s2, val_s2);

    branch(0, w1v1h, w1v1l, w2v1h, w2v1l, dout + (size_t)NN * NCLS, w1);
    branch(1, w1v2h, w1v2l, w2v2h, w2v2l, dout + 2 * (size_t)NN * NCLS, w2);
    bweights<<<(NN + 255) / 256, 256, 0, stream>>>(w1, w2, bb1, bb2);
    branch(2, w1vh, w1vl, w2vh, w2vl, dout, nullptr);

    mi(2, wgh, wgl, zbuf);
    mi(0, wgg1h, wgg1l, zbuf + (size_t)BT * MH);
    mi(1, wgg2h, wgg2l, zbuf + 2 * (size_t)BT * MH);

    split_bf16<<<((long)3 * BT * MH + 255) / 256, 256, 0, stream>>>(zbuf, z_hi, z_lo, (long)3 * BT * MH);
    hipMemsetAsync(stats, 0, (size_t)3 * 3 * BT * 4, stream);
    contrast_mfma<<<dim3(64, 64, 3), 256, 0, stream>>>(z_hi, z_lo, stats);
    contrast_reduce<<<3, 256, 0, stream>>>(stats, dout + (size_t)3 * NN * NCLS);
}

// Round 4
// 1584.039 us; speedup vs baseline: 3.1306x; 1.5306x over previous
//
#include <hip/hip_runtime.h>
#include <math.h>

#define NN 30000
#define EE 480000
#define FD 256
#define CH 128
#define NCLS 16
#define GH 64
#define MH 128
#define BT 4096
#define CL1c 0.5f
#define CL2c 0.5f
#define LAMc 0.5f
#define ALPHAc 1.0f
#define TAUc 0.5f
#define EPSc 1e-8f

typedef __attribute__((ext_vector_type(8))) short short8;
typedef __attribute__((ext_vector_type(4))) float f32x4;

// ---------- helpers ----------
__device__ __forceinline__ unsigned enc_f32(float f) {
    unsigned b = __float_as_uint(f);
    return (b & 0x80000000u) ? ~b : (b | 0x80000000u);
}
__device__ __forceinline__ float dec_f32(unsigned u) {
    return (u & 0x80000000u) ? __uint_as_float(u ^ 0x80000000u) : __uint_as_float(~u);
}
__device__ __forceinline__ unsigned short f2bf(float x) {
    unsigned b = __float_as_uint(x);
    unsigned r = b + 0x7FFFu + ((b >> 16) & 1u);
    return (unsigned short)(r >> 16);
}
__device__ __forceinline__ float bf2f(unsigned short h) {
    return __uint_as_float(((unsigned)h) << 16);
}
__device__ __forceinline__ float4 fma4(float s, float4 x, float4 a) {
    a.x = fmaf(s, x.x, a.x); a.y = fmaf(s, x.y, a.y);
    a.z = fmaf(s, x.z, a.z); a.w = fmaf(s, x.w, a.w);
    return a;
}

// ---------- bf16 hi/lo split ----------
__global__ void split_bf16(const float* __restrict__ x, unsigned short* __restrict__ hi,
                           unsigned short* __restrict__ lo, long n) {
    long i = (long)blockIdx.x * 256 + threadIdx.x;
    if (i >= n) return;
    float v = x[i];
    unsigned short h = f2bf(v);
    hi[i] = h;
    lo[i] = f2bf(v - bf2f(h));
}

__global__ void splitT_bf16(const float* __restrict__ B, unsigned short* __restrict__ hi,
                            unsigned short* __restrict__ lo, int K, int N) {
    int i = blockIdx.x * 256 + threadIdx.x;
    if (i >= K * N) return;
    int k = i / N, n = i % N;
    float v = B[i];
    unsigned short h = f2bf(v);
    hi[(size_t)n * K + k] = h;
    lo[(size_t)n * K + k] = f2bf(v - bf2f(h));
}

// ---------- MFMA GEMM: C[M x NT*16] = A[M x K] @ B (BT given as [N][K]) ----------
template <int NT>
__global__ __launch_bounds__(256) void gemm_mfma(
    const unsigned short* __restrict__ Ahi, const unsigned short* __restrict__ Alo,
    const unsigned short* __restrict__ BThi, const unsigned short* __restrict__ BTlo,
    float* __restrict__ C, int M, int K)
{
    __shared__ unsigned short Ah[128 * 40], Al[128 * 40];
    __shared__ unsigned short Bh[NT * 16 * 40], Bl[NT * 16 * 40];
    int t = threadIdx.x;
    int w = t >> 6, l = t & 63;
    int lane = l & 15, quad = l >> 4;
    int row0 = blockIdx.x * 128;
    f32x4 acc[2][NT];
#pragma unroll
    for (int s = 0; s < 2; s++)
#pragma unroll
        for (int n = 0; n < NT; n++) acc[s][n] = (f32x4)(0.f);

    int ar = t >> 1, ako = (t & 1) << 4;
    int nkc = K >> 5;
    for (int kc = 0; kc < nkc; kc++) {
        int kb = kc << 5;
        {
            int gr = row0 + ar;
            float4 h0, h1, l0, l1;
            if (gr < M) {
                const float4* pH = (const float4*)&Ahi[(size_t)gr * K + kb + ako];
                const float4* pL = (const float4*)&Alo[(size_t)gr * K + kb + ako];
                h0 = pH[0]; h1 = pH[1]; l0 = pL[0]; l1 = pL[1];
            } else {
                h0 = h1 = l0 = l1 = make_float4(0.f, 0.f, 0.f, 0.f);
            }
            float4* dH = (float4*)&Ah[ar * 40 + ako];
            dH[0] = h0; dH[1] = h1;
            float4* dL = (float4*)&Al[ar * 40 + ako];
            dL[0] = l0; dL[1] = l1;
        }
        if (ar < NT * 16) {
            const float4* pH = (const float4*)&BThi[(size_t)ar * K + kb + ako];
            const float4* pL = (const float4*)&BTlo[(size_t)ar * K + kb + ako];
            float4 h0 = pH[0], h1 = pH[1], l0 = pL[0], l1 = pL[1];
            float4* dH = (float4*)&Bh[ar * 40 + ako];
            dH[0] = h0; dH[1] = h1;
            float4* dL = (float4*)&Bl[ar * 40 + ako];
            dL[0] = l0; dL[1] = l1;
        }
        __syncthreads();
        short8 aH[2], aL[2];
#pragma unroll
        for (int s = 0; s < 2; s++) {
            int r = w * 32 + s * 16 + lane;
            aH[s] = *(const short8*)&Ah[r * 40 + quad * 8];
            aL[s] = *(const short8*)&Al[r * 40 + quad * 8];
        }
#pragma unroll
        for (int n = 0; n < NT; n++) {
            int r = n * 16 + lane;
            short8 bH = *(const short8*)&Bh[r * 40 + quad * 8];
            short8 bL = *(const short8*)&Bl[r * 40 + quad * 8];
#pragma unroll
            for (int s = 0; s < 2; s++) {
                acc[s][n] = __builtin_amdgcn_mfma_f32_16x16x32_bf16(aH[s], bH, acc[s][n], 0, 0, 0);
                acc[s][n] = __builtin_amdgcn_mfma_f32_16x16x32_bf16(aH[s], bL, acc[s][n], 0, 0, 0);
                acc[s][n] = __builtin_amdgcn_mfma_f32_16x16x32_bf16(aL[s], bH, acc[s][n], 0, 0, 0);
            }
        }
        __syncthreads();
    }
    const int N = NT * 16;
#pragma unroll
    for (int s = 0; s < 2; s++) {
        int rb = row0 + w * 32 + s * 16 + quad * 4;
#pragma unroll
        for (int reg = 0; reg < 4; reg++) {
            int gr = rb + reg;
            if (gr >= M) continue;
#pragma unroll
            for (int n = 0; n < NT; n++)
                C[(size_t)gr * N + n * 16 + lane] = acc[s][n][reg];
        }
    }
}

// ---------- MFMA contrast ----------
__global__ __launch_bounds__(256) void contrast_mfma(
    const unsigned short* __restrict__ zhi, const unsigned short* __restrict__ zlo,
    float* __restrict__ stats)
{
    int p = blockIdx.z;
    int pa = (p == 2) ? 1 : 0;
    int pb = (p == 0) ? 1 : 2;
    const unsigned short* Ag = zhi + (size_t)pa * BT * MH;
    const unsigned short* Agl = zlo + (size_t)pa * BT * MH;
    const unsigned short* Bg = zhi + (size_t)pb * BT * MH;
    const unsigned short* Bgl = zlo + (size_t)pb * BT * MH;
    float* diag = stats + (size_t)p * 3 * BT;
    float* rs = diag + BT;
    float* cs = rs + BT;
    __shared__ unsigned short Ah[64 * 136], Al[64 * 136], Bh[64 * 136], Bl[64 * 136];
    int t = threadIdx.x;
    int w = t >> 6, l = t & 63, lane = l & 15, quad = l >> 4;
    int i0 = blockIdx.y * 64, j0 = blockIdx.x * 64;
    {
        int r = t >> 2, ko = (t & 3) << 5;
        const float4* s; float4* d;
        s = (const float4*)&Ag[(size_t)(i0 + r) * MH + ko];  d = (float4*)&Ah[r * 136 + ko];
        d[0] = s[0]; d[1] = s[1]; d[2] = s[2]; d[3] = s[3];
        s = (const float4*)&Agl[(size_t)(i0 + r) * MH + ko]; d = (float4*)&Al[r * 136 + ko];
        d[0] = s[0]; d[1] = s[1]; d[2] = s[2]; d[3] = s[3];
        s = (const float4*)&Bg[(size_t)(j0 + r) * MH + ko];  d = (float4*)&Bh[r * 136 + ko];
        d[0] = s[0]; d[1] = s[1]; d[2] = s[2]; d[3] = s[3];
        s = (const float4*)&Bgl[(size_t)(j0 + r) * MH + ko]; d = (float4*)&Bl[r * 136 + ko];
        d[0] = s[0]; d[1] = s[1]; d[2] = s[2]; d[3] = s[3];
    }
    __syncthreads();
    f32x4 acc[4];
#pragma unroll
    for (int n = 0; n < 4; n++) acc[n] = (f32x4)(0.f);
#pragma unroll
    for (int kc = 0; kc < 4; kc++) {
        int kb = kc * 32 + quad * 8;
        int rA = (w * 16 + lane) * 136 + kb;
        short8 aH = *(const short8*)&Ah[rA];
        short8 aL = *(const short8*)&Al[rA];
#pragma unroll
        for (int n = 0; n < 4; n++) {
            int rB = (n * 16 + lane) * 136 + kb;
            short8 bH = *(const short8*)&Bh[rB];
            short8 bL = *(const short8*)&Bl[rB];
            acc[n] = __builtin_amdgcn_mfma_f32_16x16x32_bf16(aH, bH, acc[n], 0, 0, 0);
            acc[n] = __builtin_amdgcn_mfma_f32_16x16x32_bf16(aH, bL, acc[n], 0, 0, 0);
            acc[n] = __builtin_amdgcn_mfma_f32_16x16x32_bf16(aL, bH, acc[n], 0, 0, 0);
        }
    }
    float rowp[4] = {0.f, 0.f, 0.f, 0.f};
    float colp[4] = {0.f, 0.f, 0.f, 0.f};
#pragma unroll
    for (int n = 0; n < 4; n++)
#pragma unroll
        for (int reg = 0; reg < 4; reg++) {
            float m = expf(acc[n][reg] * (1.0f / TAUc));
            rowp[reg] += m;
            colp[n] += m;
            int gi = i0 + w * 16 + quad * 4 + reg;
            int gj = j0 + n * 16 + lane;
            if (gi == gj) diag[gi] = m;
        }
#pragma unroll
    for (int reg = 0; reg < 4; reg++) {
        float v = rowp[reg];
        v += __shfl_xor(v, 1); v += __shfl_xor(v, 2);
        v += __shfl_xor(v, 4); v += __shfl_xor(v, 8);
        if (lane == 0) atomicAdd(&rs[i0 + w * 16 + quad * 4 + reg], v);
    }
    float cval = 0.f;
#pragma unroll
    for (int n = 0; n < 4; n++) {
        float v = colp[n];
        v += __shfl_xor(v, 16); v += __shfl_xor(v, 32);
        if (quad == n) cval = v;
    }
    __syncthreads();
    float* scol = (float*)Ah;
    if (t < 64) scol[t] = 0.f;
    __syncthreads();
    atomicAdd(&scol[quad * 16 + lane], cval);
    __syncthreads();
    if (t < 64) atomicAdd(&cs[j0 + t], scol[t]);
}

// ---------- CSR build ----------
__global__ void count_dir(const int* __restrict__ ind, int* __restrict__ cnt) {
    int e = blockIdx.x * 256 + threadIdx.x;
    if (e >= EE) return;
    atomicAdd(&cnt[ind[e]], 1);
}
__global__ void count_sym(const int* __restrict__ ind, int* __restrict__ cnt) {
    int e = blockIdx.x * 256 + threadIdx.x;
    if (e >= EE) return;
    atomicAdd(&cnt[ind[e]], 1);
    atomicAdd(&cnt[ind[EE + e]], 1);
}
__global__ __launch_bounds__(1024) void scan_block(const int* __restrict__ cnt,
                                                   int* __restrict__ rowptr,
                                                   int* __restrict__ bsum) {
    __shared__ int tmp[1024];
    int t = threadIdx.x;
    int i = blockIdx.x * 1024 + t;
    int v = (i < NN) ? cnt[i] : 0;
    tmp[t] = v;
    __syncthreads();
    for (int off = 1; off < 1024; off <<= 1) {
        int add = (t >= off) ? tmp[t - off] : 0;
        __syncthreads();
        tmp[t] += add;
        __syncthreads();
    }
    if (i <= NN) rowptr[i] = tmp[t] - v;
    if (t == 1023) bsum[blockIdx.x] = tmp[1023];
}
__global__ void scan_bsum(int* __restrict__ bsum, int nb) {
    int t = threadIdx.x;
    int orig = (t < nb) ? bsum[t] : 0;
    int v = orig;
    for (int off = 1; off < 64; off <<= 1) {
        int u = __shfl_up(v, off);
        if (t >= off) v += u;
    }
    if (t < nb) bsum[t] = v - orig;
}
__global__ void scan_add(const int* __restrict__ bsum, int* __restrict__ rowptr,
                         int* __restrict__ cursor) {
    int i = blockIdx.x * 1024 + threadIdx.x;
    if (i <= NN) {
        int r = rowptr[i] + bsum[blockIdx.x];
        rowptr[i] = r;
        if (i < NN) cursor[i] = r;
    }
}
__global__ void scatter_dir(const int* __restrict__ ind, const float* __restrict__ vals,
                            int* __restrict__ cur, int* __restrict__ col,
                            float* __restrict__ val) {
    int e = blockIdx.x * 256 + threadIdx.x;
    if (e >= EE) return;
    int r = ind[e];
    int p = atomicAdd(&cur[r], 1);
    col[p] = ind[EE + e];
    val[p] = vals[e];
}
__global__ void scatter_sym(const int* __restrict__ ind, const float* __restrict__ nv,
                            int* __restrict__ cur, int* __restrict__ col,
                            float* __restrict__ val) {
    int e = blockIdx.x * 256 + threadIdx.x;
    if (e >= EE) return;
    int r = ind[e], c = ind[EE + e];
    float v = nv[e];
    int p = atomicAdd(&cur[r], 1);
    col[p] = c; val[p] = v;
    int q = atomicAdd(&cur[c], 1);
    col[q] = r; val[q] = v;
}

// ---------- CSR SpMM v2: float4 per thread, unrolled gather ----------
// F floats per row; TPR = F/4 threads per row; block 256 threads.
template <int F, bool RELU>
__global__ __launch_bounds__(256) void spmm_csr(
    const int* __restrict__ rowptr, const int* __restrict__ col,
    const float* __restrict__ val,
    const float* __restrict__ x, float* __restrict__ out)
{
    const int TPR = F / 4;
    const int RPB = 256 / TPR;
    int row = blockIdx.x * RPB + threadIdx.x / TPR;
    int o = threadIdx.x % TPR;
    if (row >= NN) return;
    const float4* x4 = (const float4*)x;
    int p0 = rowptr[row], p1 = rowptr[row + 1];
    float4 a0 = {0,0,0,0}, a1 = {0,0,0,0}, a2 = {0,0,0,0}, a3 = {0,0,0,0};
    int j = p0;
    for (; j + 4 <= p1; j += 4) {
        int c0 = col[j], c1 = col[j+1], c2 = col[j+2], c3 = col[j+3];
        float v0 = val[j], v1 = val[j+1], v2 = val[j+2], v3 = val[j+3];
        float4 x0 = x4[(size_t)c0 * TPR + o];
        float4 x1 = x4[(size_t)c1 * TPR + o];
        float4 x2 = x4[(size_t)c2 * TPR + o];
        float4 x3 = x4[(size_t)c3 * TPR + o];
        a0 = fma4(v0, x0, a0); a1 = fma4(v1, x1, a1);
        a2 = fma4(v2, x2, a2); a3 = fma4(v3, x3, a3);
    }
    for (; j < p1; j++)
        a0 = fma4(val[j], x4[(size_t)col[j] * TPR + o], a0);
    float4 r;
    r.x = (a0.x + a1.x) + (a2.x + a3.x);
    r.y = (a0.y + a1.y) + (a2.y + a3.y);
    r.z = (a0.z + a1.z) + (a2.z + a3.z);
    r.w = (a0.w + a1.w) + (a2.w + a3.w);
    if (RELU) {
        r.x = fmaxf(r.x, 0.f); r.y = fmaxf(r.y, 0.f);
        r.z = fmaxf(r.z, 0.f); r.w = fmaxf(r.w, 0.f);
    }
    ((float4*)out)[(size_t)row * TPR + o] = r;
}

template <int F, bool RELU>
__global__ __launch_bounds__(256) void spmm_csr_fused(
    const int* __restrict__ rp1, const int* __restrict__ col1, const float* __restrict__ val1,
    const float* __restrict__ b1,
    const int* __restrict__ rp2, const int* __restrict__ col2, const float* __restrict__ val2,
    const float* __restrict__ b2,
    const float* __restrict__ x, float* __restrict__ out)
{
    const int TPR = F / 4;
    const int RPB = 256 / TPR;
    int row = blockIdx.x * RPB + threadIdx.x / TPR;
    int o = threadIdx.x % TPR;
    if (row >= NN) return;
    const float4* x4 = (const float4*)x;
    float4 s1, s2;
    {
        int p0 = rp1[row], p1 = rp1[row + 1];
        float4 a0 = {0,0,0,0}, a1 = {0,0,0,0}, a2 = {0,0,0,0}, a3 = {0,0,0,0};
        int j = p0;
        for (; j + 4 <= p1; j += 4) {
            int c0 = col1[j], c1 = col1[j+1], c2 = col1[j+2], c3 = col1[j+3];
            float v0 = val1[j], v1 = val1[j+1], v2 = val1[j+2], v3 = val1[j+3];
            float4 x0 = x4[(size_t)c0 * TPR + o];
            float4 x1 = x4[(size_t)c1 * TPR + o];
            float4 x2 = x4[(size_t)c2 * TPR + o];
            float4 x3 = x4[(size_t)c3 * TPR + o];
            a0 = fma4(v0, x0, a0); a1 = fma4(v1, x1, a1);
            a2 = fma4(v2, x2, a2); a3 = fma4(v3, x3, a3);
        }
        for (; j < p1; j++)
            a0 = fma4(val1[j], x4[(size_t)col1[j] * TPR + o], a0);
        s1.x = (a0.x + a1.x) + (a2.x + a3.x);
        s1.y = (a0.y + a1.y) + (a2.y + a3.y);
        s1.z = (a0.z + a1.z) + (a2.z + a3.z);
        s1.w = (a0.w + a1.w) + (a2.w + a3.w);
    }
    {
        int p0 = rp2[row], p1 = rp2[row + 1];
        float4 a0 = {0,0,0,0}, a1 = {0,0,0,0}, a2 = {0,0,0,0}, a3 = {0,0,0,0};
        int j = p0;
        for (; j + 4 <= p1; j += 4) {
            int c0 = col2[j], c1 = col2[j+1], c2 = col2[j+2], c3 = col2[j+3];
            float v0 = val2[j], v1 = val2[j+1], v2 = val2[j+2], v3 = val2[j+3];
            float4 x0 = x4[(size_t)c0 * TPR + o];
            float4 x1 = x4[(size_t)c1 * TPR + o];
            float4 x2 = x4[(size_t)c2 * TPR + o];
            float4 x3 = x4[(size_t)c3 * TPR + o];
            a0 = fma4(v0, x0, a0); a1 = fma4(v1, x1, a1);
            a2 = fma4(v2, x2, a2); a3 = fma4(v3, x3, a3);
        }
        for (; j < p1; j++)
            a0 = fma4(val2[j], x4[(size_t)col2[j] * TPR + o], a0);
        s2.x = (a0.x + a1.x) + (a2.x + a3.x);
        s2.y = (a0.y + a1.y) + (a2.y + a3.y);
        s2.z = (a0.z + a1.z) + (a2.z + a3.z);
        s2.w = (a0.w + a1.w) + (a2.w + a3.w);
    }
    float w1 = b1[row], w2 = b2[row];
    float4 r;
    r.x = w1 * s1.x + w2 * s2.x;
    r.y = w1 * s1.y + w2 * s2.y;
    r.z = w1 * s1.z + w2 * s2.z;
    r.w = w1 * s1.w + w2 * s2.w;
    if (RELU) {
        r.x = fmaxf(r.x, 0.f); r.y = fmaxf(r.y, 0.f);
        r.z = fmaxf(r.z, 0.f); r.w = fmaxf(r.w, 0.f);
    }
    ((float4*)out)[(size_t)row * TPR + o] = r;
}

// ---------- gen_view edge-score pipeline ----------
__global__ __launch_bounds__(256) void node_scores(
    const float* __restrict__ emb, const float* __restrict__ Wm,
    float* __restrict__ sa, float* __restrict__ sb)
{
    int node = blockIdx.x * 4 + threadIdx.x / 64;
    int lane = threadIdx.x % 64;
    if (node >= NN) return;
    float e = emb[(size_t)node * GH + lane];
    float va = e * Wm[lane];
    float vb = e * Wm[GH + lane];
#pragma unroll
    for (int off = 32; off; off >>= 1) {
        va += __shfl_down(va, off);
        vb += __shfl_down(vb, off);
    }
    if (lane == 0) { sa[node] = va; sb[node] = vb; }
}

__global__ void edge_score(const float* __restrict__ sa, const float* __restrict__ sb,
                           const float* __restrict__ bm, const int* __restrict__ ind,
                           float* __restrict__ ebuf, unsigned* __restrict__ rowmax)
{
    int e = blockIdx.x * 256 + threadIdx.x;
    if (e >= EE) return;
    int r = ind[e], c = ind[EE + e];
    float s = sa[r] + sb[c] + bm[0];
    ebuf[e] = s;
    atomicMax(&rowmax[r], enc_f32(s));
}

__global__ void edge_exp(const int* __restrict__ ind, float* __restrict__ ebuf,
                         const unsigned* __restrict__ rowmax, float* __restrict__ rowsum)
{
    int e = blockIdx.x * 256 + threadIdx.x;
    if (e >= EE) return;
    int r = ind[e];
    float ex = expf(ebuf[e] - dec_f32(rowmax[r]));
    ebuf[e] = ex;
    atomicAdd(&rowsum[r], ex);
}

__global__ void edge_nv(const int* __restrict__ ind, const float* __restrict__ ebuf,
                        const float* __restrict__ rowsum, const float* __restrict__ vals,
                        float coml, float* __restrict__ nv)
{
    int e = blockIdx.x * 256 + threadIdx.x;
    if (e >= EE) return;
    int r = ind[e];
    nv[e] = vals[e] + coml * ebuf[e] / rowsum[r];
}

// ---------- per-node softmax / logits / top2 weight ----------
__global__ void softmax16(const float* __restrict__ S, float* __restrict__ logits,
                          float* __restrict__ w)
{
    int node = blockIdx.x * 256 + threadIdx.x;
    if (node >= NN) return;
    float v[NCLS];
    float mx = -3.4e38f;
#pragma unroll
    for (int j = 0; j < NCLS; j++) { v[j] = S[(size_t)node * NCLS + j]; mx = fmaxf(mx, v[j]); }
    float s = 0.f;
#pragma unroll
    for (int j = 0; j < NCLS; j++) { v[j] = expf(v[j] - mx); s += v[j]; }
    float inv = 1.f / s;
    float fir = -1.f, sec = -1.f;
#pragma unroll
    for (int j = 0; j < NCLS; j++) {
        float p = v[j] * inv;
        logits[(size_t)node * NCLS + j] = logf(p + EPSc);
        if (p > fir) { sec = fir; fir = p; }
        else if (p > sec) { sec = p; }
    }
    if (w) w[node] = expf(ALPHAc * (LAMc * logf(fir + EPSc) + (1.f - LAMc) * logf(fir - sec + EPSc)));
}

__global__ void bweights(const float* __restrict__ w1, const float* __restrict__ w2,
                         float* __restrict__ b1, float* __restrict__ b2)
{
    int i = blockIdx.x * 256 + threadIdx.x;
    if (i >= NN) return;
    float a = w1[i], b = w2[i];
    float inv = 1.f / (a + b);
    b1[i] = a * inv;
    b2[i] = b * inv;
}

// ---------- projection head on batch rows + L2-normalize ----------
__global__ __launch_bounds__(128) void proj_norm(
    const float* __restrict__ G, const int* __restrict__ idx,
    const float* __restrict__ Wp1, const float* __restrict__ bp1,
    const float* __restrict__ Wp2, const float* __restrict__ bp2,
    float* __restrict__ z)
{
    __shared__ float g[MH], u[MH];
    __shared__ float red[2];
    int i = blockIdx.x, t = threadIdx.x;
    int node = idx[i];
    g[t] = G[(size_t)node * MH + t];
    __syncthreads();
    float acc = bp1[t];
    for (int k = 0; k < MH; k++) acc = fmaf(g[k], Wp1[k * MH + t], acc);
    u[t] = acc > 0.f ? acc : (expf(acc) - 1.f);
    __syncthreads();
    float acc2 = bp2[t];
    for (int k = 0; k < MH; k++) acc2 = fmaf(u[k], Wp2[k * MH + t], acc2);
    float sq = acc2 * acc2;
#pragma unroll
    for (int off = 32; off; off >>= 1) sq += __shfl_down(sq, off);
    if ((t & 63) == 0) red[t >> 6] = sq;
    __syncthreads();
    float nrm = sqrtf(red[0] + red[1]);
    z[(size_t)i * MH + t] = acc2 / nrm;
}

__global__ void contrast_reduce(const float* __restrict__ stats, float* __restrict__ out3)
{
    int p = blockIdx.x, t = threadIdx.x;
    const float* diag = stats + (size_t)p * 3 * BT;
    const float* rs = diag + BT;
    const float* cs = rs + BT;
    float s1 = 0.f, s2 = 0.f;
    for (int i = t; i < BT; i += 256) {
        float d = diag[i];
        s1 += logf(d / (rs[i] + EPSc) + EPSc);
        s2 += logf(d / (cs[i] + EPSc) + EPSc);
    }
#pragma unroll
    for (int off = 32; off; off >>= 1) { s1 += __shfl_down(s1, off); s2 += __shfl_down(s2, off); }
    __shared__ float sh[8];
    if ((t & 63) == 0) { sh[(t >> 6) * 2] = s1; sh[(t >> 6) * 2 + 1] = s2; }
    __syncthreads();
    if (t == 0) {
        float a = sh[0] + sh[2] + sh[4] + sh[6];
        float b = sh[1] + sh[3] + sh[5] + sh[7];
        out3[p] = 0.5f * (-a / BT - b / BT);
    }
}

// ---------- host ----------
extern "C" void kernel_launch(void* const* d_in, const int* in_sizes, int n_in,
                              void* d_out, int out_size, void* d_ws, size_t ws_size,
                              hipStream_t stream)
{
    const float* feat   = (const float*)d_in[0];
    const int*   ind1   = (const int*)d_in[1];
    const float* vals1  = (const float*)d_in[2];
    const int*   ind2   = (const int*)d_in[3];
    const float* vals2  = (const float*)d_in[4];
    const int*   idxb   = (const int*)d_in[5];
    const float* W_gen1 = (const float*)d_in[6];
    const float* Wm1    = (const float*)d_in[7];
    const float* bm1    = (const float*)d_in[8];
    const float* W_gen2 = (const float*)d_in[9];
    const float* Wm2    = (const float*)d_in[10];
    const float* bm2    = (const float*)d_in[11];
    const float* W1_v1  = (const float*)d_in[12];
    const float* W2_v1  = (const float*)d_in[13];
    const float* W1_v2  = (const float*)d_in[14];
    const float* W2_v2  = (const float*)d_in[15];
    const float* W1_v   = (const float*)d_in[16];
    const float* W2_v   = (const float*)d_in[17];
    const float* Wg     = (const float*)d_in[18];
    const float* Wg1    = (const float*)d_in[19];
    const float* Wg2    = (const float*)d_in[20];
    const float* Wp1    = (const float*)d_in[21];
    const float* bp1    = (const float*)d_in[22];
    const float* Wp2    = (const float*)d_in[23];
    const float* bp2    = (const float*)d_in[24];
    float* dout = (float*)d_out;

    float* ws = (float*)d_ws;
    size_t off = 0;
    auto alloc = [&](size_t n) { n = (n + 3) & ~(size_t)3; float* p = ws + off; off += n; return p; };
    auto alloc_s = [&](size_t n) { return (unsigned short*)alloc((n + 1) / 2); };

    float* bufP = alloc((size_t)NN * CH);
    float* bufQ = alloc((size_t)NN * CH);
    float* bufR = alloc((size_t)NN * NCLS);
    float* nv1  = alloc(EE);
    float* nv2  = alloc(EE);
    float* ebuf = alloc(EE);
    float* sa   = alloc(NN);
    float* sb   = alloc(NN);
    unsigned* rowmax = (unsigned*)alloc(NN);
    float* rowsum = alloc(NN);
    float* w1 = alloc(NN);
    float* w2 = alloc(NN);
    float* bb1 = alloc(NN);
    float* bb2 = alloc(NN);
    float* zbuf = alloc((size_t)3 * BT * MH);
    float* stats = alloc((size_t)3 * 3 * BT);
    int*   col_s1 = (int*)alloc(2 * (size_t)EE);
    float* val_s1 = alloc(2 * (size_t)EE);
    int*   col_s2 = (int*)alloc(2 * (size_t)EE);
    float* val_s2 = alloc(2 * (size_t)EE);
    int*   col_d1 = (int*)alloc(EE);
    float* val_d1 = alloc(EE);
    int*   col_d2 = (int*)alloc(EE);
    float* val_d2 = alloc(EE);
    int* rp_s1 = (int*)alloc(NN + 1);
    int* rp_s2 = (int*)alloc(NN + 1);
    int* rp_d1 = (int*)alloc(NN + 1);
    int* rp_d2 = (int*)alloc(NN + 1);
    int* cnt    = (int*)alloc(NN);
    int* cursor = (int*)alloc(NN);
    int* bsum   = (int*)alloc(64);
    unsigned short* feat_hi = alloc_s((size_t)NN * FD);
    unsigned short* feat_lo = alloc_s((size_t)NN * FD);
    unsigned short* q_hi = alloc_s((size_t)NN * CH);
    unsigned short* q_lo = alloc_s((size_t)NN * CH);
    unsigned short* z_hi = alloc_s((size_t)3 * BT * MH);
    unsigned short* z_lo = alloc_s((size_t)3 * BT * MH);
    auto wsplit = [&](const float* W, int K, int N, unsigned short*& hi, unsigned short*& lo) {
        hi = alloc_s((size_t)N * K);
        lo = alloc_s((size_t)N * K);
        splitT_bf16<<<(K * N + 255) / 256, 256, 0, stream>>>(W, hi, lo, K, N);
    };
    float* bufT = bufP;

    split_bf16<<<((long)NN * FD + 255) / 256, 256, 0, stream>>>(feat, feat_hi, feat_lo, (long)NN * FD);
    unsigned short *wg1h, *wg1l, *wg2h, *wg2l;
    unsigned short *w1v1h, *w1v1l, *w1v2h, *w1v2l, *w1vh, *w1vl;
    unsigned short *w2v1h, *w2v1l, *w2v2h, *w2v2l, *w2vh, *w2vl;
    unsigned short *wgh, *wgl, *wgg1h, *wgg1l, *wgg2h, *wgg2l;
    wsplit(W_gen1, FD, GH, wg1h, wg1l);
    wsplit(W_gen2, FD, GH, wg2h, wg2l);
    wsplit(W1_v1, FD, CH, w1v1h, w1v1l);
    wsplit(W1_v2, FD, CH, w1v2h, w1v2l);
    wsplit(W1_v, FD, CH, w1vh, w1vl);
    wsplit(W2_v1, CH, NCLS, w2v1h, w2v1l);
    wsplit(W2_v2, CH, NCLS, w2v2h, w2v2l);
    wsplit(W2_v, CH, NCLS, w2vh, w2vl);
    wsplit(Wg, FD, MH, wgh, wgl);
    wsplit(Wg1, FD, MH, wgg1h, wgg1l);
    wsplit(Wg2, FD, MH, wgg2h, wgg2l);

    const int NB = (NN + 1 + 1023) / 1024;
    auto scan = [&](int* rowptr) {
        scan_block<<<NB, 1024, 0, stream>>>(cnt, rowptr, bsum);
        scan_bsum<<<1, 64, 0, stream>>>(bsum, NB);
        scan_add<<<NB, 1024, 0, stream>>>(bsum, rowptr, cursor);
    };
    auto build_dir = [&](const int* ind, const float* vals, int* rowptr, int* col, float* val) {
        hipMemsetAsync(cnt, 0, NN * 4, stream);
        count_dir<<<(EE + 255) / 256, 256, 0, stream>>>(ind, cnt);
        scan(rowptr);
        scatter_dir<<<(EE + 255) / 256, 256, 0, stream>>>(ind, vals, cursor, col, val);
    };
    auto build_sym = [&](const int* ind, const float* nv, int* rowptr, int* col, float* val) {
        hipMemsetAsync(cnt, 0, NN * 4, stream);
        count_sym<<<(EE + 255) / 256, 256, 0, stream>>>(ind, cnt);
        scan(rowptr);
        scatter_sym<<<(EE + 255) / 256, 256, 0, stream>>>(ind, nv, cursor, col, val);
    };

    const int GB = (NN + 127) / 128;

    auto gen_view = [&](const int* ind, const float* vals,
                        const unsigned short* wh, const unsigned short* wl,
                        const float* Wm, const float* bm, float coml,
                        const int* rp_d, const int* col_d, const float* val_d, float* nv) {
        gemm_mfma<4><<<GB, 256, 0, stream>>>(feat_hi, feat_lo, wh, wl, bufP, NN, FD);
        spmm_csr<64, true><<<(NN + 15) / 16, 256, 0, stream>>>(rp_d, col_d, val_d, bufP, bufQ);
        node_scores<<<(NN + 3) / 4, 256, 0, stream>>>(bufQ, Wm, sa, sb);
        hipMemsetAsync(rowmax, 0, NN * 4, stream);
        hipMemsetAsync(rowsum, 0, NN * 4, stream);
        edge_score<<<(EE + 255) / 256, 256, 0, stream>>>(sa, sb, bm, ind, ebuf, rowmax);
        edge_exp<<<(EE + 255) / 256, 256, 0, stream>>>(ind, ebuf, rowmax, rowsum);
        edge_nv<<<(EE + 255) / 256, 256, 0, stream>>>(ind, ebuf, rowsum, vals, coml, nv);
    };

    auto run_spmm128 = [&](int mode, const float* x, float* out) {
        const int G = (NN + 7) / 8;
        if (mode == 0)
            spmm_csr<128, true><<<G, 256, 0, stream>>>(rp_s1, col_s1, val_s1, x, out);
        else if (mode == 1)
            spmm_csr<128, true><<<G, 256, 0, stream>>>(rp_s2, col_s2, val_s2, x, out);
        else
            spmm_csr_fused<128, true><<<G, 256, 0, stream>>>(
                rp_s1, col_s1, val_s1, bb1, rp_s2, col_s2, val_s2, bb2, x, out);
    };
    auto run_spmm16 = [&](int mode, const float* x, float* out) {
        const int G = (NN + 63) / 64;
        if (mode == 0)
            spmm_csr<16, false><<<G, 256, 0, stream>>>(rp_s1, col_s1, val_s1, x, out);
        else if (mode == 1)
            spmm_csr<16, false><<<G, 256, 0, stream>>>(rp_s2, col_s2, val_s2, x, out);
        else
            spmm_csr_fused<16, false><<<G, 256, 0, stream>>>(
                rp_s1, col_s1, val_s1, bb1, rp_s2, col_s2, val_s2, bb2, x, out);
    };

    auto branch = [&](int mode, const unsigned short* w1h, const unsigned short* w1l,
                      const unsigned short* w2h, const unsigned short* w2l,
                      float* logits, float* w) {
        gemm_mfma<8><<<GB, 256, 0, stream>>>(feat_hi, feat_lo, w1h, w1l, bufP, NN, FD);
        run_spmm128(mode, bufP, bufQ);
        split_bf16<<<((long)NN * CH + 255) / 256, 256, 0, stream>>>(bufQ, q_hi, q_lo, (long)NN * CH);
        gemm_mfma<1><<<GB, 256, 0, stream>>>(q_hi, q_lo, w2h, w2l, bufR, NN, CH);
        run_spmm16(mode, bufR, bufT);
        softmax16<<<(NN + 255) / 256, 256, 0, stream>>>(bufT, logits, w);
    };

    auto mi = [&](int mode, const unsigned short* wh, const unsigned short* wl, float* zout) {
        gemm_mfma<8><<<GB, 256, 0, stream>>>(feat_hi, feat_lo, wh, wl, bufP, NN, FD);
        run_spmm128(mode, bufP, bufQ);
        proj_norm<<<BT, 128, 0, stream>>>(bufQ, idxb, Wp1, bp1, Wp2, bp2, zout);
    };

    // ================= sequence =================
    build_dir(ind1, vals1, rp_d1, col_d1, val_d1);
    build_dir(ind2, vals2, rp_d2, col_d2, val_d2);

    gen_view(ind1, vals1, wg1h, wg1l, Wm1, bm1, CL1c, rp_d1, col_d1, val_d1, nv1);
    gen_view(ind2, vals2, wg2h, wg2l, Wm2, bm2, CL2c, rp_d2, col_d2, val_d2, nv2);

    build_sym(ind1, nv1, rp_s1, col_s1, val_s1);
    build_sym(ind2, nv2, rp_s2, col_s2, val_s2);

    branch(0, w1v1h, w1v1l, w2v1h, w2v1l, dout + (size_t)NN * NCLS, w1);
    branch(1, w1v2h, w1v2l, w2v2h, w2v2l, dout + 2 * (size_t)NN * NCLS, w2);
    bweights<<<(NN + 255) / 256, 256, 0, stream>>>(w1, w2, bb1, bb2);
    branch(2, w1vh, w1vl, w2vh, w2vl, dout, nullptr);

    mi(2, wgh, wgl, zbuf);
    mi(0, wgg1h, wgg1l, zbuf + (size_t)BT * MH);
    mi(1, wgg2h, wgg2l, zbuf + 2 * (size_t)BT * MH);

    split_bf16<<<((long)3 * BT * MH + 255) / 256, 256, 0, stream>>>(zbuf, z_hi, z_lo, (long)3 * BT * MH);
    hipMemsetAsync(stats, 0, (size_t)3 * 3 * BT * 4, stream);
    contrast_mfma<<<dim3(64, 64, 3), 256, 0, stream>>>(z_hi, z_lo, stats);
    contrast_reduce<<<3, 256, 0, stream>>>(stats, dout + (size_t)3 * NN * NCLS);
}

// Round 5
// 1338.359 us; speedup vs baseline: 3.7053x; 1.1836x over previous
//
#include <hip/hip_runtime.h>
#include <math.h>

#define NN 30000
#define EE 480000
#define FD 256
#define CH 128
#define NCLS 16
#define GH 64
#define MH 128
#define BT 4096
#define CL1c 0.5f
#define CL2c 0.5f
#define LAMc 0.5f
#define ALPHAc 1.0f
#define TAUc 0.5f
#define EPSc 1e-8f

typedef __attribute__((ext_vector_type(8))) short short8;
typedef __attribute__((ext_vector_type(4))) float f32x4;

// ---------- helpers ----------
__device__ __forceinline__ unsigned enc_f32(float f) {
    unsigned b = __float_as_uint(f);
    return (b & 0x80000000u) ? ~b : (b | 0x80000000u);
}
__device__ __forceinline__ float dec_f32(unsigned u) {
    return (u & 0x80000000u) ? __uint_as_float(u ^ 0x80000000u) : __uint_as_float(~u);
}
__device__ __forceinline__ unsigned short f2bf(float x) {
    unsigned b = __float_as_uint(x);
    unsigned r = b + 0x7FFFu + ((b >> 16) & 1u);
    return (unsigned short)(r >> 16);
}
__device__ __forceinline__ float bf2f(unsigned short h) {
    return __uint_as_float(((unsigned)h) << 16);
}
__device__ __forceinline__ float4 fma4(float s, float4 x, float4 a) {
    a.x = fmaf(s, x.x, a.x); a.y = fmaf(s, x.y, a.y);
    a.z = fmaf(s, x.z, a.z); a.w = fmaf(s, x.w, a.w);
    return a;
}

// ---------- bf16 hi/lo split ----------
__global__ void split_bf16(const float* __restrict__ x, unsigned short* __restrict__ hi,
                           unsigned short* __restrict__ lo, long n) {
    long i = (long)blockIdx.x * 256 + threadIdx.x;
    if (i >= n) return;
    float v = x[i];
    unsigned short h = f2bf(v);
    hi[i] = h;
    lo[i] = f2bf(v - bf2f(h));
}

__global__ void splitT_bf16(const float* __restrict__ B, unsigned short* __restrict__ hi,
                            unsigned short* __restrict__ lo, int K, int N) {
    int i = blockIdx.x * 256 + threadIdx.x;
    if (i >= K * N) return;
    int k = i / N, n = i % N;
    float v = B[i];
    unsigned short h = f2bf(v);
    hi[(size_t)n * K + k] = h;
    lo[(size_t)n * K + k] = f2bf(v - bf2f(h));
}

// ---------- MFMA GEMM: C[M x NT*16] = A[M x K] @ B (BT given as [N][K]) ----------
template <int NT>
__global__ __launch_bounds__(256) void gemm_mfma(
    const unsigned short* __restrict__ Ahi, const unsigned short* __restrict__ Alo,
    const unsigned short* __restrict__ BThi, const unsigned short* __restrict__ BTlo,
    float* __restrict__ C, int M, int K)
{
    __shared__ unsigned short Ah[128 * 40], Al[128 * 40];
    __shared__ unsigned short Bh[NT * 16 * 40], Bl[NT * 16 * 40];
    int t = threadIdx.x;
    int w = t >> 6, l = t & 63;
    int lane = l & 15, quad = l >> 4;
    int row0 = blockIdx.x * 128;
    f32x4 acc[2][NT];
#pragma unroll
    for (int s = 0; s < 2; s++)
#pragma unroll
        for (int n = 0; n < NT; n++) acc[s][n] = (f32x4)(0.f);

    int ar = t >> 1, ako = (t & 1) << 4;
    int nkc = K >> 5;
    for (int kc = 0; kc < nkc; kc++) {
        int kb = kc << 5;
        {
            int gr = row0 + ar;
            float4 h0, h1, l0, l1;
            if (gr < M) {
                const float4* pH = (const float4*)&Ahi[(size_t)gr * K + kb + ako];
                const float4* pL = (const float4*)&Alo[(size_t)gr * K + kb + ako];
                h0 = pH[0]; h1 = pH[1]; l0 = pL[0]; l1 = pL[1];
            } else {
                h0 = h1 = l0 = l1 = make_float4(0.f, 0.f, 0.f, 0.f);
            }
            float4* dH = (float4*)&Ah[ar * 40 + ako];
            dH[0] = h0; dH[1] = h1;
            float4* dL = (float4*)&Al[ar * 40 + ako];
            dL[0] = l0; dL[1] = l1;
        }
        if (ar < NT * 16) {
            const float4* pH = (const float4*)&BThi[(size_t)ar * K + kb + ako];
            const float4* pL = (const float4*)&BTlo[(size_t)ar * K + kb + ako];
            float4 h0 = pH[0], h1 = pH[1], l0 = pL[0], l1 = pL[1];
            float4* dH = (float4*)&Bh[ar * 40 + ako];
            dH[0] = h0; dH[1] = h1;
            float4* dL = (float4*)&Bl[ar * 40 + ako];
            dL[0] = l0; dL[1] = l1;
        }
        __syncthreads();
        short8 aH[2], aL[2];
#pragma unroll
        for (int s = 0; s < 2; s++) {
            int r = w * 32 + s * 16 + lane;
            aH[s] = *(const short8*)&Ah[r * 40 + quad * 8];
            aL[s] = *(const short8*)&Al[r * 40 + quad * 8];
        }
#pragma unroll
        for (int n = 0; n < NT; n++) {
            int r = n * 16 + lane;
            short8 bH = *(const short8*)&Bh[r * 40 + quad * 8];
            short8 bL = *(const short8*)&Bl[r * 40 + quad * 8];
#pragma unroll
            for (int s = 0; s < 2; s++) {
                acc[s][n] = __builtin_amdgcn_mfma_f32_16x16x32_bf16(aH[s], bH, acc[s][n], 0, 0, 0);
                acc[s][n] = __builtin_amdgcn_mfma_f32_16x16x32_bf16(aH[s], bL, acc[s][n], 0, 0, 0);
                acc[s][n] = __builtin_amdgcn_mfma_f32_16x16x32_bf16(aL[s], bH, acc[s][n], 0, 0, 0);
            }
        }
        __syncthreads();
    }
    const int N = NT * 16;
#pragma unroll
    for (int s = 0; s < 2; s++) {
        int rb = row0 + w * 32 + s * 16 + quad * 4;
#pragma unroll
        for (int reg = 0; reg < 4; reg++) {
            int gr = rb + reg;
            if (gr >= M) continue;
#pragma unroll
            for (int n = 0; n < NT; n++)
                C[(size_t)gr * N + n * 16 + lane] = acc[s][n][reg];
        }
    }
}

// ---------- contrast: direct-from-L2 bf16 MFMA, no LDS staging ----------
// stats[p]: diag[BT], rowsum[BT], colsum[BT] of exp(2 * za.zb^T)
__global__ __launch_bounds__(256) void contrast_direct(
    const unsigned short* __restrict__ z16, float* __restrict__ stats)
{
    int p = blockIdx.z;
    int pa = (p == 2) ? 1 : 0;
    int pb = (p == 0) ? 1 : 2;
    const unsigned short* A = z16 + (size_t)pa * BT * MH;
    const unsigned short* B = z16 + (size_t)pb * BT * MH;
    float* diag = stats + (size_t)p * 3 * BT;
    float* rs = diag + BT;
    float* cs = rs + BT;
    int t = threadIdx.x;
    int w = t >> 6, l = t & 63, m = l & 15, quad = l >> 4;
    int i0 = blockIdx.y * 128, j0 = blockIdx.x * 128;

    // hoist A fragments: rows i0 + w*32 + s*16 + m, k = kc*32 + quad*8
    short8 afr[2][4];
#pragma unroll
    for (int s = 0; s < 2; s++) {
        const unsigned short* arow = &A[(size_t)(i0 + w * 32 + s * 16 + m) * MH + quad * 8];
#pragma unroll
        for (int kc = 0; kc < 4; kc++)
            afr[s][kc] = *(const short8*)(arow + kc * 32);
    }
    f32x4 acc[2][8];
#pragma unroll
    for (int s = 0; s < 2; s++)
#pragma unroll
        for (int n = 0; n < 8; n++) acc[s][n] = (f32x4)(0.f);

#pragma unroll
    for (int kc = 0; kc < 4; kc++) {
#pragma unroll
        for (int n = 0; n < 8; n++) {
            short8 bf = *(const short8*)&B[(size_t)(j0 + n * 16 + m) * MH + kc * 32 + quad * 8];
            acc[0][n] = __builtin_amdgcn_mfma_f32_16x16x32_bf16(afr[0][kc], bf, acc[0][n], 0, 0, 0);
            acc[1][n] = __builtin_amdgcn_mfma_f32_16x16x32_bf16(afr[1][kc], bf, acc[1][n], 0, 0, 0);
        }
    }

    // epilogue
    float colp[8];
#pragma unroll
    for (int n = 0; n < 8; n++) colp[n] = 0.f;
#pragma unroll
    for (int s = 0; s < 2; s++) {
        int rbase = i0 + w * 32 + s * 16 + quad * 4;
#pragma unroll
        for (int reg = 0; reg < 4; reg++) {
            float rsum = 0.f;
            int gi = rbase + reg;
#pragma unroll
            for (int n = 0; n < 8; n++) {
                float mv = expf(acc[s][n][reg] * 2.0f);
                rsum += mv;
                colp[n] += mv;
                int gj = j0 + n * 16 + m;
                if (gi == gj) diag[gi] = mv;
            }
            rsum += __shfl_xor(rsum, 1); rsum += __shfl_xor(rsum, 2);
            rsum += __shfl_xor(rsum, 4); rsum += __shfl_xor(rsum, 8);
            if (m == 0) atomicAdd(&rs[gi], rsum);
        }
    }
    __shared__ float scol[128];
    if (t < 128) scol[t] = 0.f;
    __syncthreads();
#pragma unroll
    for (int n = 0; n < 8; n++) {
        float v = colp[n];
        v += __shfl_xor(v, 16); v += __shfl_xor(v, 32);
        if (quad == (n & 3)) atomicAdd(&scol[n * 16 + m], v);
    }
    __syncthreads();
    if (t < 128) atomicAdd(&cs[j0 + t], scol[t]);
}

// ---------- CSR build ----------
__global__ void count_dir(const int* __restrict__ ind, int* __restrict__ cnt) {
    int e = blockIdx.x * 256 + threadIdx.x;
    if (e >= EE) return;
    atomicAdd(&cnt[ind[e]], 1);
}
__global__ void count_sym(const int* __restrict__ ind, int* __restrict__ cnt) {
    int e = blockIdx.x * 256 + threadIdx.x;
    if (e >= EE) return;
    atomicAdd(&cnt[ind[e]], 1);
    atomicAdd(&cnt[ind[EE + e]], 1);
}
__global__ __launch_bounds__(1024) void scan_block(const int* __restrict__ cnt,
                                                   int* __restrict__ rowptr,
                                                   int* __restrict__ bsum) {
    __shared__ int tmp[1024];
    int t = threadIdx.x;
    int i = blockIdx.x * 1024 + t;
    int v = (i < NN) ? cnt[i] : 0;
    tmp[t] = v;
    __syncthreads();
    for (int off = 1; off < 1024; off <<= 1) {
        int add = (t >= off) ? tmp[t - off] : 0;
        __syncthreads();
        tmp[t] += add;
        __syncthreads();
    }
    if (i <= NN) rowptr[i] = tmp[t] - v;
    if (t == 1023) bsum[blockIdx.x] = tmp[1023];
}
__global__ void scan_bsum(int* __restrict__ bsum, int nb) {
    int t = threadIdx.x;
    int orig = (t < nb) ? bsum[t] : 0;
    int v = orig;
    for (int off = 1; off < 64; off <<= 1) {
        int u = __shfl_up(v, off);
        if (t >= off) v += u;
    }
    if (t < nb) bsum[t] = v - orig;
}
__global__ void scan_add(const int* __restrict__ bsum, int* __restrict__ rowptr,
                         int* __restrict__ cursor) {
    int i = blockIdx.x * 1024 + threadIdx.x;
    if (i <= NN) {
        int r = rowptr[i] + bsum[blockIdx.x];
        rowptr[i] = r;
        if (i < NN) cursor[i] = r;
    }
}
__global__ void scatter_dir(const int* __restrict__ ind, const float* __restrict__ vals,
                            int* __restrict__ cur, int* __restrict__ col,
                            float* __restrict__ val) {
    int e = blockIdx.x * 256 + threadIdx.x;
    if (e >= EE) return;
    int r = ind[e];
    int p = atomicAdd(&cur[r], 1);
    col[p] = ind[EE + e];
    val[p] = vals[e];
}
__global__ void scatter_sym(const int* __restrict__ ind, const float* __restrict__ nv,
                            int* __restrict__ cur, int* __restrict__ col,
                            float* __restrict__ val) {
    int e = blockIdx.x * 256 + threadIdx.x;
    if (e >= EE) return;
    int r = ind[e], c = ind[EE + e];
    float v = nv[e];
    int p = atomicAdd(&cur[r], 1);
    col[p] = c; val[p] = v;
    int q = atomicAdd(&cur[c], 1);
    col[q] = r; val[q] = v;
}

// ---------- CSR SpMM: float4 per thread, unrolled gather ----------
template <int F, bool RELU>
__global__ __launch_bounds__(256) void spmm_csr(
    const int* __restrict__ rowptr, const int* __restrict__ col,
    const float* __restrict__ val,
    const float* __restrict__ x, float* __restrict__ out)
{
    const int TPR = F / 4;
    const int RPB = 256 / TPR;
    int row = blockIdx.x * RPB + threadIdx.x / TPR;
    int o = threadIdx.x % TPR;
    if (row >= NN) return;
    const float4* x4 = (const float4*)x;
    int p0 = rowptr[row], p1 = rowptr[row + 1];
    float4 a0 = {0,0,0,0}, a1 = {0,0,0,0}, a2 = {0,0,0,0}, a3 = {0,0,0,0};
    int j = p0;
    for (; j + 4 <= p1; j += 4) {
        int c0 = col[j], c1 = col[j+1], c2 = col[j+2], c3 = col[j+3];
        float v0 = val[j], v1 = val[j+1], v2 = val[j+2], v3 = val[j+3];
        float4 x0 = x4[(size_t)c0 * TPR + o];
        float4 x1 = x4[(size_t)c1 * TPR + o];
        float4 x2 = x4[(size_t)c2 * TPR + o];
        float4 x3 = x4[(size_t)c3 * TPR + o];
        a0 = fma4(v0, x0, a0); a1 = fma4(v1, x1, a1);
        a2 = fma4(v2, x2, a2); a3 = fma4(v3, x3, a3);
    }
    for (; j < p1; j++)
        a0 = fma4(val[j], x4[(size_t)col[j] * TPR + o], a0);
    float4 r;
    r.x = (a0.x + a1.x) + (a2.x + a3.x);
    r.y = (a0.y + a1.y) + (a2.y + a3.y);
    r.z = (a0.z + a1.z) + (a2.z + a3.z);
    r.w = (a0.w + a1.w) + (a2.w + a3.w);
    if (RELU) {
        r.x = fmaxf(r.x, 0.f); r.y = fmaxf(r.y, 0.f);
        r.z = fmaxf(r.z, 0.f); r.w = fmaxf(r.w, 0.f);
    }
    ((float4*)out)[(size_t)row * TPR + o] = r;
}

template <int F, bool RELU>
__global__ __launch_bounds__(256) void spmm_csr_fused(
    const int* __restrict__ rp1, const int* __restrict__ col1, const float* __restrict__ val1,
    const float* __restrict__ b1,
    const int* __restrict__ rp2, const int* __restrict__ col2, const float* __restrict__ val2,
    const float* __restrict__ b2,
    const float* __restrict__ x, float* __restrict__ out)
{
    const int TPR = F / 4;
    const int RPB = 256 / TPR;
    int row = blockIdx.x * RPB + threadIdx.x / TPR;
    int o = threadIdx.x % TPR;
    if (row >= NN) return;
    const float4* x4 = (const float4*)x;
    float4 s1, s2;
    {
        int p0 = rp1[row], p1 = rp1[row + 1];
        float4 a0 = {0,0,0,0}, a1 = {0,0,0,0}, a2 = {0,0,0,0}, a3 = {0,0,0,0};
        int j = p0;
        for (; j + 4 <= p1; j += 4) {
            int c0 = col1[j], c1 = col1[j+1], c2 = col1[j+2], c3 = col1[j+3];
            float v0 = val1[j], v1 = val1[j+1], v2 = val1[j+2], v3 = val1[j+3];
            float4 x0 = x4[(size_t)c0 * TPR + o];
            float4 x1 = x4[(size_t)c1 * TPR + o];
            float4 x2 = x4[(size_t)c2 * TPR + o];
            float4 x3 = x4[(size_t)c3 * TPR + o];
            a0 = fma4(v0, x0, a0); a1 = fma4(v1, x1, a1);
            a2 = fma4(v2, x2, a2); a3 = fma4(v3, x3, a3);
        }
        for (; j < p1; j++)
            a0 = fma4(val1[j], x4[(size_t)col1[j] * TPR + o], a0);
        s1.x = (a0.x + a1.x) + (a2.x + a3.x);
        s1.y = (a0.y + a1.y) + (a2.y + a3.y);
        s1.z = (a0.z + a1.z) + (a2.z + a3.z);
        s1.w = (a0.w + a1.w) + (a2.w + a3.w);
    }
    {
        int p0 = rp2[row], p1 = rp2[row + 1];
        float4 a0 = {0,0,0,0}, a1 = {0,0,0,0}, a2 = {0,0,0,0}, a3 = {0,0,0,0};
        int j = p0;
        for (; j + 4 <= p1; j += 4) {
            int c0 = col2[j], c1 = col2[j+1], c2 = col2[j+2], c3 = col2[j+3];
            float v0 = val2[j], v1 = val2[j+1], v2 = val2[j+2], v3 = val2[j+3];
            float4 x0 = x4[(size_t)c0 * TPR + o];
            float4 x1 = x4[(size_t)c1 * TPR + o];
            float4 x2 = x4[(size_t)c2 * TPR + o];
            float4 x3 = x4[(size_t)c3 * TPR + o];
            a0 = fma4(v0, x0, a0); a1 = fma4(v1, x1, a1);
            a2 = fma4(v2, x2, a2); a3 = fma4(v3, x3, a3);
        }
        for (; j < p1; j++)
            a0 = fma4(val2[j], x4[(size_t)col2[j] * TPR + o], a0);
        s2.x = (a0.x + a1.x) + (a2.x + a3.x);
        s2.y = (a0.y + a1.y) + (a2.y + a3.y);
        s2.z = (a0.z + a1.z) + (a2.z + a3.z);
        s2.w = (a0.w + a1.w) + (a2.w + a3.w);
    }
    float w1 = b1[row], w2 = b2[row];
    float4 r;
    r.x = w1 * s1.x + w2 * s2.x;
    r.y = w1 * s1.y + w2 * s2.y;
    r.z = w1 * s1.z + w2 * s2.z;
    r.w = w1 * s1.w + w2 * s2.w;
    if (RELU) {
        r.x = fmaxf(r.x, 0.f); r.y = fmaxf(r.y, 0.f);
        r.z = fmaxf(r.z, 0.f); r.w = fmaxf(r.w, 0.f);
    }
    ((float4*)out)[(size_t)row * TPR + o] = r;
}

// ---------- batch-rows variants: compute only rows[] (compact output) ----------
__global__ __launch_bounds__(256) void spmm_csr_rows128(
    const int* __restrict__ rowptr, const int* __restrict__ col,
    const float* __restrict__ val, const int* __restrict__ rows,
    const float* __restrict__ x, float* __restrict__ out)
{
    int ri = blockIdx.x * 8 + threadIdx.x / 32;
    int o = threadIdx.x % 32;
    if (ri >= BT) return;
    int row = rows[ri];
    const float4* x4 = (const float4*)x;
    int p0 = rowptr[row], p1 = rowptr[row + 1];
    float4 a0 = {0,0,0,0}, a1 = {0,0,0,0}, a2 = {0,0,0,0}, a3 = {0,0,0,0};
    int j = p0;
    for (; j + 4 <= p1; j += 4) {
        int c0 = col[j], c1 = col[j+1], c2 = col[j+2], c3 = col[j+3];
        float v0 = val[j], v1 = val[j+1], v2 = val[j+2], v3 = val[j+3];
        a0 = fma4(v0, x4[(size_t)c0 * 32 + o], a0);
        a1 = fma4(v1, x4[(size_t)c1 * 32 + o], a1);
        a2 = fma4(v2, x4[(size_t)c2 * 32 + o], a2);
        a3 = fma4(v3, x4[(size_t)c3 * 32 + o], a3);
    }
    for (; j < p1; j++)
        a0 = fma4(val[j], x4[(size_t)col[j] * 32 + o], a0);
    float4 r;
    r.x = fmaxf((a0.x + a1.x) + (a2.x + a3.x), 0.f);
    r.y = fmaxf((a0.y + a1.y) + (a2.y + a3.y), 0.f);
    r.z = fmaxf((a0.z + a1.z) + (a2.z + a3.z), 0.f);
    r.w = fmaxf((a0.w + a1.w) + (a2.w + a3.w), 0.f);
    ((float4*)out)[(size_t)ri * 32 + o] = r;
}

__global__ __launch_bounds__(256) void spmm_csr_fused_rows128(
    const int* __restrict__ rp1, const int* __restrict__ col1, const float* __restrict__ val1,
    const float* __restrict__ b1,
    const int* __restrict__ rp2, const int* __restrict__ col2, const float* __restrict__ val2,
    const float* __restrict__ b2,
    const int* __restrict__ rows,
    const float* __restrict__ x, float* __restrict__ out)
{
    int ri = blockIdx.x * 8 + threadIdx.x / 32;
    int o = threadIdx.x % 32;
    if (ri >= BT) return;
    int row = rows[ri];
    const float4* x4 = (const float4*)x;
    float4 s1 = {0,0,0,0}, s2 = {0,0,0,0};
    {
        int p0 = rp1[row], p1 = rp1[row + 1];
        float4 a0 = {0,0,0,0}, a1 = {0,0,0,0}, a2 = {0,0,0,0}, a3 = {0,0,0,0};
        int j = p0;
        for (; j + 4 <= p1; j += 4) {
            a0 = fma4(val1[j],   x4[(size_t)col1[j]   * 32 + o], a0);
            a1 = fma4(val1[j+1], x4[(size_t)col1[j+1] * 32 + o], a1);
            a2 = fma4(val1[j+2], x4[(size_t)col1[j+2] * 32 + o], a2);
            a3 = fma4(val1[j+3], x4[(size_t)col1[j+3] * 32 + o], a3);
        }
        for (; j < p1; j++)
            a0 = fma4(val1[j], x4[(size_t)col1[j] * 32 + o], a0);
        s1.x = (a0.x + a1.x) + (a2.x + a3.x);
        s1.y = (a0.y + a1.y) + (a2.y + a3.y);
        s1.z = (a0.z + a1.z) + (a2.z + a3.z);
        s1.w = (a0.w + a1.w) + (a2.w + a3.w);
    }
    {
        int p0 = rp2[row], p1 = rp2[row + 1];
        float4 a0 = {0,0,0,0}, a1 = {0,0,0,0}, a2 = {0,0,0,0}, a3 = {0,0,0,0};
        int j = p0;
        for (; j + 4 <= p1; j += 4) {
            a0 = fma4(val2[j],   x4[(size_t)col2[j]   * 32 + o], a0);
            a1 = fma4(val2[j+1], x4[(size_t)col2[j+1] * 32 + o], a1);
            a2 = fma4(val2[j+2], x4[(size_t)col2[j+2] * 32 + o], a2);
            a3 = fma4(val2[j+3], x4[(size_t)col2[j+3] * 32 + o], a3);
        }
        for (; j < p1; j++)
            a0 = fma4(val2[j], x4[(size_t)col2[j] * 32 + o], a0);
        s2.x = (a0.x + a1.x) + (a2.x + a3.x);
        s2.y = (a0.y + a1.y) + (a2.y + a3.y);
        s2.z = (a0.z + a1.z) + (a2.z + a3.z);
        s2.w = (a0.w + a1.w) + (a2.w + a3.w);
    }
    float w1 = b1[row], w2 = b2[row];
    float4 r;
    r.x = fmaxf(w1 * s1.x + w2 * s2.x, 0.f);
    r.y = fmaxf(w1 * s1.y + w2 * s2.y, 0.f);
    r.z = fmaxf(w1 * s1.z + w2 * s2.z, 0.f);
    r.w = fmaxf(w1 * s1.w + w2 * s2.w, 0.f);
    ((float4*)out)[(size_t)ri * 32 + o] = r;
}

// ---------- gen_view edge-score pipeline ----------
__global__ __launch_bounds__(256) void node_scores(
    const float* __restrict__ emb, const float* __restrict__ Wm,
    float* __restrict__ sa, float* __restrict__ sb)
{
    int node = blockIdx.x * 4 + threadIdx.x / 64;
    int lane = threadIdx.x % 64;
    if (node >= NN) return;
    float e = emb[(size_t)node * GH + lane];
    float va = e * Wm[lane];
    float vb = e * Wm[GH + lane];
#pragma unroll
    for (int off = 32; off; off >>= 1) {
        va += __shfl_down(va, off);
        vb += __shfl_down(vb, off);
    }
    if (lane == 0) { sa[node] = va; sb[node] = vb; }
}

__global__ void edge_score(const float* __restrict__ sa, const float* __restrict__ sb,
                           const float* __restrict__ bm, const int* __restrict__ ind,
                           float* __restrict__ ebuf, unsigned* __restrict__ rowmax)
{
    int e = blockIdx.x * 256 + threadIdx.x;
    if (e >= EE) return;
    int r = ind[e], c = ind[EE + e];
    float s = sa[r] + sb[c] + bm[0];
    ebuf[e] = s;
    atomicMax(&rowmax[r], enc_f32(s));
}

__global__ void edge_exp(const int* __restrict__ ind, float* __restrict__ ebuf,
                         const unsigned* __restrict__ rowmax, float* __restrict__ rowsum)
{
    int e = blockIdx.x * 256 + threadIdx.x;
    if (e >= EE) return;
    int r = ind[e];
    float ex = expf(ebuf[e] - dec_f32(rowmax[r]));
    ebuf[e] = ex;
    atomicAdd(&rowsum[r], ex);
}

__global__ void edge_nv(const int* __restrict__ ind, const float* __restrict__ ebuf,
                        const float* __restrict__ rowsum, const float* __restrict__ vals,
                        float coml, float* __restrict__ nv)
{
    int e = blockIdx.x * 256 + threadIdx.x;
    if (e >= EE) return;
    int r = ind[e];
    nv[e] = vals[e] + coml * ebuf[e] / rowsum[r];
}

// ---------- per-node softmax / logits / top2 weight ----------
__global__ void softmax16(const float* __restrict__ S, float* __restrict__ logits,
                          float* __restrict__ w)
{
    int node = blockIdx.x * 256 + threadIdx.x;
    if (node >= NN) return;
    float v[NCLS];
    float mx = -3.4e38f;
#pragma unroll
    for (int j = 0; j < NCLS; j++) { v[j] = S[(size_t)node * NCLS + j]; mx = fmaxf(mx, v[j]); }
    float s = 0.f;
#pragma unroll
    for (int j = 0; j < NCLS; j++) { v[j] = expf(v[j] - mx); s += v[j]; }
    float inv = 1.f / s;
    float fir = -1.f, sec = -1.f;
#pragma unroll
    for (int j = 0; j < NCLS; j++) {
        float p = v[j] * inv;
        logits[(size_t)node * NCLS + j] = logf(p + EPSc);
        if (p > fir) { sec = fir; fir = p; }
        else if (p > sec) { sec = p; }
    }
    if (w) w[node] = expf(ALPHAc * (LAMc * logf(fir + EPSc) + (1.f - LAMc) * logf(fir - sec + EPSc)));
}

__global__ void bweights(const float* __restrict__ w1, const float* __restrict__ w2,
                         float* __restrict__ b1, float* __restrict__ b2)
{
    int i = blockIdx.x * 256 + threadIdx.x;
    if (i >= NN) return;
    float a = w1[i], b = w2[i];
    float inv = 1.f / (a + b);
    b1[i] = a * inv;
    b2[i] = b * inv;
}

// ---------- projection head (compact input) + L2-normalize, bf16 out ----------
__global__ __launch_bounds__(128) void proj_norm(
    const float* __restrict__ G,
    const float* __restrict__ Wp1, const float* __restrict__ bp1,
    const float* __restrict__ Wp2, const float* __restrict__ bp2,
    unsigned short* __restrict__ z16)
{
    __shared__ float g[MH], u[MH];
    __shared__ float red[2];
    int i = blockIdx.x, t = threadIdx.x;
    g[t] = G[(size_t)i * MH + t];
    __syncthreads();
    float acc = bp1[t];
    for (int k = 0; k < MH; k++) acc = fmaf(g[k], Wp1[k * MH + t], acc);
    u[t] = acc > 0.f ? acc : (expf(acc) - 1.f);
    __syncthreads();
    float acc2 = bp2[t];
    for (int k = 0; k < MH; k++) acc2 = fmaf(u[k], Wp2[k * MH + t], acc2);
    float sq = acc2 * acc2;
#pragma unroll
    for (int off = 32; off; off >>= 1) sq += __shfl_down(sq, off);
    if ((t & 63) == 0) red[t >> 6] = sq;
    __syncthreads();
    float nrm = sqrtf(red[0] + red[1]);
    z16[(size_t)i * MH + t] = f2bf(acc2 / nrm);
}

__global__ void contrast_reduce(const float* __restrict__ stats, float* __restrict__ out3)
{
    int p = blockIdx.x, t = threadIdx.x;
    const float* diag = stats + (size_t)p * 3 * BT;
    const float* rs = diag + BT;
    const float* cs = rs + BT;
    float s1 = 0.f, s2 = 0.f;
    for (int i = t; i < BT; i += 256) {
        float d = diag[i];
        s1 += logf(d / (rs[i] + EPSc) + EPSc);
        s2 += logf(d / (cs[i] + EPSc) + EPSc);
    }
#pragma unroll
    for (int off = 32; off; off >>= 1) { s1 += __shfl_down(s1, off); s2 += __shfl_down(s2, off); }
    __shared__ float sh[8];
    if ((t & 63) == 0) { sh[(t >> 6) * 2] = s1; sh[(t >> 6) * 2 + 1] = s2; }
    __syncthreads();
    if (t == 0) {
        float a = sh[0] + sh[2] + sh[4] + sh[6];
        float b = sh[1] + sh[3] + sh[5] + sh[7];
        out3[p] = 0.5f * (-a / BT - b / BT);
    }
}

// ---------- host ----------
extern "C" void kernel_launch(void* const* d_in, const int* in_sizes, int n_in,
                              void* d_out, int out_size, void* d_ws, size_t ws_size,
                              hipStream_t stream)
{
    const float* feat   = (const float*)d_in[0];
    const int*   ind1   = (const int*)d_in[1];
    const float* vals1  = (const float*)d_in[2];
    const int*   ind2   = (const int*)d_in[3];
    const float* vals2  = (const float*)d_in[4];
    const int*   idxb   = (const int*)d_in[5];
    const float* W_gen1 = (const float*)d_in[6];
    const float* Wm1    = (const float*)d_in[7];
    const float* bm1    = (const float*)d_in[8];
    const float* W_gen2 = (const float*)d_in[9];
    const float* Wm2    = (const float*)d_in[10];
    const float* bm2    = (const float*)d_in[11];
    const float* W1_v1  = (const float*)d_in[12];
    const float* W2_v1  = (const float*)d_in[13];
    const float* W1_v2  = (const float*)d_in[14];
    const float* W2_v2  = (const float*)d_in[15];
    const float* W1_v   = (const float*)d_in[16];
    const float* W2_v   = (const float*)d_in[17];
    const float* Wg     = (const float*)d_in[18];
    const float* Wg1    = (const float*)d_in[19];
    const float* Wg2    = (const float*)d_in[20];
    const float* Wp1    = (const float*)d_in[21];
    const float* bp1    = (const float*)d_in[22];
    const float* Wp2    = (const float*)d_in[23];
    const float* bp2    = (const float*)d_in[24];
    float* dout = (float*)d_out;

    float* ws = (float*)d_ws;
    size_t off = 0;
    auto alloc = [&](size_t n) { n = (n + 3) & ~(size_t)3; float* p = ws + off; off += n; return p; };
    auto alloc_s = [&](size_t n) { return (unsigned short*)alloc((n + 1) / 2); };

    float* bufP = alloc((size_t)NN * CH);
    float* bufQ = alloc((size_t)NN * CH);
    float* bufR = alloc((size_t)NN * NCLS);
    float* nv1  = alloc(EE);
    float* nv2  = alloc(EE);
    float* ebuf = alloc(EE);
    float* sa   = alloc(NN);
    float* sb   = alloc(NN);
    unsigned* rowmax = (unsigned*)alloc(NN);
    float* rowsum = alloc(NN);
    float* w1 = alloc(NN);
    float* w2 = alloc(NN);
    float* bb1 = alloc(NN);
    float* bb2 = alloc(NN);
    float* stats = alloc((size_t)3 * 3 * BT);
    int*   col_s1 = (int*)alloc(2 * (size_t)EE);
    float* val_s1 = alloc(2 * (size_t)EE);
    int*   col_s2 = (int*)alloc(2 * (size_t)EE);
    float* val_s2 = alloc(2 * (size_t)EE);
    int*   col_d1 = (int*)alloc(EE);
    float* val_d1 = alloc(EE);
    int*   col_d2 = (int*)alloc(EE);
    float* val_d2 = alloc(EE);
    int* rp_s1 = (int*)alloc(NN + 1);
    int* rp_s2 = (int*)alloc(NN + 1);
    int* rp_d1 = (int*)alloc(NN + 1);
    int* rp_d2 = (int*)alloc(NN + 1);
    int* cnt    = (int*)alloc(NN);
    int* cursor = (int*)alloc(NN);
    int* bsum   = (int*)alloc(64);
    unsigned short* feat_hi = alloc_s((size_t)NN * FD);
    unsigned short* feat_lo = alloc_s((size_t)NN * FD);
    unsigned short* q_hi = alloc_s((size_t)NN * CH);
    unsigned short* q_lo = alloc_s((size_t)NN * CH);
    unsigned short* z16 = alloc_s((size_t)3 * BT * MH);
    auto wsplit = [&](const float* W, int K, int N, unsigned short*& hi, unsigned short*& lo) {
        hi = alloc_s((size_t)N * K);
        lo = alloc_s((size_t)N * K);
        splitT_bf16<<<(K * N + 255) / 256, 256, 0, stream>>>(W, hi, lo, K, N);
    };
    float* bufT = bufP;

    split_bf16<<<((long)NN * FD + 255) / 256, 256, 0, stream>>>(feat, feat_hi, feat_lo, (long)NN * FD);
    unsigned short *wg1h, *wg1l, *wg2h, *wg2l;
    unsigned short *w1v1h, *w1v1l, *w1v2h, *w1v2l, *w1vh, *w1vl;
    unsigned short *w2v1h, *w2v1l, *w2v2h, *w2v2l, *w2vh, *w2vl;
    unsigned short *wgh, *wgl, *wgg1h, *wgg1l, *wgg2h, *wgg2l;
    wsplit(W_gen1, FD, GH, wg1h, wg1l);
    wsplit(W_gen2, FD, GH, wg2h, wg2l);
    wsplit(W1_v1, FD, CH, w1v1h, w1v1l);
    wsplit(W1_v2, FD, CH, w1v2h, w1v2l);
    wsplit(W1_v, FD, CH, w1vh, w1vl);
    wsplit(W2_v1, CH, NCLS, w2v1h, w2v1l);
    wsplit(W2_v2, CH, NCLS, w2v2h, w2v2l);
    wsplit(W2_v, CH, NCLS, w2vh, w2vl);
    wsplit(Wg, FD, MH, wgh, wgl);
    wsplit(Wg1, FD, MH, wgg1h, wgg1l);
    wsplit(Wg2, FD, MH, wgg2h, wgg2l);

    const int NB = (NN + 1 + 1023) / 1024;
    auto scan = [&](int* rowptr) {
        scan_block<<<NB, 1024, 0, stream>>>(cnt, rowptr, bsum);
        scan_bsum<<<1, 64, 0, stream>>>(bsum, NB);
        scan_add<<<NB, 1024, 0, stream>>>(bsum, rowptr, cursor);
    };
    auto build_dir = [&](const int* ind, const float* vals, int* rowptr, int* col, float* val) {
        hipMemsetAsync(cnt, 0, NN * 4, stream);
        count_dir<<<(EE + 255) / 256, 256, 0, stream>>>(ind, cnt);
        scan(rowptr);
        scatter_dir<<<(EE + 255) / 256, 256, 0, stream>>>(ind, vals, cursor, col, val);
    };
    auto build_sym = [&](const int* ind, const float* nv, int* rowptr, int* col, float* val) {
        hipMemsetAsync(cnt, 0, NN * 4, stream);
        count_sym<<<(EE + 255) / 256, 256, 0, stream>>>(ind, cnt);
        scan(rowptr);
        scatter_sym<<<(EE + 255) / 256, 256, 0, stream>>>(ind, nv, cursor, col, val);
    };

    const int GB = (NN + 127) / 128;

    auto gen_view = [&](const int* ind, const float* vals,
                        const unsigned short* wh, const unsigned short* wl,
                        const float* Wm, const float* bm, float coml,
                        const int* rp_d, const int* col_d, const float* val_d, float* nv) {
        gemm_mfma<4><<<GB, 256, 0, stream>>>(feat_hi, feat_lo, wh, wl, bufP, NN, FD);
        spmm_csr<64, true><<<(NN + 15) / 16, 256, 0, stream>>>(rp_d, col_d, val_d, bufP, bufQ);
        node_scores<<<(NN + 3) / 4, 256, 0, stream>>>(bufQ, Wm, sa, sb);
        hipMemsetAsync(rowmax, 0, NN * 4, stream);
        hipMemsetAsync(rowsum, 0, NN * 4, stream);
        edge_score<<<(EE + 255) / 256, 256, 0, stream>>>(sa, sb, bm, ind, ebuf, rowmax);
        edge_exp<<<(EE + 255) / 256, 256, 0, stream>>>(ind, ebuf, rowmax, rowsum);
        edge_nv<<<(EE + 255) / 256, 256, 0, stream>>>(ind, ebuf, rowsum, vals, coml, nv);
    };

    auto run_spmm128 = [&](int mode, const float* x, float* out) {
        const int G = (NN + 7) / 8;
        if (mode == 0)
            spmm_csr<128, true><<<G, 256, 0, stream>>>(rp_s1, col_s1, val_s1, x, out);
        else if (mode == 1)
            spmm_csr<128, true><<<G, 256, 0, stream>>>(rp_s2, col_s2, val_s2, x, out);
        else
            spmm_csr_fused<128, true><<<G, 256, 0, stream>>>(
                rp_s1, col_s1, val_s1, bb1, rp_s2, col_s2, val_s2, bb2, x, out);
    };
    auto run_spmm16 = [&](int mode, const float* x, float* out) {
        const int G = (NN + 63) / 64;
        if (mode == 0)
            spmm_csr<16, false><<<G, 256, 0, stream>>>(rp_s1, col_s1, val_s1, x, out);
        else if (mode == 1)
            spmm_csr<16, false><<<G, 256, 0, stream>>>(rp_s2, col_s2, val_s2, x, out);
        else
            spmm_csr_fused<16, false><<<G, 256, 0, stream>>>(
                rp_s1, col_s1, val_s1, bb1, rp_s2, col_s2, val_s2, bb2, x, out);
    };

    auto branch = [&](int mode, const unsigned short* w1h, const unsigned short* w1l,
                      const unsigned short* w2h, const unsigned short* w2l,
                      float* logits, float* w) {
        gemm_mfma<8><<<GB, 256, 0, stream>>>(feat_hi, feat_lo, w1h, w1l, bufP, NN, FD);
        run_spmm128(mode, bufP, bufQ);
        split_bf16<<<((long)NN * CH + 255) / 256, 256, 0, stream>>>(bufQ, q_hi, q_lo, (long)NN * CH);
        gemm_mfma<1><<<GB, 256, 0, stream>>>(q_hi, q_lo, w2h, w2l, bufR, NN, CH);
        run_spmm16(mode, bufR, bufT);
        softmax16<<<(NN + 255) / 256, 256, 0, stream>>>(bufT, logits, w);
    };

    auto mi = [&](int mode, const unsigned short* wh, const unsigned short* wl,
                  unsigned short* zout) {
        gemm_mfma<8><<<GB, 256, 0, stream>>>(feat_hi, feat_lo, wh, wl, bufP, NN, FD);
        const int G = (BT + 7) / 8;
        if (mode == 0)
            spmm_csr_rows128<<<G, 256, 0, stream>>>(rp_s1, col_s1, val_s1, idxb, bufP, bufQ);
        else if (mode == 1)
            spmm_csr_rows128<<<G, 256, 0, stream>>>(rp_s2, col_s2, val_s2, idxb, bufP, bufQ);
        else
            spmm_csr_fused_rows128<<<G, 256, 0, stream>>>(
                rp_s1, col_s1, val_s1, bb1, rp_s2, col_s2, val_s2, bb2, idxb, bufP, bufQ);
        proj_norm<<<BT, 128, 0, stream>>>(bufQ, Wp1, bp1, Wp2, bp2, zout);
    };

    // ================= sequence =================
    build_dir(ind1, vals1, rp_d1, col_d1, val_d1);
    build_dir(ind2, vals2, rp_d2, col_d2, val_d2);

    gen_view(ind1, vals1, wg1h, wg1l, Wm1, bm1, CL1c, rp_d1, col_d1, val_d1, nv1);
    gen_view(ind2, vals2, wg2h, wg2l, Wm2, bm2, CL2c, rp_d2, col_d2, val_d2, nv2);

    build_sym(ind1, nv1, rp_s1, col_s1, val_s1);
    build_sym(ind2, nv2, rp_s2, col_s2, val_s2);

    branch(0, w1v1h, w1v1l, w2v1h, w2v1l, dout + (size_t)NN * NCLS, w1);
    branch(1, w1v2h, w1v2l, w2v2h, w2v2l, dout + 2 * (size_t)NN * NCLS, w2);
    bweights<<<(NN + 255) / 256, 256, 0, stream>>>(w1, w2, bb1, bb2);
    branch(2, w1vh, w1vl, w2vh, w2vl, dout, nullptr);

    mi(2, wgh, wgl, z16);
    mi(0, wgg1h, wgg1l, z16 + (size_t)BT * MH);
    mi(1, wgg2h, wgg2l, z16 + 2 * (size_t)BT * MH);

    hipMemsetAsync(stats, 0, (size_t)3 * 3 * BT * 4, stream);
    contrast_direct<<<dim3(32, 32, 3), 256, 0, stream>>>(z16, stats);
    contrast_reduce<<<3, 256, 0, stream>>>(stats, dout + (size_t)3 * NN * NCLS);
}

// Round 6
// 1140.025 us; speedup vs baseline: 4.3499x; 1.1740x over previous
//
#include <hip/hip_runtime.h>
#include <math.h>

#define NN 30000
#define EE 480000
#define FD 256
#define CH 128
#define NCLS 16
#define GH 64
#define MH 128
#define BT 4096
#define CL1c 0.5f
#define CL2c 0.5f
#define LAMc 0.5f
#define ALPHAc 1.0f
#define TAUc 0.5f
#define EPSc 1e-8f

typedef __attribute__((ext_vector_type(8))) short short8;
typedef __attribute__((ext_vector_type(4))) float f32x4;

// ---------- helpers ----------
__device__ __forceinline__ unsigned enc_f32(float f) {
    unsigned b = __float_as_uint(f);
    return (b & 0x80000000u) ? ~b : (b | 0x80000000u);
}
__device__ __forceinline__ float dec_f32(unsigned u) {
    return (u & 0x80000000u) ? __uint_as_float(u ^ 0x80000000u) : __uint_as_float(~u);
}
__device__ __forceinline__ unsigned short f2bf(float x) {
    unsigned b = __float_as_uint(x);
    unsigned r = b + 0x7FFFu + ((b >> 16) & 1u);
    return (unsigned short)(r >> 16);
}
__device__ __forceinline__ float bf2f(unsigned short h) {
    return __uint_as_float(((unsigned)h) << 16);
}
__device__ __forceinline__ float4 fma4(float s, float4 x, float4 a) {
    a.x = fmaf(s, x.x, a.x); a.y = fmaf(s, x.y, a.y);
    a.z = fmaf(s, x.z, a.z); a.w = fmaf(s, x.w, a.w);
    return a;
}

// ---------- splits ----------
__global__ void split_bf16(const float* __restrict__ x, unsigned short* __restrict__ hi,
                           unsigned short* __restrict__ lo, long n) {
    long i = (long)blockIdx.x * 256 + threadIdx.x;
    if (i >= n) return;
    float v = x[i];
    unsigned short h = f2bf(v);
    hi[i] = h;
    lo[i] = f2bf(v - bf2f(h));
}

// one kernel splitting+transposing all 11 weights
struct WSArgs {
    const float* s[11];
    unsigned short* h[11];
    unsigned short* l[11];
};
__global__ void wsplit_all(WSArgs a) {
    constexpr int KK[11]  = {256,256,256,256,256,128,128,128,256,256,256};
    constexpr int NNp[11] = {64, 64, 128,128,128,16, 16, 16, 128,128,128};
    constexpr int OFF[12] = {0,16384,32768,65536,98304,131072,133120,135168,137216,169984,202752,235520};
    int i = blockIdx.x * 256 + threadIdx.x;
    if (i >= 235520) return;
    int w = 0;
#pragma unroll
    for (int t = 1; t < 11; t++) if (i >= OFF[t]) w = t;
    int j = i - OFF[w];
    int K = KK[w], N = NNp[w];
    int k = j / N, n = j % N;
    float v = a.s[w][j];
    unsigned short hh = f2bf(v);
    a.h[w][(size_t)n * K + k] = hh;
    a.l[w][(size_t)n * K + k] = f2bf(v - bf2f(hh));
}

// ---------- 3-pass hi/lo MFMA GEMM (fp32-accurate) ----------
// C[M x NT*16] = A[M x K] @ B ; BT given [N][K]. grid.y offsets: A+=y*yA, B+=y*yB, C+=y*yC
template <int NT>
__global__ __launch_bounds__(256) void gemm3(
    const unsigned short* __restrict__ Ahi, const unsigned short* __restrict__ Alo, size_t yA,
    const unsigned short* __restrict__ BThi, const unsigned short* __restrict__ BTlo, size_t yB,
    int K, float* __restrict__ C, int Cstride, size_t yC, int M)
{
    Ahi += blockIdx.y * yA; Alo += blockIdx.y * yA;
    BThi += blockIdx.y * yB; BTlo += blockIdx.y * yB;
    C += blockIdx.y * yC;
    __shared__ unsigned short Ah[128 * 40], Al[128 * 40];
    __shared__ unsigned short Bh[NT * 16 * 40], Bl[NT * 16 * 40];
    int t = threadIdx.x;
    int w = t >> 6, l = t & 63;
    int lane = l & 15, quad = l >> 4;
    int row0 = blockIdx.x * 128;
    f32x4 acc[2][NT];
#pragma unroll
    for (int s = 0; s < 2; s++)
#pragma unroll
        for (int n = 0; n < NT; n++) acc[s][n] = (f32x4)(0.f);

    int ar = t >> 1, ako = (t & 1) << 4;
    int nkc = K >> 5;
    for (int kc = 0; kc < nkc; kc++) {
        int kb = kc << 5;
        {
            int gr = row0 + ar;
            float4 h0, h1, l0, l1;
            if (gr < M) {
                const float4* pH = (const float4*)&Ahi[(size_t)gr * K + kb + ako];
                const float4* pL = (const float4*)&Alo[(size_t)gr * K + kb + ako];
                h0 = pH[0]; h1 = pH[1]; l0 = pL[0]; l1 = pL[1];
            } else {
                h0 = h1 = l0 = l1 = make_float4(0.f, 0.f, 0.f, 0.f);
            }
            float4* dH = (float4*)&Ah[ar * 40 + ako];
            dH[0] = h0; dH[1] = h1;
            float4* dL = (float4*)&Al[ar * 40 + ako];
            dL[0] = l0; dL[1] = l1;
        }
        if (ar < NT * 16) {
            const float4* pH = (const float4*)&BThi[(size_t)ar * K + kb + ako];
            const float4* pL = (const float4*)&BTlo[(size_t)ar * K + kb + ako];
            float4 h0 = pH[0], h1 = pH[1], l0 = pL[0], l1 = pL[1];
            float4* dH = (float4*)&Bh[ar * 40 + ako];
            dH[0] = h0; dH[1] = h1;
            float4* dL = (float4*)&Bl[ar * 40 + ako];
            dL[0] = l0; dL[1] = l1;
        }
        __syncthreads();
        short8 aH[2], aL[2];
#pragma unroll
        for (int s = 0; s < 2; s++) {
            int r = w * 32 + s * 16 + lane;
            aH[s] = *(const short8*)&Ah[r * 40 + quad * 8];
            aL[s] = *(const short8*)&Al[r * 40 + quad * 8];
        }
#pragma unroll
        for (int n = 0; n < NT; n++) {
            int r = n * 16 + lane;
            short8 bH = *(const short8*)&Bh[r * 40 + quad * 8];
            short8 bL = *(const short8*)&Bl[r * 40 + quad * 8];
#pragma unroll
            for (int s = 0; s < 2; s++) {
                acc[s][n] = __builtin_amdgcn_mfma_f32_16x16x32_bf16(aH[s], bH, acc[s][n], 0, 0, 0);
                acc[s][n] = __builtin_amdgcn_mfma_f32_16x16x32_bf16(aH[s], bL, acc[s][n], 0, 0, 0);
                acc[s][n] = __builtin_amdgcn_mfma_f32_16x16x32_bf16(aL[s], bH, acc[s][n], 0, 0, 0);
            }
        }
        __syncthreads();
    }
#pragma unroll
    for (int s = 0; s < 2; s++) {
        int rb = row0 + w * 32 + s * 16 + quad * 4;
#pragma unroll
        for (int reg = 0; reg < 4; reg++) {
            int gr = rb + reg;
            if (gr >= M) continue;
#pragma unroll
            for (int n = 0; n < NT; n++)
                C[(size_t)gr * Cstride + n * 16 + lane] = acc[s][n][reg];
        }
    }
}

// ---------- 1-pass bf16 MFMA GEMM (for precision-tolerant paths) ----------
template <int NT, bool OUT16>
__global__ __launch_bounds__(256) void gemm1(
    const unsigned short* __restrict__ Ahi,
    const unsigned short* __restrict__ BThi, size_t yB,
    int K, void* __restrict__ Cv, int Cstride, size_t yC, int M)
{
    BThi += blockIdx.y * yB;
    __shared__ unsigned short Ah[128 * 40];
    __shared__ unsigned short Bh[NT * 16 * 40];
    int t = threadIdx.x;
    int w = t >> 6, l = t & 63;
    int lane = l & 15, quad = l >> 4;
    int row0 = blockIdx.x * 128;
    f32x4 acc[2][NT];
#pragma unroll
    for (int s = 0; s < 2; s++)
#pragma unroll
        for (int n = 0; n < NT; n++) acc[s][n] = (f32x4)(0.f);

    int ar = t >> 1, ako = (t & 1) << 4;
    int nkc = K >> 5;
    for (int kc = 0; kc < nkc; kc++) {
        int kb = kc << 5;
        {
            int gr = row0 + ar;
            float4 h0, h1;
            if (gr < M) {
                const float4* pH = (const float4*)&Ahi[(size_t)gr * K + kb + ako];
                h0 = pH[0]; h1 = pH[1];
            } else {
                h0 = h1 = make_float4(0.f, 0.f, 0.f, 0.f);
            }
            float4* dH = (float4*)&Ah[ar * 40 + ako];
            dH[0] = h0; dH[1] = h1;
        }
        if (ar < NT * 16) {
            const float4* pH = (const float4*)&BThi[(size_t)ar * K + kb + ako];
            float4 h0 = pH[0], h1 = pH[1];
            float4* dH = (float4*)&Bh[ar * 40 + ako];
            dH[0] = h0; dH[1] = h1;
        }
        __syncthreads();
        short8 aH[2];
#pragma unroll
        for (int s = 0; s < 2; s++)
            aH[s] = *(const short8*)&Ah[(w * 32 + s * 16 + lane) * 40 + quad * 8];
#pragma unroll
        for (int n = 0; n < NT; n++) {
            short8 bH = *(const short8*)&Bh[(n * 16 + lane) * 40 + quad * 8];
#pragma unroll
            for (int s = 0; s < 2; s++)
                acc[s][n] = __builtin_amdgcn_mfma_f32_16x16x32_bf16(aH[s], bH, acc[s][n], 0, 0, 0);
        }
        __syncthreads();
    }
#pragma unroll
    for (int s = 0; s < 2; s++) {
        int rb = row0 + w * 32 + s * 16 + quad * 4;
#pragma unroll
        for (int reg = 0; reg < 4; reg++) {
            int gr = rb + reg;
            if (gr >= M) continue;
#pragma unroll
            for (int n = 0; n < NT; n++) {
                if (OUT16) {
                    unsigned short* C = (unsigned short*)Cv + blockIdx.y * yC;
                    C[(size_t)gr * Cstride + n * 16 + lane] = f2bf(acc[s][n][reg]);
                } else {
                    float* C = (float*)Cv + blockIdx.y * yC;
                    C[(size_t)gr * Cstride + n * 16 + lane] = acc[s][n][reg];
                }
            }
        }
    }
}

// ---------- contrast: direct-from-L2 bf16 MFMA ----------
__global__ __launch_bounds__(256) void contrast_direct(
    const unsigned short* __restrict__ z16, float* __restrict__ stats)
{
    int p = blockIdx.z;
    int pa = (p == 2) ? 1 : 0;
    int pb = (p == 0) ? 1 : 2;
    const unsigned short* A = z16 + (size_t)pa * BT * MH;
    const unsigned short* B = z16 + (size_t)pb * BT * MH;
    float* diag = stats + (size_t)p * 3 * BT;
    float* rs = diag + BT;
    float* cs = rs + BT;
    int t = threadIdx.x;
    int w = t >> 6, l = t & 63, m = l & 15, quad = l >> 4;
    int i0 = blockIdx.y * 128, j0 = blockIdx.x * 128;

    short8 afr[2][4];
#pragma unroll
    for (int s = 0; s < 2; s++) {
        const unsigned short* arow = &A[(size_t)(i0 + w * 32 + s * 16 + m) * MH + quad * 8];
#pragma unroll
        for (int kc = 0; kc < 4; kc++)
            afr[s][kc] = *(const short8*)(arow + kc * 32);
    }
    f32x4 acc[2][8];
#pragma unroll
    for (int s = 0; s < 2; s++)
#pragma unroll
        for (int n = 0; n < 8; n++) acc[s][n] = (f32x4)(0.f);

#pragma unroll
    for (int kc = 0; kc < 4; kc++) {
#pragma unroll
        for (int n = 0; n < 8; n++) {
            short8 bf = *(const short8*)&B[(size_t)(j0 + n * 16 + m) * MH + kc * 32 + quad * 8];
            acc[0][n] = __builtin_amdgcn_mfma_f32_16x16x32_bf16(afr[0][kc], bf, acc[0][n], 0, 0, 0);
            acc[1][n] = __builtin_amdgcn_mfma_f32_16x16x32_bf16(afr[1][kc], bf, acc[1][n], 0, 0, 0);
        }
    }
    float colp[8];
#pragma unroll
    for (int n = 0; n < 8; n++) colp[n] = 0.f;
#pragma unroll
    for (int s = 0; s < 2; s++) {
        int rbase = i0 + w * 32 + s * 16 + quad * 4;
#pragma unroll
        for (int reg = 0; reg < 4; reg++) {
            float rsum = 0.f;
            int gi = rbase + reg;
#pragma unroll
            for (int n = 0; n < 8; n++) {
                float mv = expf(acc[s][n][reg] * 2.0f);
                rsum += mv;
                colp[n] += mv;
                int gj = j0 + n * 16 + m;
                if (gi == gj) diag[gi] = mv;
            }
            rsum += __shfl_xor(rsum, 1); rsum += __shfl_xor(rsum, 2);
            rsum += __shfl_xor(rsum, 4); rsum += __shfl_xor(rsum, 8);
            if (m == 0) atomicAdd(&rs[gi], rsum);
        }
    }
    __shared__ float scol[128];
    if (t < 128) scol[t] = 0.f;
    __syncthreads();
#pragma unroll
    for (int n = 0; n < 8; n++) {
        float v = colp[n];
        v += __shfl_xor(v, 16); v += __shfl_xor(v, 32);
        if (quad == (n & 3)) atomicAdd(&scol[n * 16 + m], v);
    }
    __syncthreads();
    if (t < 128) atomicAdd(&cs[j0 + t], scol[t]);
}

// ---------- CSR builds (both graphs per launch; segment = blockIdx.y / thread) ----------
__global__ void count_dir2(const int* __restrict__ i1, const int* __restrict__ i2,
                           int* __restrict__ cnt) {
    int e = blockIdx.x * 256 + threadIdx.x;
    if (e >= EE) return;
    atomicAdd(&cnt[i1[e]], 1);
    atomicAdd(&cnt[NN + i2[e]], 1);
}
__global__ void count_sym2(const int* __restrict__ i1, const int* __restrict__ i2,
                           int* __restrict__ cnt) {
    int e = blockIdx.x * 256 + threadIdx.x;
    if (e >= EE) return;
    atomicAdd(&cnt[i1[e]], 1);
    atomicAdd(&cnt[i1[EE + e]], 1);
    atomicAdd(&cnt[NN + i2[e]], 1);
    atomicAdd(&cnt[NN + i2[EE + e]], 1);
}
__global__ __launch_bounds__(1024) void scan_block2(const int* __restrict__ cnt,
                                                    int* __restrict__ rowptr,
                                                    int* __restrict__ bsum) {
    cnt += blockIdx.y * NN; rowptr += blockIdx.y * (NN + 1); bsum += blockIdx.y * 32;
    __shared__ int tmp[1024];
    int t = threadIdx.x;
    int i = blockIdx.x * 1024 + t;
    int v = (i < NN) ? cnt[i] : 0;
    tmp[t] = v;
    __syncthreads();
    for (int off = 1; off < 1024; off <<= 1) {
        int add = (t >= off) ? tmp[t - off] : 0;
        __syncthreads();
        tmp[t] += add;
        __syncthreads();
    }
    if (i <= NN) rowptr[i] = tmp[t] - v;
    if (t == 1023) bsum[blockIdx.x] = tmp[1023];
}
__global__ void scan_bsum2(int* __restrict__ bsum, int nb) {
    bsum += blockIdx.x * 32;
    int t = threadIdx.x;
    int orig = (t < nb) ? bsum[t] : 0;
    int v = orig;
    for (int off = 1; off < 64; off <<= 1) {
        int u = __shfl_up(v, off);
        if (t >= off) v += u;
    }
    if (t < nb) bsum[t] = v - orig;
}
__global__ void scan_add2(const int* __restrict__ bsum, int* __restrict__ rowptr,
                          int* __restrict__ cursor) {
    bsum += blockIdx.y * 32; rowptr += blockIdx.y * (NN + 1); cursor += blockIdx.y * NN;
    int i = blockIdx.x * 1024 + threadIdx.x;
    if (i <= NN) {
        int r = rowptr[i] + bsum[blockIdx.x];
        rowptr[i] = r;
        if (i < NN) cursor[i] = r;
    }
}
__global__ void scatter_dir2(const int* __restrict__ i1, const float* __restrict__ v1,
                             const int* __restrict__ i2, const float* __restrict__ v2,
                             int* __restrict__ cur,
                             int* __restrict__ c1, float* __restrict__ w1,
                             int* __restrict__ c2, float* __restrict__ w2) {
    int e = blockIdx.x * 256 + threadIdx.x;
    if (e >= EE) return;
    int p = atomicAdd(&cur[i1[e]], 1);
    c1[p] = i1[EE + e]; w1[p] = v1[e];
    p = atomicAdd(&cur[NN + i2[e]], 1);
    c2[p] = i2[EE + e]; w2[p] = v2[e];
}
__global__ void scatter_sym2(const int* __restrict__ i1, const int* __restrict__ i2,
                             const float* __restrict__ nv12, int* __restrict__ cur,
                             int* __restrict__ c1, float* __restrict__ w1,
                             int* __restrict__ c2, float* __restrict__ w2) {
    int e = blockIdx.x * 256 + threadIdx.x;
    if (e >= EE) return;
    int r = i1[e], c = i1[EE + e];
    float v = nv12[e];
    int p = atomicAdd(&cur[r], 1);
    c1[p] = c; w1[p] = v;
    p = atomicAdd(&cur[c], 1);
    c1[p] = r; w1[p] = v;
    r = i2[e]; c = i2[EE + e];
    v = nv12[EE + e];
    p = atomicAdd(&cur[NN + r], 1);
    c2[p] = c; w2[p] = v;
    p = atomicAdd(&cur[NN + c], 1);
    c2[p] = r; w2[p] = v;
}

// ---------- fp32 SpMM pairs ----------
// gen: F=64, x = Pg[NN][128] slice (y*16 float4 off), out emb[2][NN][64]
__global__ __launch_bounds__(256) void spmm64_pair(
    const int* __restrict__ rp_d, const int* __restrict__ c1, const float* __restrict__ v1,
    const int* __restrict__ c2, const float* __restrict__ v2,
    const float* __restrict__ Pg, float* __restrict__ emb)
{
    int y = blockIdx.y;
    const int* rp = rp_d + y * (NN + 1);
    const int* col = y ? c2 : c1;
    const float* val = y ? v2 : v1;
    int row = blockIdx.x * 16 + threadIdx.x / 16;
    int o = threadIdx.x % 16;
    if (row >= NN) return;
    const float4* x4 = (const float4*)Pg;
    int p0 = rp[row], p1 = rp[row + 1];
    float4 a0 = {0,0,0,0}, a1 = {0,0,0,0}, a2 = {0,0,0,0}, a3 = {0,0,0,0};
    int xo = y * 16 + o;
    int j = p0;
    for (; j + 4 <= p1; j += 4) {
        a0 = fma4(val[j],   x4[(size_t)col[j]   * 32 + xo], a0);
        a1 = fma4(val[j+1], x4[(size_t)col[j+1] * 32 + xo], a1);
        a2 = fma4(val[j+2], x4[(size_t)col[j+2] * 32 + xo], a2);
        a3 = fma4(val[j+3], x4[(size_t)col[j+3] * 32 + xo], a3);
    }
    for (; j < p1; j++)
        a0 = fma4(val[j], x4[(size_t)col[j] * 32 + xo], a0);
    float4 r;
    r.x = fmaxf((a0.x + a1.x) + (a2.x + a3.x), 0.f);
    r.y = fmaxf((a0.y + a1.y) + (a2.y + a3.y), 0.f);
    r.z = fmaxf((a0.z + a1.z) + (a2.z + a3.z), 0.f);
    r.w = fmaxf((a0.w + a1.w) + (a2.w + a3.w), 0.f);
    ((float4*)emb)[((size_t)y * NN + row) * 16 + o] = r;
}

// branch0/1: F=128, x = P01[NN][256] slice, out Q01[2][NN][128], relu
__global__ __launch_bounds__(256) void spmm128_pair(
    const int* __restrict__ rp_s, const int* __restrict__ c1, const float* __restrict__ v1,
    const int* __restrict__ c2, const float* __restrict__ v2,
    const float* __restrict__ P01, float* __restrict__ Q01)
{
    int y = blockIdx.y;
    const int* rp = rp_s + y * (NN + 1);
    const int* col = y ? c2 : c1;
    const float* val = y ? v2 : v1;
    int row = blockIdx.x * 8 + threadIdx.x / 32;
    int o = threadIdx.x % 32;
    if (row >= NN) return;
    const float4* x4 = (const float4*)P01;
    int p0 = rp[row], p1 = rp[row + 1];
    float4 a0 = {0,0,0,0}, a1 = {0,0,0,0}, a2 = {0,0,0,0}, a3 = {0,0,0,0};
    int xo = y * 32 + o;
    int j = p0;
    for (; j + 4 <= p1; j += 4) {
        a0 = fma4(val[j],   x4[(size_t)col[j]   * 64 + xo], a0);
        a1 = fma4(val[j+1], x4[(size_t)col[j+1] * 64 + xo], a1);
        a2 = fma4(val[j+2], x4[(size_t)col[j+2] * 64 + xo], a2);
        a3 = fma4(val[j+3], x4[(size_t)col[j+3] * 64 + xo], a3);
    }
    for (; j < p1; j++)
        a0 = fma4(val[j], x4[(size_t)col[j] * 64 + xo], a0);
    float4 r;
    r.x = fmaxf((a0.x + a1.x) + (a2.x + a3.x), 0.f);
    r.y = fmaxf((a0.y + a1.y) + (a2.y + a3.y), 0.f);
    r.z = fmaxf((a0.z + a1.z) + (a2.z + a3.z), 0.f);
    r.w = fmaxf((a0.w + a1.w) + (a2.w + a3.w), 0.f);
    ((float4*)Q01)[((size_t)y * NN + row) * 32 + o] = r;
}

// branch0/1 layer2: F=16, x = R01 + y*NN*16, out T01 + y*NN*16
__global__ __launch_bounds__(256) void spmm16_pair(
    const int* __restrict__ rp_s, const int* __restrict__ c1, const float* __restrict__ v1,
    const int* __restrict__ c2, const float* __restrict__ v2,
    const float* __restrict__ R01, float* __restrict__ T01)
{
    int y = blockIdx.y;
    const int* rp = rp_s + y * (NN + 1);
    const int* col = y ? c2 : c1;
    const float* val = y ? v2 : v1;
    int row = blockIdx.x * 64 + threadIdx.x / 4;
    int o = threadIdx.x % 4;
    if (row >= NN) return;
    const float4* x4 = (const float4*)(R01 + (size_t)y * NN * 16);
    int p0 = rp[row], p1 = rp[row + 1];
    float4 a0 = {0,0,0,0}, a1 = {0,0,0,0}, a2 = {0,0,0,0}, a3 = {0,0,0,0};
    int j = p0;
    for (; j + 4 <= p1; j += 4) {
        a0 = fma4(val[j],   x4[(size_t)col[j]   * 4 + o], a0);
        a1 = fma4(val[j+1], x4[(size_t)col[j+1] * 4 + o], a1);
        a2 = fma4(val[j+2], x4[(size_t)col[j+2] * 4 + o], a2);
        a3 = fma4(val[j+3], x4[(size_t)col[j+3] * 4 + o], a3);
    }
    for (; j < p1; j++)
        a0 = fma4(val[j], x4[(size_t)col[j] * 4 + o], a0);
    float4 r;
    r.x = (a0.x + a1.x) + (a2.x + a3.x);
    r.y = (a0.y + a1.y) + (a2.y + a3.y);
    r.z = (a0.z + a1.z) + (a2.z + a3.z);
    r.w = (a0.w + a1.w) + (a2.w + a3.w);
    ((float4*)(T01 + (size_t)y * NN * 16))[(size_t)row * 4 + o] = r;
}

// fp32 fused F=16 (branch2 layer2 aggregate)
__global__ __launch_bounds__(256) void spmm16_fused(
    const int* __restrict__ rp_s, const int* __restrict__ c1, const float* __restrict__ v1,
    const int* __restrict__ c2, const float* __restrict__ v2,
    const float* __restrict__ bb, const float* __restrict__ x, float* __restrict__ out)
{
    int row = blockIdx.x * 64 + threadIdx.x / 4;
    int o = threadIdx.x % 4;
    if (row >= NN) return;
    const float4* x4 = (const float4*)x;
    float4 s1 = {0,0,0,0}, s2 = {0,0,0,0};
    {
        const int* rp = rp_s;
        int p0 = rp[row], p1 = rp[row + 1];
        float4 a0 = {0,0,0,0}, a1 = {0,0,0,0};
        int j = p0;
        for (; j + 2 <= p1; j += 2) {
            a0 = fma4(v1[j],   x4[(size_t)c1[j]   * 4 + o], a0);
            a1 = fma4(v1[j+1], x4[(size_t)c1[j+1] * 4 + o], a1);
        }
        for (; j < p1; j++) a0 = fma4(v1[j], x4[(size_t)c1[j] * 4 + o], a0);
        s1.x = a0.x + a1.x; s1.y = a0.y + a1.y; s1.z = a0.z + a1.z; s1.w = a0.w + a1.w;
    }
    {
        const int* rp = rp_s + (NN + 1);
        int p0 = rp[row], p1 = rp[row + 1];
        float4 a0 = {0,0,0,0}, a1 = {0,0,0,0};
        int j = p0;
        for (; j + 2 <= p1; j += 2) {
            a0 = fma4(v2[j],   x4[(size_t)c2[j]   * 4 + o], a0);
            a1 = fma4(v2[j+1], x4[(size_t)c2[j+1] * 4 + o], a1);
        }
        for (; j < p1; j++) a0 = fma4(v2[j], x4[(size_t)c2[j] * 4 + o], a0);
        s2.x = a0.x + a1.x; s2.y = a0.y + a1.y; s2.z = a0.z + a1.z; s2.w = a0.w + a1.w;
    }
    float w1 = bb[row], w2 = bb[NN + row];
    float4 r;
    r.x = w1 * s1.x + w2 * s2.x;
    r.y = w1 * s1.y + w2 * s2.y;
    r.z = w1 * s1.z + w2 * s2.z;
    r.w = w1 * s1.w + w2 * s2.w;
    ((float4*)out)[(size_t)row * 4 + o] = r;
}

// ---------- bf16-gather SpMM helpers ----------
__device__ __forceinline__ void gather_b16(
    const int* __restrict__ rp, const int* __restrict__ col, const float* __restrict__ val,
    int row, const unsigned short* __restrict__ X, int xstride, int o, float* acc)
{
    int p0 = rp[row], p1 = rp[row + 1];
    int j = p0;
    for (; j + 4 <= p1; j += 4) {
        int c0 = col[j], c1 = col[j+1], c2 = col[j+2], c3 = col[j+3];
        float v0 = val[j], v1 = val[j+1], v2 = val[j+2], v3 = val[j+3];
        short8 x0 = *(const short8*)&X[(size_t)c0 * xstride + o * 8];
        short8 x1 = *(const short8*)&X[(size_t)c1 * xstride + o * 8];
        short8 x2 = *(const short8*)&X[(size_t)c2 * xstride + o * 8];
        short8 x3 = *(const short8*)&X[(size_t)c3 * xstride + o * 8];
#pragma unroll
        for (int k = 0; k < 8; k++) {
            acc[k] = fmaf(v0, bf2f((unsigned short)x0[k]), acc[k]);
            acc[k] = fmaf(v1, bf2f((unsigned short)x1[k]), acc[k]);
            acc[k] = fmaf(v2, bf2f((unsigned short)x2[k]), acc[k]);
            acc[k] = fmaf(v3, bf2f((unsigned short)x3[k]), acc[k]);
        }
    }
    for (; j < p1; j++) {
        short8 xv = *(const short8*)&X[(size_t)col[j] * xstride + o * 8];
        float v = val[j];
#pragma unroll
        for (int k = 0; k < 8; k++)
            acc[k] = fmaf(v, bf2f((unsigned short)xv[k]), acc[k]);
    }
}

// branch2: fused F=128 bf16 gather, bf16 out (relu)
__global__ __launch_bounds__(256) void fused128_b16(
    const int* __restrict__ rp_s, const int* __restrict__ c1, const float* __restrict__ v1,
    const int* __restrict__ c2, const float* __restrict__ v2,
    const float* __restrict__ bb, const unsigned short* __restrict__ X,
    unsigned short* __restrict__ Out)
{
    int row = blockIdx.x * 16 + threadIdx.x / 16;
    int o = threadIdx.x % 16;
    if (row >= NN) return;
    float a1[8] = {}, a2[8] = {};
    gather_b16(rp_s, c1, v1, row, X, 128, o, a1);
    gather_b16(rp_s + (NN + 1), c2, v2, row, X, 128, o, a2);
    float w1 = bb[row], w2 = bb[NN + row];
    short8 outv;
#pragma unroll
    for (int k = 0; k < 8; k++) {
        float r = fmaxf(w1 * a1[k] + w2 * a2[k], 0.f);
        outv[k] = (short)f2bf(r);
    }
    *(short8*)&Out[(size_t)row * 128 + o * 8] = outv;
}

// mi: rows-only spmm, bf16 gather from Pmi[NN][384], fp32 out zQ[3][BT][128], relu
__global__ __launch_bounds__(256) void rows_spmm_b16(
    const int* __restrict__ rp_s, const int* __restrict__ c1, const float* __restrict__ v1,
    const int* __restrict__ c2, const float* __restrict__ v2,
    const float* __restrict__ bb, const int* __restrict__ rows,
    const unsigned short* __restrict__ Pmi, float* __restrict__ zQ)
{
    int y = blockIdx.y;
    int ri = blockIdx.x * 16 + threadIdx.x / 16;
    int o = threadIdx.x % 16;
    if (ri >= BT) return;
    int node = rows[ri];
    int xoff = (y == 0) ? 0 : ((y == 1) ? 128 : 256);
    const unsigned short* X = Pmi + xoff;
    float acc[8] = {};
    if (y == 0) {
        float a1[8] = {}, a2[8] = {};
        gather_b16(rp_s, c1, v1, node, X, 384, o, a1);
        gather_b16(rp_s + (NN + 1), c2, v2, node, X, 384, o, a2);
        float w1 = bb[node], w2 = bb[NN + node];
#pragma unroll
        for (int k = 0; k < 8; k++) acc[k] = w1 * a1[k] + w2 * a2[k];
    } else if (y == 1) {
        gather_b16(rp_s, c1, v1, node, X, 384, o, acc);
    } else {
        gather_b16(rp_s + (NN + 1), c2, v2, node, X, 384, o, acc);
    }
    float* out = zQ + ((size_t)y * BT + ri) * 128 + o * 8;
#pragma unroll
    for (int k = 0; k < 8; k++) out[k] = fmaxf(acc[k], 0.f);
}

// ---------- gen_view edge-score pipeline (both views per launch) ----------
__global__ __launch_bounds__(256) void node_scores_pair(
    const float* __restrict__ emb, const float* __restrict__ Wm1,
    const float* __restrict__ Wm2, float* __restrict__ sa, float* __restrict__ sb)
{
    int y = blockIdx.y;
    const float* e_ = emb + (size_t)y * NN * GH;
    const float* Wm = y ? Wm2 : Wm1;
    int node = blockIdx.x * 4 + threadIdx.x / 64;
    int lane = threadIdx.x % 64;
    if (node >= NN) return;
    float e = e_[(size_t)node * GH + lane];
    float va = e * Wm[lane];
    float vb = e * Wm[GH + lane];
#pragma unroll
    for (int off = 32; off; off >>= 1) {
        va += __shfl_down(va, off);
        vb += __shfl_down(vb, off);
    }
    if (lane == 0) { sa[y * NN + node] = va; sb[y * NN + node] = vb; }
}

__global__ void edge_score_all(const float* __restrict__ sa, const float* __restrict__ sb,
                               const float* __restrict__ bm1, const float* __restrict__ bm2,
                               const int* __restrict__ i1, const int* __restrict__ i2,
                               float* __restrict__ ebuf, unsigned* __restrict__ rowmax)
{
    int g = blockIdx.x * 256 + threadIdx.x;
    if (g >= 2 * EE) return;
    int view = g >= EE;
    int e = g - view * EE;
    const int* ind = view ? i2 : i1;
    int r = ind[e], c = ind[EE + e];
    float s = sa[view * NN + r] + sb[view * NN + c] + (view ? bm2[0] : bm1[0]);
    ebuf[g] = s;
    atomicMax(&rowmax[view * NN + r], enc_f32(s));
}

__global__ void edge_exp_all(const int* __restrict__ i1, const int* __restrict__ i2,
                             float* __restrict__ ebuf, const unsigned* __restrict__ rowmax,
                             float* __restrict__ rowsum)
{
    int g = blockIdx.x * 256 + threadIdx.x;
    if (g >= 2 * EE) return;
    int view = g >= EE;
    int e = g - view * EE;
    const int* ind = view ? i2 : i1;
    int r = ind[e];
    float ex = expf(ebuf[g] - dec_f32(rowmax[view * NN + r]));
    ebuf[g] = ex;
    atomicAdd(&rowsum[view * NN + r], ex);
}

__global__ void edge_nv_all(const int* __restrict__ i1, const int* __restrict__ i2,
                            const float* __restrict__ ebuf, const float* __restrict__ rowsum,
                            const float* __restrict__ v1, const float* __restrict__ v2,
                            float* __restrict__ nv12)
{
    int g = blockIdx.x * 256 + threadIdx.x;
    if (g >= 2 * EE) return;
    int view = g >= EE;
    int e = g - view * EE;
    const int* ind = view ? i2 : i1;
    const float* vals = view ? v2 : v1;
    int r = ind[e];
    float coml = view ? CL2c : CL1c;
    nv12[g] = vals[e] + coml * ebuf[g] / rowsum[view * NN + r];
}

// ---------- softmax / weights ----------
__global__ void softmax16y(const float* __restrict__ S01, float* __restrict__ logits_base,
                           float* __restrict__ w12)
{
    int y = blockIdx.y;
    const float* S = S01 + (size_t)y * NN * NCLS;
    float* logits = logits_base + (size_t)y * NN * NCLS;
    float* w = w12 + (size_t)y * NN;
    int node = blockIdx.x * 256 + threadIdx.x;
    if (node >= NN) return;
    float v[NCLS];
    float mx = -3.4e38f;
#pragma unroll
    for (int j = 0; j < NCLS; j++) { v[j] = S[(size_t)node * NCLS + j]; mx = fmaxf(mx, v[j]); }
    float s = 0.f;
#pragma unroll
    for (int j = 0; j < NCLS; j++) { v[j] = expf(v[j] - mx); s += v[j]; }
    float inv = 1.f / s;
    float fir = -1.f, sec = -1.f;
#pragma unroll
    for (int j = 0; j < NCLS; j++) {
        float p = v[j] * inv;
        logits[(size_t)node * NCLS + j] = logf(p + EPSc);
        if (p > fir) { sec = fir; fir = p; }
        else if (p > sec) { sec = p; }
    }
    w[node] = expf(ALPHAc * (LAMc * logf(fir + EPSc) + (1.f - LAMc) * logf(fir - sec + EPSc)));
}

__global__ void softmax16(const float* __restrict__ S, float* __restrict__ logits)
{
    int node = blockIdx.x * 256 + threadIdx.x;
    if (node >= NN) return;
    float v[NCLS];
    float mx = -3.4e38f;
#pragma unroll
    for (int j = 0; j < NCLS; j++) { v[j] = S[(size_t)node * NCLS + j]; mx = fmaxf(mx, v[j]); }
    float s = 0.f;
#pragma unroll
    for (int j = 0; j < NCLS; j++) { v[j] = expf(v[j] - mx); s += v[j]; }
    float inv = 1.f / s;
#pragma unroll
    for (int j = 0; j < NCLS; j++)
        logits[(size_t)node * NCLS + j] = logf(v[j] * inv + EPSc);
}

__global__ void bweights(const float* __restrict__ w12, float* __restrict__ bb)
{
    int i = blockIdx.x * 256 + threadIdx.x;
    if (i >= NN) return;
    float a = w12[i], b = w12[NN + i];
    float inv = 1.f / (a + b);
    bb[i] = a * inv;
    bb[NN + i] = b * inv;
}

// ---------- projection head (3 slots) + L2-normalize, bf16 out ----------
__global__ __launch_bounds__(128) void proj_norm3(
    const float* __restrict__ zQ,
    const float* __restrict__ Wp1, const float* __restrict__ bp1,
    const float* __restrict__ Wp2, const float* __restrict__ bp2,
    unsigned short* __restrict__ z16)
{
    __shared__ float g[MH], u[MH];
    __shared__ float red[2];
    size_t i = (size_t)blockIdx.y * BT + blockIdx.x;
    int t = threadIdx.x;
    g[t] = zQ[i * MH + t];
    __syncthreads();
    float acc = bp1[t];
    for (int k = 0; k < MH; k++) acc = fmaf(g[k], Wp1[k * MH + t], acc);
    u[t] = acc > 0.f ? acc : (expf(acc) - 1.f);
    __syncthreads();
    float acc2 = bp2[t];
    for (int k = 0; k < MH; k++) acc2 = fmaf(u[k], Wp2[k * MH + t], acc2);
    float sq = acc2 * acc2;
#pragma unroll
    for (int off = 32; off; off >>= 1) sq += __shfl_down(sq, off);
    if ((t & 63) == 0) red[t >> 6] = sq;
    __syncthreads();
    float nrm = sqrtf(red[0] + red[1]);
    z16[i * MH + t] = f2bf(acc2 / nrm);
}

__global__ void contrast_reduce(const float* __restrict__ stats, float* __restrict__ out3)
{
    int p = blockIdx.x, t = threadIdx.x;
    const float* diag = stats + (size_t)p * 3 * BT;
    const float* rs = diag + BT;
    const float* cs = rs + BT;
    float s1 = 0.f, s2 = 0.f;
    for (int i = t; i < BT; i += 256) {
        float d = diag[i];
        s1 += logf(d / (rs[i] + EPSc) + EPSc);
        s2 += logf(d / (cs[i] + EPSc) + EPSc);
    }
#pragma unroll
    for (int off = 32; off; off >>= 1) { s1 += __shfl_down(s1, off); s2 += __shfl_down(s2, off); }
    __shared__ float sh[8];
    if ((t & 63) == 0) { sh[(t >> 6) * 2] = s1; sh[(t >> 6) * 2 + 1] = s2; }
    __syncthreads();
    if (t == 0) {
        float a = sh[0] + sh[2] + sh[4] + sh[6];
        float b = sh[1] + sh[3] + sh[5] + sh[7];
        out3[p] = 0.5f * (-a / BT - b / BT);
    }
}

// ---------- host ----------
extern "C" void kernel_launch(void* const* d_in, const int* in_sizes, int n_in,
                              void* d_out, int out_size, void* d_ws, size_t ws_size,
                              hipStream_t stream)
{
    const float* feat   = (const float*)d_in[0];
    const int*   ind1   = (const int*)d_in[1];
    const float* vals1  = (const float*)d_in[2];
    const int*   ind2   = (const int*)d_in[3];
    const float* vals2  = (const float*)d_in[4];
    const int*   idxb   = (const int*)d_in[5];
    const float* Wm1    = (const float*)d_in[7];
    const float* bm1    = (const float*)d_in[8];
    const float* Wm2    = (const float*)d_in[10];
    const float* bm2    = (const float*)d_in[11];
    const float* Wp1    = (const float*)d_in[21];
    const float* bp1    = (const float*)d_in[22];
    const float* Wp2    = (const float*)d_in[23];
    const float* bp2    = (const float*)d_in[24];
    float* dout = (float*)d_out;

    float* ws = (float*)d_ws;
    size_t off = 0;
    auto alloc = [&](size_t n) { n = (n + 3) & ~(size_t)3; float* p = ws + off; off += n; return p; };
    auto alloc_s = [&](size_t n) { return (unsigned short*)alloc((n + 1) / 2); };

    // --- shared pool (phases: gen -> branch01 -> branch2/mi) ---
    float* pool = alloc(24960000);
    // phase0 (gen)
    float* Pg  = pool;                       // NN*128
    float* emb = pool + 3840000;             // 2*NN*64
    // phase1 (branch01)
    float* P01   = pool;                     // 2*NN*128 (cols interleaved: [NN][256])
    float* Q01   = pool + 7680000;           // [2][NN][128]
    unsigned short* q01h = (unsigned short*)(pool + 15360000); // 2*NN*128 shorts
    unsigned short* q01l = (unsigned short*)(pool + 19200000);
    float* R01   = pool + 23040000;          // [2][NN][16]
    float* T01   = pool + 24000000;          // [2][NN][16]
    // phase2 (branch2 + mi)
    unsigned short* Ph2   = (unsigned short*)pool;            // NN*128 shorts
    unsigned short* q2h   = (unsigned short*)(pool + 1920000);// NN*128 shorts
    float* R2    = pool + 3840000;           // NN*16
    float* T2    = pool + 4320000;           // NN*16
    unsigned short* Pmi16 = (unsigned short*)(pool + 4800000);// NN*384 shorts
    float* zQ    = pool + 10560000;          // 3*BT*128

    // --- persistent ---
    unsigned short* feat_hi = alloc_s((size_t)NN * FD);
    unsigned short* feat_lo = alloc_s((size_t)NN * FD);
    float* nv12 = alloc(2 * (size_t)EE);
    float* ebuf = alloc(2 * (size_t)EE);
    float* sa   = alloc(2 * NN);
    float* sb   = alloc(2 * NN);
    unsigned* rowmax = (unsigned*)alloc(2 * NN);  // adjacent with rowsum for one memset
    float* rowsum = alloc(2 * NN);
    float* w12 = alloc(2 * NN);
    float* bb  = alloc(2 * NN);
    float* stats = alloc((size_t)3 * 3 * BT);
    unsigned short* z16 = alloc_s((size_t)3 * BT * MH);
    int*   col_s1 = (int*)alloc(2 * (size_t)EE);
    float* val_s1 = alloc(2 * (size_t)EE);
    int*   col_s2 = (int*)alloc(2 * (size_t)EE);
    float* val_s2 = alloc(2 * (size_t)EE);
    int*   col_d1 = (int*)alloc(EE);
    float* val_d1 = alloc(EE);
    int*   col_d2 = (int*)alloc(EE);
    float* val_d2 = alloc(EE);
    int* rp_s = (int*)alloc(2 * (NN + 1));
    int* rp_d = (int*)alloc(2 * (NN + 1));
    int* cnt  = (int*)alloc(2 * NN);
    int* cur  = (int*)alloc(2 * NN);
    int* bsum = (int*)alloc(64);
    // weights (hi/lo, transposed, grouped)
    unsigned short* wgen12h = alloc_s(32768); unsigned short* wgen12l = alloc_s(32768);
    unsigned short* w1pairh = alloc_s(65536); unsigned short* w1pairl = alloc_s(65536);
    unsigned short* w1vh    = alloc_s(32768); unsigned short* w1vl    = alloc_s(32768);
    unsigned short* w2pairh = alloc_s(4096);  unsigned short* w2pairl = alloc_s(4096);
    unsigned short* w2vh    = alloc_s(2048);  unsigned short* w2vl    = alloc_s(2048);
    unsigned short* wgallh  = alloc_s(98304); unsigned short* wgalll  = alloc_s(98304);

    // ---- prep: splits ----
    split_bf16<<<((long)NN * FD + 255) / 256, 256, 0, stream>>>(feat, feat_hi, feat_lo, (long)NN * FD);
    {
        WSArgs a;
        a.s[0] = (const float*)d_in[6];  a.h[0] = wgen12h;          a.l[0] = wgen12l;
        a.s[1] = (const float*)d_in[9];  a.h[1] = wgen12h + 16384;  a.l[1] = wgen12l + 16384;
        a.s[2] = (const float*)d_in[12]; a.h[2] = w1pairh;          a.l[2] = w1pairl;
        a.s[3] = (const float*)d_in[14]; a.h[3] = w1pairh + 32768;  a.l[3] = w1pairl + 32768;
        a.s[4] = (const float*)d_in[16]; a.h[4] = w1vh;             a.l[4] = w1vl;
        a.s[5] = (const float*)d_in[13]; a.h[5] = w2pairh;          a.l[5] = w2pairl;
        a.s[6] = (const float*)d_in[15]; a.h[6] = w2pairh + 2048;   a.l[6] = w2pairl + 2048;
        a.s[7] = (const float*)d_in[17]; a.h[7] = w2vh;             a.l[7] = w2vl;
        a.s[8] = (const float*)d_in[18]; a.h[8] = wgallh;           a.l[8] = wgalll;
        a.s[9] = (const float*)d_in[19]; a.h[9] = wgallh + 32768;   a.l[9] = wgalll + 32768;
        a.s[10]= (const float*)d_in[20]; a.h[10]= wgallh + 65536;   a.l[10]= wgalll + 65536;
        wsplit_all<<<(235520 + 255) / 256, 256, 0, stream>>>(a);
    }

    const int NB = (NN + 1 + 1023) / 1024;
    const int GB = (NN + 127) / 128;

    // ---- dir CSR builds (both graphs) ----
    hipMemsetAsync(cnt, 0, 2 * NN * 4, stream);
    count_dir2<<<(EE + 255) / 256, 256, 0, stream>>>(ind1, ind2, cnt);
    scan_block2<<<dim3(NB, 2), 1024, 0, stream>>>(cnt, rp_d, bsum);
    scan_bsum2<<<2, 64, 0, stream>>>(bsum, NB);
    scan_add2<<<dim3(NB, 2), 1024, 0, stream>>>(bsum, rp_d, cur);
    scatter_dir2<<<(EE + 255) / 256, 256, 0, stream>>>(ind1, vals1, ind2, vals2, cur,
                                                       col_d1, val_d1, col_d2, val_d2);

    // ---- gen_view (both views) ----
    gemm3<8><<<dim3(GB, 1), 256, 0, stream>>>(feat_hi, feat_lo, 0, wgen12h, wgen12l, 0,
                                              FD, Pg, 128, 0, NN);
    spmm64_pair<<<dim3((NN + 15) / 16, 2), 256, 0, stream>>>(rp_d, col_d1, val_d1,
                                                             col_d2, val_d2, Pg, emb);
    node_scores_pair<<<dim3((NN + 3) / 4, 2), 256, 0, stream>>>(emb, Wm1, Wm2, sa, sb);
    hipMemsetAsync(rowmax, 0, 4 * NN * 4, stream);  // rowmax + rowsum (adjacent)
    edge_score_all<<<(2 * EE + 255) / 256, 256, 0, stream>>>(sa, sb, bm1, bm2, ind1, ind2, ebuf, rowmax);
    edge_exp_all<<<(2 * EE + 255) / 256, 256, 0, stream>>>(ind1, ind2, ebuf, rowmax, rowsum);
    edge_nv_all<<<(2 * EE + 255) / 256, 256, 0, stream>>>(ind1, ind2, ebuf, rowsum, vals1, vals2, nv12);

    // ---- sym CSR builds (both graphs) ----
    hipMemsetAsync(cnt, 0, 2 * NN * 4, stream);
    count_sym2<<<(EE + 255) / 256, 256, 0, stream>>>(ind1, ind2, cnt);
    scan_block2<<<dim3(NB, 2), 1024, 0, stream>>>(cnt, rp_s, bsum);
    scan_bsum2<<<2, 64, 0, stream>>>(bsum, NB);
    scan_add2<<<dim3(NB, 2), 1024, 0, stream>>>(bsum, rp_s, cur);
    scatter_sym2<<<(EE + 255) / 256, 256, 0, stream>>>(ind1, ind2, nv12, cur,
                                                       col_s1, val_s1, col_s2, val_s2);

    // ---- branches 0/1 (fp32-accurate; feeds top-2 weights) ----
    gemm3<8><<<dim3(GB, 2), 256, 0, stream>>>(feat_hi, feat_lo, 0, w1pairh, w1pairl, 32768,
                                              FD, P01, 256, 128, NN);
    spmm128_pair<<<dim3((NN + 7) / 8, 2), 256, 0, stream>>>(rp_s, col_s1, val_s1,
                                                            col_s2, val_s2, P01, Q01);
    split_bf16<<<((long)2 * NN * CH + 255) / 256, 256, 0, stream>>>(Q01, q01h, q01l, (long)2 * NN * CH);
    gemm3<1><<<dim3(GB, 2), 256, 0, stream>>>(q01h, q01l, (size_t)NN * CH, w2pairh, w2pairl, 2048,
                                              CH, R01, 16, (size_t)NN * NCLS, NN);
    spmm16_pair<<<dim3((NN + 63) / 64, 2), 256, 0, stream>>>(rp_s, col_s1, val_s1,
                                                             col_s2, val_s2, R01, T01);
    softmax16y<<<dim3((NN + 255) / 256, 2), 256, 0, stream>>>(T01, dout + (size_t)NN * NCLS, w12);
    bweights<<<(NN + 255) / 256, 256, 0, stream>>>(w12, bb);

    // ---- branch 2 (fused view; bf16 fast path) ----
    gemm1<8, true><<<dim3(GB, 1), 256, 0, stream>>>(feat_hi, w1vh, 0, FD, Ph2, 128, 0, NN);
    fused128_b16<<<(NN + 15) / 16, 256, 0, stream>>>(rp_s, col_s1, val_s1, col_s2, val_s2,
                                                     bb, Ph2, q2h);
    gemm1<1, false><<<dim3(GB, 1), 256, 0, stream>>>(q2h, w2vh, 0, CH, R2, 16, 0, NN);
    spmm16_fused<<<(NN + 63) / 64, 256, 0, stream>>>(rp_s, col_s1, val_s1, col_s2, val_s2,
                                                     bb, R2, T2);
    softmax16<<<(NN + 255) / 256, 256, 0, stream>>>(T2, dout);

    // ---- MI branch (bf16 fast path, batch rows only) ----
    gemm1<8, true><<<dim3(GB, 3), 256, 0, stream>>>(feat_hi, wgallh, 32768, FD, Pmi16, 384, 128, NN);
    rows_spmm_b16<<<dim3((BT + 15) / 16, 3), 256, 0, stream>>>(rp_s, col_s1, val_s1,
                                                               col_s2, val_s2, bb, idxb, Pmi16, zQ);
    proj_norm3<<<dim3(BT, 3), 128, 0, stream>>>(zQ, Wp1, bp1, Wp2, bp2, z16);

    // ---- contrast ----
    hipMemsetAsync(stats, 0, (size_t)3 * 3 * BT * 4, stream);
    contrast_direct<<<dim3(32, 32, 3), 256, 0, stream>>>(z16, stats);
    contrast_reduce<<<3, 256, 0, stream>>>(stats, dout + (size_t)3 * NN * NCLS);
}

// Round 7
// 1096.444 us; speedup vs baseline: 4.5228x; 1.0397x over previous
//
#include <hip/hip_runtime.h>
#include <math.h>

#define NN 30000
#define EE 480000
#define FD 256
#define CH 128
#define NCLS 16
#define GH 64
#define MH 128
#define BT 4096
#define CL1c 0.5f
#define CL2c 0.5f
#define LAMc 0.5f
#define ALPHAc 1.0f
#define TAUc 0.5f
#define EPSc 1e-8f

typedef __attribute__((ext_vector_type(8))) short short8;
typedef __attribute__((ext_vector_type(4))) float f32x4;

// ---------- helpers ----------
__device__ __forceinline__ unsigned enc_f32(float f) {
    unsigned b = __float_as_uint(f);
    return (b & 0x80000000u) ? ~b : (b | 0x80000000u);
}
__device__ __forceinline__ float dec_f32(unsigned u) {
    return (u & 0x80000000u) ? __uint_as_float(u ^ 0x80000000u) : __uint_as_float(~u);
}
__device__ __forceinline__ unsigned short f2bf(float x) {
    unsigned b = __float_as_uint(x);
    unsigned r = b + 0x7FFFu + ((b >> 16) & 1u);
    return (unsigned short)(r >> 16);
}
__device__ __forceinline__ float bf2f(unsigned short h) {
    return __uint_as_float(((unsigned)h) << 16);
}
__device__ __forceinline__ float4 fma4(float s, float4 x, float4 a) {
    a.x = fmaf(s, x.x, a.x); a.y = fmaf(s, x.y, a.y);
    a.z = fmaf(s, x.z, a.z); a.w = fmaf(s, x.w, a.w);
    return a;
}

// ---------- splits ----------
__global__ void split_bf16(const float* __restrict__ x, unsigned short* __restrict__ hi,
                           unsigned short* __restrict__ lo, long n) {
    long i = (long)blockIdx.x * 256 + threadIdx.x;
    if (i >= n) return;
    float v = x[i];
    unsigned short h = f2bf(v);
    hi[i] = h;
    lo[i] = f2bf(v - bf2f(h));
}

struct WSArgs {
    const float* s[11];
    unsigned short* h[11];
    unsigned short* l[11];
};
__global__ void wsplit_all(WSArgs a) {
    constexpr int KK[11]  = {256,256,256,256,256,128,128,128,256,256,256};
    constexpr int NNp[11] = {64, 64, 128,128,128,16, 16, 16, 128,128,128};
    constexpr int OFF[12] = {0,16384,32768,65536,98304,131072,133120,135168,137216,169984,202752,235520};
    int i = blockIdx.x * 256 + threadIdx.x;
    if (i >= 235520) return;
    int w = 0;
#pragma unroll
    for (int t = 1; t < 11; t++) if (i >= OFF[t]) w = t;
    int j = i - OFF[w];
    int K = KK[w], N = NNp[w];
    int k = j / N, n = j % N;
    float v = a.s[w][j];
    unsigned short hh = f2bf(v);
    a.h[w][(size_t)n * K + k] = hh;
    a.l[w][(size_t)n * K + k] = f2bf(v - bf2f(hh));
}

// ---------- 3-pass hi/lo MFMA GEMM ----------
template <int NT>
__global__ __launch_bounds__(256) void gemm3(
    const unsigned short* __restrict__ Ahi, const unsigned short* __restrict__ Alo, size_t yA,
    const unsigned short* __restrict__ BThi, const unsigned short* __restrict__ BTlo, size_t yB,
    int K, float* __restrict__ C, int Cstride, size_t yC, int M)
{
    Ahi += blockIdx.y * yA; Alo += blockIdx.y * yA;
    BThi += blockIdx.y * yB; BTlo += blockIdx.y * yB;
    C += blockIdx.y * yC;
    __shared__ unsigned short Ah[128 * 40], Al[128 * 40];
    __shared__ unsigned short Bh[NT * 16 * 40], Bl[NT * 16 * 40];
    int t = threadIdx.x;
    int w = t >> 6, l = t & 63;
    int lane = l & 15, quad = l >> 4;
    int row0 = blockIdx.x * 128;
    f32x4 acc[2][NT];
#pragma unroll
    for (int s = 0; s < 2; s++)
#pragma unroll
        for (int n = 0; n < NT; n++) acc[s][n] = (f32x4)(0.f);

    int ar = t >> 1, ako = (t & 1) << 4;
    int nkc = K >> 5;
    for (int kc = 0; kc < nkc; kc++) {
        int kb = kc << 5;
        {
            int gr = row0 + ar;
            float4 h0, h1, l0, l1;
            if (gr < M) {
                const float4* pH = (const float4*)&Ahi[(size_t)gr * K + kb + ako];
                const float4* pL = (const float4*)&Alo[(size_t)gr * K + kb + ako];
                h0 = pH[0]; h1 = pH[1]; l0 = pL[0]; l1 = pL[1];
            } else {
                h0 = h1 = l0 = l1 = make_float4(0.f, 0.f, 0.f, 0.f);
            }
            float4* dH = (float4*)&Ah[ar * 40 + ako];
            dH[0] = h0; dH[1] = h1;
            float4* dL = (float4*)&Al[ar * 40 + ako];
            dL[0] = l0; dL[1] = l1;
        }
        if (ar < NT * 16) {
            const float4* pH = (const float4*)&BThi[(size_t)ar * K + kb + ako];
            const float4* pL = (const float4*)&BTlo[(size_t)ar * K + kb + ako];
            float4 h0 = pH[0], h1 = pH[1], l0 = pL[0], l1 = pL[1];
            float4* dH = (float4*)&Bh[ar * 40 + ako];
            dH[0] = h0; dH[1] = h1;
            float4* dL = (float4*)&Bl[ar * 40 + ako];
            dL[0] = l0; dL[1] = l1;
        }
        __syncthreads();
        short8 aH[2], aL[2];
#pragma unroll
        for (int s = 0; s < 2; s++) {
            int r = w * 32 + s * 16 + lane;
            aH[s] = *(const short8*)&Ah[r * 40 + quad * 8];
            aL[s] = *(const short8*)&Al[r * 40 + quad * 8];
        }
#pragma unroll
        for (int n = 0; n < NT; n++) {
            int r = n * 16 + lane;
            short8 bH = *(const short8*)&Bh[r * 40 + quad * 8];
            short8 bL = *(const short8*)&Bl[r * 40 + quad * 8];
#pragma unroll
            for (int s = 0; s < 2; s++) {
                acc[s][n] = __builtin_amdgcn_mfma_f32_16x16x32_bf16(aH[s], bH, acc[s][n], 0, 0, 0);
                acc[s][n] = __builtin_amdgcn_mfma_f32_16x16x32_bf16(aH[s], bL, acc[s][n], 0, 0, 0);
                acc[s][n] = __builtin_amdgcn_mfma_f32_16x16x32_bf16(aL[s], bH, acc[s][n], 0, 0, 0);
            }
        }
        __syncthreads();
    }
#pragma unroll
    for (int s = 0; s < 2; s++) {
        int rb = row0 + w * 32 + s * 16 + quad * 4;
#pragma unroll
        for (int reg = 0; reg < 4; reg++) {
            int gr = rb + reg;
            if (gr >= M) continue;
#pragma unroll
            for (int n = 0; n < NT; n++)
                C[(size_t)gr * Cstride + n * 16 + lane] = acc[s][n][reg];
        }
    }
}

// ---------- 1-pass bf16 MFMA GEMM ----------
template <int NT, bool OUT16>
__global__ __launch_bounds__(256) void gemm1(
    const unsigned short* __restrict__ Ahi,
    const unsigned short* __restrict__ BThi, size_t yB,
    int K, void* __restrict__ Cv, int Cstride, size_t yC, int M)
{
    BThi += blockIdx.y * yB;
    __shared__ unsigned short Ah[128 * 40];
    __shared__ unsigned short Bh[NT * 16 * 40];
    int t = threadIdx.x;
    int w = t >> 6, l = t & 63;
    int lane = l & 15, quad = l >> 4;
    int row0 = blockIdx.x * 128;
    f32x4 acc[2][NT];
#pragma unroll
    for (int s = 0; s < 2; s++)
#pragma unroll
        for (int n = 0; n < NT; n++) acc[s][n] = (f32x4)(0.f);

    int ar = t >> 1, ako = (t & 1) << 4;
    int nkc = K >> 5;
    for (int kc = 0; kc < nkc; kc++) {
        int kb = kc << 5;
        {
            int gr = row0 + ar;
            float4 h0, h1;
            if (gr < M) {
                const float4* pH = (const float4*)&Ahi[(size_t)gr * K + kb + ako];
                h0 = pH[0]; h1 = pH[1];
            } else {
                h0 = h1 = make_float4(0.f, 0.f, 0.f, 0.f);
            }
            float4* dH = (float4*)&Ah[ar * 40 + ako];
            dH[0] = h0; dH[1] = h1;
        }
        if (ar < NT * 16) {
            const float4* pH = (const float4*)&BThi[(size_t)ar * K + kb + ako];
            float4 h0 = pH[0], h1 = pH[1];
            float4* dH = (float4*)&Bh[ar * 40 + ako];
            dH[0] = h0; dH[1] = h1;
        }
        __syncthreads();
        short8 aH[2];
#pragma unroll
        for (int s = 0; s < 2; s++)
            aH[s] = *(const short8*)&Ah[(w * 32 + s * 16 + lane) * 40 + quad * 8];
#pragma unroll
        for (int n = 0; n < NT; n++) {
            short8 bH = *(const short8*)&Bh[(n * 16 + lane) * 40 + quad * 8];
#pragma unroll
            for (int s = 0; s < 2; s++)
                acc[s][n] = __builtin_amdgcn_mfma_f32_16x16x32_bf16(aH[s], bH, acc[s][n], 0, 0, 0);
        }
        __syncthreads();
    }
#pragma unroll
    for (int s = 0; s < 2; s++) {
        int rb = row0 + w * 32 + s * 16 + quad * 4;
#pragma unroll
        for (int reg = 0; reg < 4; reg++) {
            int gr = rb + reg;
            if (gr >= M) continue;
#pragma unroll
            for (int n = 0; n < NT; n++) {
                if (OUT16) {
                    unsigned short* C = (unsigned short*)Cv + blockIdx.y * yC;
                    C[(size_t)gr * Cstride + n * 16 + lane] = f2bf(acc[s][n][reg]);
                } else {
                    float* C = (float*)Cv + blockIdx.y * yC;
                    C[(size_t)gr * Cstride + n * 16 + lane] = acc[s][n][reg];
                }
            }
        }
    }
}

// ---------- contrast: direct-from-L2 bf16 MFMA ----------
__global__ __launch_bounds__(256) void contrast_direct(
    const unsigned short* __restrict__ z16, float* __restrict__ stats)
{
    int p = blockIdx.z;
    int pa = (p == 2) ? 1 : 0;
    int pb = (p == 0) ? 1 : 2;
    const unsigned short* A = z16 + (size_t)pa * BT * MH;
    const unsigned short* B = z16 + (size_t)pb * BT * MH;
    float* diag = stats + (size_t)p * 3 * BT;
    float* rs = diag + BT;
    float* cs = rs + BT;
    int t = threadIdx.x;
    int w = t >> 6, l = t & 63, m = l & 15, quad = l >> 4;
    int i0 = blockIdx.y * 128, j0 = blockIdx.x * 128;

    short8 afr[2][4];
#pragma unroll
    for (int s = 0; s < 2; s++) {
        const unsigned short* arow = &A[(size_t)(i0 + w * 32 + s * 16 + m) * MH + quad * 8];
#pragma unroll
        for (int kc = 0; kc < 4; kc++)
            afr[s][kc] = *(const short8*)(arow + kc * 32);
    }
    f32x4 acc[2][8];
#pragma unroll
    for (int s = 0; s < 2; s++)
#pragma unroll
        for (int n = 0; n < 8; n++) acc[s][n] = (f32x4)(0.f);

#pragma unroll
    for (int kc = 0; kc < 4; kc++) {
#pragma unroll
        for (int n = 0; n < 8; n++) {
            short8 bf = *(const short8*)&B[(size_t)(j0 + n * 16 + m) * MH + kc * 32 + quad * 8];
            acc[0][n] = __builtin_amdgcn_mfma_f32_16x16x32_bf16(afr[0][kc], bf, acc[0][n], 0, 0, 0);
            acc[1][n] = __builtin_amdgcn_mfma_f32_16x16x32_bf16(afr[1][kc], bf, acc[1][n], 0, 0, 0);
        }
    }
    float colp[8];
#pragma unroll
    for (int n = 0; n < 8; n++) colp[n] = 0.f;
#pragma unroll
    for (int s = 0; s < 2; s++) {
        int rbase = i0 + w * 32 + s * 16 + quad * 4;
#pragma unroll
        for (int reg = 0; reg < 4; reg++) {
            float rsum = 0.f;
            int gi = rbase + reg;
#pragma unroll
            for (int n = 0; n < 8; n++) {
                float mv = expf(acc[s][n][reg] * 2.0f);
                rsum += mv;
                colp[n] += mv;
                int gj = j0 + n * 16 + m;
                if (gi == gj) diag[gi] = mv;
            }
            rsum += __shfl_xor(rsum, 1); rsum += __shfl_xor(rsum, 2);
            rsum += __shfl_xor(rsum, 4); rsum += __shfl_xor(rsum, 8);
            if (m == 0) atomicAdd(&rs[gi], rsum);
        }
    }
    __shared__ float scol[128];
    if (t < 128) scol[t] = 0.f;
    __syncthreads();
#pragma unroll
    for (int n = 0; n < 8; n++) {
        float v = colp[n];
        v += __shfl_xor(v, 16); v += __shfl_xor(v, 32);
        if (quad == (n & 3)) atomicAdd(&scol[n * 16 + m], v);
    }
    __syncthreads();
    if (t < 128) atomicAdd(&cs[j0 + t], scol[t]);
}

// ---------- unified CSR builds ----------
// cnt layout: [out1 | out2 | in1 | in2], each NN
__global__ void count_all(const int* __restrict__ i1, const int* __restrict__ i2,
                          int* __restrict__ cnt) {
    int e = blockIdx.x * 256 + threadIdx.x;
    if (e >= EE) return;
    atomicAdd(&cnt[i1[e]], 1);
    atomicAdd(&cnt[NN + i2[e]], 1);
    atomicAdd(&cnt[2 * NN + i1[EE + e]], 1);
    atomicAdd(&cnt[3 * NN + i2[EE + e]], 1);
}
// y: 0=dir1, 1=dir2, 2=sym1(out1+in1), 3=sym2(out2+in2)
__global__ __launch_bounds__(1024) void scan_block4(const int* __restrict__ cnt,
                                                    int* __restrict__ rowptr,
                                                    int* __restrict__ bsum) {
    int y = blockIdx.y;
    int* rp = rowptr + y * (NN + 1);
    int* bs = bsum + y * 32;
    __shared__ int tmp[1024];
    int t = threadIdx.x;
    int i = blockIdx.x * 1024 + t;
    int v = 0;
    if (i < NN) {
        if (y < 2) v = cnt[y * NN + i];
        else v = cnt[(y - 2) * NN + i] + cnt[y * NN + i];
    }
    tmp[t] = v;
    __syncthreads();
    for (int off = 1; off < 1024; off <<= 1) {
        int add = (t >= off) ? tmp[t - off] : 0;
        __syncthreads();
        tmp[t] += add;
        __syncthreads();
    }
    if (i <= NN) rp[i] = tmp[t] - v;
    if (t == 1023) bs[blockIdx.x] = tmp[1023];
}
__global__ void scan_bsum4(int* __restrict__ bsum, int nb) {
    bsum += blockIdx.x * 32;
    int t = threadIdx.x;
    int orig = (t < nb) ? bsum[t] : 0;
    int v = orig;
    for (int off = 1; off < 64; off <<= 1) {
        int u = __shfl_up(v, off);
        if (t >= off) v += u;
    }
    if (t < nb) bsum[t] = v - orig;
}
__global__ void scan_add4(const int* __restrict__ bsum, int* __restrict__ rowptr,
                          int* __restrict__ cursor) {
    int y = blockIdx.y;
    const int* bs = bsum + y * 32;
    int* rp = rowptr + y * (NN + 1);
    int* cur = cursor + y * NN;
    int i = blockIdx.x * 1024 + threadIdx.x;
    if (i <= NN) {
        int r = rp[i] + bs[blockIdx.x];
        rp[i] = r;
        if (i < NN) cur[i] = r;
    }
}
// packed (col,val) entries
__global__ void scatter_dir2(const int* __restrict__ i1, const float* __restrict__ v1,
                             const int* __restrict__ i2, const float* __restrict__ v2,
                             int* __restrict__ cur,
                             int2* __restrict__ ed1, int2* __restrict__ ed2) {
    int e = blockIdx.x * 256 + threadIdx.x;
    if (e >= EE) return;
    int p = atomicAdd(&cur[i1[e]], 1);
    ed1[p] = make_int2(i1[EE + e], __float_as_int(v1[e]));
    p = atomicAdd(&cur[NN + i2[e]], 1);
    ed2[p] = make_int2(i2[EE + e], __float_as_int(v2[e]));
}
__global__ void scatter_sym2(const int* __restrict__ i1, const int* __restrict__ i2,
                             const float* __restrict__ nv12, int* __restrict__ cur,
                             int2* __restrict__ es1, int2* __restrict__ es2) {
    int e = blockIdx.x * 256 + threadIdx.x;
    if (e >= EE) return;
    int r = i1[e], c = i1[EE + e];
    int vb = __float_as_int(nv12[e]);
    int p = atomicAdd(&cur[2 * NN + r], 1);
    es1[p] = make_int2(c, vb);
    p = atomicAdd(&cur[2 * NN + c], 1);
    es1[p] = make_int2(r, vb);
    r = i2[e]; c = i2[EE + e];
    vb = __float_as_int(nv12[EE + e]);
    p = atomicAdd(&cur[3 * NN + r], 1);
    es2[p] = make_int2(c, vb);
    p = atomicAdd(&cur[3 * NN + c], 1);
    es2[p] = make_int2(r, vb);
}

// ---------- fp32 SpMM pairs (packed entries) ----------
__global__ __launch_bounds__(256) void spmm64_pair(
    const int* __restrict__ rp_d, const int2* __restrict__ e1, const int2* __restrict__ e2,
    const float* __restrict__ Pg, float* __restrict__ emb)
{
    int y = blockIdx.y;
    const int* rp = rp_d + y * (NN + 1);
    const int2* arr = y ? e2 : e1;
    int row = blockIdx.x * 16 + threadIdx.x / 16;
    int o = threadIdx.x % 16;
    if (row >= NN) return;
    const float4* x4 = (const float4*)Pg;
    int p0 = rp[row], p1 = rp[row + 1];
    float4 a0 = {0,0,0,0}, a1 = {0,0,0,0}, a2 = {0,0,0,0}, a3 = {0,0,0,0};
    int xo = y * 16 + o;
    int j = p0;
    for (; j + 4 <= p1; j += 4) {
        int2 q0 = arr[j], q1 = arr[j+1], q2 = arr[j+2], q3 = arr[j+3];
        a0 = fma4(__int_as_float(q0.y), x4[(size_t)q0.x * 32 + xo], a0);
        a1 = fma4(__int_as_float(q1.y), x4[(size_t)q1.x * 32 + xo], a1);
        a2 = fma4(__int_as_float(q2.y), x4[(size_t)q2.x * 32 + xo], a2);
        a3 = fma4(__int_as_float(q3.y), x4[(size_t)q3.x * 32 + xo], a3);
    }
    for (; j < p1; j++) {
        int2 q = arr[j];
        a0 = fma4(__int_as_float(q.y), x4[(size_t)q.x * 32 + xo], a0);
    }
    float4 r;
    r.x = fmaxf((a0.x + a1.x) + (a2.x + a3.x), 0.f);
    r.y = fmaxf((a0.y + a1.y) + (a2.y + a3.y), 0.f);
    r.z = fmaxf((a0.z + a1.z) + (a2.z + a3.z), 0.f);
    r.w = fmaxf((a0.w + a1.w) + (a2.w + a3.w), 0.f);
    ((float4*)emb)[((size_t)y * NN + row) * 16 + o] = r;
}

__global__ __launch_bounds__(256) void spmm128_pair(
    const int* __restrict__ rp_s, const int2* __restrict__ e1, const int2* __restrict__ e2,
    const float* __restrict__ P01, float* __restrict__ Q01)
{
    int y = blockIdx.y;
    const int* rp = rp_s + y * (NN + 1);
    const int2* arr = y ? e2 : e1;
    int row = blockIdx.x * 8 + threadIdx.x / 32;
    int o = threadIdx.x % 32;
    if (row >= NN) return;
    const float4* x4 = (const float4*)P01;
    int p0 = rp[row], p1 = rp[row + 1];
    float4 a0 = {0,0,0,0}, a1 = {0,0,0,0}, a2 = {0,0,0,0}, a3 = {0,0,0,0};
    int xo = y * 32 + o;
    int j = p0;
    for (; j + 4 <= p1; j += 4) {
        int2 q0 = arr[j], q1 = arr[j+1], q2 = arr[j+2], q3 = arr[j+3];
        a0 = fma4(__int_as_float(q0.y), x4[(size_t)q0.x * 64 + xo], a0);
        a1 = fma4(__int_as_float(q1.y), x4[(size_t)q1.x * 64 + xo], a1);
        a2 = fma4(__int_as_float(q2.y), x4[(size_t)q2.x * 64 + xo], a2);
        a3 = fma4(__int_as_float(q3.y), x4[(size_t)q3.x * 64 + xo], a3);
    }
    for (; j < p1; j++) {
        int2 q = arr[j];
        a0 = fma4(__int_as_float(q.y), x4[(size_t)q.x * 64 + xo], a0);
    }
    float4 r;
    r.x = fmaxf((a0.x + a1.x) + (a2.x + a3.x), 0.f);
    r.y = fmaxf((a0.y + a1.y) + (a2.y + a3.y), 0.f);
    r.z = fmaxf((a0.z + a1.z) + (a2.z + a3.z), 0.f);
    r.w = fmaxf((a0.w + a1.w) + (a2.w + a3.w), 0.f);
    ((float4*)Q01)[((size_t)y * NN + row) * 32 + o] = r;
}

__global__ __launch_bounds__(256) void spmm16_pair(
    const int* __restrict__ rp_s, const int2* __restrict__ e1, const int2* __restrict__ e2,
    const float* __restrict__ R01, float* __restrict__ T01)
{
    int y = blockIdx.y;
    const int* rp = rp_s + y * (NN + 1);
    const int2* arr = y ? e2 : e1;
    int row = blockIdx.x * 64 + threadIdx.x / 4;
    int o = threadIdx.x % 4;
    if (row >= NN) return;
    const float4* x4 = (const float4*)(R01 + (size_t)y * NN * 16);
    int p0 = rp[row], p1 = rp[row + 1];
    float4 a0 = {0,0,0,0}, a1 = {0,0,0,0}, a2 = {0,0,0,0}, a3 = {0,0,0,0};
    int j = p0;
    for (; j + 4 <= p1; j += 4) {
        int2 q0 = arr[j], q1 = arr[j+1], q2 = arr[j+2], q3 = arr[j+3];
        a0 = fma4(__int_as_float(q0.y), x4[(size_t)q0.x * 4 + o], a0);
        a1 = fma4(__int_as_float(q1.y), x4[(size_t)q1.x * 4 + o], a1);
        a2 = fma4(__int_as_float(q2.y), x4[(size_t)q2.x * 4 + o], a2);
        a3 = fma4(__int_as_float(q3.y), x4[(size_t)q3.x * 4 + o], a3);
    }
    for (; j < p1; j++) {
        int2 q = arr[j];
        a0 = fma4(__int_as_float(q.y), x4[(size_t)q.x * 4 + o], a0);
    }
    float4 r;
    r.x = (a0.x + a1.x) + (a2.x + a3.x);
    r.y = (a0.y + a1.y) + (a2.y + a3.y);
    r.z = (a0.z + a1.z) + (a2.z + a3.z);
    r.w = (a0.w + a1.w) + (a2.w + a3.w);
    ((float4*)(T01 + (size_t)y * NN * 16))[(size_t)row * 4 + o] = r;
}

__global__ __launch_bounds__(256) void spmm16_fused(
    const int* __restrict__ rp_s, const int2* __restrict__ e1, const int2* __restrict__ e2,
    const float* __restrict__ bb, const float* __restrict__ x, float* __restrict__ out)
{
    int row = blockIdx.x * 64 + threadIdx.x / 4;
    int o = threadIdx.x % 4;
    if (row >= NN) return;
    const float4* x4 = (const float4*)x;
    float4 s1 = {0,0,0,0}, s2 = {0,0,0,0};
    {
        const int* rp = rp_s;
        int p0 = rp[row], p1 = rp[row + 1];
        float4 a0 = {0,0,0,0}, a1 = {0,0,0,0};
        int j = p0;
        for (; j + 2 <= p1; j += 2) {
            int2 q0 = e1[j], q1 = e1[j+1];
            a0 = fma4(__int_as_float(q0.y), x4[(size_t)q0.x * 4 + o], a0);
            a1 = fma4(__int_as_float(q1.y), x4[(size_t)q1.x * 4 + o], a1);
        }
        for (; j < p1; j++) {
            int2 q = e1[j];
            a0 = fma4(__int_as_float(q.y), x4[(size_t)q.x * 4 + o], a0);
        }
        s1.x = a0.x + a1.x; s1.y = a0.y + a1.y; s1.z = a0.z + a1.z; s1.w = a0.w + a1.w;
    }
    {
        const int* rp = rp_s + (NN + 1);
        int p0 = rp[row], p1 = rp[row + 1];
        float4 a0 = {0,0,0,0}, a1 = {0,0,0,0};
        int j = p0;
        for (; j + 2 <= p1; j += 2) {
            int2 q0 = e2[j], q1 = e2[j+1];
            a0 = fma4(__int_as_float(q0.y), x4[(size_t)q0.x * 4 + o], a0);
            a1 = fma4(__int_as_float(q1.y), x4[(size_t)q1.x * 4 + o], a1);
        }
        for (; j < p1; j++) {
            int2 q = e2[j];
            a0 = fma4(__int_as_float(q.y), x4[(size_t)q.x * 4 + o], a0);
        }
        s2.x = a0.x + a1.x; s2.y = a0.y + a1.y; s2.z = a0.z + a1.z; s2.w = a0.w + a1.w;
    }
    float w1 = bb[row], w2 = bb[NN + row];
    float4 r;
    r.x = w1 * s1.x + w2 * s2.x;
    r.y = w1 * s1.y + w2 * s2.y;
    r.z = w1 * s1.z + w2 * s2.z;
    r.w = w1 * s1.w + w2 * s2.w;
    ((float4*)out)[(size_t)row * 4 + o] = r;
}

// ---------- bf16-gather helper (packed entries) ----------
__device__ __forceinline__ void gather_b16(
    const int* __restrict__ rp, const int2* __restrict__ arr,
    int row, const unsigned short* __restrict__ X, int xstride, int o, float* acc)
{
    int p0 = rp[row], p1 = rp[row + 1];
    int j = p0;
    for (; j + 4 <= p1; j += 4) {
        int2 q0 = arr[j], q1 = arr[j+1], q2 = arr[j+2], q3 = arr[j+3];
        short8 x0 = *(const short8*)&X[(size_t)q0.x * xstride + o * 8];
        short8 x1 = *(const short8*)&X[(size_t)q1.x * xstride + o * 8];
        short8 x2 = *(const short8*)&X[(size_t)q2.x * xstride + o * 8];
        short8 x3 = *(const short8*)&X[(size_t)q3.x * xstride + o * 8];
        float v0 = __int_as_float(q0.y), v1 = __int_as_float(q1.y);
        float v2 = __int_as_float(q2.y), v3 = __int_as_float(q3.y);
#pragma unroll
        for (int k = 0; k < 8; k++) {
            acc[k] = fmaf(v0, bf2f((unsigned short)x0[k]), acc[k]);
            acc[k] = fmaf(v1, bf2f((unsigned short)x1[k]), acc[k]);
            acc[k] = fmaf(v2, bf2f((unsigned short)x2[k]), acc[k]);
            acc[k] = fmaf(v3, bf2f((unsigned short)x3[k]), acc[k]);
        }
    }
    for (; j < p1; j++) {
        int2 q = arr[j];
        short8 xv = *(const short8*)&X[(size_t)q.x * xstride + o * 8];
        float v = __int_as_float(q.y);
#pragma unroll
        for (int k = 0; k < 8; k++)
            acc[k] = fmaf(v, bf2f((unsigned short)xv[k]), acc[k]);
    }
}

__global__ __launch_bounds__(256) void fused128_b16(
    const int* __restrict__ rp_s, const int2* __restrict__ e1, const int2* __restrict__ e2,
    const float* __restrict__ bb, const unsigned short* __restrict__ X,
    unsigned short* __restrict__ Out)
{
    int row = blockIdx.x * 16 + threadIdx.x / 16;
    int o = threadIdx.x % 16;
    if (row >= NN) return;
    float a1[8] = {}, a2[8] = {};
    gather_b16(rp_s, e1, row, X, 128, o, a1);
    gather_b16(rp_s + (NN + 1), e2, row, X, 128, o, a2);
    float w1 = bb[row], w2 = bb[NN + row];
    short8 outv;
#pragma unroll
    for (int k = 0; k < 8; k++) {
        float r = fmaxf(w1 * a1[k] + w2 * a2[k], 0.f);
        outv[k] = (short)f2bf(r);
    }
    *(short8*)&Out[(size_t)row * 128 + o * 8] = outv;
}

__global__ __launch_bounds__(256) void rows_spmm_b16(
    const int* __restrict__ rp_s, const int2* __restrict__ e1, const int2* __restrict__ e2,
    const float* __restrict__ bb, const int* __restrict__ rows,
    const unsigned short* __restrict__ Pmi, float* __restrict__ zQ)
{
    int y = blockIdx.y;
    int ri = blockIdx.x * 16 + threadIdx.x / 16;
    int o = threadIdx.x % 16;
    if (ri >= BT) return;
    int node = rows[ri];
    int xoff = (y == 0) ? 0 : ((y == 1) ? 128 : 256);
    const unsigned short* X = Pmi + xoff;
    float acc[8] = {};
    if (y == 0) {
        float a1[8] = {}, a2[8] = {};
        gather_b16(rp_s, e1, node, X, 384, o, a1);
        gather_b16(rp_s + (NN + 1), e2, node, X, 384, o, a2);
        float w1 = bb[node], w2 = bb[NN + node];
#pragma unroll
        for (int k = 0; k < 8; k++) acc[k] = w1 * a1[k] + w2 * a2[k];
    } else if (y == 1) {
        gather_b16(rp_s, e1, node, X, 384, o, acc);
    } else {
        gather_b16(rp_s + (NN + 1), e2, node, X, 384, o, acc);
    }
    float* out = zQ + ((size_t)y * BT + ri) * 128 + o * 8;
#pragma unroll
    for (int k = 0; k < 8; k++) out[k] = fmaxf(acc[k], 0.f);
}

// ---------- gen_view edge-score pipeline ----------
__global__ __launch_bounds__(256) void node_scores_pair(
    const float* __restrict__ emb, const float* __restrict__ Wm1,
    const float* __restrict__ Wm2, float* __restrict__ sa, float* __restrict__ sb)
{
    int y = blockIdx.y;
    const float* e_ = emb + (size_t)y * NN * GH;
    const float* Wm = y ? Wm2 : Wm1;
    int node = blockIdx.x * 4 + threadIdx.x / 64;
    int lane = threadIdx.x % 64;
    if (node >= NN) return;
    float e = e_[(size_t)node * GH + lane];
    float va = e * Wm[lane];
    float vb = e * Wm[GH + lane];
#pragma unroll
    for (int off = 32; off; off >>= 1) {
        va += __shfl_down(va, off);
        vb += __shfl_down(vb, off);
    }
    if (lane == 0) { sa[y * NN + node] = va; sb[y * NN + node] = vb; }
}

__global__ void edge_score_all(const float* __restrict__ sa, const float* __restrict__ sb,
                               const float* __restrict__ bm1, const float* __restrict__ bm2,
                               const int* __restrict__ i1, const int* __restrict__ i2,
                               float* __restrict__ ebuf, unsigned* __restrict__ rowmax)
{
    int g = blockIdx.x * 256 + threadIdx.x;
    if (g >= 2 * EE) return;
    int view = g >= EE;
    int e = g - view * EE;
    const int* ind = view ? i2 : i1;
    int r = ind[e], c = ind[EE + e];
    float s = sa[view * NN + r] + sb[view * NN + c] + (view ? bm2[0] : bm1[0]);
    ebuf[g] = s;
    atomicMax(&rowmax[view * NN + r], enc_f32(s));
}

__global__ void edge_exp_all(const int* __restrict__ i1, const int* __restrict__ i2,
                             float* __restrict__ ebuf, const unsigned* __restrict__ rowmax,
                             float* __restrict__ rowsum)
{
    int g = blockIdx.x * 256 + threadIdx.x;
    if (g >= 2 * EE) return;
    int view = g >= EE;
    int e = g - view * EE;
    const int* ind = view ? i2 : i1;
    int r = ind[e];
    float ex = expf(ebuf[g] - dec_f32(rowmax[view * NN + r]));
    ebuf[g] = ex;
    atomicAdd(&rowsum[view * NN + r], ex);
}

__global__ void edge_nv_all(const int* __restrict__ i1, const int* __restrict__ i2,
                            const float* __restrict__ ebuf, const float* __restrict__ rowsum,
                            const float* __restrict__ v1, const float* __restrict__ v2,
                            float* __restrict__ nv12)
{
    int g = blockIdx.x * 256 + threadIdx.x;
    if (g >= 2 * EE) return;
    int view = g >= EE;
    int e = g - view * EE;
    const int* ind = view ? i2 : i1;
    const float* vals = view ? v2 : v1;
    int r = ind[e];
    float coml = view ? CL2c : CL1c;
    nv12[g] = vals[e] + coml * ebuf[g] / rowsum[view * NN + r];
}

// ---------- softmax / weights ----------
__global__ void softmax16y(const float* __restrict__ S01, float* __restrict__ logits_base,
                           float* __restrict__ w12)
{
    int y = blockIdx.y;
    const float* S = S01 + (size_t)y * NN * NCLS;
    float* logits = logits_base + (size_t)y * NN * NCLS;
    float* w = w12 + (size_t)y * NN;
    int node = blockIdx.x * 256 + threadIdx.x;
    if (node >= NN) return;
    float v[NCLS];
    float mx = -3.4e38f;
#pragma unroll
    for (int j = 0; j < NCLS; j++) { v[j] = S[(size_t)node * NCLS + j]; mx = fmaxf(mx, v[j]); }
    float s = 0.f;
#pragma unroll
    for (int j = 0; j < NCLS; j++) { v[j] = expf(v[j] - mx); s += v[j]; }
    float inv = 1.f / s;
    float fir = -1.f, sec = -1.f;
#pragma unroll
    for (int j = 0; j < NCLS; j++) {
        float p = v[j] * inv;
        logits[(size_t)node * NCLS + j] = logf(p + EPSc);
        if (p > fir) { sec = fir; fir = p; }
        else if (p > sec) { sec = p; }
    }
    w[node] = expf(ALPHAc * (LAMc * logf(fir + EPSc) + (1.f - LAMc) * logf(fir - sec + EPSc)));
}

__global__ void softmax16(const float* __restrict__ S, float* __restrict__ logits)
{
    int node = blockIdx.x * 256 + threadIdx.x;
    if (node >= NN) return;
    float v[NCLS];
    float mx = -3.4e38f;
#pragma unroll
    for (int j = 0; j < NCLS; j++) { v[j] = S[(size_t)node * NCLS + j]; mx = fmaxf(mx, v[j]); }
    float s = 0.f;
#pragma unroll
    for (int j = 0; j < NCLS; j++) { v[j] = expf(v[j] - mx); s += v[j]; }
    float inv = 1.f / s;
#pragma unroll
    for (int j = 0; j < NCLS; j++)
        logits[(size_t)node * NCLS + j] = logf(v[j] * inv + EPSc);
}

__global__ void bweights(const float* __restrict__ w12, float* __restrict__ bb)
{
    int i = blockIdx.x * 256 + threadIdx.x;
    if (i >= NN) return;
    float a = w12[i], b = w12[NN + i];
    float inv = 1.f / (a + b);
    bb[i] = a * inv;
    bb[NN + i] = b * inv;
}

// ---------- projection head + L2-normalize, bf16 out ----------
__global__ __launch_bounds__(128) void proj_norm3(
    const float* __restrict__ zQ,
    const float* __restrict__ Wp1, const float* __restrict__ bp1,
    const float* __restrict__ Wp2, const float* __restrict__ bp2,
    unsigned short* __restrict__ z16)
{
    __shared__ float g[MH], u[MH];
    __shared__ float red[2];
    size_t i = (size_t)blockIdx.y * BT + blockIdx.x;
    int t = threadIdx.x;
    g[t] = zQ[i * MH + t];
    __syncthreads();
    float acc = bp1[t];
    for (int k = 0; k < MH; k++) acc = fmaf(g[k], Wp1[k * MH + t], acc);
    u[t] = acc > 0.f ? acc : (expf(acc) - 1.f);
    __syncthreads();
    float acc2 = bp2[t];
    for (int k = 0; k < MH; k++) acc2 = fmaf(u[k], Wp2[k * MH + t], acc2);
    float sq = acc2 * acc2;
#pragma unroll
    for (int off = 32; off; off >>= 1) sq += __shfl_down(sq, off);
    if ((t & 63) == 0) red[t >> 6] = sq;
    __syncthreads();
    float nrm = sqrtf(red[0] + red[1]);
    z16[i * MH + t] = f2bf(acc2 / nrm);
}

__global__ void contrast_reduce(const float* __restrict__ stats, float* __restrict__ out3)
{
    int p = blockIdx.x, t = threadIdx.x;
    const float* diag = stats + (size_t)p * 3 * BT;
    const float* rs = diag + BT;
    const float* cs = rs + BT;
    float s1 = 0.f, s2 = 0.f;
    for (int i = t; i < BT; i += 256) {
        float d = diag[i];
        s1 += logf(d / (rs[i] + EPSc) + EPSc);
        s2 += logf(d / (cs[i] + EPSc) + EPSc);
    }
#pragma unroll
    for (int off = 32; off; off >>= 1) { s1 += __shfl_down(s1, off); s2 += __shfl_down(s2, off); }
    __shared__ float sh[8];
    if ((t & 63) == 0) { sh[(t >> 6) * 2] = s1; sh[(t >> 6) * 2 + 1] = s2; }
    __syncthreads();
    if (t == 0) {
        float a = sh[0] + sh[2] + sh[4] + sh[6];
        float b = sh[1] + sh[3] + sh[5] + sh[7];
        out3[p] = 0.5f * (-a / BT - b / BT);
    }
}

// ---------- host ----------
extern "C" void kernel_launch(void* const* d_in, const int* in_sizes, int n_in,
                              void* d_out, int out_size, void* d_ws, size_t ws_size,
                              hipStream_t stream)
{
    const float* feat   = (const float*)d_in[0];
    const int*   ind1   = (const int*)d_in[1];
    const float* vals1  = (const float*)d_in[2];
    const int*   ind2   = (const int*)d_in[3];
    const float* vals2  = (const float*)d_in[4];
    const int*   idxb   = (const int*)d_in[5];
    const float* Wm1    = (const float*)d_in[7];
    const float* bm1    = (const float*)d_in[8];
    const float* Wm2    = (const float*)d_in[10];
    const float* bm2    = (const float*)d_in[11];
    const float* Wp1    = (const float*)d_in[21];
    const float* bp1    = (const float*)d_in[22];
    const float* Wp2    = (const float*)d_in[23];
    const float* bp2    = (const float*)d_in[24];
    float* dout = (float*)d_out;

    float* ws = (float*)d_ws;
    size_t off = 0;
    auto alloc = [&](size_t n) { n = (n + 3) & ~(size_t)3; float* p = ws + off; off += n; return p; };
    auto alloc_s = [&](size_t n) { return (unsigned short*)alloc((n + 1) / 2); };

    // --- shared pool (phases: gen -> branch01 -> branch2/mi) ---
    float* pool = alloc(24960000);
    float* Pg  = pool;                       // NN*128
    float* emb = pool + 3840000;             // 2*NN*64
    float* P01   = pool;                     // [NN][256]
    float* Q01   = pool + 7680000;           // [2][NN][128]
    unsigned short* q01h = (unsigned short*)(pool + 15360000);
    unsigned short* q01l = (unsigned short*)(pool + 19200000);
    float* R01   = pool + 23040000;          // [2][NN][16]
    float* T01   = pool + 24000000;          // [2][NN][16]
    unsigned short* Ph2   = (unsigned short*)pool;
    unsigned short* q2h   = (unsigned short*)(pool + 1920000);
    float* R2    = pool + 3840000;
    float* T2    = pool + 4320000;
    unsigned short* Pmi16 = (unsigned short*)(pool + 4800000);
    float* zQ    = pool + 10560000;          // 3*BT*128

    // --- persistent ---
    unsigned short* feat_hi = alloc_s((size_t)NN * FD);
    unsigned short* feat_lo = alloc_s((size_t)NN * FD);
    float* nv12 = alloc(2 * (size_t)EE);
    float* ebuf = alloc(2 * (size_t)EE);
    float* sa   = alloc(2 * NN);
    float* sb   = alloc(2 * NN);
    unsigned* rowmax = (unsigned*)alloc(2 * NN);  // adjacent with rowsum
    float* rowsum = alloc(2 * NN);
    float* w12 = alloc(2 * NN);
    float* bb  = alloc(2 * NN);
    float* stats = alloc((size_t)3 * 3 * BT);
    unsigned short* z16 = alloc_s((size_t)3 * BT * MH);
    int2* es1 = (int2*)alloc(4 * (size_t)EE);
    int2* es2 = (int2*)alloc(4 * (size_t)EE);
    int2* ed1 = (int2*)alloc(2 * (size_t)EE);
    int2* ed2 = (int2*)alloc(2 * (size_t)EE);
    int* rp4  = (int*)alloc(4 * (NN + 1));
    int* cnt4 = (int*)alloc(4 * NN);
    int* cur4 = (int*)alloc(4 * NN);
    int* bsum = (int*)alloc(128);
    int* rp_d = rp4;
    int* rp_s = rp4 + 2 * (NN + 1);
    // weights
    unsigned short* wgen12h = alloc_s(32768); unsigned short* wgen12l = alloc_s(32768);
    unsigned short* w1pairh = alloc_s(65536); unsigned short* w1pairl = alloc_s(65536);
    unsigned short* w1vh    = alloc_s(32768); unsigned short* w1vl    = alloc_s(32768);
    unsigned short* w2pairh = alloc_s(4096);  unsigned short* w2pairl = alloc_s(4096);
    unsigned short* w2vh    = alloc_s(2048);  unsigned short* w2vl    = alloc_s(2048);
    unsigned short* wgallh  = alloc_s(98304); unsigned short* wgalll  = alloc_s(98304);

    // ---- prep ----
    split_bf16<<<((long)NN * FD + 255) / 256, 256, 0, stream>>>(feat, feat_hi, feat_lo, (long)NN * FD);
    {
        WSArgs a;
        a.s[0] = (const float*)d_in[6];  a.h[0] = wgen12h;          a.l[0] = wgen12l;
        a.s[1] = (const float*)d_in[9];  a.h[1] = wgen12h + 16384;  a.l[1] = wgen12l + 16384;
        a.s[2] = (const float*)d_in[12]; a.h[2] = w1pairh;          a.l[2] = w1pairl;
        a.s[3] = (const float*)d_in[14]; a.h[3] = w1pairh + 32768;  a.l[3] = w1pairl + 32768;
        a.s[4] = (const float*)d_in[16]; a.h[4] = w1vh;             a.l[4] = w1vl;
        a.s[5] = (const float*)d_in[13]; a.h[5] = w2pairh;          a.l[5] = w2pairl;
        a.s[6] = (const float*)d_in[15]; a.h[6] = w2pairh + 2048;   a.l[6] = w2pairl + 2048;
        a.s[7] = (const float*)d_in[17]; a.h[7] = w2vh;             a.l[7] = w2vl;
        a.s[8] = (const float*)d_in[18]; a.h[8] = wgallh;           a.l[8] = wgalll;
        a.s[9] = (const float*)d_in[19]; a.h[9] = wgallh + 32768;   a.l[9] = wgalll + 32768;
        a.s[10]= (const float*)d_in[20]; a.h[10]= wgallh + 65536;   a.l[10]= wgalll + 65536;
        wsplit_all<<<(235520 + 255) / 256, 256, 0, stream>>>(a);
    }

    const int NB = (NN + 1 + 1023) / 1024;
    const int GB = (NN + 127) / 128;

    // ---- unified CSR counts/scans (all 4 rowptrs + cursors up front) ----
    hipMemsetAsync(cnt4, 0, 4 * NN * 4, stream);
    count_all<<<(EE + 255) / 256, 256, 0, stream>>>(ind1, ind2, cnt4);
    scan_block4<<<dim3(NB, 4), 1024, 0, stream>>>(cnt4, rp4, bsum);
    scan_bsum4<<<4, 64, 0, stream>>>(bsum, NB);
    scan_add4<<<dim3(NB, 4), 1024, 0, stream>>>(bsum, rp4, cur4);
    scatter_dir2<<<(EE + 255) / 256, 256, 0, stream>>>(ind1, vals1, ind2, vals2, cur4, ed1, ed2);

    // ---- gen_view (both views) ----
    gemm3<8><<<dim3(GB, 1), 256, 0, stream>>>(feat_hi, feat_lo, 0, wgen12h, wgen12l, 0,
                                              FD, Pg, 128, 0, NN);
    spmm64_pair<<<dim3((NN + 15) / 16, 2), 256, 0, stream>>>(rp_d, ed1, ed2, Pg, emb);
    node_scores_pair<<<dim3((NN + 3) / 4, 2), 256, 0, stream>>>(emb, Wm1, Wm2, sa, sb);
    hipMemsetAsync(rowmax, 0, 4 * NN * 4, stream);
    edge_score_all<<<(2 * EE + 255) / 256, 256, 0, stream>>>(sa, sb, bm1, bm2, ind1, ind2, ebuf, rowmax);
    edge_exp_all<<<(2 * EE + 255) / 256, 256, 0, stream>>>(ind1, ind2, ebuf, rowmax, rowsum);
    edge_nv_all<<<(2 * EE + 255) / 256, 256, 0, stream>>>(ind1, ind2, ebuf, rowsum, vals1, vals2, nv12);

    // ---- sym scatter (packed) ----
    scatter_sym2<<<(EE + 255) / 256, 256, 0, stream>>>(ind1, ind2, nv12, cur4, es1, es2);

    // ---- branches 0/1 (fp32-accurate) ----
    gemm3<8><<<dim3(GB, 2), 256, 0, stream>>>(feat_hi, feat_lo, 0, w1pairh, w1pairl, 32768,
                                              FD, P01, 256, 128, NN);
    spmm128_pair<<<dim3((NN + 7) / 8, 2), 256, 0, stream>>>(rp_s, es1, es2, P01, Q01);
    split_bf16<<<((long)2 * NN * CH + 255) / 256, 256, 0, stream>>>(Q01, q01h, q01l, (long)2 * NN * CH);
    gemm3<1><<<dim3(GB, 2), 256, 0, stream>>>(q01h, q01l, (size_t)NN * CH, w2pairh, w2pairl, 2048,
                                              CH, R01, 16, (size_t)NN * NCLS, NN);
    spmm16_pair<<<dim3((NN + 63) / 64, 2), 256, 0, stream>>>(rp_s, es1, es2, R01, T01);
    softmax16y<<<dim3((NN + 255) / 256, 2), 256, 0, stream>>>(T01, dout + (size_t)NN * NCLS, w12);
    bweights<<<(NN + 255) / 256, 256, 0, stream>>>(w12, bb);

    // ---- branch 2 (bf16 fast path) ----
    gemm1<8, true><<<dim3(GB, 1), 256, 0, stream>>>(feat_hi, w1vh, 0, FD, Ph2, 128, 0, NN);
    fused128_b16<<<(NN + 15) / 16, 256, 0, stream>>>(rp_s, es1, es2, bb, Ph2, q2h);
    gemm1<1, false><<<dim3(GB, 1), 256, 0, stream>>>(q2h, w2vh, 0, CH, R2, 16, 0, NN);
    spmm16_fused<<<(NN + 63) / 64, 256, 0, stream>>>(rp_s, es1, es2, bb, R2, T2);
    softmax16<<<(NN + 255) / 256, 256, 0, stream>>>(T2, dout);

    // ---- MI branch (bf16, batch rows only) ----
    gemm1<8, true><<<dim3(GB, 3), 256, 0, stream>>>(feat_hi, wgallh, 32768, FD, Pmi16, 384, 128, NN);
    rows_spmm_b16<<<dim3((BT + 15) / 16, 3), 256, 0, stream>>>(rp_s, es1, es2, bb, idxb, Pmi16, zQ);
    proj_norm3<<<dim3(BT, 3), 128, 0, stream>>>(zQ, Wp1, bp1, Wp2, bp2, z16);

    // ---- contrast ----
    hipMemsetAsync(stats, 0, (size_t)3 * 3 * BT * 4, stream);
    contrast_direct<<<dim3(32, 32, 3), 256, 0, stream>>>(z16, stats);
    contrast_reduce<<<3, 256, 0, stream>>>(stats, dout + (size_t)3 * NN * NCLS);
}

// Round 8
// 986.818 us; speedup vs baseline: 5.0253x; 1.1111x over previous
//
#include <hip/hip_runtime.h>
#include <math.h>

#define NN 30000
#define EE 480000
#define FD 256
#define CH 128
#define NCLS 16
#define GH 64
#define MH 128
#define BT 4096
#define CL1c 0.5f
#define CL2c 0.5f
#define LAMc 0.5f
#define ALPHAc 1.0f
#define TAUc 0.5f
#define EPSc 1e-8f

typedef __attribute__((ext_vector_type(8))) short short8;
typedef __attribute__((ext_vector_type(4))) float f32x4;

// ---------- helpers ----------
__device__ __forceinline__ unsigned short f2bf(float x) {
    unsigned b = __float_as_uint(x);
    unsigned r = b + 0x7FFFu + ((b >> 16) & 1u);
    return (unsigned short)(r >> 16);
}
__device__ __forceinline__ float bf2f(unsigned short h) {
    return __uint_as_float(((unsigned)h) << 16);
}
__device__ __forceinline__ float4 fma4(float s, float4 x, float4 a) {
    a.x = fmaf(s, x.x, a.x); a.y = fmaf(s, x.y, a.y);
    a.z = fmaf(s, x.z, a.z); a.w = fmaf(s, x.w, a.w);
    return a;
}

// ---------- splits ----------
__global__ void split_bf16(const float* __restrict__ x, unsigned short* __restrict__ hi,
                           unsigned short* __restrict__ lo, long n) {
    long i = (long)blockIdx.x * 256 + threadIdx.x;
    if (i >= n) return;
    float v = x[i];
    unsigned short h = f2bf(v);
    hi[i] = h;
    lo[i] = f2bf(v - bf2f(h));
}

struct WSArgs {
    const float* s[11];
    unsigned short* h[11];
    unsigned short* l[11];
};
__global__ void wsplit_all(WSArgs a) {
    constexpr int KK[11]  = {256,256,256,256,256,128,128,128,256,256,256};
    constexpr int NNp[11] = {64, 64, 128,128,128,16, 16, 16, 128,128,128};
    constexpr int OFF[12] = {0,16384,32768,65536,98304,131072,133120,135168,137216,169984,202752,235520};
    int i = blockIdx.x * 256 + threadIdx.x;
    if (i >= 235520) return;
    int w = 0;
#pragma unroll
    for (int t = 1; t < 11; t++) if (i >= OFF[t]) w = t;
    int j = i - OFF[w];
    int K = KK[w], N = NNp[w];
    int k = j / N, n = j % N;
    float v = a.s[w][j];
    unsigned short hh = f2bf(v);
    a.h[w][(size_t)n * K + k] = hh;
    a.l[w][(size_t)n * K + k] = f2bf(v - bf2f(hh));
}

// ---------- 3-pass hi/lo MFMA GEMM ----------
template <int NT>
__global__ __launch_bounds__(256) void gemm3(
    const unsigned short* __restrict__ Ahi, const unsigned short* __restrict__ Alo, size_t yA,
    const unsigned short* __restrict__ BThi, const unsigned short* __restrict__ BTlo, size_t yB,
    int K, float* __restrict__ C, int Cstride, size_t yC, int M)
{
    Ahi += blockIdx.y * yA; Alo += blockIdx.y * yA;
    BThi += blockIdx.y * yB; BTlo += blockIdx.y * yB;
    C += blockIdx.y * yC;
    __shared__ unsigned short Ah[128 * 40], Al[128 * 40];
    __shared__ unsigned short Bh[NT * 16 * 40], Bl[NT * 16 * 40];
    int t = threadIdx.x;
    int w = t >> 6, l = t & 63;
    int lane = l & 15, quad = l >> 4;
    int row0 = blockIdx.x * 128;
    f32x4 acc[2][NT];
#pragma unroll
    for (int s = 0; s < 2; s++)
#pragma unroll
        for (int n = 0; n < NT; n++) acc[s][n] = (f32x4)(0.f);

    int ar = t >> 1, ako = (t & 1) << 4;
    int nkc = K >> 5;
    for (int kc = 0; kc < nkc; kc++) {
        int kb = kc << 5;
        {
            int gr = row0 + ar;
            float4 h0, h1, l0, l1;
            if (gr < M) {
                const float4* pH = (const float4*)&Ahi[(size_t)gr * K + kb + ako];
                const float4* pL = (const float4*)&Alo[(size_t)gr * K + kb + ako];
                h0 = pH[0]; h1 = pH[1]; l0 = pL[0]; l1 = pL[1];
            } else {
                h0 = h1 = l0 = l1 = make_float4(0.f, 0.f, 0.f, 0.f);
            }
            float4* dH = (float4*)&Ah[ar * 40 + ako];
            dH[0] = h0; dH[1] = h1;
            float4* dL = (float4*)&Al[ar * 40 + ako];
            dL[0] = l0; dL[1] = l1;
        }
        if (ar < NT * 16) {
            const float4* pH = (const float4*)&BThi[(size_t)ar * K + kb + ako];
            const float4* pL = (const float4*)&BTlo[(size_t)ar * K + kb + ako];
            float4 h0 = pH[0], h1 = pH[1], l0 = pL[0], l1 = pL[1];
            float4* dH = (float4*)&Bh[ar * 40 + ako];
            dH[0] = h0; dH[1] = h1;
            float4* dL = (float4*)&Bl[ar * 40 + ako];
            dL[0] = l0; dL[1] = l1;
        }
        __syncthreads();
        short8 aH[2], aL[2];
#pragma unroll
        for (int s = 0; s < 2; s++) {
            int r = w * 32 + s * 16 + lane;
            aH[s] = *(const short8*)&Ah[r * 40 + quad * 8];
            aL[s] = *(const short8*)&Al[r * 40 + quad * 8];
        }
#pragma unroll
        for (int n = 0; n < NT; n++) {
            int r = n * 16 + lane;
            short8 bH = *(const short8*)&Bh[r * 40 + quad * 8];
            short8 bL = *(const short8*)&Bl[r * 40 + quad * 8];
#pragma unroll
            for (int s = 0; s < 2; s++) {
                acc[s][n] = __builtin_amdgcn_mfma_f32_16x16x32_bf16(aH[s], bH, acc[s][n], 0, 0, 0);
                acc[s][n] = __builtin_amdgcn_mfma_f32_16x16x32_bf16(aH[s], bL, acc[s][n], 0, 0, 0);
                acc[s][n] = __builtin_amdgcn_mfma_f32_16x16x32_bf16(aL[s], bH, acc[s][n], 0, 0, 0);
            }
        }
        __syncthreads();
    }
#pragma unroll
    for (int s = 0; s < 2; s++) {
        int rb = row0 + w * 32 + s * 16 + quad * 4;
#pragma unroll
        for (int reg = 0; reg < 4; reg++) {
            int gr = rb + reg;
            if (gr >= M) continue;
#pragma unroll
            for (int n = 0; n < NT; n++)
                C[(size_t)gr * Cstride + n * 16 + lane] = acc[s][n][reg];
        }
    }
}

// ---------- 1-pass bf16 MFMA GEMM ----------
template <int NT, bool OUT16>
__global__ __launch_bounds__(256) void gemm1(
    const unsigned short* __restrict__ Ahi,
    const unsigned short* __restrict__ BThi, size_t yB,
    int K, void* __restrict__ Cv, int Cstride, size_t yC, int M)
{
    BThi += blockIdx.y * yB;
    __shared__ unsigned short Ah[128 * 40];
    __shared__ unsigned short Bh[NT * 16 * 40];
    int t = threadIdx.x;
    int w = t >> 6, l = t & 63;
    int lane = l & 15, quad = l >> 4;
    int row0 = blockIdx.x * 128;
    f32x4 acc[2][NT];
#pragma unroll
    for (int s = 0; s < 2; s++)
#pragma unroll
        for (int n = 0; n < NT; n++) acc[s][n] = (f32x4)(0.f);

    int ar = t >> 1, ako = (t & 1) << 4;
    int nkc = K >> 5;
    for (int kc = 0; kc < nkc; kc++) {
        int kb = kc << 5;
        {
            int gr = row0 + ar;
            float4 h0, h1;
            if (gr < M) {
                const float4* pH = (const float4*)&Ahi[(size_t)gr * K + kb + ako];
                h0 = pH[0]; h1 = pH[1];
            } else {
                h0 = h1 = make_float4(0.f, 0.f, 0.f, 0.f);
            }
            float4* dH = (float4*)&Ah[ar * 40 + ako];
            dH[0] = h0; dH[1] = h1;
        }
        if (ar < NT * 16) {
            const float4* pH = (const float4*)&BThi[(size_t)ar * K + kb + ako];
            float4 h0 = pH[0], h1 = pH[1];
            float4* dH = (float4*)&Bh[ar * 40 + ako];
            dH[0] = h0; dH[1] = h1;
        }
        __syncthreads();
        short8 aH[2];
#pragma unroll
        for (int s = 0; s < 2; s++)
            aH[s] = *(const short8*)&Ah[(w * 32 + s * 16 + lane) * 40 + quad * 8];
#pragma unroll
        for (int n = 0; n < NT; n++) {
            short8 bH = *(const short8*)&Bh[(n * 16 + lane) * 40 + quad * 8];
#pragma unroll
            for (int s = 0; s < 2; s++)
                acc[s][n] = __builtin_amdgcn_mfma_f32_16x16x32_bf16(aH[s], bH, acc[s][n], 0, 0, 0);
        }
        __syncthreads();
    }
#pragma unroll
    for (int s = 0; s < 2; s++) {
        int rb = row0 + w * 32 + s * 16 + quad * 4;
#pragma unroll
        for (int reg = 0; reg < 4; reg++) {
            int gr = rb + reg;
            if (gr >= M) continue;
#pragma unroll
            for (int n = 0; n < NT; n++) {
                if (OUT16) {
                    unsigned short* C = (unsigned short*)Cv + blockIdx.y * yC;
                    C[(size_t)gr * Cstride + n * 16 + lane] = f2bf(acc[s][n][reg]);
                } else {
                    float* C = (float*)Cv + blockIdx.y * yC;
                    C[(size_t)gr * Cstride + n * 16 + lane] = acc[s][n][reg];
                }
            }
        }
    }
}

// ---------- contrast: direct-from-L2 bf16 MFMA ----------
__global__ __launch_bounds__(256) void contrast_direct(
    const unsigned short* __restrict__ z16, float* __restrict__ stats)
{
    int p = blockIdx.z;
    int pa = (p == 2) ? 1 : 0;
    int pb = (p == 0) ? 1 : 2;
    const unsigned short* A = z16 + (size_t)pa * BT * MH;
    const unsigned short* B = z16 + (size_t)pb * BT * MH;
    float* diag = stats + (size_t)p * 3 * BT;
    float* rs = diag + BT;
    float* cs = rs + BT;
    int t = threadIdx.x;
    int w = t >> 6, l = t & 63, m = l & 15, quad = l >> 4;
    int i0 = blockIdx.y * 128, j0 = blockIdx.x * 128;

    short8 afr[2][4];
#pragma unroll
    for (int s = 0; s < 2; s++) {
        const unsigned short* arow = &A[(size_t)(i0 + w * 32 + s * 16 + m) * MH + quad * 8];
#pragma unroll
        for (int kc = 0; kc < 4; kc++)
            afr[s][kc] = *(const short8*)(arow + kc * 32);
    }
    f32x4 acc[2][8];
#pragma unroll
    for (int s = 0; s < 2; s++)
#pragma unroll
        for (int n = 0; n < 8; n++) acc[s][n] = (f32x4)(0.f);

#pragma unroll
    for (int kc = 0; kc < 4; kc++) {
#pragma unroll
        for (int n = 0; n < 8; n++) {
            short8 bf = *(const short8*)&B[(size_t)(j0 + n * 16 + m) * MH + kc * 32 + quad * 8];
            acc[0][n] = __builtin_amdgcn_mfma_f32_16x16x32_bf16(afr[0][kc], bf, acc[0][n], 0, 0, 0);
            acc[1][n] = __builtin_amdgcn_mfma_f32_16x16x32_bf16(afr[1][kc], bf, acc[1][n], 0, 0, 0);
        }
    }
    float colp[8];
#pragma unroll
    for (int n = 0; n < 8; n++) colp[n] = 0.f;
#pragma unroll
    for (int s = 0; s < 2; s++) {
        int rbase = i0 + w * 32 + s * 16 + quad * 4;
#pragma unroll
        for (int reg = 0; reg < 4; reg++) {
            float rsum = 0.f;
            int gi = rbase + reg;
#pragma unroll
            for (int n = 0; n < 8; n++) {
                float mv = expf(acc[s][n][reg] * 2.0f);
                rsum += mv;
                colp[n] += mv;
                int gj = j0 + n * 16 + m;
                if (gi == gj) diag[gi] = mv;
            }
            rsum += __shfl_xor(rsum, 1); rsum += __shfl_xor(rsum, 2);
            rsum += __shfl_xor(rsum, 4); rsum += __shfl_xor(rsum, 8);
            if (m == 0) atomicAdd(&rs[gi], rsum);
        }
    }
    __shared__ float scol[128];
    if (t < 128) scol[t] = 0.f;
    __syncthreads();
#pragma unroll
    for (int n = 0; n < 8; n++) {
        float v = colp[n];
        v += __shfl_xor(v, 16); v += __shfl_xor(v, 32);
        if (quad == (n & 3)) atomicAdd(&scol[n * 16 + m], v);
    }
    __syncthreads();
    if (t < 128) atomicAdd(&cs[j0 + t], scol[t]);
}

// ---------- unified CSR/CSC builds ----------
// cnt layout: [out1 | out2 | in1 | in2], each NN
__global__ void count_all(const int* __restrict__ i1, const int* __restrict__ i2,
                          int* __restrict__ cnt) {
    int e = blockIdx.x * 256 + threadIdx.x;
    if (e >= EE) return;
    atomicAdd(&cnt[i1[e]], 1);
    atomicAdd(&cnt[NN + i2[e]], 1);
    atomicAdd(&cnt[2 * NN + i1[EE + e]], 1);
    atomicAdd(&cnt[3 * NN + i2[EE + e]], 1);
}
// y: 0=dir1, 1=dir2, 2=csc1, 3=csc2
__global__ __launch_bounds__(1024) void scan_block4(const int* __restrict__ cnt,
                                                    int* __restrict__ rowptr,
                                                    int* __restrict__ bsum) {
    int y = blockIdx.y;
    int* rp = rowptr + y * (NN + 1);
    int* bs = bsum + y * 32;
    __shared__ int tmp[1024];
    int t = threadIdx.x;
    int i = blockIdx.x * 1024 + t;
    int v = (i < NN) ? cnt[y * NN + i] : 0;
    tmp[t] = v;
    __syncthreads();
    for (int off = 1; off < 1024; off <<= 1) {
        int add = (t >= off) ? tmp[t - off] : 0;
        __syncthreads();
        tmp[t] += add;
        __syncthreads();
    }
    if (i <= NN) rp[i] = tmp[t] - v;
    if (t == 1023) bs[blockIdx.x] = tmp[1023];
}
__global__ void scan_bsum4(int* __restrict__ bsum, int nb) {
    bsum += blockIdx.x * 32;
    int t = threadIdx.x;
    int orig = (t < nb) ? bsum[t] : 0;
    int v = orig;
    for (int off = 1; off < 64; off <<= 1) {
        int u = __shfl_up(v, off);
        if (t >= off) v += u;
    }
    if (t < nb) bsum[t] = v - orig;
}
__global__ void scan_add4(const int* __restrict__ bsum, int* __restrict__ rowptr,
                          int* __restrict__ cursor) {
    int y = blockIdx.y;
    const int* bs = bsum + y * 32;
    int* rp = rowptr + y * (NN + 1);
    int* cur = cursor + y * NN;
    int i = blockIdx.x * 1024 + threadIdx.x;
    if (i <= NN) {
        int r = rp[i] + bs[blockIdx.x];
        rp[i] = r;
        if (i < NN) cur[i] = r;
    }
}
// ONE scatter for everything: dir entries (col, val) + csc entries (src, dir_pos)
__global__ void scatter_all(const int* __restrict__ i1, const float* __restrict__ v1,
                            const int* __restrict__ i2, const float* __restrict__ v2,
                            int* __restrict__ cur,
                            int2* __restrict__ ed1, int2* __restrict__ ec1,
                            int2* __restrict__ ed2, int2* __restrict__ ec2) {
    int e = blockIdx.x * 256 + threadIdx.x;
    if (e >= EE) return;
    int r = i1[e], c = i1[EE + e];
    int p = atomicAdd(&cur[r], 1);
    ed1[p] = make_int2(c, __float_as_int(v1[e]));
    int q = atomicAdd(&cur[2 * NN + c], 1);
    ec1[q] = make_int2(r, p);
    r = i2[e]; c = i2[EE + e];
    p = atomicAdd(&cur[NN + r], 1);
    ed2[p] = make_int2(c, __float_as_int(v2[e]));
    q = atomicAdd(&cur[3 * NN + c], 1);
    ec2[q] = make_int2(r, p);
}

// ---------- row-parallel nv computation (softmax over sb[col] only — sa & bm cancel) ----------
// Overwrites ed[j].y with nv and writes nvd[j] = nv for csc indirection.
__global__ __launch_bounds__(256) void gen_nv(
    const int* __restrict__ rp_d, int2* __restrict__ ed1, int2* __restrict__ ed2,
    const float* __restrict__ sb, float* __restrict__ nvd1, float* __restrict__ nvd2)
{
    int y = blockIdx.y;
    int row = blockIdx.x * 256 + threadIdx.x;
    if (row >= NN) return;
    const int* rp = rp_d + y * (NN + 1);
    int2* ed = y ? ed2 : ed1;
    float* nvd = y ? nvd2 : nvd1;
    const float* sbv = sb + (size_t)y * NN;
    int p0 = rp[row], p1 = rp[row + 1];
    float m = -3.4e38f, sum = 0.f;
    for (int j = p0; j < p1; j++) {
        float x = sbv[ed[j].x];
        if (x > m) { sum = sum * expf(m - x) + 1.f; m = x; }
        else sum += expf(x - m);
    }
    float inv = 1.f / sum;
    for (int j = p0; j < p1; j++) {
        int2 q = ed[j];
        float nv = __int_as_float(q.y) + 0.5f * expf(sbv[q.x] - m) * inv;  // COM_L1=COM_L2=0.5
        nvd[j] = nv;
        ed[j].y = __float_as_int(nv);
    }
}

// ---------- fp32 gather helpers (dir: val embedded; csc: val via nvd) ----------
template <int STR4>
__device__ __forceinline__ void gath_dir_f32(
    const int* __restrict__ rp, const int2* __restrict__ ed, int row,
    const float4* __restrict__ x4, int xo, float4* a)
{
    int p0 = rp[row], p1 = rp[row + 1];
    int j = p0;
    for (; j + 4 <= p1; j += 4) {
        int2 q0 = ed[j], q1 = ed[j+1], q2 = ed[j+2], q3 = ed[j+3];
        a[0] = fma4(__int_as_float(q0.y), x4[(size_t)q0.x * STR4 + xo], a[0]);
        a[1] = fma4(__int_as_float(q1.y), x4[(size_t)q1.x * STR4 + xo], a[1]);
        a[2] = fma4(__int_as_float(q2.y), x4[(size_t)q2.x * STR4 + xo], a[2]);
        a[3] = fma4(__int_as_float(q3.y), x4[(size_t)q3.x * STR4 + xo], a[3]);
    }
    for (; j < p1; j++) {
        int2 q = ed[j];
        a[0] = fma4(__int_as_float(q.y), x4[(size_t)q.x * STR4 + xo], a[0]);
    }
}
template <int STR4>
__device__ __forceinline__ void gath_csc_f32(
    const int* __restrict__ rp, const int2* __restrict__ ec, const float* __restrict__ nvd,
    int row, const float4* __restrict__ x4, int xo, float4* a)
{
    int p0 = rp[row], p1 = rp[row + 1];
    int j = p0;
    for (; j + 4 <= p1; j += 4) {
        int2 q0 = ec[j], q1 = ec[j+1], q2 = ec[j+2], q3 = ec[j+3];
        float v0 = nvd[q0.y], v1 = nvd[q1.y], v2 = nvd[q2.y], v3 = nvd[q3.y];
        a[0] = fma4(v0, x4[(size_t)q0.x * STR4 + xo], a[0]);
        a[1] = fma4(v1, x4[(size_t)q1.x * STR4 + xo], a[1]);
        a[2] = fma4(v2, x4[(size_t)q2.x * STR4 + xo], a[2]);
        a[3] = fma4(v3, x4[(size_t)q3.x * STR4 + xo], a[3]);
    }
    for (; j < p1; j++) {
        int2 q = ec[j];
        a[0] = fma4(nvd[q.y], x4[(size_t)q.x * STR4 + xo], a[0]);
    }
}

// ---------- gen SpMM (dir graph, orig vals): F=64, Pg[NN][128] slices ----------
__global__ __launch_bounds__(256) void spmm64_pair(
    const int* __restrict__ rp_d, const int2* __restrict__ e1, const int2* __restrict__ e2,
    const float* __restrict__ Pg, float* __restrict__ emb)
{
    int y = blockIdx.y;
    const int* rp = rp_d + y * (NN + 1);
    const int2* arr = y ? e2 : e1;
    int row = blockIdx.x * 16 + threadIdx.x / 16;
    int o = threadIdx.x % 16;
    if (row >= NN) return;
    float4 a[4] = {};
    gath_dir_f32<32>(rp, arr, row, (const float4*)Pg, y * 16 + o, a);
    float4 r;
    r.x = fmaxf((a[0].x + a[1].x) + (a[2].x + a[3].x), 0.f);
    r.y = fmaxf((a[0].y + a[1].y) + (a[2].y + a[3].y), 0.f);
    r.z = fmaxf((a[0].z + a[1].z) + (a[2].z + a[3].z), 0.f);
    r.w = fmaxf((a[0].w + a[1].w) + (a[2].w + a[3].w), 0.f);
    ((float4*)emb)[((size_t)y * NN + row) * 16 + o] = r;
}

// ---------- sym SpMMs: dir-range (nv embedded after gen_nv) + csc-range (nvd lookup) ----------
__global__ __launch_bounds__(256) void spmm128_pair(
    const int* __restrict__ rp_d, const int* __restrict__ rp_c,
    const int2* __restrict__ ed1, const int2* __restrict__ ec1, const float* __restrict__ nvd1,
    const int2* __restrict__ ed2, const int2* __restrict__ ec2, const float* __restrict__ nvd2,
    const float* __restrict__ P01, float* __restrict__ Q01)
{
    int y = blockIdx.y;
    const int* rpd = rp_d + y * (NN + 1);
    const int* rpc = rp_c + y * (NN + 1);
    const int2* ed = y ? ed2 : ed1;
    const int2* ec = y ? ec2 : ec1;
    const float* nvd = y ? nvd2 : nvd1;
    int row = blockIdx.x * 8 + threadIdx.x / 32;
    int o = threadIdx.x % 32;
    if (row >= NN) return;
    int xo = y * 32 + o;
    float4 a[4] = {};
    gath_dir_f32<64>(rpd, ed, row, (const float4*)P01, xo, a);
    gath_csc_f32<64>(rpc, ec, nvd, row, (const float4*)P01, xo, a);
    float4 r;
    r.x = fmaxf((a[0].x + a[1].x) + (a[2].x + a[3].x), 0.f);
    r.y = fmaxf((a[0].y + a[1].y) + (a[2].y + a[3].y), 0.f);
    r.z = fmaxf((a[0].z + a[1].z) + (a[2].z + a[3].z), 0.f);
    r.w = fmaxf((a[0].w + a[1].w) + (a[2].w + a[3].w), 0.f);
    ((float4*)Q01)[((size_t)y * NN + row) * 32 + o] = r;
}

__global__ __launch_bounds__(256) void spmm16_pair(
    const int* __restrict__ rp_d, const int* __restrict__ rp_c,
    const int2* __restrict__ ed1, const int2* __restrict__ ec1, const float* __restrict__ nvd1,
    const int2* __restrict__ ed2, const int2* __restrict__ ec2, const float* __restrict__ nvd2,
    const float* __restrict__ R01, float* __restrict__ T01)
{
    int y = blockIdx.y;
    const int* rpd = rp_d + y * (NN + 1);
    const int* rpc = rp_c + y * (NN + 1);
    const int2* ed = y ? ed2 : ed1;
    const int2* ec = y ? ec2 : ec1;
    const float* nvd = y ? nvd2 : nvd1;
    int row = blockIdx.x * 64 + threadIdx.x / 4;
    int o = threadIdx.x % 4;
    if (row >= NN) return;
    const float4* x4 = (const float4*)(R01 + (size_t)y * NN * 16);
    float4 a[4] = {};
    gath_dir_f32<4>(rpd, ed, row, x4, o, a);
    gath_csc_f32<4>(rpc, ec, nvd, row, x4, o, a);
    float4 r;
    r.x = (a[0].x + a[1].x) + (a[2].x + a[3].x);
    r.y = (a[0].y + a[1].y) + (a[2].y + a[3].y);
    r.z = (a[0].z + a[1].z) + (a[2].z + a[3].z);
    r.w = (a[0].w + a[1].w) + (a[2].w + a[3].w);
    ((float4*)(T01 + (size_t)y * NN * 16))[(size_t)row * 4 + o] = r;
}

__global__ __launch_bounds__(256) void spmm16_fused(
    const int* __restrict__ rp_d, const int* __restrict__ rp_c,
    const int2* __restrict__ ed1, const int2* __restrict__ ec1, const float* __restrict__ nvd1,
    const int2* __restrict__ ed2, const int2* __restrict__ ec2, const float* __restrict__ nvd2,
    const float* __restrict__ bb, const float* __restrict__ x, float* __restrict__ out)
{
    int row = blockIdx.x * 64 + threadIdx.x / 4;
    int o = threadIdx.x % 4;
    if (row >= NN) return;
    const float4* x4 = (const float4*)x;
    float4 a[4] = {};
    gath_dir_f32<4>(rp_d, ed1, row, x4, o, a);
    gath_csc_f32<4>(rp_c, ec1, nvd1, row, x4, o, a);
    float4 s1;
    s1.x = (a[0].x + a[1].x) + (a[2].x + a[3].x);
    s1.y = (a[0].y + a[1].y) + (a[2].y + a[3].y);
    s1.z = (a[0].z + a[1].z) + (a[2].z + a[3].z);
    s1.w = (a[0].w + a[1].w) + (a[2].w + a[3].w);
    float4 b[4] = {};
    gath_dir_f32<4>(rp_d + (NN + 1), ed2, row, x4, o, b);
    gath_csc_f32<4>(rp_c + (NN + 1), ec2, nvd2, row, x4, o, b);
    float4 s2;
    s2.x = (b[0].x + b[1].x) + (b[2].x + b[3].x);
    s2.y = (b[0].y + b[1].y) + (b[2].y + b[3].y);
    s2.z = (b[0].z + b[1].z) + (b[2].z + b[3].z);
    s2.w = (b[0].w + b[1].w) + (b[2].w + b[3].w);
    float w1 = bb[row], w2 = bb[NN + row];
    float4 r;
    r.x = w1 * s1.x + w2 * s2.x;
    r.y = w1 * s1.y + w2 * s2.y;
    r.z = w1 * s1.z + w2 * s2.z;
    r.w = w1 * s1.w + w2 * s2.w;
    ((float4*)out)[(size_t)row * 4 + o] = r;
}

// ---------- bf16 gather helpers ----------
__device__ __forceinline__ void gath_dir_b16(
    const int* __restrict__ rp, const int2* __restrict__ ed, int row,
    const unsigned short* __restrict__ X, int xstride, int o, float* acc)
{
    int p0 = rp[row], p1 = rp[row + 1];
    int j = p0;
    for (; j + 4 <= p1; j += 4) {
        int2 q0 = ed[j], q1 = ed[j+1], q2 = ed[j+2], q3 = ed[j+3];
        short8 x0 = *(const short8*)&X[(size_t)q0.x * xstride + o * 8];
        short8 x1 = *(const short8*)&X[(size_t)q1.x * xstride + o * 8];
        short8 x2 = *(const short8*)&X[(size_t)q2.x * xstride + o * 8];
        short8 x3 = *(const short8*)&X[(size_t)q3.x * xstride + o * 8];
        float v0 = __int_as_float(q0.y), v1 = __int_as_float(q1.y);
        float v2 = __int_as_float(q2.y), v3 = __int_as_float(q3.y);
#pragma unroll
        for (int k = 0; k < 8; k++) {
            acc[k] = fmaf(v0, bf2f((unsigned short)x0[k]), acc[k]);
            acc[k] = fmaf(v1, bf2f((unsigned short)x1[k]), acc[k]);
            acc[k] = fmaf(v2, bf2f((unsigned short)x2[k]), acc[k]);
            acc[k] = fmaf(v3, bf2f((unsigned short)x3[k]), acc[k]);
        }
    }
    for (; j < p1; j++) {
        int2 q = ed[j];
        short8 xv = *(const short8*)&X[(size_t)q.x * xstride + o * 8];
        float v = __int_as_float(q.y);
#pragma unroll
        for (int k = 0; k < 8; k++)
            acc[k] = fmaf(v, bf2f((unsigned short)xv[k]), acc[k]);
    }
}
__device__ __forceinline__ void gath_csc_b16(
    const int* __restrict__ rp, const int2* __restrict__ ec, const float* __restrict__ nvd,
    int row, const unsigned short* __restrict__ X, int xstride, int o, float* acc)
{
    int p0 = rp[row], p1 = rp[row + 1];
    int j = p0;
    for (; j + 4 <= p1; j += 4) {
        int2 q0 = ec[j], q1 = ec[j+1], q2 = ec[j+2], q3 = ec[j+3];
        short8 x0 = *(const short8*)&X[(size_t)q0.x * xstride + o * 8];
        short8 x1 = *(const short8*)&X[(size_t)q1.x * xstride + o * 8];
        short8 x2 = *(const short8*)&X[(size_t)q2.x * xstride + o * 8];
        short8 x3 = *(const short8*)&X[(size_t)q3.x * xstride + o * 8];
        float v0 = nvd[q0.y], v1 = nvd[q1.y], v2 = nvd[q2.y], v3 = nvd[q3.y];
#pragma unroll
        for (int k = 0; k < 8; k++) {
            acc[k] = fmaf(v0, bf2f((unsigned short)x0[k]), acc[k]);
            acc[k] = fmaf(v1, bf2f((unsigned short)x1[k]), acc[k]);
            acc[k] = fmaf(v2, bf2f((unsigned short)x2[k]), acc[k]);
            acc[k] = fmaf(v3, bf2f((unsigned short)x3[k]), acc[k]);
        }
    }
    for (; j < p1; j++) {
        int2 q = ec[j];
        short8 xv = *(const short8*)&X[(size_t)q.x * xstride + o * 8];
        float v = nvd[q.y];
#pragma unroll
        for (int k = 0; k < 8; k++)
            acc[k] = fmaf(v, bf2f((unsigned short)xv[k]), acc[k]);
    }
}

__global__ __launch_bounds__(256) void fused128_b16(
    const int* __restrict__ rp_d, const int* __restrict__ rp_c,
    const int2* __restrict__ ed1, const int2* __restrict__ ec1, const float* __restrict__ nvd1,
    const int2* __restrict__ ed2, const int2* __restrict__ ec2, const float* __restrict__ nvd2,
    const float* __restrict__ bb, const unsigned short* __restrict__ X,
    unsigned short* __restrict__ Out)
{
    int row = blockIdx.x * 16 + threadIdx.x / 16;
    int o = threadIdx.x % 16;
    if (row >= NN) return;
    float a1[8] = {}, a2[8] = {};
    gath_dir_b16(rp_d, ed1, row, X, 128, o, a1);
    gath_csc_b16(rp_c, ec1, nvd1, row, X, 128, o, a1);
    gath_dir_b16(rp_d + (NN + 1), ed2, row, X, 128, o, a2);
    gath_csc_b16(rp_c + (NN + 1), ec2, nvd2, row, X, 128, o, a2);
    float w1 = bb[row], w2 = bb[NN + row];
    short8 outv;
#pragma unroll
    for (int k = 0; k < 8; k++) {
        float r = fmaxf(w1 * a1[k] + w2 * a2[k], 0.f);
        outv[k] = (short)f2bf(r);
    }
    *(short8*)&Out[(size_t)row * 128 + o * 8] = outv;
}

__global__ __launch_bounds__(256) void rows_spmm_b16(
    const int* __restrict__ rp_d, const int* __restrict__ rp_c,
    const int2* __restrict__ ed1, const int2* __restrict__ ec1, const float* __restrict__ nvd1,
    const int2* __restrict__ ed2, const int2* __restrict__ ec2, const float* __restrict__ nvd2,
    const float* __restrict__ bb, const int* __restrict__ rows,
    const unsigned short* __restrict__ Pmi, float* __restrict__ zQ)
{
    int y = blockIdx.y;
    int ri = blockIdx.x * 16 + threadIdx.x / 16;
    int o = threadIdx.x % 16;
    if (ri >= BT) return;
    int node = rows[ri];
    int xoff = (y == 0) ? 0 : ((y == 1) ? 128 : 256);
    const unsigned short* X = Pmi + xoff;
    float acc[8] = {};
    if (y == 0) {
        float a1[8] = {}, a2[8] = {};
        gath_dir_b16(rp_d, ed1, node, X, 384, o, a1);
        gath_csc_b16(rp_c, ec1, nvd1, node, X, 384, o, a1);
        gath_dir_b16(rp_d + (NN + 1), ed2, node, X, 384, o, a2);
        gath_csc_b16(rp_c + (NN + 1), ec2, nvd2, node, X, 384, o, a2);
        float w1 = bb[node], w2 = bb[NN + node];
#pragma unroll
        for (int k = 0; k < 8; k++) acc[k] = w1 * a1[k] + w2 * a2[k];
    } else if (y == 1) {
        gath_dir_b16(rp_d, ed1, node, X, 384, o, acc);
        gath_csc_b16(rp_c, ec1, nvd1, node, X, 384, o, acc);
    } else {
        gath_dir_b16(rp_d + (NN + 1), ed2, node, X, 384, o, acc);
        gath_csc_b16(rp_c + (NN + 1), ec2, nvd2, node, X, 384, o, acc);
    }
    float* out = zQ + ((size_t)y * BT + ri) * 128 + o * 8;
#pragma unroll
    for (int k = 0; k < 8; k++) out[k] = fmaxf(acc[k], 0.f);
}

// ---------- node scores: only the sb half (sa & bm cancel in row softmax) ----------
__global__ __launch_bounds__(256) void node_scores_pair(
    const float* __restrict__ emb, const float* __restrict__ Wm1,
    const float* __restrict__ Wm2, float* __restrict__ sb)
{
    int y = blockIdx.y;
    const float* e_ = emb + (size_t)y * NN * GH;
    const float* Wm = y ? Wm2 : Wm1;
    int node = blockIdx.x * 4 + threadIdx.x / 64;
    int lane = threadIdx.x % 64;
    if (node >= NN) return;
    float e = e_[(size_t)node * GH + lane];
    float vb = e * Wm[GH + lane];
#pragma unroll
    for (int off = 32; off; off >>= 1)
        vb += __shfl_down(vb, off);
    if (lane == 0) sb[y * NN + node] = vb;
}

// ---------- softmax / weights ----------
__global__ void softmax16y(const float* __restrict__ S01, float* __restrict__ logits_base,
                           float* __restrict__ w12)
{
    int y = blockIdx.y;
    const float* S = S01 + (size_t)y * NN * NCLS;
    float* logits = logits_base + (size_t)y * NN * NCLS;
    float* w = w12 + (size_t)y * NN;
    int node = blockIdx.x * 256 + threadIdx.x;
    if (node >= NN) return;
    float v[NCLS];
    float mx = -3.4e38f;
#pragma unroll
    for (int j = 0; j < NCLS; j++) { v[j] = S[(size_t)node * NCLS + j]; mx = fmaxf(mx, v[j]); }
    float s = 0.f;
#pragma unroll
    for (int j = 0; j < NCLS; j++) { v[j] = expf(v[j] - mx); s += v[j]; }
    float inv = 1.f / s;
    float fir = -1.f, sec = -1.f;
#pragma unroll
    for (int j = 0; j < NCLS; j++) {
        float p = v[j] * inv;
        logits[(size_t)node * NCLS + j] = logf(p + EPSc);
        if (p > fir) { sec = fir; fir = p; }
        else if (p > sec) { sec = p; }
    }
    w[node] = expf(ALPHAc * (LAMc * logf(fir + EPSc) + (1.f - LAMc) * logf(fir - sec + EPSc)));
}

__global__ void softmax16(const float* __restrict__ S, float* __restrict__ logits)
{
    int node = blockIdx.x * 256 + threadIdx.x;
    if (node >= NN) return;
    float v[NCLS];
    float mx = -3.4e38f;
#pragma unroll
    for (int j = 0; j < NCLS; j++) { v[j] = S[(size_t)node * NCLS + j]; mx = fmaxf(mx, v[j]); }
    float s = 0.f;
#pragma unroll
    for (int j = 0; j < NCLS; j++) { v[j] = expf(v[j] - mx); s += v[j]; }
    float inv = 1.f / s;
#pragma unroll
    for (int j = 0; j < NCLS; j++)
        logits[(size_t)node * NCLS + j] = logf(v[j] * inv + EPSc);
}

__global__ void bweights(const float* __restrict__ w12, float* __restrict__ bb)
{
    int i = blockIdx.x * 256 + threadIdx.x;
    if (i >= NN) return;
    float a = w12[i], b = w12[NN + i];
    float inv = 1.f / (a + b);
    bb[i] = a * inv;
    bb[NN + i] = b * inv;
}

// ---------- projection head + L2-normalize, bf16 out ----------
__global__ __launch_bounds__(128) void proj_norm3(
    const float* __restrict__ zQ,
    const float* __restrict__ Wp1, const float* __restrict__ bp1,
    const float* __restrict__ Wp2, const float* __restrict__ bp2,
    unsigned short* __restrict__ z16)
{
    __shared__ float g[MH], u[MH];
    __shared__ float red[2];
    size_t i = (size_t)blockIdx.y * BT + blockIdx.x;
    int t = threadIdx.x;
    g[t] = zQ[i * MH + t];
    __syncthreads();
    float acc = bp1[t];
    for (int k = 0; k < MH; k++) acc = fmaf(g[k], Wp1[k * MH + t], acc);
    u[t] = acc > 0.f ? acc : (expf(acc) - 1.f);
    __syncthreads();
    float acc2 = bp2[t];
    for (int k = 0; k < MH; k++) acc2 = fmaf(u[k], Wp2[k * MH + t], acc2);
    float sq = acc2 * acc2;
#pragma unroll
    for (int off = 32; off; off >>= 1) sq += __shfl_down(sq, off);
    if ((t & 63) == 0) red[t >> 6] = sq;
    __syncthreads();
    float nrm = sqrtf(red[0] + red[1]);
    z16[i * MH + t] = f2bf(acc2 / nrm);
}

__global__ void contrast_reduce(const float* __restrict__ stats, float* __restrict__ out3)
{
    int p = blockIdx.x, t = threadIdx.x;
    const float* diag = stats + (size_t)p * 3 * BT;
    const float* rs = diag + BT;
    const float* cs = rs + BT;
    float s1 = 0.f, s2 = 0.f;
    for (int i = t; i < BT; i += 256) {
        float d = diag[i];
        s1 += logf(d / (rs[i] + EPSc) + EPSc);
        s2 += logf(d / (cs[i] + EPSc) + EPSc);
    }
#pragma unroll
    for (int off = 32; off; off >>= 1) { s1 += __shfl_down(s1, off); s2 += __shfl_down(s2, off); }
    __shared__ float sh[8];
    if ((t & 63) == 0) { sh[(t >> 6) * 2] = s1; sh[(t >> 6) * 2 + 1] = s2; }
    __syncthreads();
    if (t == 0) {
        float a = sh[0] + sh[2] + sh[4] + sh[6];
        float b = sh[1] + sh[3] + sh[5] + sh[7];
        out3[p] = 0.5f * (-a / BT - b / BT);
    }
}

// ---------- host ----------
extern "C" void kernel_launch(void* const* d_in, const int* in_sizes, int n_in,
                              void* d_out, int out_size, void* d_ws, size_t ws_size,
                              hipStream_t stream)
{
    const float* feat   = (const float*)d_in[0];
    const int*   ind1   = (const int*)d_in[1];
    const float* vals1  = (const float*)d_in[2];
    const int*   ind2   = (const int*)d_in[3];
    const float* vals2  = (const float*)d_in[4];
    const int*   idxb   = (const int*)d_in[5];
    const float* Wm1    = (const float*)d_in[7];
    const float* Wm2    = (const float*)d_in[10];
    const float* Wp1    = (const float*)d_in[21];
    const float* bp1    = (const float*)d_in[22];
    const float* Wp2    = (const float*)d_in[23];
    const float* bp2    = (const float*)d_in[24];
    float* dout = (float*)d_out;

    float* ws = (float*)d_ws;
    size_t off = 0;
    auto alloc = [&](size_t n) { n = (n + 3) & ~(size_t)3; float* p = ws + off; off += n; return p; };
    auto alloc_s = [&](size_t n) { return (unsigned short*)alloc((n + 1) / 2); };

    // --- shared pool ---
    float* pool = alloc(24960000);
    float* Pg  = pool;                       // NN*128
    float* emb = pool + 3840000;             // 2*NN*64
    float* P01   = pool;                     // [NN][256]
    float* Q01   = pool + 7680000;           // [2][NN][128]
    unsigned short* q01h = (unsigned short*)(pool + 15360000);
    unsigned short* q01l = (unsigned short*)(pool + 19200000);
    float* R01   = pool + 23040000;          // [2][NN][16]
    float* T01   = pool + 24000000;          // [2][NN][16]
    unsigned short* Ph2   = (unsigned short*)pool;
    unsigned short* q2h   = (unsigned short*)(pool + 1920000);
    float* R2    = pool + 3840000;
    float* T2    = pool + 4320000;
    unsigned short* Pmi16 = (unsigned short*)(pool + 4800000);
    float* zQ    = pool + 10560000;          // 3*BT*128

    // --- persistent ---
    unsigned short* feat_hi = alloc_s((size_t)NN * FD);
    unsigned short* feat_lo = alloc_s((size_t)NN * FD);
    float* sb   = alloc(2 * NN);
    float* w12 = alloc(2 * NN);
    float* bb  = alloc(2 * NN);
    float* stats = alloc((size_t)3 * 3 * BT);
    unsigned short* z16 = alloc_s((size_t)3 * BT * MH);
    int2* ed1 = (int2*)alloc(2 * (size_t)EE);
    int2* ed2 = (int2*)alloc(2 * (size_t)EE);
    int2* ec1 = (int2*)alloc(2 * (size_t)EE);
    int2* ec2 = (int2*)alloc(2 * (size_t)EE);
    float* nvd1 = alloc(EE);
    float* nvd2 = alloc(EE);
    int* rp4  = (int*)alloc(4 * (NN + 1));
    int* cnt4 = (int*)alloc(4 * NN);
    int* cur4 = (int*)alloc(4 * NN);
    int* bsum = (int*)alloc(128);
    int* rp_d = rp4;
    int* rp_c = rp4 + 2 * (NN + 1);
    // weights
    unsigned short* wgen12h = alloc_s(32768); unsigned short* wgen12l = alloc_s(32768);
    unsigned short* w1pairh = alloc_s(65536); unsigned short* w1pairl = alloc_s(65536);
    unsigned short* w1vh    = alloc_s(32768); unsigned short* w1vl    = alloc_s(32768);
    unsigned short* w2pairh = alloc_s(4096);  unsigned short* w2pairl = alloc_s(4096);
    unsigned short* w2vh    = alloc_s(2048);  unsigned short* w2vl    = alloc_s(2048);
    unsigned short* wgallh  = alloc_s(98304); unsigned short* wgalll  = alloc_s(98304);

    // ---- prep ----
    split_bf16<<<((long)NN * FD + 255) / 256, 256, 0, stream>>>(feat, feat_hi, feat_lo, (long)NN * FD);
    {
        WSArgs a;
        a.s[0] = (const float*)d_in[6];  a.h[0] = wgen12h;          a.l[0] = wgen12l;
        a.s[1] = (const float*)d_in[9];  a.h[1] = wgen12h + 16384;  a.l[1] = wgen12l + 16384;
        a.s[2] = (const float*)d_in[12]; a.h[2] = w1pairh;          a.l[2] = w1pairl;
        a.s[3] = (const float*)d_in[14]; a.h[3] = w1pairh + 32768;  a.l[3] = w1pairl + 32768;
        a.s[4] = (const float*)d_in[16]; a.h[4] = w1vh;             a.l[4] = w1vl;
        a.s[5] = (const float*)d_in[13]; a.h[5] = w2pairh;          a.l[5] = w2pairl;
        a.s[6] = (const float*)d_in[15]; a.h[6] = w2pairh + 2048;   a.l[6] = w2pairl + 2048;
        a.s[7] = (const float*)d_in[17]; a.h[7] = w2vh;             a.l[7] = w2vl;
        a.s[8] = (const float*)d_in[18]; a.h[8] = wgallh;           a.l[8] = wgalll;
        a.s[9] = (const float*)d_in[19]; a.h[9] = wgallh + 32768;   a.l[9] = wgalll + 32768;
        a.s[10]= (const float*)d_in[20]; a.h[10]= wgallh + 65536;   a.l[10]= wgalll + 65536;
        wsplit_all<<<(235520 + 255) / 256, 256, 0, stream>>>(a);
    }

    const int NB = (NN + 1 + 1023) / 1024;
    const int GB = (NN + 127) / 128;

    // ---- CSR/CSC build: one count, one scan group, ONE scatter ----
    hipMemsetAsync(cnt4, 0, 4 * NN * 4, stream);
    count_all<<<(EE + 255) / 256, 256, 0, stream>>>(ind1, ind2, cnt4);
    scan_block4<<<dim3(NB, 4), 1024, 0, stream>>>(cnt4, rp4, bsum);
    scan_bsum4<<<4, 64, 0, stream>>>(bsum, NB);
    scan_add4<<<dim3(NB, 4), 1024, 0, stream>>>(bsum, rp4, cur4);
    scatter_all<<<(EE + 255) / 256, 256, 0, stream>>>(ind1, vals1, ind2, vals2, cur4,
                                                      ed1, ec1, ed2, ec2);

    // ---- gen_view (both views) ----
    gemm3<8><<<dim3(GB, 1), 256, 0, stream>>>(feat_hi, feat_lo, 0, wgen12h, wgen12l, 0,
                                              FD, Pg, 128, 0, NN);
    spmm64_pair<<<dim3((NN + 15) / 16, 2), 256, 0, stream>>>(rp_d, ed1, ed2, Pg, emb);
    node_scores_pair<<<dim3((NN + 3) / 4, 2), 256, 0, stream>>>(emb, Wm1, Wm2, sb);
    gen_nv<<<dim3((NN + 255) / 256, 2), 256, 0, stream>>>(rp_d, ed1, ed2, sb, nvd1, nvd2);

    // ---- branches 0/1 (fp32-accurate) ----
    gemm3<8><<<dim3(GB, 2), 256, 0, stream>>>(feat_hi, feat_lo, 0, w1pairh, w1pairl, 32768,
                                              FD, P01, 256, 128, NN);
    spmm128_pair<<<dim3((NN + 7) / 8, 2), 256, 0, stream>>>(rp_d, rp_c, ed1, ec1, nvd1,
                                                            ed2, ec2, nvd2, P01, Q01);
    split_bf16<<<((long)2 * NN * CH + 255) / 256, 256, 0, stream>>>(Q01, q01h, q01l, (long)2 * NN * CH);
    gemm3<1><<<dim3(GB, 2), 256, 0, stream>>>(q01h, q01l, (size_t)NN * CH, w2pairh, w2pairl, 2048,
                                              CH, R01, 16, (size_t)NN * NCLS, NN);
    spmm16_pair<<<dim3((NN + 63) / 64, 2), 256, 0, stream>>>(rp_d, rp_c, ed1, ec1, nvd1,
                                                             ed2, ec2, nvd2, R01, T01);
    softmax16y<<<dim3((NN + 255) / 256, 2), 256, 0, stream>>>(T01, dout + (size_t)NN * NCLS, w12);
    bweights<<<(NN + 255) / 256, 256, 0, stream>>>(w12, bb);

    // ---- branch 2 (bf16 fast path) ----
    gemm1<8, true><<<dim3(GB, 1), 256, 0, stream>>>(feat_hi, w1vh, 0, FD, Ph2, 128, 0, NN);
    fused128_b16<<<(NN + 15) / 16, 256, 0, stream>>>(rp_d, rp_c, ed1, ec1, nvd1,
                                                     ed2, ec2, nvd2, bb, Ph2, q2h);
    gemm1<1, false><<<dim3(GB, 1), 256, 0, stream>>>(q2h, w2vh, 0, CH, R2, 16, 0, NN);
    spmm16_fused<<<(NN + 63) / 64, 256, 0, stream>>>(rp_d, rp_c, ed1, ec1, nvd1,
                                                     ed2, ec2, nvd2, bb, R2, T2);
    softmax16<<<(NN + 255) / 256, 256, 0, stream>>>(T2, dout);

    // ---- MI branch (bf16, batch rows only) ----
    gemm1<8, true><<<dim3(GB, 3), 256, 0, stream>>>(feat_hi, wgallh, 32768, FD, Pmi16, 384, 128, NN);
    rows_spmm_b16<<<dim3((BT + 15) / 16, 3), 256, 0, stream>>>(rp_d, rp_c, ed1, ec1, nvd1,
                                                               ed2, ec2, nvd2, bb, idxb, Pmi16, zQ);
    proj_norm3<<<dim3(BT, 3), 128, 0, stream>>>(zQ, Wp1, bp1, Wp2, bp2, z16);

    // ---- contrast ----
    hipMemsetAsync(stats, 0, (size_t)3 * 3 * BT * 4, stream);
    contrast_direct<<<dim3(32, 32, 3), 256, 0, stream>>>(z16, stats);
    contrast_reduce<<<3, 256, 0, stream>>>(stats, dout + (size_t)3 * NN * NCLS);
}

// Round 9
// 872.607 us; speedup vs baseline: 5.6830x; 1.1309x over previous
//
#include <hip/hip_runtime.h>
#include <math.h>

#define NN 30000
#define EE 480000
#define FD 256
#define CH 128
#define NCLS 16
#define GH 64
#define MH 128
#define BT 4096
#define EPSc 1e-8f
#define GBc ((NN + 127) / 128)

typedef __attribute__((ext_vector_type(8))) short short8;
typedef __attribute__((ext_vector_type(4))) float f32x4;

// ---------- helpers ----------
__device__ __forceinline__ unsigned short f2bf(float x) {
    unsigned b = __float_as_uint(x);
    unsigned r = b + 0x7FFFu + ((b >> 16) & 1u);
    return (unsigned short)(r >> 16);
}
__device__ __forceinline__ float bf2f(unsigned short h) {
    return __uint_as_float(((unsigned)h) << 16);
}
__device__ __forceinline__ float4 fma4(float s, float4 x, float4 a) {
    a.x = fmaf(s, x.x, a.x); a.y = fmaf(s, x.y, a.y);
    a.z = fmaf(s, x.z, a.z); a.w = fmaf(s, x.w, a.w);
    return a;
}

// ---------- splits ----------
__global__ void split_bf16(const float* __restrict__ x, unsigned short* __restrict__ hi,
                           unsigned short* __restrict__ lo, long n) {
    long i = (long)blockIdx.x * 256 + threadIdx.x;
    if (i >= n) return;
    float v = x[i];
    unsigned short h = f2bf(v);
    hi[i] = h;
    lo[i] = f2bf(v - bf2f(h));
}

struct WSArgs {
    const float* s[11];
    unsigned short* h[11];
    unsigned short* l[11];
};
__global__ void wsplit_all(WSArgs a) {
    constexpr int KK[11]  = {256,256,256,256,256,128,128,128,256,256,256};
    constexpr int NNp[11] = {64, 64, 128,128,128,16, 16, 16, 128,128,128};
    constexpr int OFF[12] = {0,16384,32768,65536,98304,131072,133120,135168,137216,169984,202752,235520};
    int i = blockIdx.x * 256 + threadIdx.x;
    if (i >= 235520) return;
    int w = 0;
#pragma unroll
    for (int t = 1; t < 11; t++) if (i >= OFF[t]) w = t;
    int j = i - OFF[w];
    int K = KK[w], N = NNp[w];
    int k = j / N, n = j % N;
    float v = a.s[w][j];
    unsigned short hh = f2bf(v);
    a.h[w][(size_t)n * K + k] = hh;
    a.l[w][(size_t)n * K + k] = f2bf(v - bf2f(hh));
}

// ---------- GEMM bodies (shared-memory passed in) ----------
template <int NT>
__device__ __forceinline__ void gemm3_body(
    unsigned short* sm, int bx,
    const unsigned short* __restrict__ Ahi, const unsigned short* __restrict__ Alo,
    const unsigned short* __restrict__ BThi, const unsigned short* __restrict__ BTlo,
    int K, float* __restrict__ C, int Cstride, int M)
{
    unsigned short* Ah = sm;
    unsigned short* Al = Ah + 128 * 40;
    unsigned short* Bh = Al + 128 * 40;
    unsigned short* Bl = Bh + NT * 16 * 40;
    int t = threadIdx.x;
    int w = t >> 6, l = t & 63;
    int lane = l & 15, quad = l >> 4;
    int row0 = bx * 128;
    f32x4 acc[2][NT];
#pragma unroll
    for (int s = 0; s < 2; s++)
#pragma unroll
        for (int n = 0; n < NT; n++) acc[s][n] = (f32x4)(0.f);

    int ar = t >> 1, ako = (t & 1) << 4;
    int nkc = K >> 5;
    for (int kc = 0; kc < nkc; kc++) {
        int kb = kc << 5;
        {
            int gr = row0 + ar;
            float4 h0, h1, l0, l1;
            if (gr < M) {
                const float4* pH = (const float4*)&Ahi[(size_t)gr * K + kb + ako];
                const float4* pL = (const float4*)&Alo[(size_t)gr * K + kb + ako];
                h0 = pH[0]; h1 = pH[1]; l0 = pL[0]; l1 = pL[1];
            } else {
                h0 = h1 = l0 = l1 = make_float4(0.f, 0.f, 0.f, 0.f);
            }
            float4* dH = (float4*)&Ah[ar * 40 + ako];
            dH[0] = h0; dH[1] = h1;
            float4* dL = (float4*)&Al[ar * 40 + ako];
            dL[0] = l0; dL[1] = l1;
        }
        if (ar < NT * 16) {
            const float4* pH = (const float4*)&BThi[(size_t)ar * K + kb + ako];
            const float4* pL = (const float4*)&BTlo[(size_t)ar * K + kb + ako];
            float4 h0 = pH[0], h1 = pH[1], l0 = pL[0], l1 = pL[1];
            float4* dH = (float4*)&Bh[ar * 40 + ako];
            dH[0] = h0; dH[1] = h1;
            float4* dL = (float4*)&Bl[ar * 40 + ako];
            dL[0] = l0; dL[1] = l1;
        }
        __syncthreads();
        short8 aH[2], aL[2];
#pragma unroll
        for (int s = 0; s < 2; s++) {
            int r = w * 32 + s * 16 + lane;
            aH[s] = *(const short8*)&Ah[r * 40 + quad * 8];
            aL[s] = *(const short8*)&Al[r * 40 + quad * 8];
        }
#pragma unroll
        for (int n = 0; n < NT; n++) {
            int r = n * 16 + lane;
            short8 bH = *(const short8*)&Bh[r * 40 + quad * 8];
            short8 bL = *(const short8*)&Bl[r * 40 + quad * 8];
#pragma unroll
            for (int s = 0; s < 2; s++) {
                acc[s][n] = __builtin_amdgcn_mfma_f32_16x16x32_bf16(aH[s], bH, acc[s][n], 0, 0, 0);
                acc[s][n] = __builtin_amdgcn_mfma_f32_16x16x32_bf16(aH[s], bL, acc[s][n], 0, 0, 0);
                acc[s][n] = __builtin_amdgcn_mfma_f32_16x16x32_bf16(aL[s], bH, acc[s][n], 0, 0, 0);
            }
        }
        __syncthreads();
    }
#pragma unroll
    for (int s = 0; s < 2; s++) {
        int rb = row0 + w * 32 + s * 16 + quad * 4;
#pragma unroll
        for (int reg = 0; reg < 4; reg++) {
            int gr = rb + reg;
            if (gr >= M) continue;
#pragma unroll
            for (int n = 0; n < NT; n++)
                C[(size_t)gr * Cstride + n * 16 + lane] = acc[s][n][reg];
        }
    }
}

template <int NT, bool OUT16>
__device__ __forceinline__ void gemm1_body(
    unsigned short* sm, int bx,
    const unsigned short* __restrict__ Ahi,
    const unsigned short* __restrict__ BThi,
    int K, void* __restrict__ Cv, int Cstride, int M)
{
    unsigned short* Ah = sm;
    unsigned short* Bh = Ah + 128 * 40;
    int t = threadIdx.x;
    int w = t >> 6, l = t & 63;
    int lane = l & 15, quad = l >> 4;
    int row0 = bx * 128;
    f32x4 acc[2][NT];
#pragma unroll
    for (int s = 0; s < 2; s++)
#pragma unroll
        for (int n = 0; n < NT; n++) acc[s][n] = (f32x4)(0.f);

    int ar = t >> 1, ako = (t & 1) << 4;
    int nkc = K >> 5;
    for (int kc = 0; kc < nkc; kc++) {
        int kb = kc << 5;
        {
            int gr = row0 + ar;
            float4 h0, h1;
            if (gr < M) {
                const float4* pH = (const float4*)&Ahi[(size_t)gr * K + kb + ako];
                h0 = pH[0]; h1 = pH[1];
            } else {
                h0 = h1 = make_float4(0.f, 0.f, 0.f, 0.f);
            }
            float4* dH = (float4*)&Ah[ar * 40 + ako];
            dH[0] = h0; dH[1] = h1;
        }
        if (ar < NT * 16) {
            const float4* pH = (const float4*)&BThi[(size_t)ar * K + kb + ako];
            float4 h0 = pH[0], h1 = pH[1];
            float4* dH = (float4*)&Bh[ar * 40 + ako];
            dH[0] = h0; dH[1] = h1;
        }
        __syncthreads();
        short8 aH[2];
#pragma unroll
        for (int s = 0; s < 2; s++)
            aH[s] = *(const short8*)&Ah[(w * 32 + s * 16 + lane) * 40 + quad * 8];
#pragma unroll
        for (int n = 0; n < NT; n++) {
            short8 bH = *(const short8*)&Bh[(n * 16 + lane) * 40 + quad * 8];
#pragma unroll
            for (int s = 0; s < 2; s++)
                acc[s][n] = __builtin_amdgcn_mfma_f32_16x16x32_bf16(aH[s], bH, acc[s][n], 0, 0, 0);
        }
        __syncthreads();
    }
#pragma unroll
    for (int s = 0; s < 2; s++) {
        int rb = row0 + w * 32 + s * 16 + quad * 4;
#pragma unroll
        for (int reg = 0; reg < 4; reg++) {
            int gr = rb + reg;
            if (gr >= M) continue;
#pragma unroll
            for (int n = 0; n < NT; n++) {
                if (OUT16) {
                    unsigned short* C = (unsigned short*)Cv;
                    C[(size_t)gr * Cstride + n * 16 + lane] = f2bf(acc[s][n][reg]);
                } else {
                    float* C = (float*)Cv;
                    C[(size_t)gr * Cstride + n * 16 + lane] = acc[s][n][reg];
                }
            }
        }
    }
}

// standalone wrappers
template <int NT>
__global__ __launch_bounds__(256) void gemm3_k(
    const unsigned short* Ahi, const unsigned short* Alo, size_t yA,
    const unsigned short* BThi, const unsigned short* BTlo, size_t yB,
    int K, float* C, int Cstride, size_t yC, int M)
{
    __shared__ unsigned short sm[128 * 40 * 2 + NT * 16 * 40 * 2];
    gemm3_body<NT>(sm, blockIdx.x,
                   Ahi + blockIdx.y * yA, Alo + blockIdx.y * yA,
                   BThi + blockIdx.y * yB, BTlo + blockIdx.y * yB,
                   K, C + blockIdx.y * yC, Cstride, M);
}
template <int NT, bool OUT16>
__global__ __launch_bounds__(256) void gemm1_k(
    const unsigned short* Ahi, const unsigned short* BThi, size_t yB,
    int K, void* Cv, int Cstride, size_t yC, int M)
{
    __shared__ unsigned short sm[128 * 40 + NT * 16 * 40];
    gemm1_body<NT, OUT16>(sm, blockIdx.x, Ahi, BThi + blockIdx.y * yB, K,
                          OUT16 ? (void*)((unsigned short*)Cv + blockIdx.y * yC)
                                : (void*)((float*)Cv + blockIdx.y * yC),
                          Cstride, M);
}

// ---------- mega0: count(+seq) || gemm1 Ph2 || gemm1 Pmi×3 ----------
__global__ __launch_bounds__(256) void mega0(
    const int* __restrict__ i1, const int* __restrict__ i2, int* __restrict__ cnt,
    int* __restrict__ sd1, int* __restrict__ sd2,
    int* __restrict__ sc1, int* __restrict__ sc2,
    const unsigned short* __restrict__ feat_hi,
    const unsigned short* __restrict__ w1vh, unsigned short* __restrict__ Ph2,
    const unsigned short* __restrict__ wgallh, unsigned short* __restrict__ Pmi16)
{
    __shared__ unsigned short sm[128 * 40 + 8 * 16 * 40];
    int b = blockIdx.x;
    if (b < GBc) {
        gemm1_body<8, true>(sm, b, feat_hi, w1vh, FD, Ph2, 128, NN);
        return;
    }
    b -= GBc;
    if (b < 3 * GBc) {
        int y = b / GBc, bx = b % GBc;
        gemm1_body<8, true>(sm, bx, feat_hi, wgallh + (size_t)y * 32768,
                            FD, Pmi16 + (size_t)y * 128, 384, NN);
        return;
    }
    b -= 3 * GBc;
    int e = b * 256 + threadIdx.x;
    if (e >= EE) return;
    int r1 = i1[e], c1 = i1[EE + e];
    int r2 = i2[e], c2 = i2[EE + e];
    sd1[e] = atomicAdd(&cnt[r1], 1);
    sd2[e] = atomicAdd(&cnt[NN + r2], 1);
    sc1[e] = atomicAdd(&cnt[2 * NN + c1], 1);
    sc2[e] = atomicAdd(&cnt[3 * NN + c2], 1);
}

// ---------- mega1: atomic-free place || gemm3 Pg || gemm3 P01×2 ----------
__global__ __launch_bounds__(256) void mega1(
    const int* __restrict__ i1, const float* __restrict__ v1,
    const int* __restrict__ i2, const float* __restrict__ v2,
    const int* __restrict__ sd1, const int* __restrict__ sd2,
    const int* __restrict__ sc1, const int* __restrict__ sc2,
    const int* __restrict__ rp4,
    int2* __restrict__ ed1, int2* __restrict__ ec1,
    int2* __restrict__ ed2, int2* __restrict__ ec2,
    const unsigned short* __restrict__ feat_hi, const unsigned short* __restrict__ feat_lo,
    const unsigned short* __restrict__ wgen12h, const unsigned short* __restrict__ wgen12l,
    float* __restrict__ Pg,
    const unsigned short* __restrict__ w1pairh, const unsigned short* __restrict__ w1pairl,
    float* __restrict__ P01)
{
    __shared__ unsigned short sm[128 * 40 * 2 + 8 * 16 * 40 * 2];
    int b = blockIdx.x;
    if (b < GBc) {
        gemm3_body<8>(sm, b, feat_hi, feat_lo, wgen12h, wgen12l, FD, Pg, 128, NN);
        return;
    }
    b -= GBc;
    if (b < 2 * GBc) {
        int y = b / GBc, bx = b % GBc;
        gemm3_body<8>(sm, bx, feat_hi, feat_lo,
                      w1pairh + (size_t)y * 32768, w1pairl + (size_t)y * 32768,
                      FD, P01 + (size_t)y * 128, 256, NN);
        return;
    }
    b -= 2 * GBc;
    int e = b * 256 + threadIdx.x;
    if (e >= EE) return;
    const int* rp_d1 = rp4;
    const int* rp_d2 = rp4 + (NN + 1);
    const int* rp_c1 = rp4 + 2 * (NN + 1);
    const int* rp_c2 = rp4 + 3 * (NN + 1);
    int r = i1[e], c = i1[EE + e];
    int p = rp_d1[r] + sd1[e];
    ed1[p] = make_int2(c, __float_as_int(v1[e]));
    ec1[rp_c1[c] + sc1[e]] = make_int2(r, p);
    r = i2[e]; c = i2[EE + e];
    p = rp_d2[r] + sd2[e];
    ed2[p] = make_int2(c, __float_as_int(v2[e]));
    ec2[rp_c2[c] + sc2[e]] = make_int2(r, p);
}

// ---------- contrast: direct-from-L2 bf16 MFMA ----------
__global__ __launch_bounds__(256) void contrast_direct(
    const unsigned short* __restrict__ z16, float* __restrict__ stats)
{
    int p = blockIdx.z;
    int pa = (p == 2) ? 1 : 0;
    int pb = (p == 0) ? 1 : 2;
    const unsigned short* A = z16 + (size_t)pa * BT * MH;
    const unsigned short* B = z16 + (size_t)pb * BT * MH;
    float* diag = stats + (size_t)p * 3 * BT;
    float* rs = diag + BT;
    float* cs = rs + BT;
    int t = threadIdx.x;
    int w = t >> 6, l = t & 63, m = l & 15, quad = l >> 4;
    int i0 = blockIdx.y * 128, j0 = blockIdx.x * 128;

    short8 afr[2][4];
#pragma unroll
    for (int s = 0; s < 2; s++) {
        const unsigned short* arow = &A[(size_t)(i0 + w * 32 + s * 16 + m) * MH + quad * 8];
#pragma unroll
        for (int kc = 0; kc < 4; kc++)
            afr[s][kc] = *(const short8*)(arow + kc * 32);
    }
    f32x4 acc[2][8];
#pragma unroll
    for (int s = 0; s < 2; s++)
#pragma unroll
        for (int n = 0; n < 8; n++) acc[s][n] = (f32x4)(0.f);

#pragma unroll
    for (int kc = 0; kc < 4; kc++) {
#pragma unroll
        for (int n = 0; n < 8; n++) {
            short8 bf = *(const short8*)&B[(size_t)(j0 + n * 16 + m) * MH + kc * 32 + quad * 8];
            acc[0][n] = __builtin_amdgcn_mfma_f32_16x16x32_bf16(afr[0][kc], bf, acc[0][n], 0, 0, 0);
            acc[1][n] = __builtin_amdgcn_mfma_f32_16x16x32_bf16(afr[1][kc], bf, acc[1][n], 0, 0, 0);
        }
    }
    float colp[8];
#pragma unroll
    for (int n = 0; n < 8; n++) colp[n] = 0.f;
#pragma unroll
    for (int s = 0; s < 2; s++) {
        int rbase = i0 + w * 32 + s * 16 + quad * 4;
#pragma unroll
        for (int reg = 0; reg < 4; reg++) {
            float rsum = 0.f;
            int gi = rbase + reg;
#pragma unroll
            for (int n = 0; n < 8; n++) {
                float mv = expf(acc[s][n][reg] * 2.0f);
                rsum += mv;
                colp[n] += mv;
                int gj = j0 + n * 16 + m;
                if (gi == gj) diag[gi] = mv;
            }
            rsum += __shfl_xor(rsum, 1); rsum += __shfl_xor(rsum, 2);
            rsum += __shfl_xor(rsum, 4); rsum += __shfl_xor(rsum, 8);
            if (m == 0) atomicAdd(&rs[gi], rsum);
        }
    }
    __shared__ float scol[128];
    if (t < 128) scol[t] = 0.f;
    __syncthreads();
#pragma unroll
    for (int n = 0; n < 8; n++) {
        float v = colp[n];
        v += __shfl_xor(v, 16); v += __shfl_xor(v, 32);
        if (quad == (n & 3)) atomicAdd(&scol[n * 16 + m], v);
    }
    __syncthreads();
    if (t < 128) atomicAdd(&cs[j0 + t], scol[t]);
}

// ---------- scans ----------
__global__ __launch_bounds__(1024) void scan_block4(const int* __restrict__ cnt,
                                                    int* __restrict__ rowptr,
                                                    int* __restrict__ bsum) {
    int y = blockIdx.y;
    int* rp = rowptr + y * (NN + 1);
    int* bs = bsum + y * 32;
    __shared__ int tmp[1024];
    int t = threadIdx.x;
    int i = blockIdx.x * 1024 + t;
    int v = (i < NN) ? cnt[y * NN + i] : 0;
    tmp[t] = v;
    __syncthreads();
    for (int off = 1; off < 1024; off <<= 1) {
        int add = (t >= off) ? tmp[t - off] : 0;
        __syncthreads();
        tmp[t] += add;
        __syncthreads();
    }
    if (i <= NN) rp[i] = tmp[t] - v;
    if (t == 1023) bs[blockIdx.x] = tmp[1023];
}
__global__ void scan_bsum4(int* __restrict__ bsum, int nb) {
    bsum += blockIdx.x * 32;
    int t = threadIdx.x;
    int orig = (t < nb) ? bsum[t] : 0;
    int v = orig;
    for (int off = 1; off < 64; off <<= 1) {
        int u = __shfl_up(v, off);
        if (t >= off) v += u;
    }
    if (t < nb) bsum[t] = v - orig;
}
__global__ void scan_add4(const int* __restrict__ bsum, int* __restrict__ rowptr) {
    int y = blockIdx.y;
    const int* bs = bsum + y * 32;
    int* rp = rowptr + y * (NN + 1);
    int i = blockIdx.x * 1024 + threadIdx.x;
    if (i <= NN) rp[i] += bs[blockIdx.x];
}

// ---------- row-parallel nv (softmax over sb[col]; sa & bm cancel) ----------
__global__ __launch_bounds__(256) void gen_nv(
    const int* __restrict__ rp_d, int2* __restrict__ ed1, int2* __restrict__ ed2,
    const float* __restrict__ sb, float* __restrict__ nvd1, float* __restrict__ nvd2)
{
    int y = blockIdx.y;
    int row = blockIdx.x * 256 + threadIdx.x;
    if (row >= NN) return;
    const int* rp = rp_d + y * (NN + 1);
    int2* ed = y ? ed2 : ed1;
    float* nvd = y ? nvd2 : nvd1;
    const float* sbv = sb + (size_t)y * NN;
    int p0 = rp[row], p1 = rp[row + 1];
    float m = -3.4e38f, sum = 0.f;
    for (int j = p0; j < p1; j++) {
        float x = sbv[ed[j].x];
        if (x > m) { sum = sum * expf(m - x) + 1.f; m = x; }
        else sum += expf(x - m);
    }
    float inv = 1.f / sum;
    for (int j = p0; j < p1; j++) {
        int2 q = ed[j];
        float nv = __int_as_float(q.y) + 0.5f * expf(sbv[q.x] - m) * inv;
        nvd[j] = nv;
        ed[j].y = __float_as_int(nv);
    }
}

// ---------- fp32 gather helpers ----------
template <int STR4>
__device__ __forceinline__ void gath_dir_f32(
    const int* __restrict__ rp, const int2* __restrict__ ed, int row,
    const float4* __restrict__ x4, int xo, float4* a)
{
    int p0 = rp[row], p1 = rp[row + 1];
    int j = p0;
    for (; j + 4 <= p1; j += 4) {
        int2 q0 = ed[j], q1 = ed[j+1], q2 = ed[j+2], q3 = ed[j+3];
        a[0] = fma4(__int_as_float(q0.y), x4[(size_t)q0.x * STR4 + xo], a[0]);
        a[1] = fma4(__int_as_float(q1.y), x4[(size_t)q1.x * STR4 + xo], a[1]);
        a[2] = fma4(__int_as_float(q2.y), x4[(size_t)q2.x * STR4 + xo], a[2]);
        a[3] = fma4(__int_as_float(q3.y), x4[(size_t)q3.x * STR4 + xo], a[3]);
    }
    for (; j < p1; j++) {
        int2 q = ed[j];
        a[0] = fma4(__int_as_float(q.y), x4[(size_t)q.x * STR4 + xo], a[0]);
    }
}
template <int STR4>
__device__ __forceinline__ void gath_csc_f32(
    const int* __restrict__ rp, const int2* __restrict__ ec, const float* __restrict__ nvd,
    int row, const float4* __restrict__ x4, int xo, float4* a)
{
    int p0 = rp[row], p1 = rp[row + 1];
    int j = p0;
    for (; j + 4 <= p1; j += 4) {
        int2 q0 = ec[j], q1 = ec[j+1], q2 = ec[j+2], q3 = ec[j+3];
        float v0 = nvd[q0.y], v1 = nvd[q1.y], v2 = nvd[q2.y], v3 = nvd[q3.y];
        a[0] = fma4(v0, x4[(size_t)q0.x * STR4 + xo], a[0]);
        a[1] = fma4(v1, x4[(size_t)q1.x * STR4 + xo], a[1]);
        a[2] = fma4(v2, x4[(size_t)q2.x * STR4 + xo], a[2]);
        a[3] = fma4(v3, x4[(size_t)q3.x * STR4 + xo], a[3]);
    }
    for (; j < p1; j++) {
        int2 q = ec[j];
        a[0] = fma4(nvd[q.y], x4[(size_t)q.x * STR4 + xo], a[0]);
    }
}

// ---------- gen SpMM (dir graph, orig vals) ----------
__global__ __launch_bounds__(256) void spmm64_pair(
    const int* __restrict__ rp_d, const int2* __restrict__ e1, const int2* __restrict__ e2,
    const float* __restrict__ Pg, float* __restrict__ emb)
{
    int y = blockIdx.y;
    const int* rp = rp_d + y * (NN + 1);
    const int2* arr = y ? e2 : e1;
    int row = blockIdx.x * 16 + threadIdx.x / 16;
    int o = threadIdx.x % 16;
    if (row >= NN) return;
    float4 a[4] = {};
    gath_dir_f32<32>(rp, arr, row, (const float4*)Pg, y * 16 + o, a);
    float4 r;
    r.x = fmaxf((a[0].x + a[1].x) + (a[2].x + a[3].x), 0.f);
    r.y = fmaxf((a[0].y + a[1].y) + (a[2].y + a[3].y), 0.f);
    r.z = fmaxf((a[0].z + a[1].z) + (a[2].z + a[3].z), 0.f);
    r.w = fmaxf((a[0].w + a[1].w) + (a[2].w + a[3].w), 0.f);
    ((float4*)emb)[((size_t)y * NN + row) * 16 + o] = r;
}

// ---------- sym SpMMs (dir + csc halves) ----------
__global__ __launch_bounds__(256) void spmm128_pair(
    const int* __restrict__ rp_d, const int* __restrict__ rp_c,
    const int2* __restrict__ ed1, const int2* __restrict__ ec1, const float* __restrict__ nvd1,
    const int2* __restrict__ ed2, const int2* __restrict__ ec2, const float* __restrict__ nvd2,
    const float* __restrict__ P01, float* __restrict__ Q01)
{
    int y = blockIdx.y;
    const int* rpd = rp_d + y * (NN + 1);
    const int* rpc = rp_c + y * (NN + 1);
    const int2* ed = y ? ed2 : ed1;
    const int2* ec = y ? ec2 : ec1;
    const float* nvd = y ? nvd2 : nvd1;
    int row = blockIdx.x * 8 + threadIdx.x / 32;
    int o = threadIdx.x % 32;
    if (row >= NN) return;
    int xo = y * 32 + o;
    float4 a[4] = {};
    gath_dir_f32<64>(rpd, ed, row, (const float4*)P01, xo, a);
    gath_csc_f32<64>(rpc, ec, nvd, row, (const float4*)P01, xo, a);
    float4 r;
    r.x = fmaxf((a[0].x + a[1].x) + (a[2].x + a[3].x), 0.f);
    r.y = fmaxf((a[0].y + a[1].y) + (a[2].y + a[3].y), 0.f);
    r.z = fmaxf((a[0].z + a[1].z) + (a[2].z + a[3].z), 0.f);
    r.w = fmaxf((a[0].w + a[1].w) + (a[2].w + a[3].w), 0.f);
    ((float4*)Q01)[((size_t)y * NN + row) * 32 + o] = r;
}

__global__ __launch_bounds__(256) void spmm16_pair(
    const int* __restrict__ rp_d, const int* __restrict__ rp_c,
    const int2* __restrict__ ed1, const int2* __restrict__ ec1, const float* __restrict__ nvd1,
    const int2* __restrict__ ed2, const int2* __restrict__ ec2, const float* __restrict__ nvd2,
    const float* __restrict__ R01, float* __restrict__ T01)
{
    int y = blockIdx.y;
    const int* rpd = rp_d + y * (NN + 1);
    const int* rpc = rp_c + y * (NN + 1);
    const int2* ed = y ? ed2 : ed1;
    const int2* ec = y ? ec2 : ec1;
    const float* nvd = y ? nvd2 : nvd1;
    int row = blockIdx.x * 64 + threadIdx.x / 4;
    int o = threadIdx.x % 4;
    if (row >= NN) return;
    const float4* x4 = (const float4*)(R01 + (size_t)y * NN * 16);
    float4 a[4] = {};
    gath_dir_f32<4>(rpd, ed, row, x4, o, a);
    gath_csc_f32<4>(rpc, ec, nvd, row, x4, o, a);
    float4 r;
    r.x = (a[0].x + a[1].x) + (a[2].x + a[3].x);
    r.y = (a[0].y + a[1].y) + (a[2].y + a[3].y);
    r.z = (a[0].z + a[1].z) + (a[2].z + a[3].z);
    r.w = (a[0].w + a[1].w) + (a[2].w + a[3].w);
    ((float4*)(T01 + (size_t)y * NN * 16))[(size_t)row * 4 + o] = r;
}

__global__ __launch_bounds__(256) void spmm16_fused(
    const int* __restrict__ rp_d, const int* __restrict__ rp_c,
    const int2* __restrict__ ed1, const int2* __restrict__ ec1, const float* __restrict__ nvd1,
    const int2* __restrict__ ed2, const int2* __restrict__ ec2, const float* __restrict__ nvd2,
    const float* __restrict__ bb, const float* __restrict__ x, float* __restrict__ out)
{
    int row = blockIdx.x * 64 + threadIdx.x / 4;
    int o = threadIdx.x % 4;
    if (row >= NN) return;
    const float4* x4 = (const float4*)x;
    float4 a[4] = {};
    gath_dir_f32<4>(rp_d, ed1, row, x4, o, a);
    gath_csc_f32<4>(rp_c, ec1, nvd1, row, x4, o, a);
    float4 s1;
    s1.x = (a[0].x + a[1].x) + (a[2].x + a[3].x);
    s1.y = (a[0].y + a[1].y) + (a[2].y + a[3].y);
    s1.z = (a[0].z + a[1].z) + (a[2].z + a[3].z);
    s1.w = (a[0].w + a[1].w) + (a[2].w + a[3].w);
    float4 b[4] = {};
    gath_dir_f32<4>(rp_d + (NN + 1), ed2, row, x4, o, b);
    gath_csc_f32<4>(rp_c + (NN + 1), ec2, nvd2, row, x4, o, b);
    float4 s2;
    s2.x = (b[0].x + b[1].x) + (b[2].x + b[3].x);
    s2.y = (b[0].y + b[1].y) + (b[2].y + b[3].y);
    s2.z = (b[0].z + b[1].z) + (b[2].z + b[3].z);
    s2.w = (b[0].w + b[1].w) + (b[2].w + b[3].w);
    float w1 = bb[row], w2 = bb[NN + row];
    float4 r;
    r.x = w1 * s1.x + w2 * s2.x;
    r.y = w1 * s1.y + w2 * s2.y;
    r.z = w1 * s1.z + w2 * s2.z;
    r.w = w1 * s1.w + w2 * s2.w;
    ((float4*)out)[(size_t)row * 4 + o] = r;
}

// ---------- bf16 gather helpers ----------
__device__ __forceinline__ void gath_dir_b16(
    const int* __restrict__ rp, const int2* __restrict__ ed, int row,
    const unsigned short* __restrict__ X, int xstride, int o, float* acc)
{
    int p0 = rp[row], p1 = rp[row + 1];
    int j = p0;
    for (; j + 4 <= p1; j += 4) {
        int2 q0 = ed[j], q1 = ed[j+1], q2 = ed[j+2], q3 = ed[j+3];
        short8 x0 = *(const short8*)&X[(size_t)q0.x * xstride + o * 8];
        short8 x1 = *(const short8*)&X[(size_t)q1.x * xstride + o * 8];
        short8 x2 = *(const short8*)&X[(size_t)q2.x * xstride + o * 8];
        short8 x3 = *(const short8*)&X[(size_t)q3.x * xstride + o * 8];
        float v0 = __int_as_float(q0.y), v1 = __int_as_float(q1.y);
        float v2 = __int_as_float(q2.y), v3 = __int_as_float(q3.y);
#pragma unroll
        for (int k = 0; k < 8; k++) {
            acc[k] = fmaf(v0, bf2f((unsigned short)x0[k]), acc[k]);
            acc[k] = fmaf(v1, bf2f((unsigned short)x1[k]), acc[k]);
            acc[k] = fmaf(v2, bf2f((unsigned short)x2[k]), acc[k]);
            acc[k] = fmaf(v3, bf2f((unsigned short)x3[k]), acc[k]);
        }
    }
    for (; j < p1; j++) {
        int2 q = ed[j];
        short8 xv = *(const short8*)&X[(size_t)q.x * xstride + o * 8];
        float v = __int_as_float(q.y);
#pragma unroll
        for (int k = 0; k < 8; k++)
            acc[k] = fmaf(v, bf2f((unsigned short)xv[k]), acc[k]);
    }
}
__device__ __forceinline__ void gath_csc_b16(
    const int* __restrict__ rp, const int2* __restrict__ ec, const float* __restrict__ nvd,
    int row, const unsigned short* __restrict__ X, int xstride, int o, float* acc)
{
    int p0 = rp[row], p1 = rp[row + 1];
    int j = p0;
    for (; j + 4 <= p1; j += 4) {
        int2 q0 = ec[j], q1 = ec[j+1], q2 = ec[j+2], q3 = ec[j+3];
        short8 x0 = *(const short8*)&X[(size_t)q0.x * xstride + o * 8];
        short8 x1 = *(const short8*)&X[(size_t)q1.x * xstride + o * 8];
        short8 x2 = *(const short8*)&X[(size_t)q2.x * xstride + o * 8];
        short8 x3 = *(const short8*)&X[(size_t)q3.x * xstride + o * 8];
        float v0 = nvd[q0.y], v1 = nvd[q1.y], v2 = nvd[q2.y], v3 = nvd[q3.y];
#pragma unroll
        for (int k = 0; k < 8; k++) {
            acc[k] = fmaf(v0, bf2f((unsigned short)x0[k]), acc[k]);
            acc[k] = fmaf(v1, bf2f((unsigned short)x1[k]), acc[k]);
            acc[k] = fmaf(v2, bf2f((unsigned short)x2[k]), acc[k]);
            acc[k] = fmaf(v3, bf2f((unsigned short)x3[k]), acc[k]);
        }
    }
    for (; j < p1; j++) {
        int2 q = ec[j];
        short8 xv = *(const short8*)&X[(size_t)q.x * xstride + o * 8];
        float v = nvd[q.y];
#pragma unroll
        for (int k = 0; k < 8; k++)
            acc[k] = fmaf(v, bf2f((unsigned short)xv[k]), acc[k]);
    }
}

__global__ __launch_bounds__(256) void fused128_b16(
    const int* __restrict__ rp_d, const int* __restrict__ rp_c,
    const int2* __restrict__ ed1, const int2* __restrict__ ec1, const float* __restrict__ nvd1,
    const int2* __restrict__ ed2, const int2* __restrict__ ec2, const float* __restrict__ nvd2,
    const float* __restrict__ bb, const unsigned short* __restrict__ X,
    unsigned short* __restrict__ Out)
{
    int row = blockIdx.x * 16 + threadIdx.x / 16;
    int o = threadIdx.x % 16;
    if (row >= NN) return;
    float a1[8] = {}, a2[8] = {};
    gath_dir_b16(rp_d, ed1, row, X, 128, o, a1);
    gath_csc_b16(rp_c, ec1, nvd1, row, X, 128, o, a1);
    gath_dir_b16(rp_d + (NN + 1), ed2, row, X, 128, o, a2);
    gath_csc_b16(rp_c + (NN + 1), ec2, nvd2, row, X, 128, o, a2);
    float w1 = bb[row], w2 = bb[NN + row];
    short8 outv;
#pragma unroll
    for (int k = 0; k < 8; k++) {
        float r = fmaxf(w1 * a1[k] + w2 * a2[k], 0.f);
        outv[k] = (short)f2bf(r);
    }
    *(short8*)&Out[(size_t)row * 128 + o * 8] = outv;
}

__global__ __launch_bounds__(256) void rows_spmm_b16(
    const int* __restrict__ rp_d, const int* __restrict__ rp_c,
    const int2* __restrict__ ed1, const int2* __restrict__ ec1, const float* __restrict__ nvd1,
    const int2* __restrict__ ed2, const int2* __restrict__ ec2, const float* __restrict__ nvd2,
    const float* __restrict__ bb, const int* __restrict__ rows,
    const unsigned short* __restrict__ Pmi, float* __restrict__ zQ)
{
    int y = blockIdx.y;
    int ri = blockIdx.x * 16 + threadIdx.x / 16;
    int o = threadIdx.x % 16;
    if (ri >= BT) return;
    int node = rows[ri];
    int xoff = (y == 0) ? 0 : ((y == 1) ? 128 : 256);
    const unsigned short* X = Pmi + xoff;
    float acc[8] = {};
    if (y == 0) {
        float a1[8] = {}, a2[8] = {};
        gath_dir_b16(rp_d, ed1, node, X, 384, o, a1);
        gath_csc_b16(rp_c, ec1, nvd1, node, X, 384, o, a1);
        gath_dir_b16(rp_d + (NN + 1), ed2, node, X, 384, o, a2);
        gath_csc_b16(rp_c + (NN + 1), ec2, nvd2, node, X, 384, o, a2);
        float w1 = bb[node], w2 = bb[NN + node];
#pragma unroll
        for (int k = 0; k < 8; k++) acc[k] = w1 * a1[k] + w2 * a2[k];
    } else if (y == 1) {
        gath_dir_b16(rp_d, ed1, node, X, 384, o, acc);
        gath_csc_b16(rp_c, ec1, nvd1, node, X, 384, o, acc);
    } else {
        gath_dir_b16(rp_d + (NN + 1), ed2, node, X, 384, o, acc);
        gath_csc_b16(rp_c + (NN + 1), ec2, nvd2, node, X, 384, o, acc);
    }
    float* out = zQ + ((size_t)y * BT + ri) * 128 + o * 8;
#pragma unroll
    for (int k = 0; k < 8; k++) out[k] = fmaxf(acc[k], 0.f);
}

// ---------- node scores: sb only ----------
__global__ __launch_bounds__(256) void node_scores_pair(
    const float* __restrict__ emb, const float* __restrict__ Wm1,
    const float* __restrict__ Wm2, float* __restrict__ sb)
{
    int y = blockIdx.y;
    const float* e_ = emb + (size_t)y * NN * GH;
    const float* Wm = y ? Wm2 : Wm1;
    int node = blockIdx.x * 4 + threadIdx.x / 64;
    int lane = threadIdx.x % 64;
    if (node >= NN) return;
    float e = e_[(size_t)node * GH + lane];
    float vb = e * Wm[GH + lane];
#pragma unroll
    for (int off = 32; off; off >>= 1)
        vb += __shfl_down(vb, off);
    if (lane == 0) sb[y * NN + node] = vb;
}

// ---------- softmax / weights ----------
__global__ void softmax16y(const float* __restrict__ S01, float* __restrict__ logits_base,
                           float* __restrict__ w12)
{
    int y = blockIdx.y;
    const float* S = S01 + (size_t)y * NN * NCLS;
    float* logits = logits_base + (size_t)y * NN * NCLS;
    float* w = w12 + (size_t)y * NN;
    int node = blockIdx.x * 256 + threadIdx.x;
    if (node >= NN) return;
    float v[NCLS];
    float mx = -3.4e38f;
#pragma unroll
    for (int j = 0; j < NCLS; j++) { v[j] = S[(size_t)node * NCLS + j]; mx = fmaxf(mx, v[j]); }
    float s = 0.f;
#pragma unroll
    for (int j = 0; j < NCLS; j++) { v[j] = expf(v[j] - mx); s += v[j]; }
    float inv = 1.f / s;
    float fir = -1.f, sec = -1.f;
#pragma unroll
    for (int j = 0; j < NCLS; j++) {
        float p = v[j] * inv;
        logits[(size_t)node * NCLS + j] = logf(p + EPSc);
        if (p > fir) { sec = fir; fir = p; }
        else if (p > sec) { sec = p; }
    }
    w[node] = expf(0.5f * logf(fir + EPSc) + 0.5f * logf(fir - sec + EPSc));
}

__global__ void softmax16(const float* __restrict__ S, float* __restrict__ logits)
{
    int node = blockIdx.x * 256 + threadIdx.x;
    if (node >= NN) return;
    float v[NCLS];
    float mx = -3.4e38f;
#pragma unroll
    for (int j = 0; j < NCLS; j++) { v[j] = S[(size_t)node * NCLS + j]; mx = fmaxf(mx, v[j]); }
    float s = 0.f;
#pragma unroll
    for (int j = 0; j < NCLS; j++) { v[j] = expf(v[j] - mx); s += v[j]; }
    float inv = 1.f / s;
#pragma unroll
    for (int j = 0; j < NCLS; j++)
        logits[(size_t)node * NCLS + j] = logf(v[j] * inv + EPSc);
}

__global__ void bweights(const float* __restrict__ w12, float* __restrict__ bb)
{
    int i = blockIdx.x * 256 + threadIdx.x;
    if (i >= NN) return;
    float a = w12[i], b = w12[NN + i];
    float inv = 1.f / (a + b);
    bb[i] = a * inv;
    bb[NN + i] = b * inv;
}

// ---------- projection head + L2-normalize, bf16 out ----------
__global__ __launch_bounds__(128) void proj_norm3(
    const float* __restrict__ zQ,
    const float* __restrict__ Wp1, const float* __restrict__ bp1,
    const float* __restrict__ Wp2, const float* __restrict__ bp2,
    unsigned short* __restrict__ z16)
{
    __shared__ float g[MH], u[MH];
    __shared__ float red[2];
    size_t i = (size_t)blockIdx.y * BT + blockIdx.x;
    int t = threadIdx.x;
    g[t] = zQ[i * MH + t];
    __syncthreads();
    float acc = bp1[t];
    for (int k = 0; k < MH; k++) acc = fmaf(g[k], Wp1[k * MH + t], acc);
    u[t] = acc > 0.f ? acc : (expf(acc) - 1.f);
    __syncthreads();
    float acc2 = bp2[t];
    for (int k = 0; k < MH; k++) acc2 = fmaf(u[k], Wp2[k * MH + t], acc2);
    float sq = acc2 * acc2;
#pragma unroll
    for (int off = 32; off; off >>= 1) sq += __shfl_down(sq, off);
    if ((t & 63) == 0) red[t >> 6] = sq;
    __syncthreads();
    float nrm = sqrtf(red[0] + red[1]);
    z16[i * MH + t] = f2bf(acc2 / nrm);
}

__global__ void contrast_reduce(const float* __restrict__ stats, float* __restrict__ out3)
{
    int p = blockIdx.x, t = threadIdx.x;
    const float* diag = stats + (size_t)p * 3 * BT;
    const float* rs = diag + BT;
    const float* cs = rs + BT;
    float s1 = 0.f, s2 = 0.f;
    for (int i = t; i < BT; i += 256) {
        float d = diag[i];
        s1 += logf(d / (rs[i] + EPSc) + EPSc);
        s2 += logf(d / (cs[i] + EPSc) + EPSc);
    }
#pragma unroll
    for (int off = 32; off; off >>= 1) { s1 += __shfl_down(s1, off); s2 += __shfl_down(s2, off); }
    __shared__ float sh[8];
    if ((t & 63) == 0) { sh[(t >> 6) * 2] = s1; sh[(t >> 6) * 2 + 1] = s2; }
    __syncthreads();
    if (t == 0) {
        float a = sh[0] + sh[2] + sh[4] + sh[6];
        float b = sh[1] + sh[3] + sh[5] + sh[7];
        out3[p] = 0.5f * (-a / BT - b / BT);
    }
}

// ---------- host ----------
extern "C" void kernel_launch(void* const* d_in, const int* in_sizes, int n_in,
                              void* d_out, int out_size, void* d_ws, size_t ws_size,
                              hipStream_t stream)
{
    const float* feat   = (const float*)d_in[0];
    const int*   ind1   = (const int*)d_in[1];
    const float* vals1  = (const float*)d_in[2];
    const int*   ind2   = (const int*)d_in[3];
    const float* vals2  = (const float*)d_in[4];
    const int*   idxb   = (const int*)d_in[5];
    const float* Wm1    = (const float*)d_in[7];
    const float* Wm2    = (const float*)d_in[10];
    const float* Wp1    = (const float*)d_in[21];
    const float* bp1    = (const float*)d_in[22];
    const float* Wp2    = (const float*)d_in[23];
    const float* bp2    = (const float*)d_in[24];
    float* dout = (float*)d_out;

    float* ws = (float*)d_ws;
    size_t off = 0;
    auto alloc = [&](size_t n) { n = (n + 3) & ~(size_t)3; float* p = ws + off; off += n; return p; };
    auto alloc_s = [&](size_t n) { return (unsigned short*)alloc((n + 1) / 2); };

    // --- shared pool ---
    float* pool = alloc(24960000);
    // phase A/B
    float* Pg   = pool;                      // [0, 3.84M)
    float* P01  = pool + 3840000;            // [3.84M, 11.52M)  [NN][256]
    float* emb  = pool + 11520000;           // [11.52M, 15.36M)
    float* Q01  = pool + 11520000;           // reuse emb after node_scores: [11.52M, 19.2M)
    unsigned short* q01h = (unsigned short*)pool;             // [0, 3.84M) after Pg dead
    unsigned short* q01l = (unsigned short*)(pool + 19200000);// [19.2M, 23.04M)
    float* R01  = pool + 23040000;           // [23.04M, 24M)
    float* T01  = pool + 24000000;           // [24M, 24.96M)
    // phase C (everything above dead)
    unsigned short* q2h = (unsigned short*)pool;              // [0, 0.96M)
    float* R2   = pool + 960000;
    float* T2   = pool + 1440000;
    float* zQ   = pool + 1920000;            // [1.92M, 3.5M)

    // --- persistent ---
    unsigned short* feat_hi = alloc_s((size_t)NN * FD);
    unsigned short* feat_lo = alloc_s((size_t)NN * FD);
    unsigned short* Ph2d    = alloc_s((size_t)NN * CH);
    unsigned short* Pmi16d  = alloc_s((size_t)NN * 384);
    float* sb   = alloc(2 * NN);
    float* w12  = alloc(2 * NN);
    float* bb   = alloc(2 * NN);
    float* stats = alloc((size_t)3 * 3 * BT);
    unsigned short* z16 = alloc_s((size_t)3 * BT * MH);
    int2* ed1 = (int2*)alloc(2 * (size_t)EE);
    int2* ed2 = (int2*)alloc(2 * (size_t)EE);
    int2* ec1 = (int2*)alloc(2 * (size_t)EE);
    int2* ec2 = (int2*)alloc(2 * (size_t)EE);
    float* nvd1 = alloc(EE);
    float* nvd2 = alloc(EE);
    int* sd1 = (int*)alloc(EE);
    int* sd2 = (int*)alloc(EE);
    int* sc1 = (int*)alloc(EE);
    int* sc2 = (int*)alloc(EE);
    int* rp4  = (int*)alloc(4 * (NN + 1));
    int* cnt4 = (int*)alloc(4 * NN);
    int* bsum = (int*)alloc(128);
    int* rp_d = rp4;
    int* rp_c = rp4 + 2 * (NN + 1);
    // weights
    unsigned short* wgen12h = alloc_s(32768); unsigned short* wgen12l = alloc_s(32768);
    unsigned short* w1pairh = alloc_s(65536); unsigned short* w1pairl = alloc_s(65536);
    unsigned short* w1vh    = alloc_s(32768); unsigned short* w1vl    = alloc_s(32768);
    unsigned short* w2pairh = alloc_s(4096);  unsigned short* w2pairl = alloc_s(4096);
    unsigned short* w2vh    = alloc_s(2048);  unsigned short* w2vl    = alloc_s(2048);
    unsigned short* wgallh  = alloc_s(98304); unsigned short* wgalll  = alloc_s(98304);

    const int NB = (NN + 1 + 1023) / 1024;
    const int NCNT = (EE + 255) / 256;

    // ---- prep ----
    hipMemsetAsync(cnt4, 0, 4 * NN * 4, stream);
    split_bf16<<<((long)NN * FD + 255) / 256, 256, 0, stream>>>(feat, feat_hi, feat_lo, (long)NN * FD);
    {
        WSArgs a;
        a.s[0] = (const float*)d_in[6];  a.h[0] = wgen12h;          a.l[0] = wgen12l;
        a.s[1] = (const float*)d_in[9];  a.h[1] = wgen12h + 16384;  a.l[1] = wgen12l + 16384;
        a.s[2] = (const float*)d_in[12]; a.h[2] = w1pairh;          a.l[2] = w1pairl;
        a.s[3] = (const float*)d_in[14]; a.h[3] = w1pairh + 32768;  a.l[3] = w1pairl + 32768;
        a.s[4] = (const float*)d_in[16]; a.h[4] = w1vh;             a.l[4] = w1vl;
        a.s[5] = (const float*)d_in[13]; a.h[5] = w2pairh;          a.l[5] = w2pairl;
        a.s[6] = (const float*)d_in[15]; a.h[6] = w2pairh + 2048;   a.l[6] = w2pairl + 2048;
        a.s[7] = (const float*)d_in[17]; a.h[7] = w2vh;             a.l[7] = w2vl;
        a.s[8] = (const float*)d_in[18]; a.h[8] = wgallh;           a.l[8] = wgalll;
        a.s[9] = (const float*)d_in[19]; a.h[9] = wgallh + 32768;   a.l[9] = wgalll + 32768;
        a.s[10]= (const float*)d_in[20]; a.h[10]= wgallh + 65536;   a.l[10]= wgalll + 65536;
        wsplit_all<<<(235520 + 255) / 256, 256, 0, stream>>>(a);
    }

    // ---- mega0: count(+seq) || Ph2 gemm1 || Pmi gemm1×3 ----
    mega0<<<4 * GBc + NCNT, 256, 0, stream>>>(ind1, ind2, cnt4, sd1, sd2, sc1, sc2,
                                              feat_hi, w1vh, Ph2d, wgallh, Pmi16d);

    // ---- scans ----
    scan_block4<<<dim3(NB, 4), 1024, 0, stream>>>(cnt4, rp4, bsum);
    scan_bsum4<<<4, 64, 0, stream>>>(bsum, NB);
    scan_add4<<<dim3(NB, 4), 1024, 0, stream>>>(bsum, rp4);

    // ---- mega1: atomic-free place || Pg gemm3 || P01 gemm3×2 ----
    mega1<<<3 * GBc + NCNT, 256, 0, stream>>>(ind1, vals1, ind2, vals2,
                                              sd1, sd2, sc1, sc2, rp4,
                                              ed1, ec1, ed2, ec2,
                                              feat_hi, feat_lo, wgen12h, wgen12l, Pg,
                                              w1pairh, w1pairl, P01);

    // ---- gen_view ----
    spmm64_pair<<<dim3((NN + 15) / 16, 2), 256, 0, stream>>>(rp_d, ed1, ed2, Pg, emb);
    node_scores_pair<<<dim3((NN + 3) / 4, 2), 256, 0, stream>>>(emb, Wm1, Wm2, sb);
    gen_nv<<<dim3((NN + 255) / 256, 2), 256, 0, stream>>>(rp_d, ed1, ed2, sb, nvd1, nvd2);

    // ---- branches 0/1 (fp32-accurate) ----
    spmm128_pair<<<dim3((NN + 7) / 8, 2), 256, 0, stream>>>(rp_d, rp_c, ed1, ec1, nvd1,
                                                            ed2, ec2, nvd2, P01, Q01);
    split_bf16<<<((long)2 * NN * CH + 255) / 256, 256, 0, stream>>>(Q01, q01h, q01l, (long)2 * NN * CH);
    gemm3_k<1><<<dim3(GBc, 2), 256, 0, stream>>>(q01h, q01l, (size_t)NN * CH,
                                                 w2pairh, w2pairl, 2048,
                                                 CH, R01, 16, (size_t)NN * NCLS, NN);
    spmm16_pair<<<dim3((NN + 63) / 64, 2), 256, 0, stream>>>(rp_d, rp_c, ed1, ec1, nvd1,
                                                             ed2, ec2, nvd2, R01, T01);
    softmax16y<<<dim3((NN + 255) / 256, 2), 256, 0, stream>>>(T01, dout + (size_t)NN * NCLS, w12);
    bweights<<<(NN + 255) / 256, 256, 0, stream>>>(w12, bb);

    // ---- branch 2 (bf16 fast path) ----
    fused128_b16<<<(NN + 15) / 16, 256, 0, stream>>>(rp_d, rp_c, ed1, ec1, nvd1,
                                                     ed2, ec2, nvd2, bb, Ph2d, q2h);
    gemm1_k<1, false><<<dim3(GBc, 1), 256, 0, stream>>>(q2h, w2vh, 0, CH, R2, 16, 0, NN);
    spmm16_fused<<<(NN + 63) / 64, 256, 0, stream>>>(rp_d, rp_c, ed1, ec1, nvd1,
                                                     ed2, ec2, nvd2, bb, R2, T2);
    softmax16<<<(NN + 255) / 256, 256, 0, stream>>>(T2, dout);

    // ---- MI branch ----
    rows_spmm_b16<<<dim3((BT + 15) / 16, 3), 256, 0, stream>>>(rp_d, rp_c, ed1, ec1, nvd1,
                                                               ed2, ec2, nvd2, bb, idxb, Pmi16d, zQ);
    proj_norm3<<<dim3(BT, 3), 128, 0, stream>>>(zQ, Wp1, bp1, Wp2, bp2, z16);

    // ---- contrast ----
    hipMemsetAsync(stats, 0, (size_t)3 * 3 * BT * 4, stream);
    contrast_direct<<<dim3(32, 32, 3), 256, 0, stream>>>(z16, stats);
    contrast_reduce<<<3, 256, 0, stream>>>(stats, dout + (size_t)3 * NN * NCLS);
}

// Round 11
// 821.929 us; speedup vs baseline: 6.0334x; 1.0617x over previous
//
#include <hip/hip_runtime.h>
#include <math.h>

#define NN 30000
#define EE 480000
#define FD 256
#define CH 128
#define NCLS 16
#define GH 64
#define MH 128
#define BT 4096
#define EPSc 1e-8f
#define GBc ((NN + 127) / 128)
#define SPB8 ((NN + 7) / 8)
#define SPB16 ((NN + 15) / 16)
#define RBc ((BT + 15) / 16)

typedef __attribute__((ext_vector_type(8))) short short8;
typedef __attribute__((ext_vector_type(4))) float f32x4;

// ---------- helpers ----------
__device__ __forceinline__ unsigned short f2bf(float x) {
    unsigned b = __float_as_uint(x);
    unsigned r = b + 0x7FFFu + ((b >> 16) & 1u);
    return (unsigned short)(r >> 16);
}
__device__ __forceinline__ float bf2f(unsigned short h) {
    return __uint_as_float(((unsigned)h) << 16);
}
__device__ __forceinline__ float4 fma4(float s, float4 x, float4 a) {
    a.x = fmaf(s, x.x, a.x); a.y = fmaf(s, x.y, a.y);
    a.z = fmaf(s, x.z, a.z); a.w = fmaf(s, x.w, a.w);
    return a;
}

// ---------- splits ----------
__global__ void split_bf16(const float* __restrict__ x, unsigned short* __restrict__ hi,
                           unsigned short* __restrict__ lo, long n) {
    long i = (long)blockIdx.x * 256 + threadIdx.x;
    if (i >= n) return;
    float v = x[i];
    unsigned short h = f2bf(v);
    hi[i] = h;
    lo[i] = f2bf(v - bf2f(h));
}

struct WSArgs {
    const float* s[8];
    unsigned short* h[8];
    unsigned short* l[8];
};
// weights needing bf16 split: wgen1, wgen2, w1v1, w1v2, w1v, Wg, Wg1, Wg2 (all K=256)
__global__ void wsplit_all(WSArgs a) {
    constexpr int NNp[8] = {64, 64, 128, 128, 128, 128, 128, 128};
    constexpr int OFF[9] = {0, 16384, 32768, 65536, 98304, 131072, 163840, 196608, 229376};
    int i = blockIdx.x * 256 + threadIdx.x;
    if (i >= 229376) return;
    int w = 0;
#pragma unroll
    for (int t = 1; t < 8; t++) if (i >= OFF[t]) w = t;
    int j = i - OFF[w];
    int N = NNp[w];
    int k = j / N, n = j % N;
    float v = a.s[w][j];
    unsigned short hh = f2bf(v);
    a.h[w][(size_t)n * 256 + k] = hh;
    a.l[w][(size_t)n * 256 + k] = f2bf(v - bf2f(hh));
}

// ---------- GEMM bodies ----------
template <int NT, bool OUT16>
__device__ __forceinline__ void gemm3_body(
    unsigned short* sm, int bx,
    const unsigned short* __restrict__ Ahi, const unsigned short* __restrict__ Alo,
    const unsigned short* __restrict__ BThi, const unsigned short* __restrict__ BTlo,
    int K, void* __restrict__ Cv, int Cstride, int M)
{
    unsigned short* Ah = sm;
    unsigned short* Al = Ah + 128 * 40;
    unsigned short* Bh = Al + 128 * 40;
    unsigned short* Bl = Bh + NT * 16 * 40;
    int t = threadIdx.x;
    int w = t >> 6, l = t & 63;
    int lane = l & 15, quad = l >> 4;
    int row0 = bx * 128;
    f32x4 acc[2][NT];
#pragma unroll
    for (int s = 0; s < 2; s++)
#pragma unroll
        for (int n = 0; n < NT; n++) acc[s][n] = (f32x4)(0.f);

    int ar = t >> 1, ako = (t & 1) << 4;
    int nkc = K >> 5;
    for (int kc = 0; kc < nkc; kc++) {
        int kb = kc << 5;
        {
            int gr = row0 + ar;
            float4 h0, h1, l0, l1;
            if (gr < M) {
                const float4* pH = (const float4*)&Ahi[(size_t)gr * K + kb + ako];
                const float4* pL = (const float4*)&Alo[(size_t)gr * K + kb + ako];
                h0 = pH[0]; h1 = pH[1]; l0 = pL[0]; l1 = pL[1];
            } else {
                h0 = h1 = l0 = l1 = make_float4(0.f, 0.f, 0.f, 0.f);
            }
            float4* dH = (float4*)&Ah[ar * 40 + ako];
            dH[0] = h0; dH[1] = h1;
            float4* dL = (float4*)&Al[ar * 40 + ako];
            dL[0] = l0; dL[1] = l1;
        }
        if (ar < NT * 16) {
            const float4* pH = (const float4*)&BThi[(size_t)ar * K + kb + ako];
            const float4* pL = (const float4*)&BTlo[(size_t)ar * K + kb + ako];
            float4 h0 = pH[0], h1 = pH[1], l0 = pL[0], l1 = pL[1];
            float4* dH = (float4*)&Bh[ar * 40 + ako];
            dH[0] = h0; dH[1] = h1;
            float4* dL = (float4*)&Bl[ar * 40 + ako];
            dL[0] = l0; dL[1] = l1;
        }
        __syncthreads();
        short8 aH[2], aL[2];
#pragma unroll
        for (int s = 0; s < 2; s++) {
            int r = w * 32 + s * 16 + lane;
            aH[s] = *(const short8*)&Ah[r * 40 + quad * 8];
            aL[s] = *(const short8*)&Al[r * 40 + quad * 8];
        }
#pragma unroll
        for (int n = 0; n < NT; n++) {
            int r = n * 16 + lane;
            short8 bH = *(const short8*)&Bh[r * 40 + quad * 8];
            short8 bL = *(const short8*)&Bl[r * 40 + quad * 8];
#pragma unroll
            for (int s = 0; s < 2; s++) {
                acc[s][n] = __builtin_amdgcn_mfma_f32_16x16x32_bf16(aH[s], bH, acc[s][n], 0, 0, 0);
                acc[s][n] = __builtin_amdgcn_mfma_f32_16x16x32_bf16(aH[s], bL, acc[s][n], 0, 0, 0);
                acc[s][n] = __builtin_amdgcn_mfma_f32_16x16x32_bf16(aL[s], bH, acc[s][n], 0, 0, 0);
            }
        }
        __syncthreads();
    }
#pragma unroll
    for (int s = 0; s < 2; s++) {
        int rb = row0 + w * 32 + s * 16 + quad * 4;
#pragma unroll
        for (int reg = 0; reg < 4; reg++) {
            int gr = rb + reg;
            if (gr >= M) continue;
#pragma unroll
            for (int n = 0; n < NT; n++) {
                if (OUT16)
                    ((unsigned short*)Cv)[(size_t)gr * Cstride + n * 16 + lane] = f2bf(acc[s][n][reg]);
                else
                    ((float*)Cv)[(size_t)gr * Cstride + n * 16 + lane] = acc[s][n][reg];
            }
        }
    }
}

template <int NT, bool OUT16>
__device__ __forceinline__ void gemm1_body(
    unsigned short* sm, int bx,
    const unsigned short* __restrict__ Ahi,
    const unsigned short* __restrict__ BThi,
    int K, void* __restrict__ Cv, int Cstride, int M)
{
    unsigned short* Ah = sm;
    unsigned short* Bh = Ah + 128 * 40;
    int t = threadIdx.x;
    int w = t >> 6, l = t & 63;
    int lane = l & 15, quad = l >> 4;
    int row0 = bx * 128;
    f32x4 acc[2][NT];
#pragma unroll
    for (int s = 0; s < 2; s++)
#pragma unroll
        for (int n = 0; n < NT; n++) acc[s][n] = (f32x4)(0.f);

    int ar = t >> 1, ako = (t & 1) << 4;
    int nkc = K >> 5;
    for (int kc = 0; kc < nkc; kc++) {
        int kb = kc << 5;
        {
            int gr = row0 + ar;
            float4 h0, h1;
            if (gr < M) {
                const float4* pH = (const float4*)&Ahi[(size_t)gr * K + kb + ako];
                h0 = pH[0]; h1 = pH[1];
            } else {
                h0 = h1 = make_float4(0.f, 0.f, 0.f, 0.f);
            }
            float4* dH = (float4*)&Ah[ar * 40 + ako];
            dH[0] = h0; dH[1] = h1;
        }
        if (ar < NT * 16) {
            const float4* pH = (const float4*)&BThi[(size_t)ar * K + kb + ako];
            float4 h0 = pH[0], h1 = pH[1];
            float4* dH = (float4*)&Bh[ar * 40 + ako];
            dH[0] = h0; dH[1] = h1;
        }
        __syncthreads();
        short8 aH[2];
#pragma unroll
        for (int s = 0; s < 2; s++)
            aH[s] = *(const short8*)&Ah[(w * 32 + s * 16 + lane) * 40 + quad * 8];
#pragma unroll
        for (int n = 0; n < NT; n++) {
            short8 bH = *(const short8*)&Bh[(n * 16 + lane) * 40 + quad * 8];
#pragma unroll
            for (int s = 0; s < 2; s++)
                acc[s][n] = __builtin_amdgcn_mfma_f32_16x16x32_bf16(aH[s], bH, acc[s][n], 0, 0, 0);
        }
        __syncthreads();
    }
#pragma unroll
    for (int s = 0; s < 2; s++) {
        int rb = row0 + w * 32 + s * 16 + quad * 4;
#pragma unroll
        for (int reg = 0; reg < 4; reg++) {
            int gr = rb + reg;
            if (gr >= M) continue;
#pragma unroll
            for (int n = 0; n < NT; n++) {
                if (OUT16)
                    ((unsigned short*)Cv)[(size_t)gr * Cstride + n * 16 + lane] = f2bf(acc[s][n][reg]);
                else
                    ((float*)Cv)[(size_t)gr * Cstride + n * 16 + lane] = acc[s][n][reg];
            }
        }
    }
}

// ---------- mega0: count(+seq) || gemm1 Ph2 || gemm1 Pmi×3 ----------
__global__ __launch_bounds__(256) void mega0(
    const int* __restrict__ i1, const int* __restrict__ i2, int* __restrict__ cnt,
    int* __restrict__ sd1, int* __restrict__ sd2,
    int* __restrict__ sc1, int* __restrict__ sc2,
    const unsigned short* __restrict__ feat_hi,
    const unsigned short* __restrict__ w1vh, unsigned short* __restrict__ Ph2,
    const unsigned short* __restrict__ wgallh, unsigned short* __restrict__ Pmi16)
{
    __shared__ unsigned short sm[128 * 40 + 8 * 16 * 40];
    int b = blockIdx.x;
    if (b < GBc) {
        gemm1_body<8, true>(sm, b, feat_hi, w1vh, FD, Ph2, 128, NN);
        return;
    }
    b -= GBc;
    if (b < 3 * GBc) {
        int y = b / GBc, bx = b % GBc;
        gemm1_body<8, true>(sm, bx, feat_hi, wgallh + (size_t)y * 32768,
                            FD, Pmi16 + (size_t)y * 128, 384, NN);
        return;
    }
    b -= 3 * GBc;
    int e = b * 256 + threadIdx.x;
    if (e >= EE) return;
    int r1 = i1[e], c1 = i1[EE + e];
    int r2 = i2[e], c2 = i2[EE + e];
    sd1[e] = atomicAdd(&cnt[r1], 1);
    sd2[e] = atomicAdd(&cnt[NN + r2], 1);
    sc1[e] = atomicAdd(&cnt[2 * NN + c1], 1);
    sc2[e] = atomicAdd(&cnt[3 * NN + c2], 1);
}

// ---------- mega1: atomic-free place || gemm3 Pg || gemm3 P01 (fp32) ×2 ----------
__global__ __launch_bounds__(256) void mega1(
    const int* __restrict__ i1, const float* __restrict__ v1,
    const int* __restrict__ i2, const float* __restrict__ v2,
    const int* __restrict__ sd1, const int* __restrict__ sd2,
    const int* __restrict__ sc1, const int* __restrict__ sc2,
    const int* __restrict__ rp4,
    int2* __restrict__ ed1, int2* __restrict__ ec1,
    int2* __restrict__ ed2, int2* __restrict__ ec2,
    const unsigned short* __restrict__ feat_hi, const unsigned short* __restrict__ feat_lo,
    const unsigned short* __restrict__ wgen12h, const unsigned short* __restrict__ wgen12l,
    float* __restrict__ Pg,
    const unsigned short* __restrict__ w1pairh, const unsigned short* __restrict__ w1pairl,
    float* __restrict__ P01)
{
    __shared__ unsigned short sm[128 * 40 * 2 + 8 * 16 * 40 * 2];
    int b = blockIdx.x;
    if (b < GBc) {
        gemm3_body<8, false>(sm, b, feat_hi, feat_lo, wgen12h, wgen12l, FD, Pg, 128, NN);
        return;
    }
    b -= GBc;
    if (b < 2 * GBc) {
        int y = b / GBc, bx = b % GBc;
        gemm3_body<8, false>(sm, bx, feat_hi, feat_lo,
                             w1pairh + (size_t)y * 32768, w1pairl + (size_t)y * 32768,
                             FD, P01 + (size_t)y * 128, 256, NN);
        return;
    }
    b -= 2 * GBc;
    int e = b * 256 + threadIdx.x;
    if (e >= EE) return;
    const int* rp_d1 = rp4;
    const int* rp_d2 = rp4 + (NN + 1);
    const int* rp_c1 = rp4 + 2 * (NN + 1);
    const int* rp_c2 = rp4 + 3 * (NN + 1);
    int r = i1[e], c = i1[EE + e];
    int p = rp_d1[r] + sd1[e];
    ed1[p] = make_int2(c, __float_as_int(v1[e]));
    ec1[rp_c1[c] + sc1[e]] = make_int2(r, p);
    r = i2[e]; c = i2[EE + e];
    p = rp_d2[r] + sd2[e];
    ed2[p] = make_int2(c, __float_as_int(v2[e]));
    ec2[rp_c2[c] + sc2[e]] = make_int2(r, p);
}

// ---------- contrast ----------
__global__ __launch_bounds__(256) void contrast_direct(
    const unsigned short* __restrict__ z16, float* __restrict__ stats)
{
    int p = blockIdx.z;
    int pa = (p == 2) ? 1 : 0;
    int pb = (p == 0) ? 1 : 2;
    const unsigned short* A = z16 + (size_t)pa * BT * MH;
    const unsigned short* B = z16 + (size_t)pb * BT * MH;
    float* diag = stats + (size_t)p * 3 * BT;
    float* rs = diag + BT;
    float* cs = rs + BT;
    int t = threadIdx.x;
    int w = t >> 6, l = t & 63, m = l & 15, quad = l >> 4;
    int i0 = blockIdx.y * 128, j0 = blockIdx.x * 128;

    short8 afr[2][4];
#pragma unroll
    for (int s = 0; s < 2; s++) {
        const unsigned short* arow = &A[(size_t)(i0 + w * 32 + s * 16 + m) * MH + quad * 8];
#pragma unroll
        for (int kc = 0; kc < 4; kc++)
            afr[s][kc] = *(const short8*)(arow + kc * 32);
    }
    f32x4 acc[2][8];
#pragma unroll
    for (int s = 0; s < 2; s++)
#pragma unroll
        for (int n = 0; n < 8; n++) acc[s][n] = (f32x4)(0.f);

#pragma unroll
    for (int kc = 0; kc < 4; kc++) {
#pragma unroll
        for (int n = 0; n < 8; n++) {
            short8 bf = *(const short8*)&B[(size_t)(j0 + n * 16 + m) * MH + kc * 32 + quad * 8];
            acc[0][n] = __builtin_amdgcn_mfma_f32_16x16x32_bf16(afr[0][kc], bf, acc[0][n], 0, 0, 0);
            acc[1][n] = __builtin_amdgcn_mfma_f32_16x16x32_bf16(afr[1][kc], bf, acc[1][n], 0, 0, 0);
        }
    }
    float colp[8];
#pragma unroll
    for (int n = 0; n < 8; n++) colp[n] = 0.f;
#pragma unroll
    for (int s = 0; s < 2; s++) {
        int rbase = i0 + w * 32 + s * 16 + quad * 4;
#pragma unroll
        for (int reg = 0; reg < 4; reg++) {
            float rsum = 0.f;
            int gi = rbase + reg;
#pragma unroll
            for (int n = 0; n < 8; n++) {
                float mv = expf(acc[s][n][reg] * 2.0f);
                rsum += mv;
                colp[n] += mv;
                int gj = j0 + n * 16 + m;
                if (gi == gj) diag[gi] = mv;
            }
            rsum += __shfl_xor(rsum, 1); rsum += __shfl_xor(rsum, 2);
            rsum += __shfl_xor(rsum, 4); rsum += __shfl_xor(rsum, 8);
            if (m == 0) atomicAdd(&rs[gi], rsum);
        }
    }
    __shared__ float scol[128];
    if (t < 128) scol[t] = 0.f;
    __syncthreads();
#pragma unroll
    for (int n = 0; n < 8; n++) {
        float v = colp[n];
        v += __shfl_xor(v, 16); v += __shfl_xor(v, 32);
        if (quad == (n & 3)) atomicAdd(&scol[n * 16 + m], v);
    }
    __syncthreads();
    if (t < 128) atomicAdd(&cs[j0 + t], scol[t]);
}

// ---------- scans ----------
__global__ __launch_bounds__(1024) void scan_block4(const int* __restrict__ cnt,
                                                    int* __restrict__ rowptr,
                                                    int* __restrict__ bsum) {
    int y = blockIdx.y;
    int* rp = rowptr + y * (NN + 1);
    int* bs = bsum + y * 32;
    __shared__ int tmp[1024];
    int t = threadIdx.x;
    int i = blockIdx.x * 1024 + t;
    int v = (i < NN) ? cnt[y * NN + i] : 0;
    tmp[t] = v;
    __syncthreads();
    for (int off = 1; off < 1024; off <<= 1) {
        int add = (t >= off) ? tmp[t - off] : 0;
        __syncthreads();
        tmp[t] += add;
        __syncthreads();
    }
    if (i <= NN) rp[i] = tmp[t] - v;
    if (t == 1023) bs[blockIdx.x] = tmp[1023];
}
__global__ void scan_bsum4(int* __restrict__ bsum, int nb) {
    bsum += blockIdx.x * 32;
    int t = threadIdx.x;
    int orig = (t < nb) ? bsum[t] : 0;
    int v = orig;
    for (int off = 1; off < 64; off <<= 1) {
        int u = __shfl_up(v, off);
        if (t >= off) v += u;
    }
    if (t < nb) bsum[t] = v - orig;
}
__global__ void scan_add4(const int* __restrict__ bsum, int* __restrict__ rowptr) {
    int y = blockIdx.y;
    const int* bs = bsum + y * 32;
    int* rp = rowptr + y * (NN + 1);
    int i = blockIdx.x * 1024 + threadIdx.x;
    if (i <= NN) rp[i] += bs[blockIdx.x];
}

// ---------- row-parallel nv ----------
__global__ __launch_bounds__(256) void gen_nv(
    const int* __restrict__ rp_d, int2* __restrict__ ed1, int2* __restrict__ ed2,
    const float* __restrict__ sb, float* __restrict__ nvd1, float* __restrict__ nvd2)
{
    int y = blockIdx.y;
    int row = blockIdx.x * 256 + threadIdx.x;
    if (row >= NN) return;
    const int* rp = rp_d + y * (NN + 1);
    int2* ed = y ? ed2 : ed1;
    float* nvd = y ? nvd2 : nvd1;
    const float* sbv = sb + (size_t)y * NN;
    int p0 = rp[row], p1 = rp[row + 1];
    float m = -3.4e38f, sum = 0.f;
    for (int j = p0; j < p1; j++) {
        float x = sbv[ed[j].x];
        if (x > m) { sum = sum * expf(m - x) + 1.f; m = x; }
        else sum += expf(x - m);
    }
    float inv = 1.f / sum;
    for (int j = p0; j < p1; j++) {
        int2 q = ed[j];
        float nv = __int_as_float(q.y) + 0.5f * expf(sbv[q.x] - m) * inv;
        nvd[j] = nv;
        ed[j].y = __float_as_int(nv);
    }
}

// ---------- fp32 gather helpers ----------
template <int STR4>
__device__ __forceinline__ void gath_dir_f32(
    const int* __restrict__ rp, const int2* __restrict__ ed, int row,
    const float4* __restrict__ x4, int xo, float4* a)
{
    int p0 = rp[row], p1 = rp[row + 1];
    int j = p0;
    for (; j + 4 <= p1; j += 4) {
        int2 q0 = ed[j], q1 = ed[j+1], q2 = ed[j+2], q3 = ed[j+3];
        a[0] = fma4(__int_as_float(q0.y), x4[(size_t)q0.x * STR4 + xo], a[0]);
        a[1] = fma4(__int_as_float(q1.y), x4[(size_t)q1.x * STR4 + xo], a[1]);
        a[2] = fma4(__int_as_float(q2.y), x4[(size_t)q2.x * STR4 + xo], a[2]);
        a[3] = fma4(__int_as_float(q3.y), x4[(size_t)q3.x * STR4 + xo], a[3]);
    }
    for (; j < p1; j++) {
        int2 q = ed[j];
        a[0] = fma4(__int_as_float(q.y), x4[(size_t)q.x * STR4 + xo], a[0]);
    }
}
template <int STR4>
__device__ __forceinline__ void gath_csc_f32(
    const int* __restrict__ rp, const int2* __restrict__ ec, const float* __restrict__ nvd,
    int row, const float4* __restrict__ x4, int xo, float4* a)
{
    int p0 = rp[row], p1 = rp[row + 1];
    int j = p0;
    for (; j + 4 <= p1; j += 4) {
        int2 q0 = ec[j], q1 = ec[j+1], q2 = ec[j+2], q3 = ec[j+3];
        float v0 = nvd[q0.y], v1 = nvd[q1.y], v2 = nvd[q2.y], v3 = nvd[q3.y];
        a[0] = fma4(v0, x4[(size_t)q0.x * STR4 + xo], a[0]);
        a[1] = fma4(v1, x4[(size_t)q1.x * STR4 + xo], a[1]);
        a[2] = fma4(v2, x4[(size_t)q2.x * STR4 + xo], a[2]);
        a[3] = fma4(v3, x4[(size_t)q3.x * STR4 + xo], a[3]);
    }
    for (; j < p1; j++) {
        int2 q = ec[j];
        a[0] = fma4(nvd[q.y], x4[(size_t)q.x * STR4 + xo], a[0]);
    }
}

// ---------- gen SpMM (dir graph, orig vals, fp32 Pg) ----------
__global__ __launch_bounds__(256) void spmm64_pair(
    const int* __restrict__ rp_d, const int2* __restrict__ e1, const int2* __restrict__ e2,
    const float* __restrict__ Pg, float* __restrict__ emb)
{
    int y = blockIdx.y;
    const int* rp = rp_d + y * (NN + 1);
    const int2* arr = y ? e2 : e1;
    int row = blockIdx.x * 16 + threadIdx.x / 16;
    int o = threadIdx.x % 16;
    if (row >= NN) return;
    float4 a[4] = {};
    gath_dir_f32<32>(rp, arr, row, (const float4*)Pg, y * 16 + o, a);
    float4 r;
    r.x = fmaxf((a[0].x + a[1].x) + (a[2].x + a[3].x), 0.f);
    r.y = fmaxf((a[0].y + a[1].y) + (a[2].y + a[3].y), 0.f);
    r.z = fmaxf((a[0].z + a[1].z) + (a[2].z + a[3].z), 0.f);
    r.w = fmaxf((a[0].w + a[1].w) + (a[2].w + a[3].w), 0.f);
    ((float4*)emb)[((size_t)y * NN + row) * 16 + o] = r;
}

// ---------- fp32 F=16 SpMMs ----------
__global__ __launch_bounds__(256) void spmm16_pair(
    const int* __restrict__ rp_d, const int* __restrict__ rp_c,
    const int2* __restrict__ ed1, const int2* __restrict__ ec1, const float* __restrict__ nvd1,
    const int2* __restrict__ ed2, const int2* __restrict__ ec2, const float* __restrict__ nvd2,
    const float* __restrict__ R01, float* __restrict__ T01)
{
    int y = blockIdx.y;
    const int* rpd = rp_d + y * (NN + 1);
    const int* rpc = rp_c + y * (NN + 1);
    const int2* ed = y ? ed2 : ed1;
    const int2* ec = y ? ec2 : ec1;
    const float* nvd = y ? nvd2 : nvd1;
    int row = blockIdx.x * 64 + threadIdx.x / 4;
    int o = threadIdx.x % 4;
    if (row >= NN) return;
    const float4* x4 = (const float4*)(R01 + (size_t)y * NN * 16);
    float4 a[4] = {};
    gath_dir_f32<4>(rpd, ed, row, x4, o, a);
    gath_csc_f32<4>(rpc, ec, nvd, row, x4, o, a);
    float4 r;
    r.x = (a[0].x + a[1].x) + (a[2].x + a[3].x);
    r.y = (a[0].y + a[1].y) + (a[2].y + a[3].y);
    r.z = (a[0].z + a[1].z) + (a[2].z + a[3].z);
    r.w = (a[0].w + a[1].w) + (a[2].w + a[3].w);
    ((float4*)(T01 + (size_t)y * NN * 16))[(size_t)row * 4 + o] = r;
}

__global__ __launch_bounds__(256) void spmm16_fused(
    const int* __restrict__ rp_d, const int* __restrict__ rp_c,
    const int2* __restrict__ ed1, const int2* __restrict__ ec1, const float* __restrict__ nvd1,
    const int2* __restrict__ ed2, const int2* __restrict__ ec2, const float* __restrict__ nvd2,
    const float* __restrict__ bb, const float* __restrict__ x, float* __restrict__ out)
{
    int row = blockIdx.x * 64 + threadIdx.x / 4;
    int o = threadIdx.x % 4;
    if (row >= NN) return;
    const float4* x4 = (const float4*)x;
    float4 a[4] = {};
    gath_dir_f32<4>(rp_d, ed1, row, x4, o, a);
    gath_csc_f32<4>(rp_c, ec1, nvd1, row, x4, o, a);
    float4 s1;
    s1.x = (a[0].x + a[1].x) + (a[2].x + a[3].x);
    s1.y = (a[0].y + a[1].y) + (a[2].y + a[3].y);
    s1.z = (a[0].z + a[1].z) + (a[2].z + a[3].z);
    s1.w = (a[0].w + a[1].w) + (a[2].w + a[3].w);
    float4 b[4] = {};
    gath_dir_f32<4>(rp_d + (NN + 1), ed2, row, x4, o, b);
    gath_csc_f32<4>(rp_c + (NN + 1), ec2, nvd2, row, x4, o, b);
    float4 s2;
    s2.x = (b[0].x + b[1].x) + (b[2].x + b[3].x);
    s2.y = (b[0].y + b[1].y) + (b[2].y + b[3].y);
    s2.z = (b[0].z + b[1].z) + (b[2].z + b[3].z);
    s2.w = (b[0].w + b[1].w) + (b[2].w + b[3].w);
    float w1 = bb[row], w2 = bb[NN + row];
    float4 r;
    r.x = w1 * s1.x + w2 * s2.x;
    r.y = w1 * s1.y + w2 * s2.y;
    r.z = w1 * s1.z + w2 * s2.z;
    r.w = w1 * s1.w + w2 * s2.w;
    ((float4*)out)[(size_t)row * 4 + o] = r;
}

// ---------- bf16 gather helpers ----------
__device__ __forceinline__ void gath_dir_b16(
    const int* __restrict__ rp, const int2* __restrict__ ed, int row,
    const unsigned short* __restrict__ X, int xstride, int o, float* acc)
{
    int p0 = rp[row], p1 = rp[row + 1];
    int j = p0;
    for (; j + 4 <= p1; j += 4) {
        int2 q0 = ed[j], q1 = ed[j+1], q2 = ed[j+2], q3 = ed[j+3];
        short8 x0 = *(const short8*)&X[(size_t)q0.x * xstride + o * 8];
        short8 x1 = *(const short8*)&X[(size_t)q1.x * xstride + o * 8];
        short8 x2 = *(const short8*)&X[(size_t)q2.x * xstride + o * 8];
        short8 x3 = *(const short8*)&X[(size_t)q3.x * xstride + o * 8];
        float v0 = __int_as_float(q0.y), v1 = __int_as_float(q1.y);
        float v2 = __int_as_float(q2.y), v3 = __int_as_float(q3.y);
#pragma unroll
        for (int k = 0; k < 8; k++) {
            acc[k] = fmaf(v0, bf2f((unsigned short)x0[k]), acc[k]);
            acc[k] = fmaf(v1, bf2f((unsigned short)x1[k]), acc[k]);
            acc[k] = fmaf(v2, bf2f((unsigned short)x2[k]), acc[k]);
            acc[k] = fmaf(v3, bf2f((unsigned short)x3[k]), acc[k]);
        }
    }
    for (; j < p1; j++) {
        int2 q = ed[j];
        short8 xv = *(const short8*)&X[(size_t)q.x * xstride + o * 8];
        float v = __int_as_float(q.y);
#pragma unroll
        for (int k = 0; k < 8; k++)
            acc[k] = fmaf(v, bf2f((unsigned short)xv[k]), acc[k]);
    }
}
__device__ __forceinline__ void gath_csc_b16(
    const int* __restrict__ rp, const int2* __restrict__ ec, const float* __restrict__ nvd,
    int row, const unsigned short* __restrict__ X, int xstride, int o, float* acc)
{
    int p0 = rp[row], p1 = rp[row + 1];
    int j = p0;
    for (; j + 4 <= p1; j += 4) {
        int2 q0 = ec[j], q1 = ec[j+1], q2 = ec[j+2], q3 = ec[j+3];
        short8 x0 = *(const short8*)&X[(size_t)q0.x * xstride + o * 8];
        short8 x1 = *(const short8*)&X[(size_t)q1.x * xstride + o * 8];
        short8 x2 = *(const short8*)&X[(size_t)q2.x * xstride + o * 8];
        short8 x3 = *(const short8*)&X[(size_t)q3.x * xstride + o * 8];
        float v0 = nvd[q0.y], v1 = nvd[q1.y], v2 = nvd[q2.y], v3 = nvd[q3.y];
#pragma unroll
        for (int k = 0; k < 8; k++) {
            acc[k] = fmaf(v0, bf2f((unsigned short)x0[k]), acc[k]);
            acc[k] = fmaf(v1, bf2f((unsigned short)x1[k]), acc[k]);
            acc[k] = fmaf(v2, bf2f((unsigned short)x2[k]), acc[k]);
            acc[k] = fmaf(v3, bf2f((unsigned short)x3[k]), acc[k]);
        }
    }
    for (; j < p1; j++) {
        int2 q = ec[j];
        short8 xv = *(const short8*)&X[(size_t)q.x * xstride + o * 8];
        float v = nvd[q.y];
#pragma unroll
        for (int k = 0; k < 8; k++)
            acc[k] = fmaf(v, bf2f((unsigned short)xv[k]), acc[k]);
    }
}

// ---------- rows (MI) body ----------
__device__ __forceinline__ void rows_b16_body(
    int bx, int y, const int* __restrict__ rp_d, const int* __restrict__ rp_c,
    const int2* __restrict__ ed1, const int2* __restrict__ ec1, const float* __restrict__ nvd1,
    const int2* __restrict__ ed2, const int2* __restrict__ ec2, const float* __restrict__ nvd2,
    const float* __restrict__ bb, const int* __restrict__ rows,
    const unsigned short* __restrict__ Pmi, float* __restrict__ zQ)
{
    int ri = bx * 16 + threadIdx.x / 16;
    int o = threadIdx.x % 16;
    if (ri >= BT) return;
    int node = rows[ri];
    int xoff = (y == 0) ? 0 : ((y == 1) ? 128 : 256);
    const unsigned short* X = Pmi + xoff;
    float acc[8] = {};
    if (y == 0) {
        float a1[8] = {}, a2[8] = {};
        gath_dir_b16(rp_d, ed1, node, X, 384, o, a1);
        gath_csc_b16(rp_c, ec1, nvd1, node, X, 384, o, a1);
        gath_dir_b16(rp_d + (NN + 1), ed2, node, X, 384, o, a2);
        gath_csc_b16(rp_c + (NN + 1), ec2, nvd2, node, X, 384, o, a2);
        float w1 = bb[node], w2 = bb[NN + node];
#pragma unroll
        for (int k = 0; k < 8; k++) acc[k] = w1 * a1[k] + w2 * a2[k];
    } else if (y == 1) {
        gath_dir_b16(rp_d, ed1, node, X, 384, o, acc);
        gath_csc_b16(rp_c, ec1, nvd1, node, X, 384, o, acc);
    } else {
        gath_dir_b16(rp_d + (NN + 1), ed2, node, X, 384, o, acc);
        gath_csc_b16(rp_c + (NN + 1), ec2, nvd2, node, X, 384, o, acc);
    }
    float* out = zQ + ((size_t)y * BT + ri) * 128 + o * 8;
#pragma unroll
    for (int k = 0; k < 8; k++) out[k] = fmaxf(acc[k], 0.f);
}

// ---------- spmm128 fp32 + fused L2 (relu(Q)@W2 -> R01) ----------
__device__ __forceinline__ void spmm128f_body(
    float* sm, int bx, int y, const int* __restrict__ rp_d, const int* __restrict__ rp_c,
    const int2* __restrict__ ed, const int2* __restrict__ ec, const float* __restrict__ nvd,
    const float* __restrict__ P01, const float* __restrict__ W2, float* __restrict__ R01)
{
    float* W2s = sm;            // 2048
    float* Qs  = sm + 2048;     // 8*128
    for (int i = threadIdx.x; i < 2048; i += 256) W2s[i] = W2[i];
    int r = threadIdx.x / 32;
    int o = threadIdx.x % 32;
    int row = bx * 8 + r;
    float4 a[4] = {};
    if (row < NN) {
        gath_dir_f32<64>(rp_d + y * (NN + 1), ed, row, (const float4*)P01, y * 32 + o, a);
        gath_csc_f32<64>(rp_c + y * (NN + 1), ec, nvd, row, (const float4*)P01, y * 32 + o, a);
    }
    float4 q;
    q.x = fmaxf((a[0].x + a[1].x) + (a[2].x + a[3].x), 0.f);
    q.y = fmaxf((a[0].y + a[1].y) + (a[2].y + a[3].y), 0.f);
    q.z = fmaxf((a[0].z + a[1].z) + (a[2].z + a[3].z), 0.f);
    q.w = fmaxf((a[0].w + a[1].w) + (a[2].w + a[3].w), 0.f);
    *(float4*)&Qs[r * 128 + o * 4] = q;
    __syncthreads();
    int t = threadIdx.x;
    if (t < 128) {
        int rr = t >> 4, c = t & 15;
        int grow = bx * 8 + rr;
        if (grow < NN) {
            float acc = 0.f;
            const float* qrow = &Qs[rr * 128];
#pragma unroll 8
            for (int k = 0; k < 128; k++)
                acc = fmaf(qrow[k], W2s[k * 16 + c], acc);
            R01[((size_t)y * NN + grow) * 16 + c] = acc;
        }
    }
}

// ---------- branch2 fused spmm (bf16 gather) + fused L2 -> R2 ----------
__device__ __forceinline__ void fused128b2_body(
    float* sm, int bx, const int* __restrict__ rp_d, const int* __restrict__ rp_c,
    const int2* __restrict__ ed1, const int2* __restrict__ ec1, const float* __restrict__ nvd1,
    const int2* __restrict__ ed2, const int2* __restrict__ ec2, const float* __restrict__ nvd2,
    const float* __restrict__ bb, const unsigned short* __restrict__ Ph2,
    const float* __restrict__ W2v, float* __restrict__ R2)
{
    float* W2s = sm;            // 2048
    float* Qs  = sm + 2048;     // 16*128
    for (int i = threadIdx.x; i < 2048; i += 256) W2s[i] = W2v[i];
    int r = threadIdx.x / 16;
    int o = threadIdx.x % 16;
    int row = bx * 16 + r;
    float a1[8] = {}, a2[8] = {};
    float w1 = 0.f, w2 = 0.f;
    if (row < NN) {
        gath_dir_b16(rp_d, ed1, row, Ph2, 128, o, a1);
        gath_csc_b16(rp_c, ec1, nvd1, row, Ph2, 128, o, a1);
        gath_dir_b16(rp_d + (NN + 1), ed2, row, Ph2, 128, o, a2);
        gath_csc_b16(rp_c + (NN + 1), ec2, nvd2, row, Ph2, 128, o, a2);
        w1 = bb[row]; w2 = bb[NN + row];
    }
#pragma unroll
    for (int k = 0; k < 8; k++)
        Qs[r * 128 + o * 8 + k] = fmaxf(w1 * a1[k] + w2 * a2[k], 0.f);
    __syncthreads();
    int t = threadIdx.x;
    int rr = t >> 4, c = t & 15;
    int grow = bx * 16 + rr;
    if (grow < NN) {
        float acc = 0.f;
        const float* qrow = &Qs[rr * 128];
#pragma unroll 8
        for (int k = 0; k < 128; k++)
            acc = fmaf(qrow[k], W2s[k * 16 + c], acc);
        R2[(size_t)grow * 16 + c] = acc;
    }
}

// ---------- mega2: spmm128f (y=0,1) || rows y=1,2 ----------
__global__ __launch_bounds__(256) void mega2(
    const int* __restrict__ rp_d, const int* __restrict__ rp_c,
    const int2* __restrict__ ed1, const int2* __restrict__ ec1, const float* __restrict__ nvd1,
    const int2* __restrict__ ed2, const int2* __restrict__ ec2, const float* __restrict__ nvd2,
    const float* __restrict__ P01, const float* __restrict__ W2v1, const float* __restrict__ W2v2,
    float* __restrict__ R01,
    const int* __restrict__ rows, const unsigned short* __restrict__ Pmi,
    float* __restrict__ zQ)
{
    __shared__ float sm[2048 + 8 * 128];
    int b = blockIdx.x;
    if (b < 2 * SPB8) {
        int y = b / SPB8;
        spmm128f_body(sm, b % SPB8, y, rp_d, rp_c, y ? ed2 : ed1, y ? ec2 : ec1,
                      y ? nvd2 : nvd1, P01, y ? W2v2 : W2v1, R01);
        return;
    }
    b -= 2 * SPB8;
    int y = 1 + b / RBc;
    rows_b16_body(b % RBc, y, rp_d, rp_c, ed1, ec1, nvd1, ed2, ec2, nvd2,
                  nullptr, rows, Pmi, zQ);
}

// ---------- mega3: fused128b2 || rows y=0 ----------
__global__ __launch_bounds__(256) void mega3(
    const int* __restrict__ rp_d, const int* __restrict__ rp_c,
    const int2* __restrict__ ed1, const int2* __restrict__ ec1, const float* __restrict__ nvd1,
    const int2* __restrict__ ed2, const int2* __restrict__ ec2, const float* __restrict__ nvd2,
    const float* __restrict__ bb, const unsigned short* __restrict__ Ph2,
    const float* __restrict__ W2v, float* __restrict__ R2,
    const int* __restrict__ rows, const unsigned short* __restrict__ Pmi,
    float* __restrict__ zQ)
{
    __shared__ float sm[2048 + 16 * 128];
    int b = blockIdx.x;
    if (b < SPB16) {
        fused128b2_body(sm, b, rp_d, rp_c, ed1, ec1, nvd1, ed2, ec2, nvd2,
                        bb, Ph2, W2v, R2);
        return;
    }
    rows_b16_body(b - SPB16, 0, rp_d, rp_c, ed1, ec1, nvd1, ed2, ec2, nvd2,
                  bb, rows, Pmi, zQ);
}

// ---------- node scores: sb only ----------
__global__ __launch_bounds__(256) void node_scores_pair(
    const float* __restrict__ emb, const float* __restrict__ Wm1,
    const float* __restrict__ Wm2, float* __restrict__ sb)
{
    int y = blockIdx.y;
    const float* e_ = emb + (size_t)y * NN * GH;
    const float* Wm = y ? Wm2 : Wm1;
    int node = blockIdx.x * 4 + threadIdx.x / 64;
    int lane = threadIdx.x % 64;
    if (node >= NN) return;
    float e = e_[(size_t)node * GH + lane];
    float vb = e * Wm[GH + lane];
#pragma unroll
    for (int off = 32; off; off >>= 1)
        vb += __shfl_down(vb, off);
    if (lane == 0) sb[y * NN + node] = vb;
}

// ---------- softmax / weights ----------
__global__ void softmax16y(const float* __restrict__ S01, float* __restrict__ logits_base,
                           float* __restrict__ w12)
{
    int y = blockIdx.y;
    const float* S = S01 + (size_t)y * NN * NCLS;
    float* logits = logits_base + (size_t)y * NN * NCLS;
    float* w = w12 + (size_t)y * NN;
    int node = blockIdx.x * 256 + threadIdx.x;
    if (node >= NN) return;
    float v[NCLS];
    float mx = -3.4e38f;
#pragma unroll
    for (int j = 0; j < NCLS; j++) { v[j] = S[(size_t)node * NCLS + j]; mx = fmaxf(mx, v[j]); }
    float s = 0.f;
#pragma unroll
    for (int j = 0; j < NCLS; j++) { v[j] = expf(v[j] - mx); s += v[j]; }
    float inv = 1.f / s;
    float fir = -1.f, sec = -1.f;
#pragma unroll
    for (int j = 0; j < NCLS; j++) {
        float p = v[j] * inv;
        logits[(size_t)node * NCLS + j] = logf(p + EPSc);
        if (p > fir) { sec = fir; fir = p; }
        else if (p > sec) { sec = p; }
    }
    w[node] = expf(0.5f * logf(fir + EPSc) + 0.5f * logf(fir - sec + EPSc));
}

__global__ void softmax16(const float* __restrict__ S, float* __restrict__ logits)
{
    int node = blockIdx.x * 256 + threadIdx.x;
    if (node >= NN) return;
    float v[NCLS];
    float mx = -3.4e38f;
#pragma unroll
    for (int j = 0; j < NCLS; j++) { v[j] = S[(size_t)node * NCLS + j]; mx = fmaxf(mx, v[j]); }
    float s = 0.f;
#pragma unroll
    for (int j = 0; j < NCLS; j++) { v[j] = expf(v[j] - mx); s += v[j]; }
    float inv = 1.f / s;
#pragma unroll
    for (int j = 0; j < NCLS; j++)
        logits[(size_t)node * NCLS + j] = logf(v[j] * inv + EPSc);
}

__global__ void bweights(const float* __restrict__ w12, float* __restrict__ bb)
{
    int i = blockIdx.x * 256 + threadIdx.x;
    if (i >= NN) return;
    float a = w12[i], b = w12[NN + i];
    float inv = 1.f / (a + b);
    bb[i] = a * inv;
    bb[NN + i] = b * inv;
}

// ---------- projection head + L2-normalize, bf16 out ----------
__global__ __launch_bounds__(128) void proj_norm3(
    const float* __restrict__ zQ,
    const float* __restrict__ Wp1, const float* __restrict__ bp1,
    const float* __restrict__ Wp2, const float* __restrict__ bp2,
    unsigned short* __restrict__ z16)
{
    __shared__ float g[MH], u[MH];
    __shared__ float red[2];
    size_t i = (size_t)blockIdx.y * BT + blockIdx.x;
    int t = threadIdx.x;
    g[t] = zQ[i * MH + t];
    __syncthreads();
    float acc = bp1[t];
    for (int k = 0; k < MH; k++) acc = fmaf(g[k], Wp1[k * MH + t], acc);
    u[t] = acc > 0.f ? acc : (expf(acc) - 1.f);
    __syncthreads();
    float acc2 = bp2[t];
    for (int k = 0; k < MH; k++) acc2 = fmaf(u[k], Wp2[k * MH + t], acc2);
    float sq = acc2 * acc2;
#pragma unroll
    for (int off = 32; off; off >>= 1) sq += __shfl_down(sq, off);
    if ((t & 63) == 0) red[t >> 6] = sq;
    __syncthreads();
    float nrm = sqrtf(red[0] + red[1]);
    z16[i * MH + t] = f2bf(acc2 / nrm);
}

__global__ void contrast_reduce(const float* __restrict__ stats, float* __restrict__ out3)
{
    int p = blockIdx.x, t = threadIdx.x;
    const float* diag = stats + (size_t)p * 3 * BT;
    const float* rs = diag + BT;
    const float* cs = rs + BT;
    float s1 = 0.f, s2 = 0.f;
    for (int i = t; i < BT; i += 256) {
        float d = diag[i];
        s1 += logf(d / (rs[i] + EPSc) + EPSc);
        s2 += logf(d / (cs[i] + EPSc) + EPSc);
    }
#pragma unroll
    for (int off = 32; off; off >>= 1) { s1 += __shfl_down(s1, off); s2 += __shfl_down(s2, off); }
    __shared__ float sh[8];
    if ((t & 63) == 0) { sh[(t >> 6) * 2] = s1; sh[(t >> 6) * 2 + 1] = s2; }
    __syncthreads();
    if (t == 0) {
        float a = sh[0] + sh[2] + sh[4] + sh[6];
        float b = sh[1] + sh[3] + sh[5] + sh[7];
        out3[p] = 0.5f * (-a / BT - b / BT);
    }
}

// ---------- host ----------
extern "C" void kernel_launch(void* const* d_in, const int* in_sizes, int n_in,
                              void* d_out, int out_size, void* d_ws, size_t ws_size,
                              hipStream_t stream)
{
    const float* feat   = (const float*)d_in[0];
    const int*   ind1   = (const int*)d_in[1];
    const float* vals1  = (const float*)d_in[2];
    const int*   ind2   = (const int*)d_in[3];
    const float* vals2  = (const float*)d_in[4];
    const int*   idxb   = (const int*)d_in[5];
    const float* Wm1    = (const float*)d_in[7];
    const float* Wm2    = (const float*)d_in[10];
    const float* W2_v1  = (const float*)d_in[13];
    const float* W2_v2  = (const float*)d_in[15];
    const float* W2_v   = (const float*)d_in[17];
    const float* Wp1    = (const float*)d_in[21];
    const float* bp1    = (const float*)d_in[22];
    const float* Wp2    = (const float*)d_in[23];
    const float* bp2    = (const float*)d_in[24];
    float* dout = (float*)d_out;

    float* ws = (float*)d_ws;
    size_t off = 0;
    auto alloc = [&](size_t n) { n = (n + 3) & ~(size_t)3; float* p = ws + off; off += n; return p; };
    auto alloc_s = [&](size_t n) { return (unsigned short*)alloc((n + 1) / 2); };

    // --- shared pool ---
    float* pool = alloc(24960000);
    float* Pg   = pool;                      // [0, 3.84M)
    float* P01  = pool + 3840000;            // [3.84M, 11.52M)  [NN][256] f32
    float* emb  = pool + 11520000;           // [11.52M, 15.36M)
    float* R01  = pool + 15360000;           // [15.36M, 16.32M)
    float* T01  = pool + 16400000;           // [16.4M, 17.36M)
    float* zQ   = pool + 17400000;           // [17.4M, 18.98M)
    // phase C (Pg dead after spmm64)
    float* R2   = pool;                      // [0, 0.48M)
    float* T2   = pool + 500000;             // [0.5M, 0.98M)

    // --- persistent ---
    unsigned short* feat_hi = alloc_s((size_t)NN * FD);
    unsigned short* feat_lo = alloc_s((size_t)NN * FD);
    unsigned short* Ph2d    = alloc_s((size_t)NN * CH);
    unsigned short* Pmi16d  = alloc_s((size_t)NN * 384);
    float* sb   = alloc(2 * NN);
    float* w12  = alloc(2 * NN);
    float* bb   = alloc(2 * NN);
    float* stats = alloc((size_t)3 * 3 * BT);
    unsigned short* z16 = alloc_s((size_t)3 * BT * MH);
    int2* ed1 = (int2*)alloc(2 * (size_t)EE);
    int2* ed2 = (int2*)alloc(2 * (size_t)EE);
    int2* ec1 = (int2*)alloc(2 * (size_t)EE);
    int2* ec2 = (int2*)alloc(2 * (size_t)EE);
    float* nvd1 = alloc(EE);
    float* nvd2 = alloc(EE);
    int* sd1 = (int*)alloc(EE);
    int* sd2 = (int*)alloc(EE);
    int* sc1 = (int*)alloc(EE);
    int* sc2 = (int*)alloc(EE);
    int* rp4  = (int*)alloc(4 * (NN + 1));
    int* cnt4 = (int*)alloc(4 * NN);
    int* bsum = (int*)alloc(128);
    int* rp_d = rp4;
    int* rp_c = rp4 + 2 * (NN + 1);
    // weights (bf16 splits for K=256 GEMMs)
    unsigned short* wgen12h = alloc_s(32768); unsigned short* wgen12l = alloc_s(32768);
    unsigned short* w1pairh = alloc_s(65536); unsigned short* w1pairl = alloc_s(65536);
    unsigned short* w1vh    = alloc_s(32768); unsigned short* w1vl    = alloc_s(32768);
    unsigned short* wgallh  = alloc_s(98304); unsigned short* wgalll  = alloc_s(98304);

    const int NB = (NN + 1 + 1023) / 1024;
    const int NCNT = (EE + 255) / 256;

    // ---- prep ----
    hipMemsetAsync(cnt4, 0, 4 * NN * 4, stream);
    split_bf16<<<((long)NN * FD + 255) / 256, 256, 0, stream>>>(feat, feat_hi, feat_lo, (long)NN * FD);
    {
        WSArgs a;
        a.s[0] = (const float*)d_in[6];  a.h[0] = wgen12h;          a.l[0] = wgen12l;
        a.s[1] = (const float*)d_in[9];  a.h[1] = wgen12h + 16384;  a.l[1] = wgen12l + 16384;
        a.s[2] = (const float*)d_in[12]; a.h[2] = w1pairh;          a.l[2] = w1pairl;
        a.s[3] = (const float*)d_in[14]; a.h[3] = w1pairh + 32768;  a.l[3] = w1pairl + 32768;
        a.s[4] = (const float*)d_in[16]; a.h[4] = w1vh;             a.l[4] = w1vl;
        a.s[5] = (const float*)d_in[18]; a.h[5] = wgallh;           a.l[5] = wgalll;
        a.s[6] = (const float*)d_in[19]; a.h[6] = wgallh + 32768;   a.l[6] = wgalll + 32768;
        a.s[7] = (const float*)d_in[20]; a.h[7] = wgallh + 65536;   a.l[7] = wgalll + 65536;
        wsplit_all<<<(229376 + 255) / 256, 256, 0, stream>>>(a);
    }

    // ---- mega0: count(+seq) || Ph2 gemm1 || Pmi gemm1×3 ----
    mega0<<<4 * GBc + NCNT, 256, 0, stream>>>(ind1, ind2, cnt4, sd1, sd2, sc1, sc2,
                                              feat_hi, w1vh, Ph2d, wgallh, Pmi16d);

    // ---- scans ----
    scan_block4<<<dim3(NB, 4), 1024, 0, stream>>>(cnt4, rp4, bsum);
    scan_bsum4<<<4, 64, 0, stream>>>(bsum, NB);
    scan_add4<<<dim3(NB, 4), 1024, 0, stream>>>(bsum, rp4);

    // ---- mega1: atomic-free place || Pg gemm3 || P01 gemm3×2 (fp32 out) ----
    mega1<<<3 * GBc + NCNT, 256, 0, stream>>>(ind1, vals1, ind2, vals2,
                                              sd1, sd2, sc1, sc2, rp4,
                                              ed1, ec1, ed2, ec2,
                                              feat_hi, feat_lo, wgen12h, wgen12l, Pg,
                                              w1pairh, w1pairl, P01);

    // ---- gen_view ----
    spmm64_pair<<<dim3((NN + 15) / 16, 2), 256, 0, stream>>>(rp_d, ed1, ed2, Pg, emb);
    node_scores_pair<<<dim3((NN + 3) / 4, 2), 256, 0, stream>>>(emb, Wm1, Wm2, sb);
    gen_nv<<<dim3((NN + 255) / 256, 2), 256, 0, stream>>>(rp_d, ed1, ed2, sb, nvd1, nvd2);

    // ---- mega2: branch01 spmm+L2 (fp32) || mi rows y=1,2 ----
    mega2<<<2 * SPB8 + 2 * RBc, 256, 0, stream>>>(rp_d, rp_c, ed1, ec1, nvd1,
                                                  ed2, ec2, nvd2, P01, W2_v1, W2_v2,
                                                  R01, idxb, Pmi16d, zQ);

    // ---- branches 0/1 layer-2 aggregate + softmax ----
    spmm16_pair<<<dim3((NN + 63) / 64, 2), 256, 0, stream>>>(rp_d, rp_c, ed1, ec1, nvd1,
                                                             ed2, ec2, nvd2, R01, T01);
    softmax16y<<<dim3((NN + 255) / 256, 2), 256, 0, stream>>>(T01, dout + (size_t)NN * NCLS, w12);
    bweights<<<(NN + 255) / 256, 256, 0, stream>>>(w12, bb);

    // ---- mega3: branch2 fused spmm+L2 || mi rows y=0 ----
    mega3<<<SPB16 + RBc, 256, 0, stream>>>(rp_d, rp_c, ed1, ec1, nvd1, ed2, ec2, nvd2,
                                           bb, Ph2d, W2_v, R2, idxb, Pmi16d, zQ);

    // ---- branch 2 layer-2 aggregate + softmax ----
    spmm16_fused<<<(NN + 63) / 64, 256, 0, stream>>>(rp_d, rp_c, ed1, ec1, nvd1,
                                                     ed2, ec2, nvd2, bb, R2, T2);
    softmax16<<<(NN + 255) / 256, 256, 0, stream>>>(T2, dout);

    // ---- MI projection + contrast ----
    proj_norm3<<<dim3(BT, 3), 128, 0, stream>>>(zQ, Wp1, bp1, Wp2, bp2, z16);
    hipMemsetAsync(stats, 0, (size_t)3 * 3 * BT * 4, stream);
    contrast_direct<<<dim3(32, 32, 3), 256, 0, stream>>>(z16, stats);
    contrast_reduce<<<3, 256, 0, stream>>>(stats, dout + (size_t)3 * NN * NCLS);
}

// Round 12
// 795.148 us; speedup vs baseline: 6.2366x; 1.0337x over previous
//
#include <hip/hip_runtime.h>
#include <math.h>

#define NN 30000
#define EE 480000
#define FD 256
#define CH 128
#define NCLS 16
#define GH 64
#define MH 128
#define BT 4096
#define EPSc 1e-8f
#define GBc ((NN + 127) / 128)
#define SPB8 ((NN + 7) / 8)
#define SPB16 ((NN + 15) / 16)
#define RBc ((BT + 15) / 16)

typedef __attribute__((ext_vector_type(8))) short short8;
typedef __attribute__((ext_vector_type(4))) float f32x4;

// ---------- helpers ----------
__device__ __forceinline__ unsigned short f2bf(float x) {
    unsigned b = __float_as_uint(x);
    unsigned r = b + 0x7FFFu + ((b >> 16) & 1u);
    return (unsigned short)(r >> 16);
}
__device__ __forceinline__ float bf2f(unsigned short h) {
    return __uint_as_float(((unsigned)h) << 16);
}
__device__ __forceinline__ float4 fma4(float s, float4 x, float4 a) {
    a.x = fmaf(s, x.x, a.x); a.y = fmaf(s, x.y, a.y);
    a.z = fmaf(s, x.z, a.z); a.w = fmaf(s, x.w, a.w);
    return a;
}

// ---------- splits ----------
__global__ void split_bf16(const float* __restrict__ x, unsigned short* __restrict__ hi,
                           unsigned short* __restrict__ lo, long n) {
    long i = (long)blockIdx.x * 256 + threadIdx.x;
    if (i >= n) return;
    float v = x[i];
    unsigned short h = f2bf(v);
    hi[i] = h;
    lo[i] = f2bf(v - bf2f(h));
}

struct WSArgs {
    const float* s[8];
    unsigned short* h[8];
    unsigned short* l[8];
};
__global__ void wsplit_all(WSArgs a) {
    constexpr int NNp[8] = {64, 64, 128, 128, 128, 128, 128, 128};
    constexpr int OFF[9] = {0, 16384, 32768, 65536, 98304, 131072, 163840, 196608, 229376};
    int i = blockIdx.x * 256 + threadIdx.x;
    if (i >= 229376) return;
    int w = 0;
#pragma unroll
    for (int t = 1; t < 8; t++) if (i >= OFF[t]) w = t;
    int j = i - OFF[w];
    int N = NNp[w];
    int k = j / N, n = j % N;
    float v = a.s[w][j];
    unsigned short hh = f2bf(v);
    a.h[w][(size_t)n * 256 + k] = hh;
    a.l[w][(size_t)n * 256 + k] = f2bf(v - bf2f(hh));
}

// ---------- GEMM bodies ----------
template <int NT, bool OUT16>
__device__ __forceinline__ void gemm3_body(
    unsigned short* sm, int bx,
    const unsigned short* __restrict__ Ahi, const unsigned short* __restrict__ Alo,
    const unsigned short* __restrict__ BThi, const unsigned short* __restrict__ BTlo,
    int K, void* __restrict__ Cv, int Cstride, int M)
{
    unsigned short* Ah = sm;
    unsigned short* Al = Ah + 128 * 40;
    unsigned short* Bh = Al + 128 * 40;
    unsigned short* Bl = Bh + NT * 16 * 40;
    int t = threadIdx.x;
    int w = t >> 6, l = t & 63;
    int lane = l & 15, quad = l >> 4;
    int row0 = bx * 128;
    f32x4 acc[2][NT];
#pragma unroll
    for (int s = 0; s < 2; s++)
#pragma unroll
        for (int n = 0; n < NT; n++) acc[s][n] = (f32x4)(0.f);

    int ar = t >> 1, ako = (t & 1) << 4;
    int nkc = K >> 5;
    for (int kc = 0; kc < nkc; kc++) {
        int kb = kc << 5;
        {
            int gr = row0 + ar;
            float4 h0, h1, l0, l1;
            if (gr < M) {
                const float4* pH = (const float4*)&Ahi[(size_t)gr * K + kb + ako];
                const float4* pL = (const float4*)&Alo[(size_t)gr * K + kb + ako];
                h0 = pH[0]; h1 = pH[1]; l0 = pL[0]; l1 = pL[1];
            } else {
                h0 = h1 = l0 = l1 = make_float4(0.f, 0.f, 0.f, 0.f);
            }
            float4* dH = (float4*)&Ah[ar * 40 + ako];
            dH[0] = h0; dH[1] = h1;
            float4* dL = (float4*)&Al[ar * 40 + ako];
            dL[0] = l0; dL[1] = l1;
        }
        if (ar < NT * 16) {
            const float4* pH = (const float4*)&BThi[(size_t)ar * K + kb + ako];
            const float4* pL = (const float4*)&BTlo[(size_t)ar * K + kb + ako];
            float4 h0 = pH[0], h1 = pH[1], l0 = pL[0], l1 = pL[1];
            float4* dH = (float4*)&Bh[ar * 40 + ako];
            dH[0] = h0; dH[1] = h1;
            float4* dL = (float4*)&Bl[ar * 40 + ako];
            dL[0] = l0; dL[1] = l1;
        }
        __syncthreads();
        short8 aH[2], aL[2];
#pragma unroll
        for (int s = 0; s < 2; s++) {
            int r = w * 32 + s * 16 + lane;
            aH[s] = *(const short8*)&Ah[r * 40 + quad * 8];
            aL[s] = *(const short8*)&Al[r * 40 + quad * 8];
        }
#pragma unroll
        for (int n = 0; n < NT; n++) {
            int r = n * 16 + lane;
            short8 bH = *(const short8*)&Bh[r * 40 + quad * 8];
            short8 bL = *(const short8*)&Bl[r * 40 + quad * 8];
#pragma unroll
            for (int s = 0; s < 2; s++) {
                acc[s][n] = __builtin_amdgcn_mfma_f32_16x16x32_bf16(aH[s], bH, acc[s][n], 0, 0, 0);
                acc[s][n] = __builtin_amdgcn_mfma_f32_16x16x32_bf16(aH[s], bL, acc[s][n], 0, 0, 0);
                acc[s][n] = __builtin_amdgcn_mfma_f32_16x16x32_bf16(aL[s], bH, acc[s][n], 0, 0, 0);
            }
        }
        __syncthreads();
    }
#pragma unroll
    for (int s = 0; s < 2; s++) {
        int rb = row0 + w * 32 + s * 16 + quad * 4;
#pragma unroll
        for (int reg = 0; reg < 4; reg++) {
            int gr = rb + reg;
            if (gr >= M) continue;
#pragma unroll
            for (int n = 0; n < NT; n++) {
                if (OUT16)
                    ((unsigned short*)Cv)[(size_t)gr * Cstride + n * 16 + lane] = f2bf(acc[s][n][reg]);
                else
                    ((float*)Cv)[(size_t)gr * Cstride + n * 16 + lane] = acc[s][n][reg];
            }
        }
    }
}

template <int NT, bool OUT16>
__device__ __forceinline__ void gemm1_body(
    unsigned short* sm, int bx,
    const unsigned short* __restrict__ Ahi,
    const unsigned short* __restrict__ BThi,
    int K, void* __restrict__ Cv, int Cstride, int M)
{
    unsigned short* Ah = sm;
    unsigned short* Bh = Ah + 128 * 40;
    int t = threadIdx.x;
    int w = t >> 6, l = t & 63;
    int lane = l & 15, quad = l >> 4;
    int row0 = bx * 128;
    f32x4 acc[2][NT];
#pragma unroll
    for (int s = 0; s < 2; s++)
#pragma unroll
        for (int n = 0; n < NT; n++) acc[s][n] = (f32x4)(0.f);

    int ar = t >> 1, ako = (t & 1) << 4;
    int nkc = K >> 5;
    for (int kc = 0; kc < nkc; kc++) {
        int kb = kc << 5;
        {
            int gr = row0 + ar;
            float4 h0, h1;
            if (gr < M) {
                const float4* pH = (const float4*)&Ahi[(size_t)gr * K + kb + ako];
                h0 = pH[0]; h1 = pH[1];
            } else {
                h0 = h1 = make_float4(0.f, 0.f, 0.f, 0.f);
            }
            float4* dH = (float4*)&Ah[ar * 40 + ako];
            dH[0] = h0; dH[1] = h1;
        }
        if (ar < NT * 16) {
            const float4* pH = (const float4*)&BThi[(size_t)ar * K + kb + ako];
            float4 h0 = pH[0], h1 = pH[1];
            float4* dH = (float4*)&Bh[ar * 40 + ako];
            dH[0] = h0; dH[1] = h1;
        }
        __syncthreads();
        short8 aH[2];
#pragma unroll
        for (int s = 0; s < 2; s++)
            aH[s] = *(const short8*)&Ah[(w * 32 + s * 16 + lane) * 40 + quad * 8];
#pragma unroll
        for (int n = 0; n < NT; n++) {
            short8 bH = *(const short8*)&Bh[(n * 16 + lane) * 40 + quad * 8];
#pragma unroll
            for (int s = 0; s < 2; s++)
                acc[s][n] = __builtin_amdgcn_mfma_f32_16x16x32_bf16(aH[s], bH, acc[s][n], 0, 0, 0);
        }
        __syncthreads();
    }
#pragma unroll
    for (int s = 0; s < 2; s++) {
        int rb = row0 + w * 32 + s * 16 + quad * 4;
#pragma unroll
        for (int reg = 0; reg < 4; reg++) {
            int gr = rb + reg;
            if (gr >= M) continue;
#pragma unroll
            for (int n = 0; n < NT; n++) {
                if (OUT16)
                    ((unsigned short*)Cv)[(size_t)gr * Cstride + n * 16 + lane] = f2bf(acc[s][n][reg]);
                else
                    ((float*)Cv)[(size_t)gr * Cstride + n * 16 + lane] = acc[s][n][reg];
            }
        }
    }
}

// ---------- mega0: count(+seq) || gemm1 Ph2 || gemm1 Pmi×3 ----------
__global__ __launch_bounds__(256) void mega0(
    const int* __restrict__ i1, const int* __restrict__ i2, int* __restrict__ cnt,
    int* __restrict__ sd1, int* __restrict__ sd2,
    int* __restrict__ sc1, int* __restrict__ sc2,
    const unsigned short* __restrict__ feat_hi,
    const unsigned short* __restrict__ w1vh, unsigned short* __restrict__ Ph2,
    const unsigned short* __restrict__ wgallh, unsigned short* __restrict__ Pmi16)
{
    __shared__ unsigned short sm[128 * 40 + 8 * 16 * 40];
    int b = blockIdx.x;
    if (b < GBc) {
        gemm1_body<8, true>(sm, b, feat_hi, w1vh, FD, Ph2, 128, NN);
        return;
    }
    b -= GBc;
    if (b < 3 * GBc) {
        int y = b / GBc, bx = b % GBc;
        gemm1_body<8, true>(sm, bx, feat_hi, wgallh + (size_t)y * 32768,
                            FD, Pmi16 + (size_t)y * 128, 384, NN);
        return;
    }
    b -= 3 * GBc;
    int e = b * 256 + threadIdx.x;
    if (e >= EE) return;
    int r1 = i1[e], c1 = i1[EE + e];
    int r2 = i2[e], c2 = i2[EE + e];
    sd1[e] = atomicAdd(&cnt[r1], 1);
    sd2[e] = atomicAdd(&cnt[NN + r2], 1);
    sc1[e] = atomicAdd(&cnt[2 * NN + c1], 1);
    sc2[e] = atomicAdd(&cnt[3 * NN + c2], 1);
}

// ---------- mega1: atomic-free place || gemm3 Pg || gemm3 P01 ×2 ----------
__global__ __launch_bounds__(256) void mega1(
    const int* __restrict__ i1, const float* __restrict__ v1,
    const int* __restrict__ i2, const float* __restrict__ v2,
    const int* __restrict__ sd1, const int* __restrict__ sd2,
    const int* __restrict__ sc1, const int* __restrict__ sc2,
    const int* __restrict__ rp4,
    int2* __restrict__ ed1, int2* __restrict__ ec1,
    int2* __restrict__ ed2, int2* __restrict__ ec2,
    const unsigned short* __restrict__ feat_hi, const unsigned short* __restrict__ feat_lo,
    const unsigned short* __restrict__ wgen12h, const unsigned short* __restrict__ wgen12l,
    float* __restrict__ Pg,
    const unsigned short* __restrict__ w1pairh, const unsigned short* __restrict__ w1pairl,
    float* __restrict__ P01)
{
    __shared__ unsigned short sm[128 * 40 * 2 + 8 * 16 * 40 * 2];
    int b = blockIdx.x;
    if (b < GBc) {
        gemm3_body<8, false>(sm, b, feat_hi, feat_lo, wgen12h, wgen12l, FD, Pg, 128, NN);
        return;
    }
    b -= GBc;
    if (b < 2 * GBc) {
        int y = b / GBc, bx = b % GBc;
        gemm3_body<8, false>(sm, bx, feat_hi, feat_lo,
                             w1pairh + (size_t)y * 32768, w1pairl + (size_t)y * 32768,
                             FD, P01 + (size_t)y * 128, 256, NN);
        return;
    }
    b -= 2 * GBc;
    int e = b * 256 + threadIdx.x;
    if (e >= EE) return;
    const int* rp_d1 = rp4;
    const int* rp_d2 = rp4 + (NN + 1);
    const int* rp_c1 = rp4 + 2 * (NN + 1);
    const int* rp_c2 = rp4 + 3 * (NN + 1);
    int r = i1[e], c = i1[EE + e];
    int p = rp_d1[r] + sd1[e];
    ed1[p] = make_int2(c, __float_as_int(v1[e]));
    ec1[rp_c1[c] + sc1[e]] = make_int2(r, p);
    r = i2[e]; c = i2[EE + e];
    p = rp_d2[r] + sd2[e];
    ed2[p] = make_int2(c, __float_as_int(v2[e]));
    ec2[rp_c2[c] + sc2[e]] = make_int2(r, p);
}

// ---------- contrast ----------
__global__ __launch_bounds__(256) void contrast_direct(
    const unsigned short* __restrict__ z16, float* __restrict__ stats)
{
    int p = blockIdx.z;
    int pa = (p == 2) ? 1 : 0;
    int pb = (p == 0) ? 1 : 2;
    const unsigned short* A = z16 + (size_t)pa * BT * MH;
    const unsigned short* B = z16 + (size_t)pb * BT * MH;
    float* diag = stats + (size_t)p * 3 * BT;
    float* rs = diag + BT;
    float* cs = rs + BT;
    int t = threadIdx.x;
    int w = t >> 6, l = t & 63, m = l & 15, quad = l >> 4;
    int i0 = blockIdx.y * 128, j0 = blockIdx.x * 128;

    short8 afr[2][4];
#pragma unroll
    for (int s = 0; s < 2; s++) {
        const unsigned short* arow = &A[(size_t)(i0 + w * 32 + s * 16 + m) * MH + quad * 8];
#pragma unroll
        for (int kc = 0; kc < 4; kc++)
            afr[s][kc] = *(const short8*)(arow + kc * 32);
    }
    f32x4 acc[2][8];
#pragma unroll
    for (int s = 0; s < 2; s++)
#pragma unroll
        for (int n = 0; n < 8; n++) acc[s][n] = (f32x4)(0.f);

#pragma unroll
    for (int kc = 0; kc < 4; kc++) {
#pragma unroll
        for (int n = 0; n < 8; n++) {
            short8 bf = *(const short8*)&B[(size_t)(j0 + n * 16 + m) * MH + kc * 32 + quad * 8];
            acc[0][n] = __builtin_amdgcn_mfma_f32_16x16x32_bf16(afr[0][kc], bf, acc[0][n], 0, 0, 0);
            acc[1][n] = __builtin_amdgcn_mfma_f32_16x16x32_bf16(afr[1][kc], bf, acc[1][n], 0, 0, 0);
        }
    }
    float colp[8];
#pragma unroll
    for (int n = 0; n < 8; n++) colp[n] = 0.f;
#pragma unroll
    for (int s = 0; s < 2; s++) {
        int rbase = i0 + w * 32 + s * 16 + quad * 4;
#pragma unroll
        for (int reg = 0; reg < 4; reg++) {
            float rsum = 0.f;
            int gi = rbase + reg;
#pragma unroll
            for (int n = 0; n < 8; n++) {
                float mv = expf(acc[s][n][reg] * 2.0f);
                rsum += mv;
                colp[n] += mv;
                int gj = j0 + n * 16 + m;
                if (gi == gj) diag[gi] = mv;
            }
            rsum += __shfl_xor(rsum, 1); rsum += __shfl_xor(rsum, 2);
            rsum += __shfl_xor(rsum, 4); rsum += __shfl_xor(rsum, 8);
            if (m == 0) atomicAdd(&rs[gi], rsum);
        }
    }
    __shared__ float scol[128];
    if (t < 128) scol[t] = 0.f;
    __syncthreads();
#pragma unroll
    for (int n = 0; n < 8; n++) {
        float v = colp[n];
        v += __shfl_xor(v, 16); v += __shfl_xor(v, 32);
        if (quad == (n & 3)) atomicAdd(&scol[n * 16 + m], v);
    }
    __syncthreads();
    if (t < 128) atomicAdd(&cs[j0 + t], scol[t]);
}

// ---------- scans ----------
__global__ __launch_bounds__(1024) void scan_block4(const int* __restrict__ cnt,
                                                    int* __restrict__ rowptr,
                                                    int* __restrict__ bsum) {
    int y = blockIdx.y;
    int* rp = rowptr + y * (NN + 1);
    int* bs = bsum + y * 32;
    __shared__ int tmp[1024];
    int t = threadIdx.x;
    int i = blockIdx.x * 1024 + t;
    int v = (i < NN) ? cnt[y * NN + i] : 0;
    tmp[t] = v;
    __syncthreads();
    for (int off = 1; off < 1024; off <<= 1) {
        int add = (t >= off) ? tmp[t - off] : 0;
        __syncthreads();
        tmp[t] += add;
        __syncthreads();
    }
    if (i <= NN) rp[i] = tmp[t] - v;
    if (t == 1023) bs[blockIdx.x] = tmp[1023];
}
__global__ void scan_bsum4(int* __restrict__ bsum, int nb) {
    bsum += blockIdx.x * 32;
    int t = threadIdx.x;
    int orig = (t < nb) ? bsum[t] : 0;
    int v = orig;
    for (int off = 1; off < 64; off <<= 1) {
        int u = __shfl_up(v, off);
        if (t >= off) v += u;
    }
    if (t < nb) bsum[t] = v - orig;
}
__global__ void scan_add4(const int* __restrict__ bsum, int* __restrict__ rowptr) {
    int y = blockIdx.y;
    const int* bs = bsum + y * 32;
    int* rp = rowptr + y * (NN + 1);
    int i = blockIdx.x * 1024 + threadIdx.x;
    if (i <= NN) rp[i] += bs[blockIdx.x];
}

// ---------- row-parallel nv ----------
__global__ __launch_bounds__(256) void gen_nv(
    const int* __restrict__ rp_d, int2* __restrict__ ed1, int2* __restrict__ ed2,
    const float* __restrict__ sb, float* __restrict__ nvd1, float* __restrict__ nvd2)
{
    int y = blockIdx.y;
    int row = blockIdx.x * 256 + threadIdx.x;
    if (row >= NN) return;
    const int* rp = rp_d + y * (NN + 1);
    int2* ed = y ? ed2 : ed1;
    float* nvd = y ? nvd2 : nvd1;
    const float* sbv = sb + (size_t)y * NN;
    int p0 = rp[row], p1 = rp[row + 1];
    float m = -3.4e38f, sum = 0.f;
    for (int j = p0; j < p1; j++) {
        float x = sbv[ed[j].x];
        if (x > m) { sum = sum * expf(m - x) + 1.f; m = x; }
        else sum += expf(x - m);
    }
    float inv = 1.f / sum;
    for (int j = p0; j < p1; j++) {
        int2 q = ed[j];
        float nv = __int_as_float(q.y) + 0.5f * expf(sbv[q.x] - m) * inv;
        nvd[j] = nv;
        ed[j].y = __float_as_int(nv);
    }
}

// ---------- fp32 gather helpers (8-deep MLP) ----------
template <int STR4>
__device__ __forceinline__ void gath_dir_f32(
    const int* __restrict__ rp, const int2* __restrict__ ed, int row,
    const float4* __restrict__ x4, int xo, float4* a)
{
    int p0 = rp[row], p1 = rp[row + 1];
    int j = p0;
    for (; j + 8 <= p1; j += 8) {
        int2 q0 = ed[j], q1 = ed[j+1], q2 = ed[j+2], q3 = ed[j+3];
        int2 q4 = ed[j+4], q5 = ed[j+5], q6 = ed[j+6], q7 = ed[j+7];
        float4 x0 = x4[(size_t)q0.x * STR4 + xo];
        float4 x1 = x4[(size_t)q1.x * STR4 + xo];
        float4 x2 = x4[(size_t)q2.x * STR4 + xo];
        float4 x3 = x4[(size_t)q3.x * STR4 + xo];
        float4 x5 = x4[(size_t)q4.x * STR4 + xo];
        float4 x6 = x4[(size_t)q5.x * STR4 + xo];
        float4 x7 = x4[(size_t)q6.x * STR4 + xo];
        float4 x8 = x4[(size_t)q7.x * STR4 + xo];
        a[0] = fma4(__int_as_float(q0.y), x0, a[0]);
        a[1] = fma4(__int_as_float(q1.y), x1, a[1]);
        a[2] = fma4(__int_as_float(q2.y), x2, a[2]);
        a[3] = fma4(__int_as_float(q3.y), x3, a[3]);
        a[0] = fma4(__int_as_float(q4.y), x5, a[0]);
        a[1] = fma4(__int_as_float(q5.y), x6, a[1]);
        a[2] = fma4(__int_as_float(q6.y), x7, a[2]);
        a[3] = fma4(__int_as_float(q7.y), x8, a[3]);
    }
    for (; j + 4 <= p1; j += 4) {
        int2 q0 = ed[j], q1 = ed[j+1], q2 = ed[j+2], q3 = ed[j+3];
        a[0] = fma4(__int_as_float(q0.y), x4[(size_t)q0.x * STR4 + xo], a[0]);
        a[1] = fma4(__int_as_float(q1.y), x4[(size_t)q1.x * STR4 + xo], a[1]);
        a[2] = fma4(__int_as_float(q2.y), x4[(size_t)q2.x * STR4 + xo], a[2]);
        a[3] = fma4(__int_as_float(q3.y), x4[(size_t)q3.x * STR4 + xo], a[3]);
    }
    for (; j < p1; j++) {
        int2 q = ed[j];
        a[0] = fma4(__int_as_float(q.y), x4[(size_t)q.x * STR4 + xo], a[0]);
    }
}
template <int STR4>
__device__ __forceinline__ void gath_csc_f32(
    const int* __restrict__ rp, const int2* __restrict__ ec, const float* __restrict__ nvd,
    int row, const float4* __restrict__ x4, int xo, float4* a)
{
    int p0 = rp[row], p1 = rp[row + 1];
    int j = p0;
    for (; j + 8 <= p1; j += 8) {
        int2 q0 = ec[j], q1 = ec[j+1], q2 = ec[j+2], q3 = ec[j+3];
        int2 q4 = ec[j+4], q5 = ec[j+5], q6 = ec[j+6], q7 = ec[j+7];
        float4 x0 = x4[(size_t)q0.x * STR4 + xo];
        float4 x1 = x4[(size_t)q1.x * STR4 + xo];
        float4 x2 = x4[(size_t)q2.x * STR4 + xo];
        float4 x3 = x4[(size_t)q3.x * STR4 + xo];
        float4 x5 = x4[(size_t)q4.x * STR4 + xo];
        float4 x6 = x4[(size_t)q5.x * STR4 + xo];
        float4 x7 = x4[(size_t)q6.x * STR4 + xo];
        float4 x8 = x4[(size_t)q7.x * STR4 + xo];
        float v0 = nvd[q0.y], v1 = nvd[q1.y], v2 = nvd[q2.y], v3 = nvd[q3.y];
        float v4 = nvd[q4.y], v5 = nvd[q5.y], v6 = nvd[q6.y], v7 = nvd[q7.y];
        a[0] = fma4(v0, x0, a[0]);
        a[1] = fma4(v1, x1, a[1]);
        a[2] = fma4(v2, x2, a[2]);
        a[3] = fma4(v3, x3, a[3]);
        a[0] = fma4(v4, x5, a[0]);
        a[1] = fma4(v5, x6, a[1]);
        a[2] = fma4(v6, x7, a[2]);
        a[3] = fma4(v7, x8, a[3]);
    }
    for (; j + 4 <= p1; j += 4) {
        int2 q0 = ec[j], q1 = ec[j+1], q2 = ec[j+2], q3 = ec[j+3];
        float v0 = nvd[q0.y], v1 = nvd[q1.y], v2 = nvd[q2.y], v3 = nvd[q3.y];
        a[0] = fma4(v0, x4[(size_t)q0.x * STR4 + xo], a[0]);
        a[1] = fma4(v1, x4[(size_t)q1.x * STR4 + xo], a[1]);
        a[2] = fma4(v2, x4[(size_t)q2.x * STR4 + xo], a[2]);
        a[3] = fma4(v3, x4[(size_t)q3.x * STR4 + xo], a[3]);
    }
    for (; j < p1; j++) {
        int2 q = ec[j];
        a[0] = fma4(nvd[q.y], x4[(size_t)q.x * STR4 + xo], a[0]);
    }
}

// ---------- gen SpMM fused with node scores (emb never materialized) ----------
__global__ __launch_bounds__(256) void spmm64_scores(
    const int* __restrict__ rp_d, const int2* __restrict__ e1, const int2* __restrict__ e2,
    const float* __restrict__ Pg, const float* __restrict__ Wm1,
    const float* __restrict__ Wm2, float* __restrict__ sb)
{
    int y = blockIdx.y;
    const int* rp = rp_d + y * (NN + 1);
    const int2* arr = y ? e2 : e1;
    int row = blockIdx.x * 16 + threadIdx.x / 16;
    int o = threadIdx.x % 16;
    if (row >= NN) return;
    float4 a[4] = {};
    gath_dir_f32<32>(rp, arr, row, (const float4*)Pg, y * 16 + o, a);
    float4 r;
    r.x = fmaxf((a[0].x + a[1].x) + (a[2].x + a[3].x), 0.f);
    r.y = fmaxf((a[0].y + a[1].y) + (a[2].y + a[3].y), 0.f);
    r.z = fmaxf((a[0].z + a[1].z) + (a[2].z + a[3].z), 0.f);
    r.w = fmaxf((a[0].w + a[1].w) + (a[2].w + a[3].w), 0.f);
    const float* Wmh = (y ? Wm2 : Wm1) + GH;  // second half (sa & bm cancel)
    float part = r.x * Wmh[o * 4] + r.y * Wmh[o * 4 + 1]
               + r.z * Wmh[o * 4 + 2] + r.w * Wmh[o * 4 + 3];
    part += __shfl_xor(part, 1); part += __shfl_xor(part, 2);
    part += __shfl_xor(part, 4); part += __shfl_xor(part, 8);
    if (o == 0) sb[y * NN + row] = part;
}

// ---------- softmax epilogue over 16 values held 4-per-lane (4-lane groups) ----------
__device__ __forceinline__ void softmax16_epi(
    float4 r, int node, float* __restrict__ logits, float* __restrict__ wout)
{
    int o = threadIdx.x & 3;
    float mx = fmaxf(fmaxf(r.x, r.y), fmaxf(r.z, r.w));
    mx = fmaxf(mx, __shfl_xor(mx, 1));
    mx = fmaxf(mx, __shfl_xor(mx, 2));
    float e0 = expf(r.x - mx), e1 = expf(r.y - mx), e2 = expf(r.z - mx), e3 = expf(r.w - mx);
    float s = (e0 + e1) + (e2 + e3);
    s += __shfl_xor(s, 1);
    s += __shfl_xor(s, 2);
    float inv = 1.f / s;
    float p0 = e0 * inv, p1 = e1 * inv, p2 = e2 * inv, p3 = e3 * inv;
    float4 lg;
    lg.x = logf(p0 + EPSc); lg.y = logf(p1 + EPSc);
    lg.z = logf(p2 + EPSc); lg.w = logf(p3 + EPSc);
    ((float4*)logits)[(size_t)node * 4 + o] = lg;
    if (wout) {
        // local top2 of 4
        float f = p0, se = -1.f;
        if (p1 > f) { se = f; f = p1; } else se = p1;
        if (p2 > f) { se = f; f = p2; } else if (p2 > se) se = p2;
        if (p3 > f) { se = f; f = p3; } else if (p3 > se) se = p3;
        // merge across lanes
#pragma unroll
        for (int d = 1; d <= 2; d <<= 1) {
            float of = __shfl_xor(f, d), os = __shfl_xor(se, d);
            if (of > f) { se = fmaxf(f, os); f = of; }
            else se = fmaxf(se, of);
        }
        if (o == 0)
            wout[node] = expf(0.5f * logf(f + EPSc) + 0.5f * logf(f - se + EPSc));
    }
}

// ---------- spmm16 + softmax (branches 0/1): logits + w12 ----------
__global__ __launch_bounds__(256) void spmm16_softmax_pair(
    const int* __restrict__ rp_d, const int* __restrict__ rp_c,
    const int2* __restrict__ ed1, const int2* __restrict__ ec1, const float* __restrict__ nvd1,
    const int2* __restrict__ ed2, const int2* __restrict__ ec2, const float* __restrict__ nvd2,
    const float* __restrict__ R01, float* __restrict__ logits_base, float* __restrict__ w12)
{
    int y = blockIdx.y;
    const int* rpd = rp_d + y * (NN + 1);
    const int* rpc = rp_c + y * (NN + 1);
    const int2* ed = y ? ed2 : ed1;
    const int2* ec = y ? ec2 : ec1;
    const float* nvd = y ? nvd2 : nvd1;
    int row = blockIdx.x * 64 + threadIdx.x / 4;
    int o = threadIdx.x % 4;
    if (row >= NN) return;
    const float4* x4 = (const float4*)(R01 + (size_t)y * NN * 16);
    float4 a[4] = {};
    gath_dir_f32<4>(rpd, ed, row, x4, o, a);
    gath_csc_f32<4>(rpc, ec, nvd, row, x4, o, a);
    float4 r;
    r.x = (a[0].x + a[1].x) + (a[2].x + a[3].x);
    r.y = (a[0].y + a[1].y) + (a[2].y + a[3].y);
    r.z = (a[0].z + a[1].z) + (a[2].z + a[3].z);
    r.w = (a[0].w + a[1].w) + (a[2].w + a[3].w);
    softmax16_epi(r, row, logits_base + (size_t)y * NN * NCLS, w12 + (size_t)y * NN);
}

// ---------- spmm16 fused graph + softmax (branch 2): logits_v ----------
__global__ __launch_bounds__(256) void spmm16_fused_softmax(
    const int* __restrict__ rp_d, const int* __restrict__ rp_c,
    const int2* __restrict__ ed1, const int2* __restrict__ ec1, const float* __restrict__ nvd1,
    const int2* __restrict__ ed2, const int2* __restrict__ ec2, const float* __restrict__ nvd2,
    const float* __restrict__ w12, const float* __restrict__ x, float* __restrict__ logits)
{
    int row = blockIdx.x * 64 + threadIdx.x / 4;
    int o = threadIdx.x % 4;
    if (row >= NN) return;
    const float4* x4 = (const float4*)x;
    float4 a[4] = {};
    gath_dir_f32<4>(rp_d, ed1, row, x4, o, a);
    gath_csc_f32<4>(rp_c, ec1, nvd1, row, x4, o, a);
    float4 s1;
    s1.x = (a[0].x + a[1].x) + (a[2].x + a[3].x);
    s1.y = (a[0].y + a[1].y) + (a[2].y + a[3].y);
    s1.z = (a[0].z + a[1].z) + (a[2].z + a[3].z);
    s1.w = (a[0].w + a[1].w) + (a[2].w + a[3].w);
    float4 b[4] = {};
    gath_dir_f32<4>(rp_d + (NN + 1), ed2, row, x4, o, b);
    gath_csc_f32<4>(rp_c + (NN + 1), ec2, nvd2, row, x4, o, b);
    float4 s2;
    s2.x = (b[0].x + b[1].x) + (b[2].x + b[3].x);
    s2.y = (b[0].y + b[1].y) + (b[2].y + b[3].y);
    s2.z = (b[0].z + b[1].z) + (b[2].z + b[3].z);
    s2.w = (b[0].w + b[1].w) + (b[2].w + b[3].w);
    float wa = w12[row], wb = w12[NN + row];
    float inv = 1.f / (wa + wb);
    float w1 = wa * inv, w2 = wb * inv;
    float4 r;
    r.x = w1 * s1.x + w2 * s2.x;
    r.y = w1 * s1.y + w2 * s2.y;
    r.z = w1 * s1.z + w2 * s2.z;
    r.w = w1 * s1.w + w2 * s2.w;
    softmax16_epi(r, row, logits, nullptr);
}

// ---------- bf16 gather helpers ----------
__device__ __forceinline__ void gath_dir_b16(
    const int* __restrict__ rp, const int2* __restrict__ ed, int row,
    const unsigned short* __restrict__ X, int xstride, int o, float* acc)
{
    int p0 = rp[row], p1 = rp[row + 1];
    int j = p0;
    for (; j + 4 <= p1; j += 4) {
        int2 q0 = ed[j], q1 = ed[j+1], q2 = ed[j+2], q3 = ed[j+3];
        short8 x0 = *(const short8*)&X[(size_t)q0.x * xstride + o * 8];
        short8 x1 = *(const short8*)&X[(size_t)q1.x * xstride + o * 8];
        short8 x2 = *(const short8*)&X[(size_t)q2.x * xstride + o * 8];
        short8 x3 = *(const short8*)&X[(size_t)q3.x * xstride + o * 8];
        float v0 = __int_as_float(q0.y), v1 = __int_as_float(q1.y);
        float v2 = __int_as_float(q2.y), v3 = __int_as_float(q3.y);
#pragma unroll
        for (int k = 0; k < 8; k++) {
            acc[k] = fmaf(v0, bf2f((unsigned short)x0[k]), acc[k]);
            acc[k] = fmaf(v1, bf2f((unsigned short)x1[k]), acc[k]);
            acc[k] = fmaf(v2, bf2f((unsigned short)x2[k]), acc[k]);
            acc[k] = fmaf(v3, bf2f((unsigned short)x3[k]), acc[k]);
        }
    }
    for (; j < p1; j++) {
        int2 q = ed[j];
        short8 xv = *(const short8*)&X[(size_t)q.x * xstride + o * 8];
        float v = __int_as_float(q.y);
#pragma unroll
        for (int k = 0; k < 8; k++)
            acc[k] = fmaf(v, bf2f((unsigned short)xv[k]), acc[k]);
    }
}
__device__ __forceinline__ void gath_csc_b16(
    const int* __restrict__ rp, const int2* __restrict__ ec, const float* __restrict__ nvd,
    int row, const unsigned short* __restrict__ X, int xstride, int o, float* acc)
{
    int p0 = rp[row], p1 = rp[row + 1];
    int j = p0;
    for (; j + 4 <= p1; j += 4) {
        int2 q0 = ec[j], q1 = ec[j+1], q2 = ec[j+2], q3 = ec[j+3];
        short8 x0 = *(const short8*)&X[(size_t)q0.x * xstride + o * 8];
        short8 x1 = *(const short8*)&X[(size_t)q1.x * xstride + o * 8];
        short8 x2 = *(const short8*)&X[(size_t)q2.x * xstride + o * 8];
        short8 x3 = *(const short8*)&X[(size_t)q3.x * xstride + o * 8];
        float v0 = nvd[q0.y], v1 = nvd[q1.y], v2 = nvd[q2.y], v3 = nvd[q3.y];
#pragma unroll
        for (int k = 0; k < 8; k++) {
            acc[k] = fmaf(v0, bf2f((unsigned short)x0[k]), acc[k]);
            acc[k] = fmaf(v1, bf2f((unsigned short)x1[k]), acc[k]);
            acc[k] = fmaf(v2, bf2f((unsigned short)x2[k]), acc[k]);
            acc[k] = fmaf(v3, bf2f((unsigned short)x3[k]), acc[k]);
        }
    }
    for (; j < p1; j++) {
        int2 q = ec[j];
        short8 xv = *(const short8*)&X[(size_t)q.x * xstride + o * 8];
        float v = nvd[q.y];
#pragma unroll
        for (int k = 0; k < 8; k++)
            acc[k] = fmaf(v, bf2f((unsigned short)xv[k]), acc[k]);
    }
}

// ---------- rows (MI) body ----------
__device__ __forceinline__ void rows_b16_body(
    int bx, int y, const int* __restrict__ rp_d, const int* __restrict__ rp_c,
    const int2* __restrict__ ed1, const int2* __restrict__ ec1, const float* __restrict__ nvd1,
    const int2* __restrict__ ed2, const int2* __restrict__ ec2, const float* __restrict__ nvd2,
    const float* __restrict__ w12, const int* __restrict__ rows,
    const unsigned short* __restrict__ Pmi, float* __restrict__ zQ)
{
    int ri = bx * 16 + threadIdx.x / 16;
    int o = threadIdx.x % 16;
    if (ri >= BT) return;
    int node = rows[ri];
    int xoff = (y == 0) ? 0 : ((y == 1) ? 128 : 256);
    const unsigned short* X = Pmi + xoff;
    float acc[8] = {};
    if (y == 0) {
        float a1[8] = {}, a2[8] = {};
        gath_dir_b16(rp_d, ed1, node, X, 384, o, a1);
        gath_csc_b16(rp_c, ec1, nvd1, node, X, 384, o, a1);
        gath_dir_b16(rp_d + (NN + 1), ed2, node, X, 384, o, a2);
        gath_csc_b16(rp_c + (NN + 1), ec2, nvd2, node, X, 384, o, a2);
        float wa = w12[node], wb = w12[NN + node];
        float inv = 1.f / (wa + wb);
        float w1 = wa * inv, w2 = wb * inv;
#pragma unroll
        for (int k = 0; k < 8; k++) acc[k] = w1 * a1[k] + w2 * a2[k];
    } else if (y == 1) {
        gath_dir_b16(rp_d, ed1, node, X, 384, o, acc);
        gath_csc_b16(rp_c, ec1, nvd1, node, X, 384, o, acc);
    } else {
        gath_dir_b16(rp_d + (NN + 1), ed2, node, X, 384, o, acc);
        gath_csc_b16(rp_c + (NN + 1), ec2, nvd2, node, X, 384, o, acc);
    }
    float* out = zQ + ((size_t)y * BT + ri) * 128 + o * 8;
#pragma unroll
    for (int k = 0; k < 8; k++) out[k] = fmaxf(acc[k], 0.f);
}

// ---------- spmm128 fp32 + fused L2 ----------
__device__ __forceinline__ void spmm128f_body(
    float* sm, int bx, int y, const int* __restrict__ rp_d, const int* __restrict__ rp_c,
    const int2* __restrict__ ed, const int2* __restrict__ ec, const float* __restrict__ nvd,
    const float* __restrict__ P01, const float* __restrict__ W2, float* __restrict__ R01)
{
    float* W2s = sm;            // 2048
    float* Qs  = sm + 2048;     // 8*128
    for (int i = threadIdx.x; i < 2048; i += 256) W2s[i] = W2[i];
    int r = threadIdx.x / 32;
    int o = threadIdx.x % 32;
    int row = bx * 8 + r;
    float4 a[4] = {};
    if (row < NN) {
        gath_dir_f32<64>(rp_d + y * (NN + 1), ed, row, (const float4*)P01, y * 32 + o, a);
        gath_csc_f32<64>(rp_c + y * (NN + 1), ec, nvd, row, (const float4*)P01, y * 32 + o, a);
    }
    float4 q;
    q.x = fmaxf((a[0].x + a[1].x) + (a[2].x + a[3].x), 0.f);
    q.y = fmaxf((a[0].y + a[1].y) + (a[2].y + a[3].y), 0.f);
    q.z = fmaxf((a[0].z + a[1].z) + (a[2].z + a[3].z), 0.f);
    q.w = fmaxf((a[0].w + a[1].w) + (a[2].w + a[3].w), 0.f);
    *(float4*)&Qs[r * 128 + o * 4] = q;
    __syncthreads();
    int t = threadIdx.x;
    if (t < 128) {
        int rr = t >> 4, c = t & 15;
        int grow = bx * 8 + rr;
        if (grow < NN) {
            float acc = 0.f;
            const float* qrow = &Qs[rr * 128];
#pragma unroll 8
            for (int k = 0; k < 128; k++)
                acc = fmaf(qrow[k], W2s[k * 16 + c], acc);
            R01[((size_t)y * NN + grow) * 16 + c] = acc;
        }
    }
}

// ---------- branch2 fused spmm (bf16) + fused L2 ----------
__device__ __forceinline__ void fused128b2_body(
    float* sm, int bx, const int* __restrict__ rp_d, const int* __restrict__ rp_c,
    const int2* __restrict__ ed1, const int2* __restrict__ ec1, const float* __restrict__ nvd1,
    const int2* __restrict__ ed2, const int2* __restrict__ ec2, const float* __restrict__ nvd2,
    const float* __restrict__ w12, const unsigned short* __restrict__ Ph2,
    const float* __restrict__ W2v, float* __restrict__ R2)
{
    float* W2s = sm;            // 2048
    float* Qs  = sm + 2048;     // 16*128
    for (int i = threadIdx.x; i < 2048; i += 256) W2s[i] = W2v[i];
    int r = threadIdx.x / 16;
    int o = threadIdx.x % 16;
    int row = bx * 16 + r;
    float a1[8] = {}, a2[8] = {};
    float w1 = 0.f, w2 = 0.f;
    if (row < NN) {
        gath_dir_b16(rp_d, ed1, row, Ph2, 128, o, a1);
        gath_csc_b16(rp_c, ec1, nvd1, row, Ph2, 128, o, a1);
        gath_dir_b16(rp_d + (NN + 1), ed2, row, Ph2, 128, o, a2);
        gath_csc_b16(rp_c + (NN + 1), ec2, nvd2, row, Ph2, 128, o, a2);
        float wa = w12[row], wb = w12[NN + row];
        float inv = 1.f / (wa + wb);
        w1 = wa * inv; w2 = wb * inv;
    }
#pragma unroll
    for (int k = 0; k < 8; k++)
        Qs[r * 128 + o * 8 + k] = fmaxf(w1 * a1[k] + w2 * a2[k], 0.f);
    __syncthreads();
    int t = threadIdx.x;
    int rr = t >> 4, c = t & 15;
    int grow = bx * 16 + rr;
    if (grow < NN) {
        float acc = 0.f;
        const float* qrow = &Qs[rr * 128];
#pragma unroll 8
        for (int k = 0; k < 128; k++)
            acc = fmaf(qrow[k], W2s[k * 16 + c], acc);
        R2[(size_t)grow * 16 + c] = acc;
    }
}

// ---------- mega2: spmm128f (y=0,1) || rows y=1,2 ----------
__global__ __launch_bounds__(256) void mega2(
    const int* __restrict__ rp_d, const int* __restrict__ rp_c,
    const int2* __restrict__ ed1, const int2* __restrict__ ec1, const float* __restrict__ nvd1,
    const int2* __restrict__ ed2, const int2* __restrict__ ec2, const float* __restrict__ nvd2,
    const float* __restrict__ P01, const float* __restrict__ W2v1, const float* __restrict__ W2v2,
    float* __restrict__ R01,
    const int* __restrict__ rows, const unsigned short* __restrict__ Pmi,
    float* __restrict__ zQ)
{
    __shared__ float sm[2048 + 8 * 128];
    int b = blockIdx.x;
    if (b < 2 * SPB8) {
        int y = b / SPB8;
        spmm128f_body(sm, b % SPB8, y, rp_d, rp_c, y ? ed2 : ed1, y ? ec2 : ec1,
                      y ? nvd2 : nvd1, P01, y ? W2v2 : W2v1, R01);
        return;
    }
    b -= 2 * SPB8;
    int y = 1 + b / RBc;
    rows_b16_body(b % RBc, y, rp_d, rp_c, ed1, ec1, nvd1, ed2, ec2, nvd2,
                  nullptr, rows, Pmi, zQ);
}

// ---------- mega3: fused128b2 || rows y=0 ----------
__global__ __launch_bounds__(256) void mega3(
    const int* __restrict__ rp_d, const int* __restrict__ rp_c,
    const int2* __restrict__ ed1, const int2* __restrict__ ec1, const float* __restrict__ nvd1,
    const int2* __restrict__ ed2, const int2* __restrict__ ec2, const float* __restrict__ nvd2,
    const float* __restrict__ w12, const unsigned short* __restrict__ Ph2,
    const float* __restrict__ W2v, float* __restrict__ R2,
    const int* __restrict__ rows, const unsigned short* __restrict__ Pmi,
    float* __restrict__ zQ)
{
    __shared__ float sm[2048 + 16 * 128];
    int b = blockIdx.x;
    if (b < SPB16) {
        fused128b2_body(sm, b, rp_d, rp_c, ed1, ec1, nvd1, ed2, ec2, nvd2,
                        w12, Ph2, W2v, R2);
        return;
    }
    rows_b16_body(b - SPB16, 0, rp_d, rp_c, ed1, ec1, nvd1, ed2, ec2, nvd2,
                  w12, rows, Pmi, zQ);
}

// ---------- projection head + L2-normalize, bf16 out ----------
__global__ __launch_bounds__(128) void proj_norm3(
    const float* __restrict__ zQ,
    const float* __restrict__ Wp1, const float* __restrict__ bp1,
    const float* __restrict__ Wp2, const float* __restrict__ bp2,
    unsigned short* __restrict__ z16)
{
    __shared__ float g[MH], u[MH];
    __shared__ float red[2];
    size_t i = (size_t)blockIdx.y * BT + blockIdx.x;
    int t = threadIdx.x;
    g[t] = zQ[i * MH + t];
    __syncthreads();
    float acc = bp1[t];
    for (int k = 0; k < MH; k++) acc = fmaf(g[k], Wp1[k * MH + t], acc);
    u[t] = acc > 0.f ? acc : (expf(acc) - 1.f);
    __syncthreads();
    float acc2 = bp2[t];
    for (int k = 0; k < MH; k++) acc2 = fmaf(u[k], Wp2[k * MH + t], acc2);
    float sq = acc2 * acc2;
#pragma unroll
    for (int off = 32; off; off >>= 1) sq += __shfl_down(sq, off);
    if ((t & 63) == 0) red[t >> 6] = sq;
    __syncthreads();
    float nrm = sqrtf(red[0] + red[1]);
    z16[i * MH + t] = f2bf(acc2 / nrm);
}

__global__ void contrast_reduce(const float* __restrict__ stats, float* __restrict__ out3)
{
    int p = blockIdx.x, t = threadIdx.x;
    const float* diag = stats + (size_t)p * 3 * BT;
    const float* rs = diag + BT;
    const float* cs = rs + BT;
    float s1 = 0.f, s2 = 0.f;
    for (int i = t; i < BT; i += 256) {
        float d = diag[i];
        s1 += logf(d / (rs[i] + EPSc) + EPSc);
        s2 += logf(d / (cs[i] + EPSc) + EPSc);
    }
#pragma unroll
    for (int off = 32; off; off >>= 1) { s1 += __shfl_down(s1, off); s2 += __shfl_down(s2, off); }
    __shared__ float sh[8];
    if ((t & 63) == 0) { sh[(t >> 6) * 2] = s1; sh[(t >> 6) * 2 + 1] = s2; }
    __syncthreads();
    if (t == 0) {
        float a = sh[0] + sh[2] + sh[4] + sh[6];
        float b = sh[1] + sh[3] + sh[5] + sh[7];
        out3[p] = 0.5f * (-a / BT - b / BT);
    }
}

// ---------- host ----------
extern "C" void kernel_launch(void* const* d_in, const int* in_sizes, int n_in,
                              void* d_out, int out_size, void* d_ws, size_t ws_size,
                              hipStream_t stream)
{
    const float* feat   = (const float*)d_in[0];
    const int*   ind1   = (const int*)d_in[1];
    const float* vals1  = (const float*)d_in[2];
    const int*   ind2   = (const int*)d_in[3];
    const float* vals2  = (const float*)d_in[4];
    const int*   idxb   = (const int*)d_in[5];
    const float* Wm1    = (const float*)d_in[7];
    const float* Wm2    = (const float*)d_in[10];
    const float* W2_v1  = (const float*)d_in[13];
    const float* W2_v2  = (const float*)d_in[15];
    const float* W2_v   = (const float*)d_in[17];
    const float* Wp1    = (const float*)d_in[21];
    const float* bp1    = (const float*)d_in[22];
    const float* Wp2    = (const float*)d_in[23];
    const float* bp2    = (const float*)d_in[24];
    float* dout = (float*)d_out;

    float* ws = (float*)d_ws;
    size_t off = 0;
    auto alloc = [&](size_t n) { n = (n + 3) & ~(size_t)3; float* p = ws + off; off += n; return p; };
    auto alloc_s = [&](size_t n) { return (unsigned short*)alloc((n + 1) / 2); };

    // --- shared pool ---
    float* pool = alloc(16000000);
    float* Pg   = pool;                      // [0, 3.84M)
    float* P01  = pool + 3840000;            // [3.84M, 11.52M)  [NN][256] f32
    float* R01  = pool + 11520000;           // [11.52M, 12.48M)
    float* zQ   = pool + 12480000;           // [12.48M, 14.06M)
    float* R2   = pool;                      // overlays Pg (dead after spmm64_scores)

    // --- persistent ---
    unsigned short* feat_hi = alloc_s((size_t)NN * FD);
    unsigned short* feat_lo = alloc_s((size_t)NN * FD);
    unsigned short* Ph2d    = alloc_s((size_t)NN * CH);
    unsigned short* Pmi16d  = alloc_s((size_t)NN * 384);
    float* sb   = alloc(2 * NN);
    float* w12  = alloc(2 * NN);
    float* stats = alloc((size_t)3 * 3 * BT);
    unsigned short* z16 = alloc_s((size_t)3 * BT * MH);
    int2* ed1 = (int2*)alloc(2 * (size_t)EE);
    int2* ed2 = (int2*)alloc(2 * (size_t)EE);
    int2* ec1 = (int2*)alloc(2 * (size_t)EE);
    int2* ec2 = (int2*)alloc(2 * (size_t)EE);
    float* nvd1 = alloc(EE);
    float* nvd2 = alloc(EE);
    int* sd1 = (int*)alloc(EE);
    int* sd2 = (int*)alloc(EE);
    int* sc1 = (int*)alloc(EE);
    int* sc2 = (int*)alloc(EE);
    int* rp4  = (int*)alloc(4 * (NN + 1));
    int* cnt4 = (int*)alloc(4 * NN);
    int* bsum = (int*)alloc(128);
    int* rp_d = rp4;
    int* rp_c = rp4 + 2 * (NN + 1);
    // weights (bf16 splits for K=256 GEMMs)
    unsigned short* wgen12h = alloc_s(32768); unsigned short* wgen12l = alloc_s(32768);
    unsigned short* w1pairh = alloc_s(65536); unsigned short* w1pairl = alloc_s(65536);
    unsigned short* w1vh    = alloc_s(32768); unsigned short* w1vl    = alloc_s(32768);
    unsigned short* wgallh  = alloc_s(98304); unsigned short* wgalll  = alloc_s(98304);

    const int NB = (NN + 1 + 1023) / 1024;
    const int NCNT = (EE + 255) / 256;

    // ---- prep ----
    hipMemsetAsync(cnt4, 0, 4 * NN * 4, stream);
    split_bf16<<<((long)NN * FD + 255) / 256, 256, 0, stream>>>(feat, feat_hi, feat_lo, (long)NN * FD);
    {
        WSArgs a;
        a.s[0] = (const float*)d_in[6];  a.h[0] = wgen12h;          a.l[0] = wgen12l;
        a.s[1] = (const float*)d_in[9];  a.h[1] = wgen12h + 16384;  a.l[1] = wgen12l + 16384;
        a.s[2] = (const float*)d_in[12]; a.h[2] = w1pairh;          a.l[2] = w1pairl;
        a.s[3] = (const float*)d_in[14]; a.h[3] = w1pairh + 32768;  a.l[3] = w1pairl + 32768;
        a.s[4] = (const float*)d_in[16]; a.h[4] = w1vh;             a.l[4] = w1vl;
        a.s[5] = (const float*)d_in[18]; a.h[5] = wgallh;           a.l[5] = wgalll;
        a.s[6] = (const float*)d_in[19]; a.h[6] = wgallh + 32768;   a.l[6] = wgalll + 32768;
        a.s[7] = (const float*)d_in[20]; a.h[7] = wgallh + 65536;   a.l[7] = wgalll + 65536;
        wsplit_all<<<(229376 + 255) / 256, 256, 0, stream>>>(a);
    }

    // ---- mega0: count(+seq) || Ph2 gemm1 || Pmi gemm1×3 ----
    mega0<<<4 * GBc + NCNT, 256, 0, stream>>>(ind1, ind2, cnt4, sd1, sd2, sc1, sc2,
                                              feat_hi, w1vh, Ph2d, wgallh, Pmi16d);

    // ---- scans ----
    scan_block4<<<dim3(NB, 4), 1024, 0, stream>>>(cnt4, rp4, bsum);
    scan_bsum4<<<4, 64, 0, stream>>>(bsum, NB);
    scan_add4<<<dim3(NB, 4), 1024, 0, stream>>>(bsum, rp4);

    // ---- mega1: atomic-free place || Pg gemm3 || P01 gemm3×2 ----
    mega1<<<3 * GBc + NCNT, 256, 0, stream>>>(ind1, vals1, ind2, vals2,
                                              sd1, sd2, sc1, sc2, rp4,
                                              ed1, ec1, ed2, ec2,
                                              feat_hi, feat_lo, wgen12h, wgen12l, Pg,
                                              w1pairh, w1pairl, P01);

    // ---- gen_view: spmm64 fused with node scores, then nv ----
    spmm64_scores<<<dim3((NN + 15) / 16, 2), 256, 0, stream>>>(rp_d, ed1, ed2, Pg, Wm1, Wm2, sb);
    gen_nv<<<dim3((NN + 255) / 256, 2), 256, 0, stream>>>(rp_d, ed1, ed2, sb, nvd1, nvd2);

    // ---- mega2: branch01 spmm+L2 (fp32) || mi rows y=1,2 ----
    mega2<<<2 * SPB8 + 2 * RBc, 256, 0, stream>>>(rp_d, rp_c, ed1, ec1, nvd1,
                                                  ed2, ec2, nvd2, P01, W2_v1, W2_v2,
                                                  R01, idxb, Pmi16d, zQ);

    // ---- branches 0/1: layer-2 aggregate + fused softmax + w12 ----
    spmm16_softmax_pair<<<dim3((NN + 63) / 64, 2), 256, 0, stream>>>(
        rp_d, rp_c, ed1, ec1, nvd1, ed2, ec2, nvd2, R01, dout + (size_t)NN * NCLS, w12);

    // ---- mega3: branch2 fused spmm+L2 || mi rows y=0 ----
    mega3<<<SPB16 + RBc, 256, 0, stream>>>(rp_d, rp_c, ed1, ec1, nvd1, ed2, ec2, nvd2,
                                           w12, Ph2d, W2_v, R2, idxb, Pmi16d, zQ);

    // ---- branch 2: layer-2 aggregate + fused softmax ----
    spmm16_fused_softmax<<<(NN + 63) / 64, 256, 0, stream>>>(
        rp_d, rp_c, ed1, ec1, nvd1, ed2, ec2, nvd2, w12, R2, dout);

    // ---- MI projection + contrast ----
    proj_norm3<<<dim3(BT, 3), 128, 0, stream>>>(zQ, Wp1, bp1, Wp2, bp2, z16);
    hipMemsetAsync(stats, 0, (size_t)3 * 3 * BT * 4, stream);
    contrast_direct<<<dim3(32, 32, 3), 256, 0, stream>>>(z16, stats);
    contrast_reduce<<<3, 256, 0, stream>>>(stats, dout + (size_t)3 * NN * NCLS);
}